// Round 3
// baseline (3566.145 us; speedup 1.0000x reference)
//
#include <hip/hip_runtime.h>
#include <hip/hip_bf16.h>
#include <math.h>

constexpr int Bn = 32, Nn = 4096, Dn = 512, NSn = 16, HIn = 128;
constexpr float kScale = 0.04419417382415922f; // 512^-0.5
constexpr float kEps = 1e-8f;

__device__ __forceinline__ float wred(float v) {
#pragma unroll
  for (int m = 32; m > 0; m >>= 1) v += __shfl_xor(v, m);
  return v;
}
__device__ __forceinline__ double wredd(double v) {
#pragma unroll
  for (int m = 32; m > 0; m >>= 1) v += __shfl_xor(v, m);
  return v;
}

// ---------------- per-row LN stats of inputs ----------------
__global__ __launch_bounds__(256) void k_rowstats(const float* __restrict__ in,
                                                  float* __restrict__ mu, float* __restrict__ rsig) {
  int row = blockIdx.x * 4 + (threadIdx.x >> 6);
  int lane = threadIdx.x & 63;
  const float4* p = reinterpret_cast<const float4*>(in + (size_t)row * Dn) + lane * 2;
  float4 a = p[0], b = p[1];
  float s = a.x + a.y + a.z + a.w + b.x + b.y + b.z + b.w;
  float q = a.x*a.x + a.y*a.y + a.z*a.z + a.w*a.w + b.x*b.x + b.y*b.y + b.z*b.z + b.w*b.w;
  s = wred(s); q = wred(q);
  if (lane == 0) {
    float m = s * (1.0f / 512.0f);
    float var = q * (1.0f / 512.0f) - m * m;
    mu[row] = m;
    rsig[row] = 1.0f / sqrtf(var + 1e-5f);
  }
}

// ---------------- slots init ----------------
__global__ __launch_bounds__(256) void k_slots_init(const float* __restrict__ smu, const float* __restrict__ sls,
                                                    const float* __restrict__ noise, float* __restrict__ slots) {
  int r = blockIdx.x;
  for (int d = threadIdx.x; d < Dn; d += 256)
    slots[(size_t)r * Dn + d] = smu[d] + expf(sls[d]) * noise[(size_t)r * Dn + d];
}

// ---------------- LN of [R,512] rows (prologue only) ----------------
__global__ __launch_bounds__(256) void k_ln_rows(const float* __restrict__ src, const float* __restrict__ w,
                                                 const float* __restrict__ b, float* __restrict__ dst) {
  int r = blockIdx.x;
  __shared__ float red[8];
  int t = threadIdx.x;
  float x0 = src[(size_t)r * Dn + t], x1 = src[(size_t)r * Dn + 256 + t];
  float s = x0 + x1, q = x0 * x0 + x1 * x1;
  s = wred(s); q = wred(q);
  if ((t & 63) == 0) { red[t >> 6] = s; red[4 + (t >> 6)] = q; }
  __syncthreads();
  float S = red[0] + red[1] + red[2] + red[3];
  float Q = red[4] + red[5] + red[6] + red[7];
  float m = S * (1.0f / 512.0f);
  float rs = 1.0f / sqrtf(Q * (1.0f / 512.0f) - m * m + 1e-5f);
  dst[(size_t)r * Dn + t] = (x0 - m) * rs * w[t] + b[t];
  dst[(size_t)r * Dn + 256 + t] = (x1 - m) * rs * w[256 + t] + b[256 + t];
}

// ---------------- small GEMM (prologue Wq only) ----------------
template <bool TRANS, bool RELU, bool ADD>
__global__ __launch_bounds__(256) void k_gemm_sm(const float* __restrict__ A, const float* __restrict__ W,
                                                 const float* __restrict__ bias, float* __restrict__ out,
                                                 int Nc, int K) {
  __shared__ float as_[64][17];
  __shared__ float ws_[16][65];
  int m0 = blockIdx.y * 64, n0 = blockIdx.x * 64;
  int t = threadIdx.x, tx = t & 15, ty = t >> 4;
  float acc[4][4] = {};
  for (int k0 = 0; k0 < K; k0 += 16) {
#pragma unroll
    for (int e = 0; e < 4; ++e) {
      int idx = t + e * 256;
      int r = idx >> 4, c = idx & 15;
      as_[r][c] = A[(size_t)(m0 + r) * K + k0 + c];
    }
#pragma unroll
    for (int e = 0; e < 4; ++e) {
      int idx = t + e * 256;
      if (!TRANS) {
        int r = idx >> 6, c = idx & 63;
        ws_[r][c] = W[(size_t)(k0 + r) * Nc + n0 + c];
      } else {
        int r = idx >> 4, c = idx & 15;
        ws_[c][r] = W[(size_t)(n0 + r) * K + k0 + c];
      }
    }
    __syncthreads();
#pragma unroll
    for (int kc = 0; kc < 16; ++kc) {
      float av[4], wv[4];
#pragma unroll
      for (int i = 0; i < 4; ++i) av[i] = as_[ty * 4 + i][kc];
#pragma unroll
      for (int j = 0; j < 4; ++j) wv[j] = ws_[kc][tx * 4 + j];
#pragma unroll
      for (int i = 0; i < 4; ++i)
#pragma unroll
        for (int j = 0; j < 4; ++j) acc[i][j] += av[i] * wv[j];
    }
    __syncthreads();
  }
#pragma unroll
  for (int i = 0; i < 4; ++i)
#pragma unroll
    for (int j = 0; j < 4; ++j) {
      int m = m0 + ty * 4 + i, n = n0 + tx * 4 + j;
      float v = acc[i][j] + bias[n];
      if (RELU) v = fmaxf(v, 0.0f);
      if (ADD) v += out[(size_t)m * Nc + n];
      out[(size_t)m * Nc + n] = v;
    }
}

// ---------------- transpose src[R][C] -> dst[C][R] ----------------
__global__ __launch_bounds__(256) void k_transp(const float* __restrict__ src, float* __restrict__ dst,
                                                int R, int C) {
  __shared__ float tile[64][65];
  int j0 = blockIdx.x * 64, i0 = blockIdx.y * 64;
  int t = threadIdx.x;
#pragma unroll
  for (int e = 0; e < 16; ++e) {
    int idx = t + e * 256;
    int r = idx >> 6, c = idx & 63;
    tile[r][c] = src[(size_t)(i0 + r) * C + j0 + c];
  }
  __syncthreads();
#pragma unroll
  for (int e = 0; e < 16; ++e) {
    int idx = t + e * 256;
    int r = idx >> 6, c = idx & 63;
    dst[(size_t)(j0 + r) * R + i0 + c] = tile[c][r];
  }
}

// ---------------- u = Wk_h @ q, folded with LN weights + SCALE ----------------
__global__ __launch_bounds__(256) void k_qkt(const float* __restrict__ q, const float* __restrict__ Wk,
                                             const float* __restrict__ bk, const float* __restrict__ lnw,
                                             const float* __restrict__ lnb, float* __restrict__ qkt,
                                             float* __restrict__ alpha, float* __restrict__ beta) {
  int b = blockIdx.y, hi = blockIdx.x, h = hi >> 4, i = hi & 15;
  __shared__ __align__(16) float qs[64];
  __shared__ float r2[8];
  int t = threadIdx.x;
  if (t < 64) qs[t] = q[(size_t)(b * NSn + i) * Dn + h * 64 + t];
  __syncthreads();
  float pa = 0.0f, pb = 0.0f;
  for (int d = t; d < Dn; d += 256) {
    const float4* wr = reinterpret_cast<const float4*>(Wk + (size_t)d * Dn + h * 64);
    const float4* q4 = reinterpret_cast<const float4*>(qs);
    float u = 0.0f;
#pragma unroll
    for (int k = 0; k < 16; ++k) {
      float4 wv = wr[k], qv = q4[k];
      u += wv.x * qv.x + wv.y * qv.y + wv.z * qv.z + wv.w * qv.w;
    }
    qkt[(size_t)(b * HIn + hi) * Dn + d] = kScale * lnw[d] * u;
    pa += lnb[d] * u;
    pb += lnw[d] * u;
  }
  pa = wred(pa); pb = wred(pb);
  if ((t & 63) == 0) { r2[t >> 6] = pa; r2[4 + (t >> 6)] = pb; }
  __syncthreads();
  if (t == 0) {
    float qb_ = 0.0f;
    for (int k = 0; k < 64; ++k) qb_ += qs[k] * bk[h * 64 + k];
    alpha[b * HIn + hi] = kScale * (r2[0] + r2[1] + r2[2] + r2[3] + qb_);
    beta[b * HIn + hi]  = kScale * (r2[4] + r2[5] + r2[6] + r2[7]);
  }
}

// ---------------- dots GEMM + softmax over slots + EPS + partial sums ----------------
__global__ __launch_bounds__(256) void k_dots(const float* __restrict__ in, const float* __restrict__ qkt,
                                              const float* __restrict__ alpha, const float* __restrict__ beta,
                                              const float* __restrict__ mu, const float* __restrict__ rsig,
                                              float* __restrict__ A, float* __restrict__ Spart,
                                              float* __restrict__ c1part) {
  int b = blockIdx.y, jt = blockIdx.x, j0 = jt * 128;
  __shared__ __align__(16) float xs[16][132];
  __shared__ __align__(16) float us[16][132];
  __shared__ float sm[64][132];
  __shared__ float rsL[128], muL[128], aL[128], bL[128];
  int t = threadIdx.x, tx = t & 15, ty = t >> 4;
  float acc[8][8] = {};
  const size_t inbase = ((size_t)b * Nn + j0) * Dn;
  const size_t ubase = (size_t)b * HIn * Dn;
  for (int k0 = 0; k0 < Dn; k0 += 16) {
#pragma unroll
    for (int e = 0; e < 8; ++e) {
      int idx = t + e * 256;
      int r = idx >> 4, c = idx & 15;
      xs[c][r] = in[inbase + (size_t)r * Dn + k0 + c];
    }
#pragma unroll
    for (int e = 0; e < 8; ++e) {
      int idx = t + e * 256;
      int r = idx >> 4, c = idx & 15;
      us[c][r] = qkt[ubase + (size_t)r * Dn + k0 + c];
    }
    __syncthreads();
#pragma unroll
    for (int kc = 0; kc < 16; ++kc) {
      float4 x0 = *reinterpret_cast<const float4*>(&xs[kc][ty * 8]);
      float4 x1 = *reinterpret_cast<const float4*>(&xs[kc][ty * 8 + 4]);
      float4 u0 = *reinterpret_cast<const float4*>(&us[kc][tx * 8]);
      float4 u1 = *reinterpret_cast<const float4*>(&us[kc][tx * 8 + 4]);
      float xv[8] = {x0.x, x0.y, x0.z, x0.w, x1.x, x1.y, x1.z, x1.w};
      float uv[8] = {u0.x, u0.y, u0.z, u0.w, u1.x, u1.y, u1.z, u1.w};
#pragma unroll
      for (int a_ = 0; a_ < 8; ++a_)
#pragma unroll
        for (int b_ = 0; b_ < 8; ++b_) acc[a_][b_] += xv[a_] * uv[b_];
    }
    __syncthreads();
  }
  if (t < 128) {
    rsL[t] = rsig[(size_t)b * Nn + j0 + t];
    muL[t] = mu[(size_t)b * Nn + j0 + t];
    aL[t] = alpha[b * HIn + t];
    bL[t] = beta[b * HIn + t];
  }
  for (int half = 0; half < 2; ++half) {
    __syncthreads();
    if ((ty >> 3) == half) {
#pragma unroll
      for (int ji = 0; ji < 8; ++ji) {
        int jl = (ty & 7) * 8 + ji;
        int jg = half * 64 + jl;
        float rs = rsL[jg], mr = muL[jg] * rs;
#pragma unroll
        for (int ui = 0; ui < 8; ++ui) {
          int hi = tx * 8 + ui;
          sm[jl][hi] = acc[ji][ui] * rs + aL[hi] - mr * bL[hi];
        }
      }
    }
    __syncthreads();
    for (int task = t; task < 512; task += 256) {
      int j = task & 63, h = task >> 6;
      float* p = &sm[j][h * 16];
      float mx = p[0];
#pragma unroll
      for (int i = 1; i < 16; ++i) mx = fmaxf(mx, p[i]);
      float e[16];
      float ssum = 0.0f;
#pragma unroll
      for (int i = 0; i < 16; ++i) { e[i] = expf(p[i] - mx); ssum += e[i]; }
      float inv = 1.0f / ssum;
#pragma unroll
      for (int i = 0; i < 16; ++i) p[i] = e[i] * inv + kEps;
    }
    __syncthreads();
    if (t < 128) {
      float ss = 0.0f, cc = 0.0f;
#pragma unroll
      for (int j = 0; j < 64; ++j) {
        float a = sm[j][t];
        ss += a;
        cc += a * muL[half * 64 + j] * rsL[half * 64 + j];
      }
      int sub = (b * 64 + jt * 2 + half) * HIn + t;
      Spart[sub] = ss;
      c1part[sub] = cc;
    }
    for (int idx = t; idx < 8192; idx += 256) {
      int hi = idx >> 6, j = idx & 63;
      A[(size_t)(b * HIn + hi) * Nn + j0 + half * 64 + j] = sm[j][hi] * rsL[half * 64 + j];
    }
  }
}

// ---------------- AX = A @ X  (K-split x4) ----------------
__global__ __launch_bounds__(256) void k_ax(const float* __restrict__ Abuf, const float* __restrict__ in,
                                            float* __restrict__ AXp) {
  int d0 = blockIdx.x * 128;
  int kp = blockIdx.y;
  int b = blockIdx.z;
  __shared__ __align__(16) float as_[16][132];
  __shared__ __align__(16) float xs_[16][132];
  int t = threadIdx.x, tx = t & 15, ty = t >> 4;
  float acc[8][8] = {};
  for (int k0 = kp * 1024; k0 < kp * 1024 + 1024; k0 += 16) {
#pragma unroll
    for (int e = 0; e < 8; ++e) {
      int idx = t + e * 256;
      int r = idx >> 4, c = idx & 15;
      as_[c][r] = Abuf[(size_t)(b * HIn + r) * Nn + k0 + c];
    }
#pragma unroll
    for (int e = 0; e < 8; ++e) {
      int idx = t + e * 256;
      int kc = idx >> 7, dd = idx & 127;
      xs_[kc][dd] = in[((size_t)b * Nn + k0 + kc) * Dn + d0 + dd];
    }
    __syncthreads();
#pragma unroll
    for (int kc = 0; kc < 16; ++kc) {
      float4 a0 = *reinterpret_cast<const float4*>(&as_[kc][ty * 8]);
      float4 a1 = *reinterpret_cast<const float4*>(&as_[kc][ty * 8 + 4]);
      float4 x0 = *reinterpret_cast<const float4*>(&xs_[kc][tx * 8]);
      float4 x1 = *reinterpret_cast<const float4*>(&xs_[kc][tx * 8 + 4]);
      float av[8] = {a0.x, a0.y, a0.z, a0.w, a1.x, a1.y, a1.z, a1.w};
      float xv[8] = {x0.x, x0.y, x0.z, x0.w, x1.x, x1.y, x1.z, x1.w};
#pragma unroll
      for (int u = 0; u < 8; ++u)
#pragma unroll
        for (int v = 0; v < 8; ++v) acc[u][v] += av[u] * xv[v];
    }
    __syncthreads();
  }
#pragma unroll
  for (int u = 0; u < 8; ++u)
#pragma unroll
    for (int v = 0; v < 8; ++v)
      AXp[(((size_t)kp * Bn + b) * HIn + ty * 8 + u) * Dn + d0 + tx * 8 + v] = acc[u][v];
}

// ---------------- fused slot-side chain ----------------
// Per block: 4 slot rows. reduceS + upd-proj + Wc + (WihT/WhhT GEMM + GRU) +
// LN_ff + W1(relu) + W2(+residual) + LN_s + Wq  -> slots, qbuf
__global__ __launch_bounds__(256) void k_slot_update(
    const float* __restrict__ AXp, const float* __restrict__ Spart, const float* __restrict__ c1part,
    const float* __restrict__ lnw_in, const float* __restrict__ lnb_in,
    const float* __restrict__ Wv, const float* __restrict__ bv,
    const float* __restrict__ Wc, const float* __restrict__ bc,
    const float* __restrict__ WihT, const float* __restrict__ bih,
    const float* __restrict__ WhhT, const float* __restrict__ bhh,
    const float* __restrict__ lnffw, const float* __restrict__ lnffb,
    const float* __restrict__ W1, const float* __restrict__ b1,
    const float* __restrict__ W2, const float* __restrict__ b2,
    const float* __restrict__ lnsw, const float* __restrict__ lnsb,
    const float* __restrict__ Wq, const float* __restrict__ bq,
    float* __restrict__ slots, float* __restrict__ qbuf) {
  __shared__ float smx[14432];
  float* sprev = smx;           // 4*512  (prev slots; alive through GRU)
  float* updRow = smx + 2048;   // 4*512  (P3->P4), later snew/s2
  float* updc  = smx + 4096;    // 4*512  (P4->P6), later sln
  float* sS = smx + 6144;       // 32
  float* sC = smx + 6176;       // 32
  float* sI = smx + 6208;       // 32
  float* dyn = smx + 6240;      // 8192: vx-pair / gh / h1
  float* snew = updRow;
  float* sln = updc;

  int t = threadIdx.x;
  int r0 = blockIdx.x * 4;
  int b = r0 >> 4;
  int i0 = r0 & 15;
  int wv_ = t >> 6, ln_ = t & 63;

  // P0: load prev slots rows
  for (int idx = t; idx < 512; idx += 256)
    reinterpret_cast<float4*>(sprev)[idx] =
        reinterpret_cast<const float4*>(slots + (size_t)r0 * Dn)[idx];

  // P1: S/c1 per (row, head) — wave w handles h = 2w, 2w+1
#pragma unroll
  for (int rr = 0; rr < 4; ++rr) {
#pragma unroll
    for (int hs = 0; hs < 2; ++hs) {
      int h = wv_ * 2 + hs;
      int hi = h * 16 + i0 + rr;
      float vs = Spart[(size_t)(b * 64 + ln_) * HIn + hi];
      float vc = c1part[(size_t)(b * 64 + ln_) * HIn + hi];
      vs = wred(vs); vc = wred(vc);
      if (ln_ == 0) { sS[rr * 8 + h] = vs; sC[rr * 8 + h] = vc; sI[rr * 8 + h] = 1.0f / vs; }
    }
  }
  __syncthreads();

  // P2/P3: vx (2 rows at a time) then upd projection through Wv
  for (int pr = 0; pr < 2; ++pr) {
    for (int rr2 = 0; rr2 < 2; ++rr2) {
      int rr = pr * 2 + rr2;
#pragma unroll
      for (int h = 0; h < 8; ++h) {
        int hi = h * 16 + i0 + rr;
        float c1v = sC[rr * 8 + h], iv = sI[rr * 8 + h];
        for (int d = t; d < 512; d += 256) {
          float G = AXp[((size_t)(0 * Bn + b) * HIn + hi) * Dn + d]
                  + AXp[((size_t)(1 * Bn + b) * HIn + hi) * Dn + d]
                  + AXp[((size_t)(2 * Bn + b) * HIn + hi) * Dn + d]
                  + AXp[((size_t)(3 * Bn + b) * HIn + hi) * Dn + d];
          dyn[(rr2 * 8 + h) * 512 + d] = lnw_in[d] * (G - c1v) * iv + lnb_in[d];
        }
      }
    }
    __syncthreads();
    {
      int cA = t, cB = t + 256;
      int hA = cA >> 6, hB = cB >> 6;
      float a00 = 0, a01 = 0, a10 = 0, a11 = 0;
#pragma unroll 8
      for (int d = 0; d < 512; ++d) {
        float w0 = Wv[(size_t)d * 512 + cA], w1 = Wv[(size_t)d * 512 + cB];
        a00 += dyn[(0 * 8 + hA) * 512 + d] * w0;
        a01 += dyn[(0 * 8 + hB) * 512 + d] * w1;
        a10 += dyn[(1 * 8 + hA) * 512 + d] * w0;
        a11 += dyn[(1 * 8 + hB) * 512 + d] * w1;
      }
      updRow[(pr * 2 + 0) * 512 + cA] = a00 + bv[cA];
      updRow[(pr * 2 + 0) * 512 + cB] = a01 + bv[cB];
      updRow[(pr * 2 + 1) * 512 + cA] = a10 + bv[cA];
      updRow[(pr * 2 + 1) * 512 + cB] = a11 + bv[cB];
    }
    __syncthreads();
  }

  // P4: updc = updRow @ Wc + bc
  {
    int cA = t, cB = t + 256;
    float a[4][2] = {};
#pragma unroll 8
    for (int k = 0; k < 512; ++k) {
      float w0 = Wc[(size_t)k * 512 + cA], w1 = Wc[(size_t)k * 512 + cB];
#pragma unroll
      for (int rr = 0; rr < 4; ++rr) {
        float av = updRow[rr * 512 + k];
        a[rr][0] += av * w0; a[rr][1] += av * w1;
      }
    }
#pragma unroll
    for (int rr = 0; rr < 4; ++rr) {
      updc[rr * 512 + cA] = a[rr][0] + bc[cA];
      updc[rr * 512 + cB] = a[rr][1] + bc[cB];
    }
  }
  __syncthreads();

  // P5: gh = sprev @ WhhT + bhh  (into dyn[4*1536])
  {
    float a[4][6] = {};
#pragma unroll 4
    for (int k = 0; k < 512; ++k) {
      float w[6];
#pragma unroll
      for (int cg = 0; cg < 6; ++cg) w[cg] = WhhT[(size_t)k * 1536 + cg * 256 + t];
#pragma unroll
      for (int rr = 0; rr < 4; ++rr) {
        float av = sprev[rr * 512 + k];
#pragma unroll
        for (int cg = 0; cg < 6; ++cg) a[rr][cg] += av * w[cg];
      }
    }
#pragma unroll
    for (int rr = 0; rr < 4; ++rr)
#pragma unroll
      for (int cg = 0; cg < 6; ++cg)
        dyn[rr * 1536 + cg * 256 + t] = a[rr][cg] + bhh[cg * 256 + t];
  }
  __syncthreads();

  // P6: gi in registers + GRU pointwise -> snew (overwrites updRow)
  {
    float a[4][6] = {};
#pragma unroll 4
    for (int k = 0; k < 512; ++k) {
      float w[6];
#pragma unroll
      for (int cg = 0; cg < 6; ++cg) w[cg] = WihT[(size_t)k * 1536 + cg * 256 + t];
#pragma unroll
      for (int rr = 0; rr < 4; ++rr) {
        float av = updc[rr * 512 + k];
#pragma unroll
        for (int cg = 0; cg < 6; ++cg) a[rr][cg] += av * w[cg];
      }
    }
#pragma unroll
    for (int rr = 0; rr < 4; ++rr) {
#pragma unroll
      for (int j = 0; j < 2; ++j) {
        int c = j * 256 + t;
        float gir = a[rr][j] + bih[c];
        float giz = a[rr][2 + j] + bih[512 + c];
        float gin = a[rr][4 + j] + bih[1024 + c];
        float ghr = dyn[rr * 1536 + c];
        float ghz = dyn[rr * 1536 + 512 + c];
        float ghn = dyn[rr * 1536 + 1024 + c];
        float rg = 1.0f / (1.0f + expf(-(gir + ghr)));
        float zg = 1.0f / (1.0f + expf(-(giz + ghz)));
        float ng = tanhf(gin + rg * ghn);
        snew[rr * 512 + c] = (1.0f - zg) * ng + zg * sprev[rr * 512 + c];
      }
    }
  }
  __syncthreads();

  // P8: LN(snew, ln_ff) -> sln (wave per row)
  {
    int rr = wv_;
    const float4* sp = reinterpret_cast<const float4*>(snew + rr * 512) + ln_ * 2;
    float4 A4 = sp[0], B4 = sp[1];
    float s = A4.x + A4.y + A4.z + A4.w + B4.x + B4.y + B4.z + B4.w;
    float q = A4.x*A4.x + A4.y*A4.y + A4.z*A4.z + A4.w*A4.w +
              B4.x*B4.x + B4.y*B4.y + B4.z*B4.z + B4.w*B4.w;
    s = wred(s); q = wred(q);
    float m = s * (1.0f / 512.0f);
    float rs = 1.0f / sqrtf(q * (1.0f / 512.0f) - m * m + 1e-5f);
    float xv[8] = {A4.x, A4.y, A4.z, A4.w, B4.x, B4.y, B4.z, B4.w};
#pragma unroll
    for (int e = 0; e < 8; ++e) {
      int d = ln_ * 8 + e;
      sln[rr * 512 + d] = (xv[e] - m) * rs * lnffw[d] + lnffb[d];
    }
  }
  __syncthreads();

  // P9: h1 = relu(sln @ W1 + b1) -> dyn[4*2048]
  for (int ph = 0; ph < 2; ++ph) {
    float a[4][4] = {};
#pragma unroll 4
    for (int k = 0; k < 512; ++k) {
      float w[4];
#pragma unroll
      for (int cg = 0; cg < 4; ++cg) w[cg] = W1[(size_t)k * 2048 + ph * 1024 + cg * 256 + t];
#pragma unroll
      for (int rr = 0; rr < 4; ++rr) {
        float av = sln[rr * 512 + k];
#pragma unroll
        for (int cg = 0; cg < 4; ++cg) a[rr][cg] += av * w[cg];
      }
    }
#pragma unroll
    for (int rr = 0; rr < 4; ++rr)
#pragma unroll
      for (int cg = 0; cg < 4; ++cg) {
        int c = ph * 1024 + cg * 256 + t;
        dyn[rr * 2048 + c] = fmaxf(a[rr][cg] + b1[c], 0.0f);
      }
  }
  __syncthreads();

  // P10: s2 = snew + h1 @ W2 + b2 -> slots (global) and snew (LDS)
  {
    int cA = t, cB = t + 256;
    float a[4][2] = {};
#pragma unroll 8
    for (int k = 0; k < 2048; ++k) {
      float w0 = W2[(size_t)k * 512 + cA], w1 = W2[(size_t)k * 512 + cB];
#pragma unroll
      for (int rr = 0; rr < 4; ++rr) {
        float hv = dyn[rr * 2048 + k];
        a[rr][0] += hv * w0; a[rr][1] += hv * w1;
      }
    }
#pragma unroll
    for (int rr = 0; rr < 4; ++rr) {
      float v0 = snew[rr * 512 + cA] + a[rr][0] + b2[cA];
      float v1 = snew[rr * 512 + cB] + a[rr][1] + b2[cB];
      slots[(size_t)(r0 + rr) * Dn + cA] = v0;
      slots[(size_t)(r0 + rr) * Dn + cB] = v1;
      snew[rr * 512 + cA] = v0;
      snew[rr * 512 + cB] = v1;
    }
  }
  __syncthreads();

  // P11: LN(snew, ln_s) -> sln; q = sln @ Wq + bq -> qbuf
  {
    int rr = wv_;
    const float4* sp = reinterpret_cast<const float4*>(snew + rr * 512) + ln_ * 2;
    float4 A4 = sp[0], B4 = sp[1];
    float s = A4.x + A4.y + A4.z + A4.w + B4.x + B4.y + B4.z + B4.w;
    float q = A4.x*A4.x + A4.y*A4.y + A4.z*A4.z + A4.w*A4.w +
              B4.x*B4.x + B4.y*B4.y + B4.z*B4.z + B4.w*B4.w;
    s = wred(s); q = wred(q);
    float m = s * (1.0f / 512.0f);
    float rs = 1.0f / sqrtf(q * (1.0f / 512.0f) - m * m + 1e-5f);
    float xv[8] = {A4.x, A4.y, A4.z, A4.w, B4.x, B4.y, B4.z, B4.w};
#pragma unroll
    for (int e = 0; e < 8; ++e) {
      int d = ln_ * 8 + e;
      sln[rr * 512 + d] = (xv[e] - m) * rs * lnsw[d] + lnsb[d];
    }
  }
  __syncthreads();
  {
    int cA = t, cB = t + 256;
    float a[4][2] = {};
#pragma unroll 8
    for (int k = 0; k < 512; ++k) {
      float w0 = Wq[(size_t)k * 512 + cA], w1 = Wq[(size_t)k * 512 + cB];
#pragma unroll
      for (int rr = 0; rr < 4; ++rr) {
        float av = sln[rr * 512 + k];
        a[rr][0] += av * w0; a[rr][1] += av * w1;
      }
    }
#pragma unroll
    for (int rr = 0; rr < 4; ++rr) {
      qbuf[(size_t)(r0 + rr) * Dn + cA] = a[rr][0] + bq[cA];
      qbuf[(size_t)(r0 + rr) * Dn + cB] = a[rr][1] + bq[cB];
    }
  }
}

// ---------------- keep gate (zero dropped slots in place) ----------------
__global__ void k_keepscale(const float* __restrict__ Wkeep, const float* __restrict__ gk,
                            float* __restrict__ slots) {
  int g = blockIdx.x;
  int lane = threadIdx.x;
  float4* sp = reinterpret_cast<float4*>(slots + (size_t)g * Dn) + lane * 2;
  float4 s0 = sp[0], s1 = sp[1];
  float sv[8] = {s0.x, s0.y, s0.z, s0.w, s1.x, s1.y, s1.z, s1.w};
  double d0 = 0.0, d1 = 0.0;
#pragma unroll
  for (int e = 0; e < 8; ++e) {
    int d = lane * 8 + e;
    d0 += (double)sv[e] * (double)Wkeep[d * 2];
    d1 += (double)sv[e] * (double)Wkeep[d * 2 + 1];
  }
  d0 = wredd(d0);
  d1 = wredd(d1);
  int keepi = 0;
  if (lane == 0) keepi = ((d1 + (double)gk[g * 2 + 1]) > (d0 + (double)gk[g * 2])) ? 1 : 0;
  keepi = __shfl(keepi, 0);
  if (!keepi) {
    float4 z = {0.0f, 0.0f, 0.0f, 0.0f};
    sp[0] = z;
    sp[1] = z;
  }
}

// ---------------- per-slot scalars for route decomposition ----------------
__global__ void k_slotscalars(const float* __restrict__ slots, const float* __restrict__ lnw,
                              const float* __restrict__ lnb, double* __restrict__ swd,
                              double* __restrict__ sbd) {
  int g = blockIdx.x, lane = threadIdx.x;
  const float4* sp = reinterpret_cast<const float4*>(slots + (size_t)g * Dn) + lane * 2;
  const float4* wp = reinterpret_cast<const float4*>(lnw) + lane * 2;
  const float4* bp = reinterpret_cast<const float4*>(lnb) + lane * 2;
  float4 s0 = sp[0], s1 = sp[1], w0 = wp[0], w1 = wp[1], b0 = bp[0], b1 = bp[1];
  double pw = (double)s0.x * w0.x + (double)s0.y * w0.y + (double)s0.z * w0.z + (double)s0.w * w0.w +
              (double)s1.x * w1.x + (double)s1.y * w1.y + (double)s1.z * w1.z + (double)s1.w * w1.w;
  double pb = (double)s0.x * b0.x + (double)s0.y * b0.y + (double)s0.z * b0.z + (double)s0.w * b0.w +
              (double)s1.x * b1.x + (double)s1.y * b1.y + (double)s1.z * b1.z + (double)s1.w * b1.w;
  pw = wredd(pw);
  pb = wredd(pb);
  if (lane == 0) { swd[g] = pw; sbd[g] = pb; }
}

// ---------------- hard route + gather output (tiled mini-GEMM) ----------------
__global__ __launch_bounds__(256) void k_route_out(const float* __restrict__ in, const float* __restrict__ slots,
                                                   const float* __restrict__ lnw, const double* __restrict__ swd,
                                                   const double* __restrict__ sbd, const float* __restrict__ mu,
                                                   const float* __restrict__ rsig,
                                                   const float* __restrict__ g_route, float* __restrict__ out) {
  int b = blockIdx.y, j0 = blockIdx.x * 128;
  __shared__ __align__(16) float sl[16 * 516];
  __shared__ __align__(16) float lw[512];
  __shared__ __align__(16) float xs[16][132];
  __shared__ double lgd[128][17];
  __shared__ int besti[128];
  int t = threadIdx.x, tx = t & 15, ty = t >> 4;

  for (int idx = t; idx < 2048; idx += 256) {
    int i = idx >> 7, c = idx & 127;
    *reinterpret_cast<float4*>(&sl[i * 516 + c * 4]) =
        *reinterpret_cast<const float4*>(&slots[(size_t)(b * NSn + i) * Dn + c * 4]);
  }
  if (t < 128)
    *reinterpret_cast<float4*>(&lw[t * 4]) = *reinterpret_cast<const float4*>(&lnw[t * 4]);

  float acc[8] = {};
  double accd[8] = {};
  const size_t inbase = ((size_t)b * Nn + j0) * Dn;
  __syncthreads();

  for (int k0 = 0; k0 < Dn; k0 += 16) {
    float pre[8];
#pragma unroll
    for (int e = 0; e < 8; ++e) {
      int idx = t + e * 256;
      int r = idx >> 4, c = idx & 15;
      pre[e] = in[inbase + (size_t)r * Dn + k0 + c];
    }
    __syncthreads();
#pragma unroll
    for (int e = 0; e < 8; ++e) {
      int idx = t + e * 256;
      int r = idx >> 4, c = idx & 15;
      xs[c][r] = pre[e] * lw[k0 + c];
    }
    __syncthreads();
#pragma unroll
    for (int kc = 0; kc < 16; ++kc) {
      float sv = sl[tx * 516 + k0 + kc];
      float4 x0 = *reinterpret_cast<const float4*>(&xs[kc][ty * 8]);
      float4 x1 = *reinterpret_cast<const float4*>(&xs[kc][ty * 8 + 4]);
      acc[0] += x0.x * sv; acc[1] += x0.y * sv; acc[2] += x0.z * sv; acc[3] += x0.w * sv;
      acc[4] += x1.x * sv; acc[5] += x1.y * sv; acc[6] += x1.z * sv; acc[7] += x1.w * sv;
    }
    if ((k0 & 127) == 112) {
#pragma unroll
      for (int e = 0; e < 8; ++e) { accd[e] += (double)acc[e]; acc[e] = 0.0f; }
    }
  }

  double sw_i = swd[b * NSn + tx], sb_i = sbd[b * NSn + tx];
#pragma unroll
  for (int r = 0; r < 8; ++r) {
    int j = ty * 8 + r;
    double rsj = (double)rsig[(size_t)b * Nn + j0 + j];
    double muj = (double)mu[(size_t)b * Nn + j0 + j];
    double g = (double)g_route[((size_t)b * NSn + tx) * Nn + j0 + j];
    lgd[j][tx] = (double)kScale * (rsj * accd[r] + sb_i - muj * rsj * sw_i) + g;
  }
  __syncthreads();
  if (t < 128) {
    double best = lgd[t][0];
    int bi = 0;
#pragma unroll
    for (int i = 1; i < 16; ++i) {
      double v = lgd[t][i];
      if (v > best) { best = v; bi = i; }
    }
    besti[t] = bi;
  }
  __syncthreads();
  for (int idx = t; idx < 128 * 128; idx += 256) {
    int j = idx >> 7, c = idx & 127;
    *reinterpret_cast<float4*>(&out[inbase + (size_t)j * Dn + c * 4]) =
        *reinterpret_cast<const float4*>(&sl[besti[j] * 516 + c * 4]);
  }
}

extern "C" void kernel_launch(void* const* d_in, const int* in_sizes, int n_in,
                              void* d_out, int out_size, void* d_ws, size_t ws_size,
                              hipStream_t stream) {
  (void)in_sizes; (void)n_in; (void)out_size; (void)ws_size;
  const float* in = (const float*)d_in[0];
  const float* slots_mu = (const float*)d_in[1];
  const float* slots_ls = (const float*)d_in[2];
  const float* ln_in_w = (const float*)d_in[3];
  const float* ln_in_b = (const float*)d_in[4];
  const float* ln_s_w = (const float*)d_in[5];
  const float* ln_s_b = (const float*)d_in[6];
  const float* ln_ff_w = (const float*)d_in[7];
  const float* ln_ff_b = (const float*)d_in[8];
  const float* Wq = (const float*)d_in[9];
  const float* bq = (const float*)d_in[10];
  const float* Wk = (const float*)d_in[11];
  const float* bk = (const float*)d_in[12];
  const float* Wv = (const float*)d_in[13];
  const float* bv = (const float*)d_in[14];
  const float* Wc = (const float*)d_in[15];
  const float* bc = (const float*)d_in[16];
  const float* Wih = (const float*)d_in[17];
  const float* bih = (const float*)d_in[18];
  const float* Whh = (const float*)d_in[19];
  const float* bhh = (const float*)d_in[20];
  const float* W1 = (const float*)d_in[21];
  const float* b1 = (const float*)d_in[22];
  const float* W2 = (const float*)d_in[23];
  const float* b2 = (const float*)d_in[24];
  const float* Wkeep = (const float*)d_in[25];
  const float* noise = (const float*)d_in[26];
  const float* g_keep = (const float*)d_in[27];
  const float* g_route = (const float*)d_in[28];
  float* out = (float*)d_out;

  char* wptr = (char*)d_ws;
  auto alloc = [&](size_t bytes) {
    char* p = wptr;
    wptr += (bytes + 255) & ~(size_t)255;
    return p;
  };
  float* mu = (float*)alloc((size_t)Bn * Nn * 4);
  float* rsig = (float*)alloc((size_t)Bn * Nn * 4);
  float* slots = (float*)alloc((size_t)Bn * NSn * Dn * 4);
  float* sln = (float*)alloc((size_t)Bn * NSn * Dn * 4);
  float* qbuf = (float*)alloc((size_t)Bn * NSn * Dn * 4);
  float* qkt = (float*)alloc((size_t)Bn * HIn * Dn * 4);
  float* alpha = (float*)alloc((size_t)Bn * HIn * 4);
  float* beta = (float*)alloc((size_t)Bn * HIn * 4);
  float* Abuf = (float*)alloc((size_t)Bn * HIn * Nn * 4);
  float* Spart = (float*)alloc((size_t)Bn * 64 * HIn * 4);
  float* c1part = (float*)alloc((size_t)Bn * 64 * HIn * 4);
  float* AXp = (float*)alloc((size_t)4 * Bn * HIn * Dn * 4);
  float* WihT = (float*)alloc((size_t)Dn * 1536 * 4);
  float* WhhT = (float*)alloc((size_t)Dn * 1536 * 4);
  double* swd = (double*)alloc((size_t)Bn * NSn * 8);
  double* sbd = (double*)alloc((size_t)Bn * NSn * 8);

  k_rowstats<<<Bn * Nn / 4, 256, 0, stream>>>(in, mu, rsig);
  k_slots_init<<<Bn * NSn, 256, 0, stream>>>(slots_mu, slots_ls, noise, slots);
  k_transp<<<dim3(512 / 64, 1536 / 64), 256, 0, stream>>>(Wih, WihT, 1536, 512);
  k_transp<<<dim3(512 / 64, 1536 / 64), 256, 0, stream>>>(Whh, WhhT, 1536, 512);
  k_ln_rows<<<Bn * NSn, 256, 0, stream>>>(slots, ln_s_w, ln_s_b, sln);
  k_gemm_sm<false, false, false><<<dim3(8, 8), 256, 0, stream>>>(sln, Wq, bq, qbuf, 512, 512);

  for (int it = 0; it < 3; ++it) {
    k_qkt<<<dim3(HIn, Bn), 256, 0, stream>>>(qbuf, Wk, bk, ln_in_w, ln_in_b, qkt, alpha, beta);
    k_dots<<<dim3(Nn / 128, Bn), 256, 0, stream>>>(in, qkt, alpha, beta, mu, rsig, Abuf, Spart, c1part);
    k_ax<<<dim3(4, 4, Bn), 256, 0, stream>>>(Abuf, in, AXp);
    k_slot_update<<<128, 256, 0, stream>>>(AXp, Spart, c1part, ln_in_w, ln_in_b,
                                           Wv, bv, Wc, bc, WihT, bih, WhhT, bhh,
                                           ln_ff_w, ln_ff_b, W1, b1, W2, b2,
                                           ln_s_w, ln_s_b, Wq, bq, slots, qbuf);
  }

  k_keepscale<<<Bn * NSn, 64, 0, stream>>>(Wkeep, g_keep, slots);
  k_slotscalars<<<Bn * NSn, 64, 0, stream>>>(slots, ln_in_w, ln_in_b, swd, sbd);
  k_route_out<<<dim3(Nn / 128, Bn), 256, 0, stream>>>(in, slots, ln_in_w, swd, sbd, mu, rsig, g_route, out);
}

// Round 4
// 3021.074 us; speedup vs baseline: 1.1804x; 1.1804x over previous
//
#include <hip/hip_runtime.h>
#include <hip/hip_bf16.h>
#include <math.h>

constexpr int Bn = 32, Nn = 4096, Dn = 512, NSn = 16, HIn = 128;
constexpr float kScale = 0.04419417382415922f; // 512^-0.5
constexpr float kEps = 1e-8f;

__device__ __forceinline__ float wred(float v) {
#pragma unroll
  for (int m = 32; m > 0; m >>= 1) v += __shfl_xor(v, m);
  return v;
}
__device__ __forceinline__ double wredd(double v) {
#pragma unroll
  for (int m = 32; m > 0; m >>= 1) v += __shfl_xor(v, m);
  return v;
}

// ---------------- per-row LN stats of inputs ----------------
__global__ __launch_bounds__(256) void k_rowstats(const float* __restrict__ in,
                                                  float* __restrict__ mu, float* __restrict__ rsig) {
  int row = blockIdx.x * 4 + (threadIdx.x >> 6);
  int lane = threadIdx.x & 63;
  const float4* p = reinterpret_cast<const float4*>(in + (size_t)row * Dn) + lane * 2;
  float4 a = p[0], b = p[1];
  float s = a.x + a.y + a.z + a.w + b.x + b.y + b.z + b.w;
  float q = a.x*a.x + a.y*a.y + a.z*a.z + a.w*a.w + b.x*b.x + b.y*b.y + b.z*b.z + b.w*b.w;
  s = wred(s); q = wred(q);
  if (lane == 0) {
    float m = s * (1.0f / 512.0f);
    float var = q * (1.0f / 512.0f) - m * m;
    mu[row] = m;
    rsig[row] = 1.0f / sqrtf(var + 1e-5f);
  }
}

// ---------------- slots init ----------------
__global__ __launch_bounds__(256) void k_slots_init(const float* __restrict__ smu, const float* __restrict__ sls,
                                                    const float* __restrict__ noise, float* __restrict__ slots) {
  int r = blockIdx.x;
  for (int d = threadIdx.x; d < Dn; d += 256)
    slots[(size_t)r * Dn + d] = smu[d] + expf(sls[d]) * noise[(size_t)r * Dn + d];
}

// ---------------- LN of [R,512] rows ----------------
__global__ __launch_bounds__(256) void k_ln_rows(const float* __restrict__ src, const float* __restrict__ w,
                                                 const float* __restrict__ b, float* __restrict__ dst) {
  int r = blockIdx.x;
  __shared__ float red[8];
  int t = threadIdx.x;
  float x0 = src[(size_t)r * Dn + t], x1 = src[(size_t)r * Dn + 256 + t];
  float s = x0 + x1, q = x0 * x0 + x1 * x1;
  s = wred(s); q = wred(q);
  if ((t & 63) == 0) { red[t >> 6] = s; red[4 + (t >> 6)] = q; }
  __syncthreads();
  float S = red[0] + red[1] + red[2] + red[3];
  float Q = red[4] + red[5] + red[6] + red[7];
  float m = S * (1.0f / 512.0f);
  float rs = 1.0f / sqrtf(Q * (1.0f / 512.0f) - m * m + 1e-5f);
  dst[(size_t)r * Dn + t] = (x0 - m) * rs * w[t] + b[t];
  dst[(size_t)r * Dn + 256 + t] = (x1 - m) * rs * w[256 + t] + b[256 + t];
}

// ---------------- small GEMM: out = act(A@W (+bias) (+out)), bias nullable ----------------
template <bool TRANS, bool RELU, bool ADD>
__global__ __launch_bounds__(256) void k_gemm_sm(const float* __restrict__ A, const float* __restrict__ W,
                                                 const float* __restrict__ bias, float* __restrict__ out,
                                                 int Nc, int K) {
  __shared__ float as_[64][17];
  __shared__ float ws_[16][65];
  int m0 = blockIdx.y * 64, n0 = blockIdx.x * 64;
  int t = threadIdx.x, tx = t & 15, ty = t >> 4;
  float acc[4][4] = {};
  for (int k0 = 0; k0 < K; k0 += 16) {
#pragma unroll
    for (int e = 0; e < 4; ++e) {
      int idx = t + e * 256;
      int r = idx >> 4, c = idx & 15;
      as_[r][c] = A[(size_t)(m0 + r) * K + k0 + c];
    }
#pragma unroll
    for (int e = 0; e < 4; ++e) {
      int idx = t + e * 256;
      if (!TRANS) {
        int r = idx >> 6, c = idx & 63;
        ws_[r][c] = W[(size_t)(k0 + r) * Nc + n0 + c];
      } else {
        int r = idx >> 4, c = idx & 15;
        ws_[c][r] = W[(size_t)(n0 + r) * K + k0 + c];
      }
    }
    __syncthreads();
#pragma unroll
    for (int kc = 0; kc < 16; ++kc) {
      float av[4], wv[4];
#pragma unroll
      for (int i = 0; i < 4; ++i) av[i] = as_[ty * 4 + i][kc];
#pragma unroll
      for (int j = 0; j < 4; ++j) wv[j] = ws_[kc][tx * 4 + j];
#pragma unroll
      for (int i = 0; i < 4; ++i)
#pragma unroll
        for (int j = 0; j < 4; ++j) acc[i][j] += av[i] * wv[j];
    }
    __syncthreads();
  }
#pragma unroll
  for (int i = 0; i < 4; ++i)
#pragma unroll
    for (int j = 0; j < 4; ++j) {
      int m = m0 + ty * 4 + i, n = n0 + tx * 4 + j;
      float v = acc[i][j] + (bias ? bias[n] : 0.0f);
      if (RELU) v = fmaxf(v, 0.0f);
      if (ADD) v += out[(size_t)m * Nc + n];
      out[(size_t)m * Nc + n] = v;
    }
}

// ---------------- M_h = Wq_h @ Wk_h^T per head (raw) -> Ms[k*4096 + h*512 + d] ----------------
__global__ __launch_bounds__(256) void k_mh(const float* __restrict__ Wq, const float* __restrict__ Wk,
                                            float* __restrict__ Ms) {
  int h = blockIdx.z, k0 = blockIdx.y * 64, d0 = blockIdx.x * 64;
  __shared__ float qa[64][65];
  __shared__ float ka[64][65];
  int t = threadIdx.x, tx = t & 15, ty = t >> 4;
#pragma unroll
  for (int e = 0; e < 16; ++e) {
    int idx = t + e * 256;
    int r = idx >> 6, c = idx & 63;
    qa[c][r] = Wq[(size_t)(k0 + r) * Dn + h * 64 + c];
    ka[c][r] = Wk[(size_t)(d0 + r) * Dn + h * 64 + c];
  }
  __syncthreads();
  float acc[4][4] = {};
#pragma unroll 4
  for (int c = 0; c < 64; ++c) {
    float av[4], bv[4];
#pragma unroll
    for (int i = 0; i < 4; ++i) av[i] = qa[c][ty * 4 + i];
#pragma unroll
    for (int j = 0; j < 4; ++j) bv[j] = ka[c][tx * 4 + j];
#pragma unroll
    for (int i = 0; i < 4; ++i)
#pragma unroll
      for (int j = 0; j < 4; ++j) acc[i][j] += av[i] * bv[j];
  }
#pragma unroll
  for (int i = 0; i < 4; ++i)
#pragma unroll
    for (int j = 0; j < 4; ++j)
      Ms[(size_t)(k0 + ty * 4 + i) * 4096 + h * 512 + d0 + tx * 4 + j] = acc[i][j];
}

// ---------------- vbias_h[d] = Wk[d, h64:]·bq[h64:]; raw + scaled ----------------
__global__ __launch_bounds__(256) void k_vbias(const float* __restrict__ Wk, const float* __restrict__ bq,
                                               const float* __restrict__ lnw, float* __restrict__ vb_raw,
                                               float* __restrict__ vb_s) {
  __shared__ float bqs[512];
  int t = threadIdx.x;
  bqs[t] = bq[t]; bqs[256 + t] = bq[256 + t];
  __syncthreads();
  int d = blockIdx.x * 256 + t;
  float vb[8] = {};
  const float4* wr = reinterpret_cast<const float4*>(Wk + (size_t)d * Dn);
#pragma unroll 8
  for (int c4 = 0; c4 < 128; ++c4) {
    float4 wv = wr[c4];
    int h = c4 >> 4;
    int c = c4 * 4;
    vb[h] += wv.x * bqs[c] + wv.y * bqs[c + 1] + wv.z * bqs[c + 2] + wv.w * bqs[c + 3];
  }
  float lw = lnw[d];
#pragma unroll
  for (int h = 0; h < 8; ++h) {
    vb_raw[h * 512 + d] = vb[h];
    vb_s[h * 512 + d] = kScale * lw * vb[h];
  }
}

// ---------------- fold: scale Ms in place by kScale*lnw[d]; avec/bvec ----------------
__global__ __launch_bounds__(256) void k_mfold(float* __restrict__ Ms, const float* __restrict__ Wq,
                                               const float* __restrict__ bk, const float* __restrict__ lnw,
                                               const float* __restrict__ lnb, float* __restrict__ avec,
                                               float* __restrict__ bvec) {
  __shared__ float lws[512], lbs[512], bks[512];
  int t = threadIdx.x;
  lws[t] = lnw[t]; lws[256 + t] = lnw[256 + t];
  lbs[t] = lnb[t]; lbs[256 + t] = lnb[256 + t];
  bks[t] = bk[t]; bks[256 + t] = bk[256 + t];
  __syncthreads();
  int g = blockIdx.x * 256 + t;
  int k = g >> 3, h = g & 7;
  float* mr = Ms + (size_t)k * 4096 + h * 512;
  float mlnb = 0.0f, mlnw = 0.0f;
  for (int d = 0; d < 512; d += 4) {
    float4 m4 = *reinterpret_cast<const float4*>(mr + d);
    mlnb += m4.x * lbs[d] + m4.y * lbs[d + 1] + m4.z * lbs[d + 2] + m4.w * lbs[d + 3];
    mlnw += m4.x * lws[d] + m4.y * lws[d + 1] + m4.z * lws[d + 2] + m4.w * lws[d + 3];
    float4 o4 = {m4.x * kScale * lws[d], m4.y * kScale * lws[d + 1],
                 m4.z * kScale * lws[d + 2], m4.w * kScale * lws[d + 3]};
    *reinterpret_cast<float4*>(mr + d) = o4;
  }
  float wqdot = 0.0f;
  const float* qr = Wq + (size_t)k * Dn + h * 64;
  for (int c = 0; c < 64; c += 4) {
    float4 q4 = *reinterpret_cast<const float4*>(qr + c);
    wqdot += q4.x * bks[h * 64 + c] + q4.y * bks[h * 64 + c + 1] +
             q4.z * bks[h * 64 + c + 2] + q4.w * bks[h * 64 + c + 3];
  }
  avec[h * 512 + k] = kScale * (mlnb + wqdot);
  bvec[h * 512 + k] = kScale * mlnw;
}

// ---------------- aconst/bconst scalars ----------------
__global__ __launch_bounds__(256) void k_consts(const float* __restrict__ vb_raw, const float* __restrict__ bq,
                                                const float* __restrict__ bk, const float* __restrict__ lnw,
                                                const float* __restrict__ lnb, float* __restrict__ aconst,
                                                float* __restrict__ bconst) {
  __shared__ float r1[256], r2[256], r3[256];
  int t = threadIdx.x;
  for (int h = 0; h < 8; ++h) {
    float p1 = 0.0f, p2 = 0.0f, p3 = 0.0f;
    for (int d = t; d < 512; d += 256) {
      float vr = vb_raw[h * 512 + d];
      p1 += lnb[d] * vr;
      p2 += lnw[d] * vr;
    }
    if (t < 64) p3 = bq[h * 64 + t] * bk[h * 64 + t];
    r1[t] = p1; r2[t] = p2; r3[t] = p3;
    __syncthreads();
    for (int s = 128; s > 0; s >>= 1) {
      if (t < s) { r1[t] += r1[t + s]; r2[t] += r2[t + s]; r3[t] += r3[t + s]; }
      __syncthreads();
    }
    if (t == 0) {
      aconst[h] = kScale * (r1[0] + r3[0]);
      bconst[h] = kScale * r2[0];
    }
    __syncthreads();
  }
}

// ---------------- bcih[n] = bc·Wih[n,:] + bih[n] ----------------
__global__ __launch_bounds__(256) void k_bcih(const float* __restrict__ bc, const float* __restrict__ Wih,
                                              const float* __restrict__ bih, float* __restrict__ bcih) {
  __shared__ float bcs[512];
  int t = threadIdx.x;
  bcs[t] = bc[t]; bcs[256 + t] = bc[256 + t];
  __syncthreads();
  int n = blockIdx.x * 256 + t;
  const float4* wr = reinterpret_cast<const float4*>(Wih + (size_t)n * Dn);
  float a = 0.0f;
#pragma unroll 8
  for (int c4 = 0; c4 < 128; ++c4) {
    float4 wv = wr[c4];
    int c = c4 * 4;
    a += wv.x * bcs[c] + wv.y * bcs[c + 1] + wv.z * bcs[c + 2] + wv.w * bcs[c + 3];
  }
  bcih[n] = a + bih[n];
}

// ---------------- qkt = sln @ Ms + vb_s, remapped to [b,hi,d] ----------------
__global__ __launch_bounds__(256) void k_qu(const float* __restrict__ sln, const float* __restrict__ Ms,
                                            const float* __restrict__ vb_s, float* __restrict__ qkt) {
  __shared__ float as_[64][17];
  __shared__ float ws_[16][65];
  int m0 = blockIdx.y * 64, n0 = blockIdx.x * 64;
  int t = threadIdx.x, tx = t & 15, ty = t >> 4;
  float acc[4][4] = {};
  for (int k0 = 0; k0 < 512; k0 += 16) {
#pragma unroll
    for (int e = 0; e < 4; ++e) {
      int idx = t + e * 256;
      int r = idx >> 4, c = idx & 15;
      as_[r][c] = sln[(size_t)(m0 + r) * Dn + k0 + c];
    }
#pragma unroll
    for (int e = 0; e < 4; ++e) {
      int idx = t + e * 256;
      int r = idx >> 6, c = idx & 63;
      ws_[r][c] = Ms[(size_t)(k0 + r) * 4096 + n0 + c];
    }
    __syncthreads();
#pragma unroll
    for (int kc = 0; kc < 16; ++kc) {
      float av[4], wv[4];
#pragma unroll
      for (int i = 0; i < 4; ++i) av[i] = as_[ty * 4 + i][kc];
#pragma unroll
      for (int j = 0; j < 4; ++j) wv[j] = ws_[kc][tx * 4 + j];
#pragma unroll
      for (int i = 0; i < 4; ++i)
#pragma unroll
        for (int j = 0; j < 4; ++j) acc[i][j] += av[i] * wv[j];
    }
    __syncthreads();
  }
#pragma unroll
  for (int i = 0; i < 4; ++i)
#pragma unroll
    for (int j = 0; j < 4; ++j) {
      int m = m0 + ty * 4 + i, n = n0 + tx * 4 + j;
      int bb = m >> 4, isl = m & 15, h = n >> 9, d = n & 511;
      qkt[((size_t)bb * HIn + h * 16 + isl) * Dn + d] = acc[i][j] + vb_s[n];
    }
}

// ---------------- alpha/beta = sln·avec_h + aconst_h ----------------
__global__ void k_ab(const float* __restrict__ sln, const float* __restrict__ avec,
                     const float* __restrict__ bvec, const float* __restrict__ aconst,
                     const float* __restrict__ bconst, float* __restrict__ alpha,
                     float* __restrict__ beta) {
  int g = blockIdx.x;           // b*128 + hi
  int hi = g & 127, b = g >> 7;
  int h = hi >> 4, i = hi & 15;
  int lane = threadIdx.x;
  const float4* sp = reinterpret_cast<const float4*>(sln + (size_t)(b * NSn + i) * Dn) + lane * 2;
  const float4* ap = reinterpret_cast<const float4*>(avec + h * 512) + lane * 2;
  const float4* bp = reinterpret_cast<const float4*>(bvec + h * 512) + lane * 2;
  float4 s0 = sp[0], s1 = sp[1], a0 = ap[0], a1 = ap[1], b0 = bp[0], b1 = bp[1];
  float pa = s0.x*a0.x + s0.y*a0.y + s0.z*a0.z + s0.w*a0.w + s1.x*a1.x + s1.y*a1.y + s1.z*a1.z + s1.w*a1.w;
  float pb = s0.x*b0.x + s0.y*b0.y + s0.z*b0.z + s0.w*b0.w + s1.x*b1.x + s1.y*b1.y + s1.z*b1.z + s1.w*b1.w;
  pa = wred(pa); pb = wred(pb);
  if (lane == 0) {
    alpha[g] = pa + aconst[h];
    beta[g] = pb + bconst[h];
  }
}

// ---------------- dots GEMM + softmax over slots + EPS + partial sums ----------------
__global__ __launch_bounds__(256) void k_dots(const float* __restrict__ in, const float* __restrict__ qkt,
                                              const float* __restrict__ alpha, const float* __restrict__ beta,
                                              const float* __restrict__ mu, const float* __restrict__ rsig,
                                              float* __restrict__ A, float* __restrict__ Spart,
                                              float* __restrict__ c1part) {
  int b = blockIdx.y, jt = blockIdx.x, j0 = jt * 128;
  __shared__ __align__(16) float xs[16][132];
  __shared__ __align__(16) float us[16][132];
  __shared__ float sm[64][132];
  __shared__ float rsL[128], muL[128], aL[128], bL[128];
  int t = threadIdx.x, tx = t & 15, ty = t >> 4;
  float acc[8][8] = {};
  const size_t inbase = ((size_t)b * Nn + j0) * Dn;
  const size_t ubase = (size_t)b * HIn * Dn;
  for (int k0 = 0; k0 < Dn; k0 += 16) {
#pragma unroll
    for (int e = 0; e < 8; ++e) {
      int idx = t + e * 256;
      int r = idx >> 4, c = idx & 15;
      xs[c][r] = in[inbase + (size_t)r * Dn + k0 + c];
    }
#pragma unroll
    for (int e = 0; e < 8; ++e) {
      int idx = t + e * 256;
      int r = idx >> 4, c = idx & 15;
      us[c][r] = qkt[ubase + (size_t)r * Dn + k0 + c];
    }
    __syncthreads();
#pragma unroll
    for (int kc = 0; kc < 16; ++kc) {
      float4 x0 = *reinterpret_cast<const float4*>(&xs[kc][ty * 8]);
      float4 x1 = *reinterpret_cast<const float4*>(&xs[kc][ty * 8 + 4]);
      float4 u0 = *reinterpret_cast<const float4*>(&us[kc][tx * 8]);
      float4 u1 = *reinterpret_cast<const float4*>(&us[kc][tx * 8 + 4]);
      float xv[8] = {x0.x, x0.y, x0.z, x0.w, x1.x, x1.y, x1.z, x1.w};
      float uv[8] = {u0.x, u0.y, u0.z, u0.w, u1.x, u1.y, u1.z, u1.w};
#pragma unroll
      for (int a_ = 0; a_ < 8; ++a_)
#pragma unroll
        for (int b_ = 0; b_ < 8; ++b_) acc[a_][b_] += xv[a_] * uv[b_];
    }
    __syncthreads();
  }
  if (t < 128) {
    rsL[t] = rsig[(size_t)b * Nn + j0 + t];
    muL[t] = mu[(size_t)b * Nn + j0 + t];
    aL[t] = alpha[b * HIn + t];
    bL[t] = beta[b * HIn + t];
  }
  for (int half = 0; half < 2; ++half) {
    __syncthreads();
    if ((ty >> 3) == half) {
#pragma unroll
      for (int ji = 0; ji < 8; ++ji) {
        int jl = (ty & 7) * 8 + ji;
        int jg = half * 64 + jl;
        float rs = rsL[jg], mr = muL[jg] * rs;
#pragma unroll
        for (int ui = 0; ui < 8; ++ui) {
          int hi = tx * 8 + ui;
          sm[jl][hi] = acc[ji][ui] * rs + aL[hi] - mr * bL[hi];
        }
      }
    }
    __syncthreads();
    for (int task = t; task < 512; task += 256) {
      int j = task & 63, h = task >> 6;
      float* p = &sm[j][h * 16];
      float mx = p[0];
#pragma unroll
      for (int i = 1; i < 16; ++i) mx = fmaxf(mx, p[i]);
      float e[16];
      float ssum = 0.0f;
#pragma unroll
      for (int i = 0; i < 16; ++i) { e[i] = expf(p[i] - mx); ssum += e[i]; }
      float inv = 1.0f / ssum;
#pragma unroll
      for (int i = 0; i < 16; ++i) p[i] = e[i] * inv + kEps;
    }
    __syncthreads();
    if (t < 128) {
      float ss = 0.0f, cc = 0.0f;
#pragma unroll
      for (int j = 0; j < 64; ++j) {
        float a = sm[j][t];
        ss += a;
        cc += a * muL[half * 64 + j] * rsL[half * 64 + j];
      }
      int sub = (b * 64 + jt * 2 + half) * HIn + t;
      Spart[sub] = ss;
      c1part[sub] = cc;
    }
    for (int idx = t; idx < 8192; idx += 256) {
      int hi = idx >> 6, j = idx & 63;
      A[(size_t)(b * HIn + hi) * Nn + j0 + half * 64 + j] = sm[j][hi] * rsL[half * 64 + j];
    }
  }
}

// ---------------- AX = A @ X  (K-split x4) ----------------
__global__ __launch_bounds__(256) void k_ax(const float* __restrict__ Abuf, const float* __restrict__ in,
                                            float* __restrict__ AXp) {
  int d0 = blockIdx.x * 128;
  int kp = blockIdx.y;
  int b = blockIdx.z;
  __shared__ __align__(16) float as_[16][132];
  __shared__ __align__(16) float xs_[16][132];
  int t = threadIdx.x, tx = t & 15, ty = t >> 4;
  float acc[8][8] = {};
  for (int k0 = kp * 1024; k0 < kp * 1024 + 1024; k0 += 16) {
#pragma unroll
    for (int e = 0; e < 8; ++e) {
      int idx = t + e * 256;
      int r = idx >> 4, c = idx & 15;
      as_[c][r] = Abuf[(size_t)(b * HIn + r) * Nn + k0 + c];
    }
#pragma unroll
    for (int e = 0; e < 8; ++e) {
      int idx = t + e * 256;
      int kc = idx >> 7, dd = idx & 127;
      xs_[kc][dd] = in[((size_t)b * Nn + k0 + kc) * Dn + d0 + dd];
    }
    __syncthreads();
#pragma unroll
    for (int kc = 0; kc < 16; ++kc) {
      float4 a0 = *reinterpret_cast<const float4*>(&as_[kc][ty * 8]);
      float4 a1 = *reinterpret_cast<const float4*>(&as_[kc][ty * 8 + 4]);
      float4 x0 = *reinterpret_cast<const float4*>(&xs_[kc][tx * 8]);
      float4 x1 = *reinterpret_cast<const float4*>(&xs_[kc][tx * 8 + 4]);
      float av[8] = {a0.x, a0.y, a0.z, a0.w, a1.x, a1.y, a1.z, a1.w};
      float xv[8] = {x0.x, x0.y, x0.z, x0.w, x1.x, x1.y, x1.z, x1.w};
#pragma unroll
      for (int u = 0; u < 8; ++u)
#pragma unroll
        for (int v = 0; v < 8; ++v) acc[u][v] += av[u] * xv[v];
    }
    __syncthreads();
  }
#pragma unroll
  for (int u = 0; u < 8; ++u)
#pragma unroll
    for (int v = 0; v < 8; ++v)
      AXp[(((size_t)kp * Bn + b) * HIn + ty * 8 + u) * Dn + d0 + tx * 8 + v] = acc[u][v];
}

// ---------------- upd = ((w*(G-c1)/S + b) @ Wv_h) + bv, S/c1 reduced inline ----------------
__global__ __launch_bounds__(256) void k_updS(const float* __restrict__ AXp, const float* __restrict__ Spart,
                                              const float* __restrict__ c1part, const float* __restrict__ lnw,
                                              const float* __restrict__ lnb, const float* __restrict__ Wv,
                                              const float* __restrict__ bv, float* __restrict__ upd) {
  int b = blockIdx.y, hi = blockIdx.x, h = hi >> 4, i = hi & 15;
  __shared__ float vx[512];
  __shared__ float red[256];
  __shared__ float sSC[2];
  int t = threadIdx.x;
  if (t < 64) {
    float vs = Spart[(size_t)(b * 64 + t) * HIn + hi];
    float vc = c1part[(size_t)(b * 64 + t) * HIn + hi];
    vs = wred(vs); vc = wred(vc);
    if (t == 0) { sSC[0] = vs; sSC[1] = vc; }
  }
  __syncthreads();
  float c1v = sSC[1];
  float invS = 1.0f / sSC[0];
  for (int d = t; d < Dn; d += 256) {
    float G = AXp[((size_t)(0 * Bn + b) * HIn + hi) * Dn + d]
            + AXp[((size_t)(1 * Bn + b) * HIn + hi) * Dn + d]
            + AXp[((size_t)(2 * Bn + b) * HIn + hi) * Dn + d]
            + AXp[((size_t)(3 * Bn + b) * HIn + hi) * Dn + d];
    vx[d] = lnw[d] * (G - c1v) * invS + lnb[d];
  }
  __syncthreads();
  int cc = t & 63, qd = t >> 6;
  float p = 0.0f;
  for (int d = qd * 128; d < qd * 128 + 128; ++d) p += vx[d] * Wv[(size_t)d * Dn + h * 64 + cc];
  red[t] = p;
  __syncthreads();
  if (qd == 0) {
    float v = red[cc] + red[64 + cc] + red[128 + cc] + red[192 + cc] + bv[h * 64 + cc];
    upd[(size_t)(b * NSn + i) * Dn + h * 64 + cc] = v;
  }
}

// ---------------- dual GEMM: z=0: gi = upd@T1 + bcih ; z=1: gh = slots@Whh^T + bhh ----------------
__global__ __launch_bounds__(256) void k_gg(const float* __restrict__ upd, const float* __restrict__ T1,
                                            const float* __restrict__ bcih, const float* __restrict__ slots,
                                            const float* __restrict__ Whh, const float* __restrict__ bhh,
                                            float* __restrict__ gi, float* __restrict__ gh) {
  bool z = (blockIdx.z == 1);
  const float* A = z ? slots : upd;
  const float* W = z ? Whh : T1;
  const float* bias = z ? bhh : bcih;
  float* out = z ? gh : gi;
  __shared__ float as_[64][17];
  __shared__ float ws_[16][65];
  int m0 = blockIdx.y * 64, n0 = blockIdx.x * 64;
  int t = threadIdx.x, tx = t & 15, ty = t >> 4;
  float acc[4][4] = {};
  for (int k0 = 0; k0 < 512; k0 += 16) {
#pragma unroll
    for (int e = 0; e < 4; ++e) {
      int idx = t + e * 256;
      int r = idx >> 4, c = idx & 15;
      as_[r][c] = A[(size_t)(m0 + r) * 512 + k0 + c];
    }
    if (!z) {
#pragma unroll
      for (int e = 0; e < 4; ++e) {
        int idx = t + e * 256;
        int r = idx >> 6, c = idx & 63;
        ws_[r][c] = W[(size_t)(k0 + r) * 1536 + n0 + c];
      }
    } else {
#pragma unroll
      for (int e = 0; e < 4; ++e) {
        int idx = t + e * 256;
        int r = idx >> 4, c = idx & 15;
        ws_[c][r] = W[(size_t)(n0 + r) * 512 + k0 + c];
      }
    }
    __syncthreads();
#pragma unroll
    for (int kc = 0; kc < 16; ++kc) {
      float av[4], wv[4];
#pragma unroll
      for (int i = 0; i < 4; ++i) av[i] = as_[ty * 4 + i][kc];
#pragma unroll
      for (int j = 0; j < 4; ++j) wv[j] = ws_[kc][tx * 4 + j];
#pragma unroll
      for (int i = 0; i < 4; ++i)
#pragma unroll
        for (int j = 0; j < 4; ++j) acc[i][j] += av[i] * wv[j];
    }
    __syncthreads();
  }
#pragma unroll
  for (int i = 0; i < 4; ++i)
#pragma unroll
    for (int j = 0; j < 4; ++j) {
      int m = m0 + ty * 4 + i, n = n0 + tx * 4 + j;
      out[(size_t)m * 1536 + n] = acc[i][j] + bias[n];
    }
}

// ---------------- GRU pointwise + LN_ff fused ----------------
__global__ __launch_bounds__(256) void k_gruln(const float* __restrict__ gi, const float* __restrict__ gh,
                                               float* __restrict__ slots, float* __restrict__ slnff,
                                               const float* __restrict__ lnffw, const float* __restrict__ lnffb) {
  int r = blockIdx.x, t = threadIdx.x;
  __shared__ float red[8];
  float sn[2];
#pragma unroll
  for (int j = 0; j < 2; ++j) {
    int c = j * 256 + t;
    float gir = gi[(size_t)r * 1536 + c];
    float giz = gi[(size_t)r * 1536 + 512 + c];
    float gin = gi[(size_t)r * 1536 + 1024 + c];
    float ghr = gh[(size_t)r * 1536 + c];
    float ghz = gh[(size_t)r * 1536 + 512 + c];
    float ghn = gh[(size_t)r * 1536 + 1024 + c];
    float rg = 1.0f / (1.0f + expf(-(gir + ghr)));
    float zg = 1.0f / (1.0f + expf(-(giz + ghz)));
    float ng = tanhf(gin + rg * ghn);
    sn[j] = (1.0f - zg) * ng + zg * slots[(size_t)r * Dn + c];
  }
  float s = sn[0] + sn[1], q = sn[0] * sn[0] + sn[1] * sn[1];
  s = wred(s); q = wred(q);
  if ((t & 63) == 0) { red[t >> 6] = s; red[4 + (t >> 6)] = q; }
  __syncthreads();
  float S = red[0] + red[1] + red[2] + red[3];
  float Q = red[4] + red[5] + red[6] + red[7];
  float m = S * (1.0f / 512.0f);
  float rs = 1.0f / sqrtf(Q * (1.0f / 512.0f) - m * m + 1e-5f);
#pragma unroll
  for (int j = 0; j < 2; ++j) {
    int c = j * 256 + t;
    slots[(size_t)r * Dn + c] = sn[j];
    slnff[(size_t)r * Dn + c] = (sn[j] - m) * rs * lnffw[c] + lnffb[c];
  }
}

// ---------------- keep gate (zero dropped slots in place) ----------------
__global__ void k_keepscale(const float* __restrict__ Wkeep, const float* __restrict__ gk,
                            float* __restrict__ slots) {
  int g = blockIdx.x;
  int lane = threadIdx.x;
  float4* sp = reinterpret_cast<float4*>(slots + (size_t)g * Dn) + lane * 2;
  float4 s0 = sp[0], s1 = sp[1];
  float sv[8] = {s0.x, s0.y, s0.z, s0.w, s1.x, s1.y, s1.z, s1.w};
  double d0 = 0.0, d1 = 0.0;
#pragma unroll
  for (int e = 0; e < 8; ++e) {
    int d = lane * 8 + e;
    d0 += (double)sv[e] * (double)Wkeep[d * 2];
    d1 += (double)sv[e] * (double)Wkeep[d * 2 + 1];
  }
  d0 = wredd(d0);
  d1 = wredd(d1);
  int keepi = 0;
  if (lane == 0) keepi = ((d1 + (double)gk[g * 2 + 1]) > (d0 + (double)gk[g * 2])) ? 1 : 0;
  keepi = __shfl(keepi, 0);
  if (!keepi) {
    float4 z = {0.0f, 0.0f, 0.0f, 0.0f};
    sp[0] = z;
    sp[1] = z;
  }
}

// ---------------- per-slot scalars for route decomposition ----------------
__global__ void k_slotscalars(const float* __restrict__ slots, const float* __restrict__ lnw,
                              const float* __restrict__ lnb, double* __restrict__ swd,
                              double* __restrict__ sbd) {
  int g = blockIdx.x, lane = threadIdx.x;
  const float4* sp = reinterpret_cast<const float4*>(slots + (size_t)g * Dn) + lane * 2;
  const float4* wp = reinterpret_cast<const float4*>(lnw) + lane * 2;
  const float4* bp = reinterpret_cast<const float4*>(lnb) + lane * 2;
  float4 s0 = sp[0], s1 = sp[1], w0 = wp[0], w1 = wp[1], b0 = bp[0], b1 = bp[1];
  double pw = (double)s0.x * w0.x + (double)s0.y * w0.y + (double)s0.z * w0.z + (double)s0.w * w0.w +
              (double)s1.x * w1.x + (double)s1.y * w1.y + (double)s1.z * w1.z + (double)s1.w * w1.w;
  double pb = (double)s0.x * b0.x + (double)s0.y * b0.y + (double)s0.z * b0.z + (double)s0.w * b0.w +
              (double)s1.x * b1.x + (double)s1.y * b1.y + (double)s1.z * b1.z + (double)s1.w * b1.w;
  pw = wredd(pw);
  pb = wredd(pb);
  if (lane == 0) { swd[g] = pw; sbd[g] = pb; }
}

// ---------------- hard route + gather output (tiled mini-GEMM) ----------------
__global__ __launch_bounds__(256) void k_route_out(const float* __restrict__ in, const float* __restrict__ slots,
                                                   const float* __restrict__ lnw, const double* __restrict__ swd,
                                                   const double* __restrict__ sbd, const float* __restrict__ mu,
                                                   const float* __restrict__ rsig,
                                                   const float* __restrict__ g_route, float* __restrict__ out) {
  int b = blockIdx.y, j0 = blockIdx.x * 128;
  __shared__ __align__(16) float sl[16 * 516];
  __shared__ __align__(16) float lw[512];
  __shared__ __align__(16) float xs[16][132];
  __shared__ double lgd[128][17];
  __shared__ int besti[128];
  int t = threadIdx.x, tx = t & 15, ty = t >> 4;

  for (int idx = t; idx < 2048; idx += 256) {
    int i = idx >> 7, c = idx & 127;
    *reinterpret_cast<float4*>(&sl[i * 516 + c * 4]) =
        *reinterpret_cast<const float4*>(&slots[(size_t)(b * NSn + i) * Dn + c * 4]);
  }
  if (t < 128)
    *reinterpret_cast<float4*>(&lw[t * 4]) = *reinterpret_cast<const float4*>(&lnw[t * 4]);

  float acc[8] = {};
  double accd[8] = {};
  const size_t inbase = ((size_t)b * Nn + j0) * Dn;
  __syncthreads();

  for (int k0 = 0; k0 < Dn; k0 += 16) {
    float pre[8];
#pragma unroll
    for (int e = 0; e < 8; ++e) {
      int idx = t + e * 256;
      int r = idx >> 4, c = idx & 15;
      pre[e] = in[inbase + (size_t)r * Dn + k0 + c];
    }
    __syncthreads();
#pragma unroll
    for (int e = 0; e < 8; ++e) {
      int idx = t + e * 256;
      int r = idx >> 4, c = idx & 15;
      xs[c][r] = pre[e] * lw[k0 + c];
    }
    __syncthreads();
#pragma unroll
    for (int kc = 0; kc < 16; ++kc) {
      float sv = sl[tx * 516 + k0 + kc];
      float4 x0 = *reinterpret_cast<const float4*>(&xs[kc][ty * 8]);
      float4 x1 = *reinterpret_cast<const float4*>(&xs[kc][ty * 8 + 4]);
      acc[0] += x0.x * sv; acc[1] += x0.y * sv; acc[2] += x0.z * sv; acc[3] += x0.w * sv;
      acc[4] += x1.x * sv; acc[5] += x1.y * sv; acc[6] += x1.z * sv; acc[7] += x1.w * sv;
    }
    if ((k0 & 127) == 112) {
#pragma unroll
      for (int e = 0; e < 8; ++e) { accd[e] += (double)acc[e]; acc[e] = 0.0f; }
    }
  }

  double sw_i = swd[b * NSn + tx], sb_i = sbd[b * NSn + tx];
#pragma unroll
  for (int r = 0; r < 8; ++r) {
    int j = ty * 8 + r;
    double rsj = (double)rsig[(size_t)b * Nn + j0 + j];
    double muj = (double)mu[(size_t)b * Nn + j0 + j];
    double g = (double)g_route[((size_t)b * NSn + tx) * Nn + j0 + j];
    lgd[j][tx] = (double)kScale * (rsj * accd[r] + sb_i - muj * rsj * sw_i) + g;
  }
  __syncthreads();
  if (t < 128) {
    double best = lgd[t][0];
    int bi = 0;
#pragma unroll
    for (int i = 1; i < 16; ++i) {
      double v = lgd[t][i];
      if (v > best) { best = v; bi = i; }
    }
    besti[t] = bi;
  }
  __syncthreads();
  for (int idx = t; idx < 128 * 128; idx += 256) {
    int j = idx >> 7, c = idx & 127;
    *reinterpret_cast<float4*>(&out[inbase + (size_t)j * Dn + c * 4]) =
        *reinterpret_cast<const float4*>(&sl[besti[j] * 516 + c * 4]);
  }
}

extern "C" void kernel_launch(void* const* d_in, const int* in_sizes, int n_in,
                              void* d_out, int out_size, void* d_ws, size_t ws_size,
                              hipStream_t stream) {
  (void)in_sizes; (void)n_in; (void)out_size; (void)ws_size;
  const float* in = (const float*)d_in[0];
  const float* slots_mu = (const float*)d_in[1];
  const float* slots_ls = (const float*)d_in[2];
  const float* ln_in_w = (const float*)d_in[3];
  const float* ln_in_b = (const float*)d_in[4];
  const float* ln_s_w = (const float*)d_in[5];
  const float* ln_s_b = (const float*)d_in[6];
  const float* ln_ff_w = (const float*)d_in[7];
  const float* ln_ff_b = (const float*)d_in[8];
  const float* Wq = (const float*)d_in[9];
  const float* bq = (const float*)d_in[10];
  const float* Wk = (const float*)d_in[11];
  const float* bk = (const float*)d_in[12];
  const float* Wv = (const float*)d_in[13];
  const float* bv = (const float*)d_in[14];
  const float* Wc = (const float*)d_in[15];
  const float* bc = (const float*)d_in[16];
  const float* Wih = (const float*)d_in[17];
  const float* bih = (const float*)d_in[18];
  const float* Whh = (const float*)d_in[19];
  const float* bhh = (const float*)d_in[20];
  const float* W1 = (const float*)d_in[21];
  const float* b1 = (const float*)d_in[22];
  const float* W2 = (const float*)d_in[23];
  const float* b2 = (const float*)d_in[24];
  const float* Wkeep = (const float*)d_in[25];
  const float* noise = (const float*)d_in[26];
  const float* g_keep = (const float*)d_in[27];
  const float* g_route = (const float*)d_in[28];
  float* out = (float*)d_out;

  char* wptr = (char*)d_ws;
  auto alloc = [&](size_t bytes) {
    char* p = wptr;
    wptr += (bytes + 255) & ~(size_t)255;
    return p;
  };
  float* mu = (float*)alloc((size_t)Bn * Nn * 4);
  float* rsig = (float*)alloc((size_t)Bn * Nn * 4);
  float* slots = (float*)alloc((size_t)Bn * NSn * Dn * 4);
  float* sln = (float*)alloc((size_t)Bn * NSn * Dn * 4);
  float* qkt = (float*)alloc((size_t)Bn * HIn * Dn * 4);
  float* alpha = (float*)alloc((size_t)Bn * HIn * 4);
  float* beta = (float*)alloc((size_t)Bn * HIn * 4);
  float* Abuf = (float*)alloc((size_t)Bn * HIn * Nn * 4);
  float* Spart = (float*)alloc((size_t)Bn * 64 * HIn * 4);
  float* c1part = (float*)alloc((size_t)Bn * 64 * HIn * 4);
  float* AXp = (float*)alloc((size_t)4 * Bn * HIn * Dn * 4);
  float* updb = (float*)alloc((size_t)Bn * NSn * Dn * 4);
  float* gibuf = (float*)alloc((size_t)Bn * NSn * 1536 * 4);
  float* ghbuf = (float*)alloc((size_t)Bn * NSn * 1536 * 4);
  float* hbuf = (float*)alloc((size_t)Bn * NSn * 2048 * 4);
  float* T1 = (float*)alloc((size_t)Dn * 1536 * 4);
  float* bcih = (float*)alloc((size_t)1536 * 4);
  float* Ms = (float*)alloc((size_t)Dn * 4096 * 4);
  float* vb_raw = (float*)alloc((size_t)4096 * 4);
  float* vb_s = (float*)alloc((size_t)4096 * 4);
  float* avec = (float*)alloc((size_t)4096 * 4);
  float* bvec = (float*)alloc((size_t)4096 * 4);
  float* aconst = (float*)alloc((size_t)8 * 4);
  float* bconst = (float*)alloc((size_t)8 * 4);
  double* swd = (double*)alloc((size_t)Bn * NSn * 8);
  double* sbd = (double*)alloc((size_t)Bn * NSn * 8);

  // prologue
  k_rowstats<<<Bn * Nn / 4, 256, 0, stream>>>(in, mu, rsig);
  k_slots_init<<<Bn * NSn, 256, 0, stream>>>(slots_mu, slots_ls, noise, slots);
  k_gemm_sm<true, false, false><<<dim3(24, 8), 256, 0, stream>>>(Wc, Wih, nullptr, T1, 1536, 512);
  k_bcih<<<6, 256, 0, stream>>>(bc, Wih, bih, bcih);
  k_mh<<<dim3(8, 8, 8), 256, 0, stream>>>(Wq, Wk, Ms);
  k_vbias<<<2, 256, 0, stream>>>(Wk, bq, ln_in_w, vb_raw, vb_s);
  k_mfold<<<16, 256, 0, stream>>>(Ms, Wq, bk, ln_in_w, ln_in_b, avec, bvec);
  k_consts<<<1, 256, 0, stream>>>(vb_raw, bq, bk, ln_in_w, ln_in_b, aconst, bconst);
  k_ln_rows<<<Bn * NSn, 256, 0, stream>>>(slots, ln_s_w, ln_s_b, sln);

  for (int it = 0; it < 3; ++it) {
    k_qu<<<dim3(64, 8), 256, 0, stream>>>(sln, Ms, vb_s, qkt);
    k_ab<<<Bn * HIn, 64, 0, stream>>>(sln, avec, bvec, aconst, bconst, alpha, beta);
    k_dots<<<dim3(Nn / 128, Bn), 256, 0, stream>>>(in, qkt, alpha, beta, mu, rsig, Abuf, Spart, c1part);
    k_ax<<<dim3(4, 4, Bn), 256, 0, stream>>>(Abuf, in, AXp);
    k_updS<<<dim3(HIn, Bn), 256, 0, stream>>>(AXp, Spart, c1part, ln_in_w, ln_in_b, Wv, bv, updb);
    k_gg<<<dim3(24, 8, 2), 256, 0, stream>>>(updb, T1, bcih, slots, Whh, bhh, gibuf, ghbuf);
    k_gruln<<<Bn * NSn, 256, 0, stream>>>(gibuf, ghbuf, slots, sln, ln_ff_w, ln_ff_b);
    k_gemm_sm<false, true, false><<<dim3(32, 8), 256, 0, stream>>>(sln, W1, b1, hbuf, 2048, 512);
    k_gemm_sm<false, false, true><<<dim3(8, 8), 256, 0, stream>>>(hbuf, W2, b2, slots, 512, 2048);
    k_ln_rows<<<Bn * NSn, 256, 0, stream>>>(slots, ln_s_w, ln_s_b, sln);
  }

  k_keepscale<<<Bn * NSn, 64, 0, stream>>>(Wkeep, g_keep, slots);
  k_slotscalars<<<Bn * NSn, 64, 0, stream>>>(slots, ln_in_w, ln_in_b, swd, sbd);
  k_route_out<<<dim3(Nn / 128, Bn), 256, 0, stream>>>(in, slots, ln_in_w, swd, sbd, mu, rsig, g_route, out);
}

// Round 5
// 2710.890 us; speedup vs baseline: 1.3155x; 1.1144x over previous
//
#include <hip/hip_runtime.h>
#include <hip/hip_bf16.h>
#include <math.h>

constexpr int Bn = 32, Nn = 4096, Dn = 512, NSn = 16, HIn = 128;
constexpr float kScale = 0.04419417382415922f; // 512^-0.5
constexpr float kEps = 1e-8f;

typedef __attribute__((ext_vector_type(8))) short short8;
typedef __attribute__((ext_vector_type(4))) float f32x4;

__device__ __forceinline__ float wred(float v) {
#pragma unroll
  for (int m = 32; m > 0; m >>= 1) v += __shfl_xor(v, m);
  return v;
}
__device__ __forceinline__ double wredd(double v) {
#pragma unroll
  for (int m = 32; m > 0; m >>= 1) v += __shfl_xor(v, m);
  return v;
}

// ---- bf16 3-way split helpers (RNE) ----
__device__ __forceinline__ unsigned short f2bf(float x) {
  unsigned u = __float_as_uint(x);
  unsigned r = (u + 0x7fffu + ((u >> 16) & 1u)) >> 16;
  return (unsigned short)r;
}
__device__ __forceinline__ float bf2f(unsigned short h) {
  return __uint_as_float(((unsigned)h) << 16);
}
__device__ __forceinline__ unsigned pack3(float x0, float x1, unsigned& mo, unsigned& lo) {
  unsigned short h0 = f2bf(x0); float r0 = x0 - bf2f(h0);
  unsigned short m0 = f2bf(r0); float q0 = r0 - bf2f(m0);
  unsigned short l0 = f2bf(q0);
  unsigned short h1 = f2bf(x1); float r1 = x1 - bf2f(h1);
  unsigned short m1 = f2bf(r1); float q1 = r1 - bf2f(m1);
  unsigned short l1 = f2bf(q1);
  mo = (unsigned)m0 | ((unsigned)m1 << 16);
  lo = (unsigned)l0 | ((unsigned)l1 << 16);
  return (unsigned)h0 | ((unsigned)h1 << 16);
}

// ---------------- per-row LN stats of inputs ----------------
__global__ __launch_bounds__(256) void k_rowstats(const float* __restrict__ in,
                                                  float* __restrict__ mu, float* __restrict__ rsig) {
  int row = blockIdx.x * 4 + (threadIdx.x >> 6);
  int lane = threadIdx.x & 63;
  const float4* p = reinterpret_cast<const float4*>(in + (size_t)row * Dn) + lane * 2;
  float4 a = p[0], b = p[1];
  float s = a.x + a.y + a.z + a.w + b.x + b.y + b.z + b.w;
  float q = a.x*a.x + a.y*a.y + a.z*a.z + a.w*a.w + b.x*b.x + b.y*b.y + b.z*b.z + b.w*b.w;
  s = wred(s); q = wred(q);
  if (lane == 0) {
    float m = s * (1.0f / 512.0f);
    float var = q * (1.0f / 512.0f) - m * m;
    mu[row] = m;
    rsig[row] = 1.0f / sqrtf(var + 1e-5f);
  }
}

// ---------------- slots init ----------------
__global__ __launch_bounds__(256) void k_slots_init(const float* __restrict__ smu, const float* __restrict__ sls,
                                                    const float* __restrict__ noise, float* __restrict__ slots) {
  int r = blockIdx.x;
  for (int d = threadIdx.x; d < Dn; d += 256)
    slots[(size_t)r * Dn + d] = smu[d] + expf(sls[d]) * noise[(size_t)r * Dn + d];
}

// ---------------- LN of [R,512] rows ----------------
__global__ __launch_bounds__(256) void k_ln_rows(const float* __restrict__ src, const float* __restrict__ w,
                                                 const float* __restrict__ b, float* __restrict__ dst) {
  int r = blockIdx.x;
  __shared__ float red[8];
  int t = threadIdx.x;
  float x0 = src[(size_t)r * Dn + t], x1 = src[(size_t)r * Dn + 256 + t];
  float s = x0 + x1, q = x0 * x0 + x1 * x1;
  s = wred(s); q = wred(q);
  if ((t & 63) == 0) { red[t >> 6] = s; red[4 + (t >> 6)] = q; }
  __syncthreads();
  float S = red[0] + red[1] + red[2] + red[3];
  float Q = red[4] + red[5] + red[6] + red[7];
  float m = S * (1.0f / 512.0f);
  float rs = 1.0f / sqrtf(Q * (1.0f / 512.0f) - m * m + 1e-5f);
  dst[(size_t)r * Dn + t] = (x0 - m) * rs * w[t] + b[t];
  dst[(size_t)r * Dn + 256 + t] = (x1 - m) * rs * w[256 + t] + b[256 + t];
}

// ---------------- small GEMM: out = act(A@W (+bias) (+out)), bias nullable ----------------
template <bool TRANS, bool RELU, bool ADD>
__global__ __launch_bounds__(256) void k_gemm_sm(const float* __restrict__ A, const float* __restrict__ W,
                                                 const float* __restrict__ bias, float* __restrict__ out,
                                                 int Nc, int K) {
  __shared__ float as_[64][17];
  __shared__ float ws_[16][65];
  int m0 = blockIdx.y * 64, n0 = blockIdx.x * 64;
  int t = threadIdx.x, tx = t & 15, ty = t >> 4;
  float acc[4][4] = {};
  for (int k0 = 0; k0 < K; k0 += 16) {
#pragma unroll
    for (int e = 0; e < 4; ++e) {
      int idx = t + e * 256;
      int r = idx >> 4, c = idx & 15;
      as_[r][c] = A[(size_t)(m0 + r) * K + k0 + c];
    }
#pragma unroll
    for (int e = 0; e < 4; ++e) {
      int idx = t + e * 256;
      if (!TRANS) {
        int r = idx >> 6, c = idx & 63;
        ws_[r][c] = W[(size_t)(k0 + r) * Nc + n0 + c];
      } else {
        int r = idx >> 4, c = idx & 15;
        ws_[c][r] = W[(size_t)(n0 + r) * K + k0 + c];
      }
    }
    __syncthreads();
#pragma unroll
    for (int kc = 0; kc < 16; ++kc) {
      float av[4], wv[4];
#pragma unroll
      for (int i = 0; i < 4; ++i) av[i] = as_[ty * 4 + i][kc];
#pragma unroll
      for (int j = 0; j < 4; ++j) wv[j] = ws_[kc][tx * 4 + j];
#pragma unroll
      for (int i = 0; i < 4; ++i)
#pragma unroll
        for (int j = 0; j < 4; ++j) acc[i][j] += av[i] * wv[j];
    }
    __syncthreads();
  }
#pragma unroll
  for (int i = 0; i < 4; ++i)
#pragma unroll
    for (int j = 0; j < 4; ++j) {
      int m = m0 + ty * 4 + i, n = n0 + tx * 4 + j;
      float v = acc[i][j] + (bias ? bias[n] : 0.0f);
      if (RELU) v = fmaxf(v, 0.0f);
      if (ADD) v += out[(size_t)m * Nc + n];
      out[(size_t)m * Nc + n] = v;
    }
}

// ---------------- M_h = Wq_h @ Wk_h^T per head (raw) -> Ms[k*4096 + h*512 + d] ----------------
__global__ __launch_bounds__(256) void k_mh(const float* __restrict__ Wq, const float* __restrict__ Wk,
                                            float* __restrict__ Ms) {
  int h = blockIdx.z, k0 = blockIdx.y * 64, d0 = blockIdx.x * 64;
  __shared__ float qa[64][65];
  __shared__ float ka[64][65];
  int t = threadIdx.x, tx = t & 15, ty = t >> 4;
#pragma unroll
  for (int e = 0; e < 16; ++e) {
    int idx = t + e * 256;
    int r = idx >> 6, c = idx & 63;
    qa[c][r] = Wq[(size_t)(k0 + r) * Dn + h * 64 + c];
    ka[c][r] = Wk[(size_t)(d0 + r) * Dn + h * 64 + c];
  }
  __syncthreads();
  float acc[4][4] = {};
#pragma unroll 4
  for (int c = 0; c < 64; ++c) {
    float av[4], bv[4];
#pragma unroll
    for (int i = 0; i < 4; ++i) av[i] = qa[c][ty * 4 + i];
#pragma unroll
    for (int j = 0; j < 4; ++j) bv[j] = ka[c][tx * 4 + j];
#pragma unroll
    for (int i = 0; i < 4; ++i)
#pragma unroll
      for (int j = 0; j < 4; ++j) acc[i][j] += av[i] * bv[j];
  }
#pragma unroll
  for (int i = 0; i < 4; ++i)
#pragma unroll
    for (int j = 0; j < 4; ++j)
      Ms[(size_t)(k0 + ty * 4 + i) * 4096 + h * 512 + d0 + tx * 4 + j] = acc[i][j];
}

// ---------------- vbias_h[d] = Wk[d, h64:]·bq[h64:]; raw + scaled ----------------
__global__ __launch_bounds__(256) void k_vbias(const float* __restrict__ Wk, const float* __restrict__ bq,
                                               const float* __restrict__ lnw, float* __restrict__ vb_raw,
                                               float* __restrict__ vb_s) {
  __shared__ float bqs[512];
  int t = threadIdx.x;
  bqs[t] = bq[t]; bqs[256 + t] = bq[256 + t];
  __syncthreads();
  int d = blockIdx.x * 256 + t;
  float vb[8] = {};
  const float4* wr = reinterpret_cast<const float4*>(Wk + (size_t)d * Dn);
#pragma unroll 8
  for (int c4 = 0; c4 < 128; ++c4) {
    float4 wv = wr[c4];
    int h = c4 >> 4;
    int c = c4 * 4;
    vb[h] += wv.x * bqs[c] + wv.y * bqs[c + 1] + wv.z * bqs[c + 2] + wv.w * bqs[c + 3];
  }
  float lw = lnw[d];
#pragma unroll
  for (int h = 0; h < 8; ++h) {
    vb_raw[h * 512 + d] = vb[h];
    vb_s[h * 512 + d] = kScale * lw * vb[h];
  }
}

// ---------------- fold: scale Ms in place by kScale*lnw[d]; avec/bvec ----------------
__global__ __launch_bounds__(256) void k_mfold(float* __restrict__ Ms, const float* __restrict__ Wq,
                                               const float* __restrict__ bk, const float* __restrict__ lnw,
                                               const float* __restrict__ lnb, float* __restrict__ avec,
                                               float* __restrict__ bvec) {
  __shared__ float lws[512], lbs[512], bks[512];
  int t = threadIdx.x;
  lws[t] = lnw[t]; lws[256 + t] = lnw[256 + t];
  lbs[t] = lnb[t]; lbs[256 + t] = lnb[256 + t];
  bks[t] = bk[t]; bks[256 + t] = bk[256 + t];
  __syncthreads();
  int g = blockIdx.x * 256 + t;
  int k = g >> 3, h = g & 7;
  float* mr = Ms + (size_t)k * 4096 + h * 512;
  float mlnb = 0.0f, mlnw = 0.0f;
  for (int d = 0; d < 512; d += 4) {
    float4 m4 = *reinterpret_cast<const float4*>(mr + d);
    mlnb += m4.x * lbs[d] + m4.y * lbs[d + 1] + m4.z * lbs[d + 2] + m4.w * lbs[d + 3];
    mlnw += m4.x * lws[d] + m4.y * lws[d + 1] + m4.z * lws[d + 2] + m4.w * lws[d + 3];
    float4 o4 = {m4.x * kScale * lws[d], m4.y * kScale * lws[d + 1],
                 m4.z * kScale * lws[d + 2], m4.w * kScale * lws[d + 3]};
    *reinterpret_cast<float4*>(mr + d) = o4;
  }
  float wqdot = 0.0f;
  const float* qr = Wq + (size_t)k * Dn + h * 64;
  for (int c = 0; c < 64; c += 4) {
    float4 q4 = *reinterpret_cast<const float4*>(qr + c);
    wqdot += q4.x * bks[h * 64 + c] + q4.y * bks[h * 64 + c + 1] +
             q4.z * bks[h * 64 + c + 2] + q4.w * bks[h * 64 + c + 3];
  }
  avec[h * 512 + k] = kScale * (mlnb + wqdot);
  bvec[h * 512 + k] = kScale * mlnw;
}

// ---------------- aconst/bconst scalars ----------------
__global__ __launch_bounds__(256) void k_consts(const float* __restrict__ vb_raw, const float* __restrict__ bq,
                                                const float* __restrict__ bk, const float* __restrict__ lnw,
                                                const float* __restrict__ lnb, float* __restrict__ aconst,
                                                float* __restrict__ bconst) {
  __shared__ float r1[256], r2[256], r3[256];
  int t = threadIdx.x;
  for (int h = 0; h < 8; ++h) {
    float p1 = 0.0f, p2 = 0.0f, p3 = 0.0f;
    for (int d = t; d < 512; d += 256) {
      float vr = vb_raw[h * 512 + d];
      p1 += lnb[d] * vr;
      p2 += lnw[d] * vr;
    }
    if (t < 64) p3 = bq[h * 64 + t] * bk[h * 64 + t];
    r1[t] = p1; r2[t] = p2; r3[t] = p3;
    __syncthreads();
    for (int s = 128; s > 0; s >>= 1) {
      if (t < s) { r1[t] += r1[t + s]; r2[t] += r2[t + s]; r3[t] += r3[t + s]; }
      __syncthreads();
    }
    if (t == 0) {
      aconst[h] = kScale * (r1[0] + r3[0]);
      bconst[h] = kScale * r2[0];
    }
    __syncthreads();
  }
}

// ---------------- bcih[n] = bc·Wih[n,:] + bih[n] ----------------
__global__ __launch_bounds__(256) void k_bcih(const float* __restrict__ bc, const float* __restrict__ Wih,
                                              const float* __restrict__ bih, float* __restrict__ bcih) {
  __shared__ float bcs[512];
  int t = threadIdx.x;
  bcs[t] = bc[t]; bcs[256 + t] = bc[256 + t];
  __syncthreads();
  int n = blockIdx.x * 256 + t;
  const float4* wr = reinterpret_cast<const float4*>(Wih + (size_t)n * Dn);
  float a = 0.0f;
#pragma unroll 8
  for (int c4 = 0; c4 < 128; ++c4) {
    float4 wv = wr[c4];
    int c = c4 * 4;
    a += wv.x * bcs[c] + wv.y * bcs[c + 1] + wv.z * bcs[c + 2] + wv.w * bcs[c + 3];
  }
  bcih[n] = a + bih[n];
}

// ---------------- qkt = sln @ Ms + vb_s, remapped to [b,hi,d] ----------------
__global__ __launch_bounds__(256) void k_qu(const float* __restrict__ sln, const float* __restrict__ Ms,
                                            const float* __restrict__ vb_s, float* __restrict__ qkt) {
  __shared__ float as_[64][17];
  __shared__ float ws_[16][65];
  int m0 = blockIdx.y * 64, n0 = blockIdx.x * 64;
  int t = threadIdx.x, tx = t & 15, ty = t >> 4;
  float acc[4][4] = {};
  for (int k0 = 0; k0 < 512; k0 += 16) {
#pragma unroll
    for (int e = 0; e < 4; ++e) {
      int idx = t + e * 256;
      int r = idx >> 4, c = idx & 15;
      as_[r][c] = sln[(size_t)(m0 + r) * Dn + k0 + c];
    }
#pragma unroll
    for (int e = 0; e < 4; ++e) {
      int idx = t + e * 256;
      int r = idx >> 6, c = idx & 63;
      ws_[r][c] = Ms[(size_t)(k0 + r) * 4096 + n0 + c];
    }
    __syncthreads();
#pragma unroll
    for (int kc = 0; kc < 16; ++kc) {
      float av[4], wv[4];
#pragma unroll
      for (int i = 0; i < 4; ++i) av[i] = as_[ty * 4 + i][kc];
#pragma unroll
      for (int j = 0; j < 4; ++j) wv[j] = ws_[kc][tx * 4 + j];
#pragma unroll
      for (int i = 0; i < 4; ++i)
#pragma unroll
        for (int j = 0; j < 4; ++j) acc[i][j] += av[i] * wv[j];
    }
    __syncthreads();
  }
#pragma unroll
  for (int i = 0; i < 4; ++i)
#pragma unroll
    for (int j = 0; j < 4; ++j) {
      int m = m0 + ty * 4 + i, n = n0 + tx * 4 + j;
      int bb = m >> 4, isl = m & 15, h = n >> 9, d = n & 511;
      qkt[((size_t)bb * HIn + h * 16 + isl) * Dn + d] = acc[i][j] + vb_s[n];
    }
}

// ---------------- alpha/beta = sln·avec_h + aconst_h ----------------
__global__ void k_ab(const float* __restrict__ sln, const float* __restrict__ avec,
                     const float* __restrict__ bvec, const float* __restrict__ aconst,
                     const float* __restrict__ bconst, float* __restrict__ alpha,
                     float* __restrict__ beta) {
  int g = blockIdx.x;           // b*128 + hi
  int hi = g & 127, b = g >> 7;
  int h = hi >> 4, i = hi & 15;
  int lane = threadIdx.x;
  const float4* sp = reinterpret_cast<const float4*>(sln + (size_t)(b * NSn + i) * Dn) + lane * 2;
  const float4* ap = reinterpret_cast<const float4*>(avec + h * 512) + lane * 2;
  const float4* bp = reinterpret_cast<const float4*>(bvec + h * 512) + lane * 2;
  float4 s0 = sp[0], s1 = sp[1], a0 = ap[0], a1 = ap[1], b0 = bp[0], b1 = bp[1];
  float pa = s0.x*a0.x + s0.y*a0.y + s0.z*a0.z + s0.w*a0.w + s1.x*a1.x + s1.y*a1.y + s1.z*a1.z + s1.w*a1.w;
  float pb = s0.x*b0.x + s0.y*b0.y + s0.z*b0.z + s0.w*b0.w + s1.x*b1.x + s1.y*b1.y + s1.z*b1.z + s1.w*b1.w;
  pa = wred(pa); pb = wred(pb);
  if (lane == 0) {
    alpha[g] = pa + aconst[h];
    beta[g] = pb + bconst[h];
  }
}

// ---------------- dots via 3-way bf16-split MFMA + in-register softmax ----------------
// block: 128 tokens x 128 hi; 4 waves each own 32 j x 128 hi.
__global__ __launch_bounds__(256) void k_dots(const float* __restrict__ in, const float* __restrict__ qkt,
                                              const float* __restrict__ alpha, const float* __restrict__ beta,
                                              const float* __restrict__ mu, const float* __restrict__ rsig,
                                              float* __restrict__ A, float* __restrict__ Spart,
                                              float* __restrict__ c1part) {
  __shared__ __align__(16) unsigned short xs_h[128][40];
  __shared__ __align__(16) unsigned short xs_m[128][40];
  __shared__ __align__(16) unsigned short xs_l[128][40];
  __shared__ __align__(16) unsigned short us_h[128][40];
  __shared__ __align__(16) unsigned short us_m[128][40];
  __shared__ __align__(16) unsigned short us_l[128][40];   // 61440 B total

  int b = blockIdx.y, jt = blockIdx.x, j0 = jt * 128;
  int t = threadIdx.x, w = t >> 6, l = t & 63;
  int lc = l & 15, lg = l >> 4, koff = lg * 8;
  const size_t inbase = ((size_t)b * Nn + j0) * Dn;
  const size_t ubase = (size_t)b * HIn * Dn;

  f32x4 acc[2][8];
#pragma unroll
  for (int i = 0; i < 2; ++i)
#pragma unroll
    for (int j2 = 0; j2 < 8; ++j2) acc[i][j2] = {0.0f, 0.0f, 0.0f, 0.0f};

  // prefetch first k-chunk
  float2 nx[8], nu[8];
#pragma unroll
  for (int e = 0; e < 8; ++e) {
    int idx = t + e * 256;
    int j = idx >> 4, kp = (idx & 15) * 2;
    nx[e] = *reinterpret_cast<const float2*>(&in[inbase + (size_t)j * Dn + kp]);
    nu[e] = *reinterpret_cast<const float2*>(&qkt[ubase + (size_t)j * Dn + kp]);
  }

  for (int k0 = 0; k0 < 512; k0 += 32) {
    // convert + write current chunk to LDS
#pragma unroll
    for (int e = 0; e < 8; ++e) {
      int idx = t + e * 256;
      int j = idx >> 4, kp = (idx & 15) * 2;
      unsigned mm, lm;
      unsigned hm = pack3(nx[e].x, nx[e].y, mm, lm);
      *reinterpret_cast<unsigned*>(&xs_h[j][kp]) = hm;
      *reinterpret_cast<unsigned*>(&xs_m[j][kp]) = mm;
      *reinterpret_cast<unsigned*>(&xs_l[j][kp]) = lm;
      hm = pack3(nu[e].x, nu[e].y, mm, lm);
      *reinterpret_cast<unsigned*>(&us_h[j][kp]) = hm;
      *reinterpret_cast<unsigned*>(&us_m[j][kp]) = mm;
      *reinterpret_cast<unsigned*>(&us_l[j][kp]) = lm;
    }
    // prefetch next chunk (overlaps with MFMA below)
    if (k0 + 32 < 512) {
#pragma unroll
      for (int e = 0; e < 8; ++e) {
        int idx = t + e * 256;
        int j = idx >> 4, kp = (idx & 15) * 2;
        nx[e] = *reinterpret_cast<const float2*>(&in[inbase + (size_t)j * Dn + k0 + 32 + kp]);
        nu[e] = *reinterpret_cast<const float2*>(&qkt[ubase + (size_t)j * Dn + k0 + 32 + kp]);
      }
    }
    __syncthreads();
    // fragments + 6-pass MFMA
    short8 ah0 = *reinterpret_cast<const short8*>(&xs_h[w * 32 + lc][koff]);
    short8 am0 = *reinterpret_cast<const short8*>(&xs_m[w * 32 + lc][koff]);
    short8 al0 = *reinterpret_cast<const short8*>(&xs_l[w * 32 + lc][koff]);
    short8 ah1 = *reinterpret_cast<const short8*>(&xs_h[w * 32 + 16 + lc][koff]);
    short8 am1 = *reinterpret_cast<const short8*>(&xs_m[w * 32 + 16 + lc][koff]);
    short8 al1 = *reinterpret_cast<const short8*>(&xs_l[w * 32 + 16 + lc][koff]);
#pragma unroll
    for (int ht = 0; ht < 8; ++ht) {
      short8 bh = *reinterpret_cast<const short8*>(&us_h[ht * 16 + lc][koff]);
      short8 bm = *reinterpret_cast<const short8*>(&us_m[ht * 16 + lc][koff]);
      short8 bl = *reinterpret_cast<const short8*>(&us_l[ht * 16 + lc][koff]);
      acc[0][ht] = __builtin_amdgcn_mfma_f32_16x16x32_bf16(ah0, bh, acc[0][ht], 0, 0, 0);
      acc[0][ht] = __builtin_amdgcn_mfma_f32_16x16x32_bf16(ah0, bm, acc[0][ht], 0, 0, 0);
      acc[0][ht] = __builtin_amdgcn_mfma_f32_16x16x32_bf16(am0, bh, acc[0][ht], 0, 0, 0);
      acc[0][ht] = __builtin_amdgcn_mfma_f32_16x16x32_bf16(ah0, bl, acc[0][ht], 0, 0, 0);
      acc[0][ht] = __builtin_amdgcn_mfma_f32_16x16x32_bf16(al0, bh, acc[0][ht], 0, 0, 0);
      acc[0][ht] = __builtin_amdgcn_mfma_f32_16x16x32_bf16(am0, bm, acc[0][ht], 0, 0, 0);
      acc[1][ht] = __builtin_amdgcn_mfma_f32_16x16x32_bf16(ah1, bh, acc[1][ht], 0, 0, 0);
      acc[1][ht] = __builtin_amdgcn_mfma_f32_16x16x32_bf16(ah1, bm, acc[1][ht], 0, 0, 0);
      acc[1][ht] = __builtin_amdgcn_mfma_f32_16x16x32_bf16(am1, bh, acc[1][ht], 0, 0, 0);
      acc[1][ht] = __builtin_amdgcn_mfma_f32_16x16x32_bf16(ah1, bl, acc[1][ht], 0, 0, 0);
      acc[1][ht] = __builtin_amdgcn_mfma_f32_16x16x32_bf16(al1, bh, acc[1][ht], 0, 0, 0);
      acc[1][ht] = __builtin_amdgcn_mfma_f32_16x16x32_bf16(am1, bm, acc[1][ht], 0, 0, 0);
    }
    __syncthreads();
  }

  // ---- epilogue: alias consts/partials into staging LDS (k-loop done) ----
  float* rsL = reinterpret_cast<float*>(&xs_h[0][0]);
  float* muL = rsL + 128;
  float* aL = rsL + 256;
  float* bL = rsL + 384;
  float (*sredS)[128] = reinterpret_cast<float(*)[128]>(rsL + 512);
  float (*sredC)[128] = reinterpret_cast<float(*)[128]>(rsL + 512 + 4 * 128);
  if (t < 128) {
    rsL[t] = rsig[(size_t)b * Nn + j0 + t];
    muL[t] = mu[(size_t)b * Nn + j0 + t];
    aL[t] = alpha[b * HIn + t];
    bL[t] = beta[b * HIn + t];
  }
  __syncthreads();

  float sS[8] = {}, sC[8] = {};
#pragma unroll
  for (int jt2 = 0; jt2 < 2; ++jt2) {
    int jbase = w * 32 + jt2 * 16 + lg * 4;
#pragma unroll
    for (int ht = 0; ht < 8; ++ht) {
      int hi = ht * 16 + lc;
      float av = aL[hi], bv = bL[hi];
      float v[4], rs4[4], mr4[4];
#pragma unroll
      for (int r = 0; r < 4; ++r) {
        int jr = jbase + r;
        rs4[r] = rsL[jr];
        mr4[r] = muL[jr] * rs4[r];
        v[r] = acc[jt2][ht][r] * rs4[r] + av - mr4[r] * bv;
      }
      float mx[4] = {v[0], v[1], v[2], v[3]};
#pragma unroll
      for (int m = 1; m <= 8; m <<= 1)
#pragma unroll
        for (int r = 0; r < 4; ++r) mx[r] = fmaxf(mx[r], __shfl_xor(mx[r], m));
      float e4[4], ss[4];
#pragma unroll
      for (int r = 0; r < 4; ++r) { e4[r] = expf(v[r] - mx[r]); ss[r] = e4[r]; }
#pragma unroll
      for (int m = 1; m <= 8; m <<= 1)
#pragma unroll
        for (int r = 0; r < 4; ++r) ss[r] += __shfl_xor(ss[r], m);
      float4 o4;
      float ps = 0.0f, pc = 0.0f;
      float p0 = e4[0] / ss[0] + kEps, p1 = e4[1] / ss[1] + kEps;
      float p2 = e4[2] / ss[2] + kEps, p3 = e4[3] / ss[3] + kEps;
      o4.x = p0 * rs4[0]; o4.y = p1 * rs4[1]; o4.z = p2 * rs4[2]; o4.w = p3 * rs4[3];
      ps = p0 + p1 + p2 + p3;
      pc = p0 * mr4[0] + p1 * mr4[1] + p2 * mr4[2] + p3 * mr4[3];
      *reinterpret_cast<float4*>(&A[(size_t)(b * HIn + hi) * Nn + j0 + jbase]) = o4;
      ps += __shfl_xor(ps, 16); ps += __shfl_xor(ps, 32);
      pc += __shfl_xor(pc, 16); pc += __shfl_xor(pc, 32);
      sS[ht] += ps; sC[ht] += pc;
    }
  }
  if (l < 16) {
#pragma unroll
    for (int ht = 0; ht < 8; ++ht) {
      sredS[w][ht * 16 + l] = sS[ht];
      sredC[w][ht * 16 + l] = sC[ht];
    }
  }
  __syncthreads();
  if (t < 128) {
    float s_ = sredS[0][t] + sredS[1][t] + sredS[2][t] + sredS[3][t];
    float c_ = sredC[0][t] + sredC[1][t] + sredC[2][t] + sredC[3][t];
    int sub = (b * 32 + jt) * HIn + t;
    Spart[sub] = s_;
    c1part[sub] = c_;
  }
}

// ---------------- AX = A @ X  (K-split x4) ----------------
__global__ __launch_bounds__(256) void k_ax(const float* __restrict__ Abuf, const float* __restrict__ in,
                                            float* __restrict__ AXp) {
  int d0 = blockIdx.x * 128;
  int kp = blockIdx.y;
  int b = blockIdx.z;
  __shared__ __align__(16) float as_[16][132];
  __shared__ __align__(16) float xs_[16][132];
  int t = threadIdx.x, tx = t & 15, ty = t >> 4;
  float acc[8][8] = {};
  for (int k0 = kp * 1024; k0 < kp * 1024 + 1024; k0 += 16) {
#pragma unroll
    for (int e = 0; e < 8; ++e) {
      int idx = t + e * 256;
      int r = idx >> 4, c = idx & 15;
      as_[c][r] = Abuf[(size_t)(b * HIn + r) * Nn + k0 + c];
    }
#pragma unroll
    for (int e = 0; e < 8; ++e) {
      int idx = t + e * 256;
      int kc = idx >> 7, dd = idx & 127;
      xs_[kc][dd] = in[((size_t)b * Nn + k0 + kc) * Dn + d0 + dd];
    }
    __syncthreads();
#pragma unroll
    for (int kc = 0; kc < 16; ++kc) {
      float4 a0 = *reinterpret_cast<const float4*>(&as_[kc][ty * 8]);
      float4 a1 = *reinterpret_cast<const float4*>(&as_[kc][ty * 8 + 4]);
      float4 x0 = *reinterpret_cast<const float4*>(&xs_[kc][tx * 8]);
      float4 x1 = *reinterpret_cast<const float4*>(&xs_[kc][tx * 8 + 4]);
      float av[8] = {a0.x, a0.y, a0.z, a0.w, a1.x, a1.y, a1.z, a1.w};
      float xv[8] = {x0.x, x0.y, x0.z, x0.w, x1.x, x1.y, x1.z, x1.w};
#pragma unroll
      for (int u = 0; u < 8; ++u)
#pragma unroll
        for (int v = 0; v < 8; ++v) acc[u][v] += av[u] * xv[v];
    }
    __syncthreads();
  }
#pragma unroll
  for (int u = 0; u < 8; ++u)
#pragma unroll
    for (int v = 0; v < 8; ++v)
      AXp[(((size_t)kp * Bn + b) * HIn + ty * 8 + u) * Dn + d0 + tx * 8 + v] = acc[u][v];
}

// ---------------- upd = ((w*(G-c1)/S + b) @ Wv_h) + bv, S/c1 reduced inline ----------------
__global__ __launch_bounds__(256) void k_updS(const float* __restrict__ AXp, const float* __restrict__ Spart,
                                              const float* __restrict__ c1part, const float* __restrict__ lnw,
                                              const float* __restrict__ lnb, const float* __restrict__ Wv,
                                              const float* __restrict__ bv, float* __restrict__ upd) {
  int b = blockIdx.y, hi = blockIdx.x, h = hi >> 4, i = hi & 15;
  __shared__ float vx[512];
  __shared__ float red[256];
  __shared__ float sSC[2];
  int t = threadIdx.x;
  if (t < 64) {
    float vs = 0.0f, vc = 0.0f;
    if (t < 32) {
      vs = Spart[(size_t)(b * 32 + t) * HIn + hi];
      vc = c1part[(size_t)(b * 32 + t) * HIn + hi];
    }
    vs = wred(vs); vc = wred(vc);
    if (t == 0) { sSC[0] = vs; sSC[1] = vc; }
  }
  __syncthreads();
  float c1v = sSC[1];
  float invS = 1.0f / sSC[0];
  for (int d = t; d < Dn; d += 256) {
    float G = AXp[((size_t)(0 * Bn + b) * HIn + hi) * Dn + d]
            + AXp[((size_t)(1 * Bn + b) * HIn + hi) * Dn + d]
            + AXp[((size_t)(2 * Bn + b) * HIn + hi) * Dn + d]
            + AXp[((size_t)(3 * Bn + b) * HIn + hi) * Dn + d];
    vx[d] = lnw[d] * (G - c1v) * invS + lnb[d];
  }
  __syncthreads();
  int cc = t & 63, qd = t >> 6;
  float p = 0.0f;
  for (int d = qd * 128; d < qd * 128 + 128; ++d) p += vx[d] * Wv[(size_t)d * Dn + h * 64 + cc];
  red[t] = p;
  __syncthreads();
  if (qd == 0) {
    float v = red[cc] + red[64 + cc] + red[128 + cc] + red[192 + cc] + bv[h * 64 + cc];
    upd[(size_t)(b * NSn + i) * Dn + h * 64 + cc] = v;
  }
}

// ---------------- dual GEMM: z=0: gi = upd@T1 + bcih ; z=1: gh = slots@Whh^T + bhh ----------------
__global__ __launch_bounds__(256) void k_gg(const float* __restrict__ upd, const float* __restrict__ T1,
                                            const float* __restrict__ bcih, const float* __restrict__ slots,
                                            const float* __restrict__ Whh, const float* __restrict__ bhh,
                                            float* __restrict__ gi, float* __restrict__ gh) {
  bool z = (blockIdx.z == 1);
  const float* A = z ? slots : upd;
  const float* W = z ? Whh : T1;
  const float* bias = z ? bhh : bcih;
  float* out = z ? gh : gi;
  __shared__ float as_[64][17];
  __shared__ float ws_[16][65];
  int m0 = blockIdx.y * 64, n0 = blockIdx.x * 64;
  int t = threadIdx.x, tx = t & 15, ty = t >> 4;
  float acc[4][4] = {};
  for (int k0 = 0; k0 < 512; k0 += 16) {
#pragma unroll
    for (int e = 0; e < 4; ++e) {
      int idx = t + e * 256;
      int r = idx >> 4, c = idx & 15;
      as_[r][c] = A[(size_t)(m0 + r) * 512 + k0 + c];
    }
    if (!z) {
#pragma unroll
      for (int e = 0; e < 4; ++e) {
        int idx = t + e * 256;
        int r = idx >> 6, c = idx & 63;
        ws_[r][c] = W[(size_t)(k0 + r) * 1536 + n0 + c];
      }
    } else {
#pragma unroll
      for (int e = 0; e < 4; ++e) {
        int idx = t + e * 256;
        int r = idx >> 4, c = idx & 15;
        ws_[c][r] = W[(size_t)(n0 + r) * 512 + k0 + c];
      }
    }
    __syncthreads();
#pragma unroll
    for (int kc = 0; kc < 16; ++kc) {
      float av[4], wv[4];
#pragma unroll
      for (int i = 0; i < 4; ++i) av[i] = as_[ty * 4 + i][kc];
#pragma unroll
      for (int j = 0; j < 4; ++j) wv[j] = ws_[kc][tx * 4 + j];
#pragma unroll
      for (int i = 0; i < 4; ++i)
#pragma unroll
        for (int j = 0; j < 4; ++j) acc[i][j] += av[i] * wv[j];
    }
    __syncthreads();
  }
#pragma unroll
  for (int i = 0; i < 4; ++i)
#pragma unroll
    for (int j = 0; j < 4; ++j) {
      int m = m0 + ty * 4 + i, n = n0 + tx * 4 + j;
      out[(size_t)m * 1536 + n] = acc[i][j] + bias[n];
    }
}

// ---------------- GRU pointwise + LN_ff fused ----------------
__global__ __launch_bounds__(256) void k_gruln(const float* __restrict__ gi, const float* __restrict__ gh,
                                               float* __restrict__ slots, float* __restrict__ slnff,
                                               const float* __restrict__ lnffw, const float* __restrict__ lnffb) {
  int r = blockIdx.x, t = threadIdx.x;
  __shared__ float red[8];
  float sn[2];
#pragma unroll
  for (int j = 0; j < 2; ++j) {
    int c = j * 256 + t;
    float gir = gi[(size_t)r * 1536 + c];
    float giz = gi[(size_t)r * 1536 + 512 + c];
    float gin = gi[(size_t)r * 1536 + 1024 + c];
    float ghr = gh[(size_t)r * 1536 + c];
    float ghz = gh[(size_t)r * 1536 + 512 + c];
    float ghn = gh[(size_t)r * 1536 + 1024 + c];
    float rg = 1.0f / (1.0f + expf(-(gir + ghr)));
    float zg = 1.0f / (1.0f + expf(-(giz + ghz)));
    float ng = tanhf(gin + rg * ghn);
    sn[j] = (1.0f - zg) * ng + zg * slots[(size_t)r * Dn + c];
  }
  float s = sn[0] + sn[1], q = sn[0] * sn[0] + sn[1] * sn[1];
  s = wred(s); q = wred(q);
  if ((t & 63) == 0) { red[t >> 6] = s; red[4 + (t >> 6)] = q; }
  __syncthreads();
  float S = red[0] + red[1] + red[2] + red[3];
  float Q = red[4] + red[5] + red[6] + red[7];
  float m = S * (1.0f / 512.0f);
  float rs = 1.0f / sqrtf(Q * (1.0f / 512.0f) - m * m + 1e-5f);
#pragma unroll
  for (int j = 0; j < 2; ++j) {
    int c = j * 256 + t;
    slots[(size_t)r * Dn + c] = sn[j];
    slnff[(size_t)r * Dn + c] = (sn[j] - m) * rs * lnffw[c] + lnffb[c];
  }
}

// ---------------- keep gate (zero dropped slots in place) ----------------
__global__ void k_keepscale(const float* __restrict__ Wkeep, const float* __restrict__ gk,
                            float* __restrict__ slots) {
  int g = blockIdx.x;
  int lane = threadIdx.x;
  float4* sp = reinterpret_cast<float4*>(slots + (size_t)g * Dn) + lane * 2;
  float4 s0 = sp[0], s1 = sp[1];
  float sv[8] = {s0.x, s0.y, s0.z, s0.w, s1.x, s1.y, s1.z, s1.w};
  double d0 = 0.0, d1 = 0.0;
#pragma unroll
  for (int e = 0; e < 8; ++e) {
    int d = lane * 8 + e;
    d0 += (double)sv[e] * (double)Wkeep[d * 2];
    d1 += (double)sv[e] * (double)Wkeep[d * 2 + 1];
  }
  d0 = wredd(d0);
  d1 = wredd(d1);
  int keepi = 0;
  if (lane == 0) keepi = ((d1 + (double)gk[g * 2 + 1]) > (d0 + (double)gk[g * 2])) ? 1 : 0;
  keepi = __shfl(keepi, 0);
  if (!keepi) {
    float4 z = {0.0f, 0.0f, 0.0f, 0.0f};
    sp[0] = z;
    sp[1] = z;
  }
}

// ---------------- per-slot scalars for route decomposition ----------------
__global__ void k_slotscalars(const float* __restrict__ slots, const float* __restrict__ lnw,
                              const float* __restrict__ lnb, double* __restrict__ swd,
                              double* __restrict__ sbd) {
  int g = blockIdx.x, lane = threadIdx.x;
  const float4* sp = reinterpret_cast<const float4*>(slots + (size_t)g * Dn) + lane * 2;
  const float4* wp = reinterpret_cast<const float4*>(lnw) + lane * 2;
  const float4* bp = reinterpret_cast<const float4*>(lnb) + lane * 2;
  float4 s0 = sp[0], s1 = sp[1], w0 = wp[0], w1 = wp[1], b0 = bp[0], b1 = bp[1];
  double pw = (double)s0.x * w0.x + (double)s0.y * w0.y + (double)s0.z * w0.z + (double)s0.w * w0.w +
              (double)s1.x * w1.x + (double)s1.y * w1.y + (double)s1.z * w1.z + (double)s1.w * w1.w;
  double pb = (double)s0.x * b0.x + (double)s0.y * b0.y + (double)s0.z * b0.z + (double)s0.w * b0.w +
              (double)s1.x * b1.x + (double)s1.y * b1.y + (double)s1.z * b1.z + (double)s1.w * b1.w;
  pw = wredd(pw);
  pb = wredd(pb);
  if (lane == 0) { swd[g] = pw; sbd[g] = pb; }
}

// ---------------- hard route + gather output (tiled mini-GEMM) ----------------
__global__ __launch_bounds__(256) void k_route_out(const float* __restrict__ in, const float* __restrict__ slots,
                                                   const float* __restrict__ lnw, const double* __restrict__ swd,
                                                   const double* __restrict__ sbd, const float* __restrict__ mu,
                                                   const float* __restrict__ rsig,
                                                   const float* __restrict__ g_route, float* __restrict__ out) {
  int b = blockIdx.y, j0 = blockIdx.x * 128;
  __shared__ __align__(16) float sl[16 * 516];
  __shared__ __align__(16) float lw[512];
  __shared__ __align__(16) float xs[16][132];
  __shared__ double lgd[128][17];
  __shared__ int besti[128];
  int t = threadIdx.x, tx = t & 15, ty = t >> 4;

  for (int idx = t; idx < 2048; idx += 256) {
    int i = idx >> 7, c = idx & 127;
    *reinterpret_cast<float4*>(&sl[i * 516 + c * 4]) =
        *reinterpret_cast<const float4*>(&slots[(size_t)(b * NSn + i) * Dn + c * 4]);
  }
  if (t < 128)
    *reinterpret_cast<float4*>(&lw[t * 4]) = *reinterpret_cast<const float4*>(&lnw[t * 4]);

  float acc[8] = {};
  double accd[8] = {};
  const size_t inbase = ((size_t)b * Nn + j0) * Dn;
  __syncthreads();

  for (int k0 = 0; k0 < Dn; k0 += 16) {
    float pre[8];
#pragma unroll
    for (int e = 0; e < 8; ++e) {
      int idx = t + e * 256;
      int r = idx >> 4, c = idx & 15;
      pre[e] = in[inbase + (size_t)r * Dn + k0 + c];
    }
    __syncthreads();
#pragma unroll
    for (int e = 0; e < 8; ++e) {
      int idx = t + e * 256;
      int r = idx >> 4, c = idx & 15;
      xs[c][r] = pre[e] * lw[k0 + c];
    }
    __syncthreads();
#pragma unroll
    for (int kc = 0; kc < 16; ++kc) {
      float sv = sl[tx * 516 + k0 + kc];
      float4 x0 = *reinterpret_cast<const float4*>(&xs[kc][ty * 8]);
      float4 x1 = *reinterpret_cast<const float4*>(&xs[kc][ty * 8 + 4]);
      acc[0] += x0.x * sv; acc[1] += x0.y * sv; acc[2] += x0.z * sv; acc[3] += x0.w * sv;
      acc[4] += x1.x * sv; acc[5] += x1.y * sv; acc[6] += x1.z * sv; acc[7] += x1.w * sv;
    }
    if ((k0 & 127) == 112) {
#pragma unroll
      for (int e = 0; e < 8; ++e) { accd[e] += (double)acc[e]; acc[e] = 0.0f; }
    }
  }

  double sw_i = swd[b * NSn + tx], sb_i = sbd[b * NSn + tx];
#pragma unroll
  for (int r = 0; r < 8; ++r) {
    int j = ty * 8 + r;
    double rsj = (double)rsig[(size_t)b * Nn + j0 + j];
    double muj = (double)mu[(size_t)b * Nn + j0 + j];
    double g = (double)g_route[((size_t)b * NSn + tx) * Nn + j0 + j];
    lgd[j][tx] = (double)kScale * (rsj * accd[r] + sb_i - muj * rsj * sw_i) + g;
  }
  __syncthreads();
  if (t < 128) {
    double best = lgd[t][0];
    int bi = 0;
#pragma unroll
    for (int i = 1; i < 16; ++i) {
      double v = lgd[t][i];
      if (v > best) { best = v; bi = i; }
    }
    besti[t] = bi;
  }
  __syncthreads();
  for (int idx = t; idx < 128 * 128; idx += 256) {
    int j = idx >> 7, c = idx & 127;
    *reinterpret_cast<float4*>(&out[inbase + (size_t)j * Dn + c * 4]) =
        *reinterpret_cast<const float4*>(&sl[besti[j] * 516 + c * 4]);
  }
}

extern "C" void kernel_launch(void* const* d_in, const int* in_sizes, int n_in,
                              void* d_out, int out_size, void* d_ws, size_t ws_size,
                              hipStream_t stream) {
  (void)in_sizes; (void)n_in; (void)out_size; (void)ws_size;
  const float* in = (const float*)d_in[0];
  const float* slots_mu = (const float*)d_in[1];
  const float* slots_ls = (const float*)d_in[2];
  const float* ln_in_w = (const float*)d_in[3];
  const float* ln_in_b = (const float*)d_in[4];
  const float* ln_s_w = (const float*)d_in[5];
  const float* ln_s_b = (const float*)d_in[6];
  const float* ln_ff_w = (const float*)d_in[7];
  const float* ln_ff_b = (const float*)d_in[8];
  const float* Wq = (const float*)d_in[9];
  const float* bq = (const float*)d_in[10];
  const float* Wk = (const float*)d_in[11];
  const float* bk = (const float*)d_in[12];
  const float* Wv = (const float*)d_in[13];
  const float* bv = (const float*)d_in[14];
  const float* Wc = (const float*)d_in[15];
  const float* bc = (const float*)d_in[16];
  const float* Wih = (const float*)d_in[17];
  const float* bih = (const float*)d_in[18];
  const float* Whh = (const float*)d_in[19];
  const float* bhh = (const float*)d_in[20];
  const float* W1 = (const float*)d_in[21];
  const float* b1 = (const float*)d_in[22];
  const float* W2 = (const float*)d_in[23];
  const float* b2 = (const float*)d_in[24];
  const float* Wkeep = (const float*)d_in[25];
  const float* noise = (const float*)d_in[26];
  const float* g_keep = (const float*)d_in[27];
  const float* g_route = (const float*)d_in[28];
  float* out = (float*)d_out;

  char* wptr = (char*)d_ws;
  auto alloc = [&](size_t bytes) {
    char* p = wptr;
    wptr += (bytes + 255) & ~(size_t)255;
    return p;
  };
  float* mu = (float*)alloc((size_t)Bn * Nn * 4);
  float* rsig = (float*)alloc((size_t)Bn * Nn * 4);
  float* slots = (float*)alloc((size_t)Bn * NSn * Dn * 4);
  float* sln = (float*)alloc((size_t)Bn * NSn * Dn * 4);
  float* qkt = (float*)alloc((size_t)Bn * HIn * Dn * 4);
  float* alpha = (float*)alloc((size_t)Bn * HIn * 4);
  float* beta = (float*)alloc((size_t)Bn * HIn * 4);
  float* Abuf = (float*)alloc((size_t)Bn * HIn * Nn * 4);
  float* Spart = (float*)alloc((size_t)Bn * 64 * HIn * 4);
  float* c1part = (float*)alloc((size_t)Bn * 64 * HIn * 4);
  float* AXp = (float*)alloc((size_t)4 * Bn * HIn * Dn * 4);
  float* updb = (float*)alloc((size_t)Bn * NSn * Dn * 4);
  float* gibuf = (float*)alloc((size_t)Bn * NSn * 1536 * 4);
  float* ghbuf = (float*)alloc((size_t)Bn * NSn * 1536 * 4);
  float* hbuf = (float*)alloc((size_t)Bn * NSn * 2048 * 4);
  float* T1 = (float*)alloc((size_t)Dn * 1536 * 4);
  float* bcih = (float*)alloc((size_t)1536 * 4);
  float* Ms = (float*)alloc((size_t)Dn * 4096 * 4);
  float* vb_raw = (float*)alloc((size_t)4096 * 4);
  float* vb_s = (float*)alloc((size_t)4096 * 4);
  float* avec = (float*)alloc((size_t)4096 * 4);
  float* bvec = (float*)alloc((size_t)4096 * 4);
  float* aconst = (float*)alloc((size_t)8 * 4);
  float* bconst = (float*)alloc((size_t)8 * 4);
  double* swd = (double*)alloc((size_t)Bn * NSn * 8);
  double* sbd = (double*)alloc((size_t)Bn * NSn * 8);

  // prologue
  k_rowstats<<<Bn * Nn / 4, 256, 0, stream>>>(in, mu, rsig);
  k_slots_init<<<Bn * NSn, 256, 0, stream>>>(slots_mu, slots_ls, noise, slots);
  k_gemm_sm<true, false, false><<<dim3(24, 8), 256, 0, stream>>>(Wc, Wih, nullptr, T1, 1536, 512);
  k_bcih<<<6, 256, 0, stream>>>(bc, Wih, bih, bcih);
  k_mh<<<dim3(8, 8, 8), 256, 0, stream>>>(Wq, Wk, Ms);
  k_vbias<<<2, 256, 0, stream>>>(Wk, bq, ln_in_w, vb_raw, vb_s);
  k_mfold<<<16, 256, 0, stream>>>(Ms, Wq, bk, ln_in_w, ln_in_b, avec, bvec);
  k_consts<<<1, 256, 0, stream>>>(vb_raw, bq, bk, ln_in_w, ln_in_b, aconst, bconst);
  k_ln_rows<<<Bn * NSn, 256, 0, stream>>>(slots, ln_s_w, ln_s_b, sln);

  for (int it = 0; it < 3; ++it) {
    k_qu<<<dim3(64, 8), 256, 0, stream>>>(sln, Ms, vb_s, qkt);
    k_ab<<<Bn * HIn, 64, 0, stream>>>(sln, avec, bvec, aconst, bconst, alpha, beta);
    k_dots<<<dim3(Nn / 128, Bn), 256, 0, stream>>>(in, qkt, alpha, beta, mu, rsig, Abuf, Spart, c1part);
    k_ax<<<dim3(4, 4, Bn), 256, 0, stream>>>(Abuf, in, AXp);
    k_updS<<<dim3(HIn, Bn), 256, 0, stream>>>(AXp, Spart, c1part, ln_in_w, ln_in_b, Wv, bv, updb);
    k_gg<<<dim3(24, 8, 2), 256, 0, stream>>>(updb, T1, bcih, slots, Whh, bhh, gibuf, ghbuf);
    k_gruln<<<Bn * NSn, 256, 0, stream>>>(gibuf, ghbuf, slots, sln, ln_ff_w, ln_ff_b);
    k_gemm_sm<false, true, false><<<dim3(32, 8), 256, 0, stream>>>(sln, W1, b1, hbuf, 2048, 512);
    k_gemm_sm<false, false, true><<<dim3(8, 8), 256, 0, stream>>>(hbuf, W2, b2, slots, 512, 2048);
    k_ln_rows<<<Bn * NSn, 256, 0, stream>>>(slots, ln_s_w, ln_s_b, sln);
  }

  k_keepscale<<<Bn * NSn, 64, 0, stream>>>(Wkeep, g_keep, slots);
  k_slotscalars<<<Bn * NSn, 64, 0, stream>>>(slots, ln_in_w, ln_in_b, swd, sbd);
  k_route_out<<<dim3(Nn / 128, Bn), 256, 0, stream>>>(in, slots, ln_in_w, swd, sbd, mu, rsig, g_route, out);
}

// Round 6
// 2444.955 us; speedup vs baseline: 1.4586x; 1.1088x over previous
//
#include <hip/hip_runtime.h>
#include <hip/hip_bf16.h>
#include <math.h>

constexpr int Bn = 32, Nn = 4096, Dn = 512, NSn = 16, HIn = 128;
constexpr float kScale = 0.04419417382415922f; // 512^-0.5
constexpr float kEps = 1e-8f;

typedef __attribute__((ext_vector_type(8))) short short8;
typedef __attribute__((ext_vector_type(4))) float f32x4;

__device__ __forceinline__ float wred(float v) {
#pragma unroll
  for (int m = 32; m > 0; m >>= 1) v += __shfl_xor(v, m);
  return v;
}
__device__ __forceinline__ double wredd(double v) {
#pragma unroll
  for (int m = 32; m > 0; m >>= 1) v += __shfl_xor(v, m);
  return v;
}

// ---- bf16 split helpers (RNE) ----
__device__ __forceinline__ unsigned short f2bf(float x) {
  unsigned u = __float_as_uint(x);
  unsigned r = (u + 0x7fffu + ((u >> 16) & 1u)) >> 16;
  return (unsigned short)r;
}
__device__ __forceinline__ float bf2f(unsigned short h) {
  return __uint_as_float(((unsigned)h) << 16);
}
__device__ __forceinline__ unsigned pack3(float x0, float x1, unsigned& mo, unsigned& lo) {
  unsigned short h0 = f2bf(x0); float r0 = x0 - bf2f(h0);
  unsigned short m0 = f2bf(r0); float q0 = r0 - bf2f(m0);
  unsigned short l0 = f2bf(q0);
  unsigned short h1 = f2bf(x1); float r1 = x1 - bf2f(h1);
  unsigned short m1 = f2bf(r1); float q1 = r1 - bf2f(m1);
  unsigned short l1 = f2bf(q1);
  mo = (unsigned)m0 | ((unsigned)m1 << 16);
  lo = (unsigned)l0 | ((unsigned)l1 << 16);
  return (unsigned)h0 | ((unsigned)h1 << 16);
}
// per-element packed hi|mid
__device__ __forceinline__ unsigned packhm(float x) {
  unsigned short h = f2bf(x);
  unsigned short m = f2bf(x - bf2f(h));
  return (unsigned)h | ((unsigned)m << 16);
}

// ---------------- per-row LN stats of inputs ----------------
__global__ __launch_bounds__(256) void k_rowstats(const float* __restrict__ in,
                                                  float* __restrict__ mu, float* __restrict__ rsig) {
  int row = blockIdx.x * 4 + (threadIdx.x >> 6);
  int lane = threadIdx.x & 63;
  const float4* p = reinterpret_cast<const float4*>(in + (size_t)row * Dn) + lane * 2;
  float4 a = p[0], b = p[1];
  float s = a.x + a.y + a.z + a.w + b.x + b.y + b.z + b.w;
  float q = a.x*a.x + a.y*a.y + a.z*a.z + a.w*a.w + b.x*b.x + b.y*b.y + b.z*b.z + b.w*b.w;
  s = wred(s); q = wred(q);
  if (lane == 0) {
    float m = s * (1.0f / 512.0f);
    float var = q * (1.0f / 512.0f) - m * m;
    mu[row] = m;
    rsig[row] = 1.0f / sqrtf(var + 1e-5f);
  }
}

// ---------------- transpose + hi/mid split: in[B,N,D] -> inT[B,D,N] (u32 = h|m<<16) ----------------
__global__ __launch_bounds__(256) void k_tsplit(const float* __restrict__ in, unsigned* __restrict__ inT) {
  __shared__ float tile[64][65];
  int b = blockIdx.z, j0 = blockIdx.x * 64, d0 = blockIdx.y * 64;
  int t = threadIdx.x;
#pragma unroll
  for (int e = 0; e < 16; ++e) {
    int idx = t + e * 256;
    int r = idx >> 6, c = idx & 63;
    tile[r][c] = in[((size_t)b * Nn + j0 + r) * Dn + d0 + c];
  }
  __syncthreads();
#pragma unroll
  for (int e = 0; e < 16; ++e) {
    int idx = t + e * 256;
    int r = idx >> 6, c = idx & 63;
    inT[((size_t)b * Dn + d0 + r) * Nn + j0 + c] = packhm(tile[c][r]);
  }
}

// ---------------- slots init ----------------
__global__ __launch_bounds__(256) void k_slots_init(const float* __restrict__ smu, const float* __restrict__ sls,
                                                    const float* __restrict__ noise, float* __restrict__ slots) {
  int r = blockIdx.x;
  for (int d = threadIdx.x; d < Dn; d += 256)
    slots[(size_t)r * Dn + d] = smu[d] + expf(sls[d]) * noise[(size_t)r * Dn + d];
}

// ---------------- LN of [R,512] rows ----------------
__global__ __launch_bounds__(256) void k_ln_rows(const float* __restrict__ src, const float* __restrict__ w,
                                                 const float* __restrict__ b, float* __restrict__ dst) {
  int r = blockIdx.x;
  __shared__ float red[8];
  int t = threadIdx.x;
  float x0 = src[(size_t)r * Dn + t], x1 = src[(size_t)r * Dn + 256 + t];
  float s = x0 + x1, q = x0 * x0 + x1 * x1;
  s = wred(s); q = wred(q);
  if ((t & 63) == 0) { red[t >> 6] = s; red[4 + (t >> 6)] = q; }
  __syncthreads();
  float S = red[0] + red[1] + red[2] + red[3];
  float Q = red[4] + red[5] + red[6] + red[7];
  float m = S * (1.0f / 512.0f);
  float rs = 1.0f / sqrtf(Q * (1.0f / 512.0f) - m * m + 1e-5f);
  dst[(size_t)r * Dn + t] = (x0 - m) * rs * w[t] + b[t];
  dst[(size_t)r * Dn + 256 + t] = (x1 - m) * rs * w[256 + t] + b[256 + t];
}

// ---------------- small GEMM: out = act(A@W (+bias) (+out)), bias nullable ----------------
template <bool TRANS, bool RELU, bool ADD>
__global__ __launch_bounds__(256) void k_gemm_sm(const float* __restrict__ A, const float* __restrict__ W,
                                                 const float* __restrict__ bias, float* __restrict__ out,
                                                 int Nc, int K) {
  __shared__ float as_[64][17];
  __shared__ float ws_[16][65];
  int m0 = blockIdx.y * 64, n0 = blockIdx.x * 64;
  int t = threadIdx.x, tx = t & 15, ty = t >> 4;
  float acc[4][4] = {};
  for (int k0 = 0; k0 < K; k0 += 16) {
#pragma unroll
    for (int e = 0; e < 4; ++e) {
      int idx = t + e * 256;
      int r = idx >> 4, c = idx & 15;
      as_[r][c] = A[(size_t)(m0 + r) * K + k0 + c];
    }
#pragma unroll
    for (int e = 0; e < 4; ++e) {
      int idx = t + e * 256;
      if (!TRANS) {
        int r = idx >> 6, c = idx & 63;
        ws_[r][c] = W[(size_t)(k0 + r) * Nc + n0 + c];
      } else {
        int r = idx >> 4, c = idx & 15;
        ws_[c][r] = W[(size_t)(n0 + r) * K + k0 + c];
      }
    }
    __syncthreads();
#pragma unroll
    for (int kc = 0; kc < 16; ++kc) {
      float av[4], wv[4];
#pragma unroll
      for (int i = 0; i < 4; ++i) av[i] = as_[ty * 4 + i][kc];
#pragma unroll
      for (int j = 0; j < 4; ++j) wv[j] = ws_[kc][tx * 4 + j];
#pragma unroll
      for (int i = 0; i < 4; ++i)
#pragma unroll
        for (int j = 0; j < 4; ++j) acc[i][j] += av[i] * wv[j];
    }
    __syncthreads();
  }
#pragma unroll
  for (int i = 0; i < 4; ++i)
#pragma unroll
    for (int j = 0; j < 4; ++j) {
      int m = m0 + ty * 4 + i, n = n0 + tx * 4 + j;
      float v = acc[i][j] + (bias ? bias[n] : 0.0f);
      if (RELU) v = fmaxf(v, 0.0f);
      if (ADD) v += out[(size_t)m * Nc + n];
      out[(size_t)m * Nc + n] = v;
    }
}

// ---------------- M_h = Wq_h @ Wk_h^T per head (raw) -> Ms[k*4096 + h*512 + d] ----------------
__global__ __launch_bounds__(256) void k_mh(const float* __restrict__ Wq, const float* __restrict__ Wk,
                                            float* __restrict__ Ms) {
  int h = blockIdx.z, k0 = blockIdx.y * 64, d0 = blockIdx.x * 64;
  __shared__ float qa[64][65];
  __shared__ float ka[64][65];
  int t = threadIdx.x, tx = t & 15, ty = t >> 4;
#pragma unroll
  for (int e = 0; e < 16; ++e) {
    int idx = t + e * 256;
    int r = idx >> 6, c = idx & 63;
    qa[c][r] = Wq[(size_t)(k0 + r) * Dn + h * 64 + c];
    ka[c][r] = Wk[(size_t)(d0 + r) * Dn + h * 64 + c];
  }
  __syncthreads();
  float acc[4][4] = {};
#pragma unroll 4
  for (int c = 0; c < 64; ++c) {
    float av[4], bv[4];
#pragma unroll
    for (int i = 0; i < 4; ++i) av[i] = qa[c][ty * 4 + i];
#pragma unroll
    for (int j = 0; j < 4; ++j) bv[j] = ka[c][tx * 4 + j];
#pragma unroll
    for (int i = 0; i < 4; ++i)
#pragma unroll
      for (int j = 0; j < 4; ++j) acc[i][j] += av[i] * bv[j];
  }
#pragma unroll
  for (int i = 0; i < 4; ++i)
#pragma unroll
    for (int j = 0; j < 4; ++j)
      Ms[(size_t)(k0 + ty * 4 + i) * 4096 + h * 512 + d0 + tx * 4 + j] = acc[i][j];
}

// ---------------- vbias_h[d] = Wk[d, h64:]·bq[h64:]; raw + scaled ----------------
__global__ __launch_bounds__(256) void k_vbias(const float* __restrict__ Wk, const float* __restrict__ bq,
                                               const float* __restrict__ lnw, float* __restrict__ vb_raw,
                                               float* __restrict__ vb_s) {
  __shared__ float bqs[512];
  int t = threadIdx.x;
  bqs[t] = bq[t]; bqs[256 + t] = bq[256 + t];
  __syncthreads();
  int d = blockIdx.x * 256 + t;
  float vb[8] = {};
  const float4* wr = reinterpret_cast<const float4*>(Wk + (size_t)d * Dn);
#pragma unroll 8
  for (int c4 = 0; c4 < 128; ++c4) {
    float4 wv = wr[c4];
    int h = c4 >> 4;
    int c = c4 * 4;
    vb[h] += wv.x * bqs[c] + wv.y * bqs[c + 1] + wv.z * bqs[c + 2] + wv.w * bqs[c + 3];
  }
  float lw = lnw[d];
#pragma unroll
  for (int h = 0; h < 8; ++h) {
    vb_raw[h * 512 + d] = vb[h];
    vb_s[h * 512 + d] = kScale * lw * vb[h];
  }
}

// ---------------- fold: scale Ms in place by kScale*lnw[d]; avec/bvec ----------------
__global__ __launch_bounds__(256) void k_mfold(float* __restrict__ Ms, const float* __restrict__ Wq,
                                               const float* __restrict__ bk, const float* __restrict__ lnw,
                                               const float* __restrict__ lnb, float* __restrict__ avec,
                                               float* __restrict__ bvec) {
  __shared__ float lws[512], lbs[512], bks[512];
  int t = threadIdx.x;
  lws[t] = lnw[t]; lws[256 + t] = lnw[256 + t];
  lbs[t] = lnb[t]; lbs[256 + t] = lnb[256 + t];
  bks[t] = bk[t]; bks[256 + t] = bk[256 + t];
  __syncthreads();
  int g = blockIdx.x * 256 + t;
  int k = g >> 3, h = g & 7;
  float* mr = Ms + (size_t)k * 4096 + h * 512;
  float mlnb = 0.0f, mlnw = 0.0f;
  for (int d = 0; d < 512; d += 4) {
    float4 m4 = *reinterpret_cast<const float4*>(mr + d);
    mlnb += m4.x * lbs[d] + m4.y * lbs[d + 1] + m4.z * lbs[d + 2] + m4.w * lbs[d + 3];
    mlnw += m4.x * lws[d] + m4.y * lws[d + 1] + m4.z * lws[d + 2] + m4.w * lws[d + 3];
    float4 o4 = {m4.x * kScale * lws[d], m4.y * kScale * lws[d + 1],
                 m4.z * kScale * lws[d + 2], m4.w * kScale * lws[d + 3]};
    *reinterpret_cast<float4*>(mr + d) = o4;
  }
  float wqdot = 0.0f;
  const float* qr = Wq + (size_t)k * Dn + h * 64;
  for (int c = 0; c < 64; c += 4) {
    float4 q4 = *reinterpret_cast<const float4*>(qr + c);
    wqdot += q4.x * bks[h * 64 + c] + q4.y * bks[h * 64 + c + 1] +
             q4.z * bks[h * 64 + c + 2] + q4.w * bks[h * 64 + c + 3];
  }
  avec[h * 512 + k] = kScale * (mlnb + wqdot);
  bvec[h * 512 + k] = kScale * mlnw;
}

// ---------------- aconst/bconst scalars ----------------
__global__ __launch_bounds__(256) void k_consts(const float* __restrict__ vb_raw, const float* __restrict__ bq,
                                                const float* __restrict__ bk, const float* __restrict__ lnw,
                                                const float* __restrict__ lnb, float* __restrict__ aconst,
                                                float* __restrict__ bconst) {
  __shared__ float r1[256], r2[256], r3[256];
  int t = threadIdx.x;
  for (int h = 0; h < 8; ++h) {
    float p1 = 0.0f, p2 = 0.0f, p3 = 0.0f;
    for (int d = t; d < 512; d += 256) {
      float vr = vb_raw[h * 512 + d];
      p1 += lnb[d] * vr;
      p2 += lnw[d] * vr;
    }
    if (t < 64) p3 = bq[h * 64 + t] * bk[h * 64 + t];
    r1[t] = p1; r2[t] = p2; r3[t] = p3;
    __syncthreads();
    for (int s = 128; s > 0; s >>= 1) {
      if (t < s) { r1[t] += r1[t + s]; r2[t] += r2[t + s]; r3[t] += r3[t + s]; }
      __syncthreads();
    }
    if (t == 0) {
      aconst[h] = kScale * (r1[0] + r3[0]);
      bconst[h] = kScale * r2[0];
    }
    __syncthreads();
  }
}

// ---------------- bcih[n] = bc·Wih[n,:] + bih[n] ----------------
__global__ __launch_bounds__(256) void k_bcih(const float* __restrict__ bc, const float* __restrict__ Wih,
                                              const float* __restrict__ bih, float* __restrict__ bcih) {
  __shared__ float bcs[512];
  int t = threadIdx.x;
  bcs[t] = bc[t]; bcs[256 + t] = bc[256 + t];
  __syncthreads();
  int n = blockIdx.x * 256 + t;
  const float4* wr = reinterpret_cast<const float4*>(Wih + (size_t)n * Dn);
  float a = 0.0f;
#pragma unroll 8
  for (int c4 = 0; c4 < 128; ++c4) {
    float4 wv = wr[c4];
    int c = c4 * 4;
    a += wv.x * bcs[c] + wv.y * bcs[c + 1] + wv.z * bcs[c + 2] + wv.w * bcs[c + 3];
  }
  bcih[n] = a + bih[n];
}

// ---------------- qkt = sln @ Ms + vb_s, remapped to [b,hi,d] ----------------
__global__ __launch_bounds__(256) void k_qu(const float* __restrict__ sln, const float* __restrict__ Ms,
                                            const float* __restrict__ vb_s, float* __restrict__ qkt) {
  __shared__ float as_[64][17];
  __shared__ float ws_[16][65];
  int m0 = blockIdx.y * 64, n0 = blockIdx.x * 64;
  int t = threadIdx.x, tx = t & 15, ty = t >> 4;
  float acc[4][4] = {};
  for (int k0 = 0; k0 < 512; k0 += 16) {
#pragma unroll
    for (int e = 0; e < 4; ++e) {
      int idx = t + e * 256;
      int r = idx >> 4, c = idx & 15;
      as_[r][c] = sln[(size_t)(m0 + r) * Dn + k0 + c];
    }
#pragma unroll
    for (int e = 0; e < 4; ++e) {
      int idx = t + e * 256;
      int r = idx >> 6, c = idx & 63;
      ws_[r][c] = Ms[(size_t)(k0 + r) * 4096 + n0 + c];
    }
    __syncthreads();
#pragma unroll
    for (int kc = 0; kc < 16; ++kc) {
      float av[4], wv[4];
#pragma unroll
      for (int i = 0; i < 4; ++i) av[i] = as_[ty * 4 + i][kc];
#pragma unroll
      for (int j = 0; j < 4; ++j) wv[j] = ws_[kc][tx * 4 + j];
#pragma unroll
      for (int i = 0; i < 4; ++i)
#pragma unroll
        for (int j = 0; j < 4; ++j) acc[i][j] += av[i] * wv[j];
    }
    __syncthreads();
  }
#pragma unroll
  for (int i = 0; i < 4; ++i)
#pragma unroll
    for (int j = 0; j < 4; ++j) {
      int m = m0 + ty * 4 + i, n = n0 + tx * 4 + j;
      int bb = m >> 4, isl = m & 15, h = n >> 9, d = n & 511;
      qkt[((size_t)bb * HIn + h * 16 + isl) * Dn + d] = acc[i][j] + vb_s[n];
    }
}

// ---------------- alpha/beta = sln·avec_h + aconst_h ----------------
__global__ void k_ab(const float* __restrict__ sln, const float* __restrict__ avec,
                     const float* __restrict__ bvec, const float* __restrict__ aconst,
                     const float* __restrict__ bconst, float* __restrict__ alpha,
                     float* __restrict__ beta) {
  int g = blockIdx.x;           // b*128 + hi
  int hi = g & 127, b = g >> 7;
  int h = hi >> 4, i = hi & 15;
  int lane = threadIdx.x;
  const float4* sp = reinterpret_cast<const float4*>(sln + (size_t)(b * NSn + i) * Dn) + lane * 2;
  const float4* ap = reinterpret_cast<const float4*>(avec + h * 512) + lane * 2;
  const float4* bp = reinterpret_cast<const float4*>(bvec + h * 512) + lane * 2;
  float4 s0 = sp[0], s1 = sp[1], a0 = ap[0], a1 = ap[1], b0 = bp[0], b1 = bp[1];
  float pa = s0.x*a0.x + s0.y*a0.y + s0.z*a0.z + s0.w*a0.w + s1.x*a1.x + s1.y*a1.y + s1.z*a1.z + s1.w*a1.w;
  float pb = s0.x*b0.x + s0.y*b0.y + s0.z*b0.z + s0.w*b0.w + s1.x*b1.x + s1.y*b1.y + s1.z*b1.z + s1.w*b1.w;
  pa = wred(pa); pb = wred(pb);
  if (lane == 0) {
    alpha[g] = pa + aconst[h];
    beta[g] = pb + bconst[h];
  }
}

// ---------------- dots via 3-way bf16-split MFMA + in-register softmax ----------------
// A output emitted as packed u32 (bf16 hi | mid<<16) per element.
__global__ __launch_bounds__(256) void k_dots(const float* __restrict__ in, const float* __restrict__ qkt,
                                              const float* __restrict__ alpha, const float* __restrict__ beta,
                                              const float* __restrict__ mu, const float* __restrict__ rsig,
                                              unsigned* __restrict__ A, float* __restrict__ Spart,
                                              float* __restrict__ c1part) {
  __shared__ __align__(16) unsigned short xs_h[128][40];
  __shared__ __align__(16) unsigned short xs_m[128][40];
  __shared__ __align__(16) unsigned short xs_l[128][40];
  __shared__ __align__(16) unsigned short us_h[128][40];
  __shared__ __align__(16) unsigned short us_m[128][40];
  __shared__ __align__(16) unsigned short us_l[128][40];

  int b = blockIdx.y, jt = blockIdx.x, j0 = jt * 128;
  int t = threadIdx.x, w = t >> 6, l = t & 63;
  int lc = l & 15, lg = l >> 4, koff = lg * 8;
  const size_t inbase = ((size_t)b * Nn + j0) * Dn;
  const size_t ubase = (size_t)b * HIn * Dn;

  f32x4 acc[2][8];
#pragma unroll
  for (int i = 0; i < 2; ++i)
#pragma unroll
    for (int j2 = 0; j2 < 8; ++j2) acc[i][j2] = {0.0f, 0.0f, 0.0f, 0.0f};

  float2 nx[8], nu[8];
#pragma unroll
  for (int e = 0; e < 8; ++e) {
    int idx = t + e * 256;
    int j = idx >> 4, kp = (idx & 15) * 2;
    nx[e] = *reinterpret_cast<const float2*>(&in[inbase + (size_t)j * Dn + kp]);
    nu[e] = *reinterpret_cast<const float2*>(&qkt[ubase + (size_t)j * Dn + kp]);
  }

  for (int k0 = 0; k0 < 512; k0 += 32) {
#pragma unroll
    for (int e = 0; e < 8; ++e) {
      int idx = t + e * 256;
      int j = idx >> 4, kp = (idx & 15) * 2;
      unsigned mm, lm;
      unsigned hm = pack3(nx[e].x, nx[e].y, mm, lm);
      *reinterpret_cast<unsigned*>(&xs_h[j][kp]) = hm;
      *reinterpret_cast<unsigned*>(&xs_m[j][kp]) = mm;
      *reinterpret_cast<unsigned*>(&xs_l[j][kp]) = lm;
      hm = pack3(nu[e].x, nu[e].y, mm, lm);
      *reinterpret_cast<unsigned*>(&us_h[j][kp]) = hm;
      *reinterpret_cast<unsigned*>(&us_m[j][kp]) = mm;
      *reinterpret_cast<unsigned*>(&us_l[j][kp]) = lm;
    }
    if (k0 + 32 < 512) {
#pragma unroll
      for (int e = 0; e < 8; ++e) {
        int idx = t + e * 256;
        int j = idx >> 4, kp = (idx & 15) * 2;
        nx[e] = *reinterpret_cast<const float2*>(&in[inbase + (size_t)j * Dn + k0 + 32 + kp]);
        nu[e] = *reinterpret_cast<const float2*>(&qkt[ubase + (size_t)j * Dn + k0 + 32 + kp]);
      }
    }
    __syncthreads();
    short8 ah0 = *reinterpret_cast<const short8*>(&xs_h[w * 32 + lc][koff]);
    short8 am0 = *reinterpret_cast<const short8*>(&xs_m[w * 32 + lc][koff]);
    short8 al0 = *reinterpret_cast<const short8*>(&xs_l[w * 32 + lc][koff]);
    short8 ah1 = *reinterpret_cast<const short8*>(&xs_h[w * 32 + 16 + lc][koff]);
    short8 am1 = *reinterpret_cast<const short8*>(&xs_m[w * 32 + 16 + lc][koff]);
    short8 al1 = *reinterpret_cast<const short8*>(&xs_l[w * 32 + 16 + lc][koff]);
#pragma unroll
    for (int ht = 0; ht < 8; ++ht) {
      short8 bh = *reinterpret_cast<const short8*>(&us_h[ht * 16 + lc][koff]);
      short8 bm = *reinterpret_cast<const short8*>(&us_m[ht * 16 + lc][koff]);
      short8 bl = *reinterpret_cast<const short8*>(&us_l[ht * 16 + lc][koff]);
      acc[0][ht] = __builtin_amdgcn_mfma_f32_16x16x32_bf16(ah0, bh, acc[0][ht], 0, 0, 0);
      acc[0][ht] = __builtin_amdgcn_mfma_f32_16x16x32_bf16(ah0, bm, acc[0][ht], 0, 0, 0);
      acc[0][ht] = __builtin_amdgcn_mfma_f32_16x16x32_bf16(am0, bh, acc[0][ht], 0, 0, 0);
      acc[0][ht] = __builtin_amdgcn_mfma_f32_16x16x32_bf16(ah0, bl, acc[0][ht], 0, 0, 0);
      acc[0][ht] = __builtin_amdgcn_mfma_f32_16x16x32_bf16(al0, bh, acc[0][ht], 0, 0, 0);
      acc[0][ht] = __builtin_amdgcn_mfma_f32_16x16x32_bf16(am0, bm, acc[0][ht], 0, 0, 0);
      acc[1][ht] = __builtin_amdgcn_mfma_f32_16x16x32_bf16(ah1, bh, acc[1][ht], 0, 0, 0);
      acc[1][ht] = __builtin_amdgcn_mfma_f32_16x16x32_bf16(ah1, bm, acc[1][ht], 0, 0, 0);
      acc[1][ht] = __builtin_amdgcn_mfma_f32_16x16x32_bf16(am1, bh, acc[1][ht], 0, 0, 0);
      acc[1][ht] = __builtin_amdgcn_mfma_f32_16x16x32_bf16(ah1, bl, acc[1][ht], 0, 0, 0);
      acc[1][ht] = __builtin_amdgcn_mfma_f32_16x16x32_bf16(al1, bh, acc[1][ht], 0, 0, 0);
      acc[1][ht] = __builtin_amdgcn_mfma_f32_16x16x32_bf16(am1, bm, acc[1][ht], 0, 0, 0);
    }
    __syncthreads();
  }

  float* rsL = reinterpret_cast<float*>(&xs_h[0][0]);
  float* muL = rsL + 128;
  float* aL = rsL + 256;
  float* bL = rsL + 384;
  float (*sredS)[128] = reinterpret_cast<float(*)[128]>(rsL + 512);
  float (*sredC)[128] = reinterpret_cast<float(*)[128]>(rsL + 512 + 4 * 128);
  if (t < 128) {
    rsL[t] = rsig[(size_t)b * Nn + j0 + t];
    muL[t] = mu[(size_t)b * Nn + j0 + t];
    aL[t] = alpha[b * HIn + t];
    bL[t] = beta[b * HIn + t];
  }
  __syncthreads();

  float sS[8] = {}, sC[8] = {};
#pragma unroll
  for (int jt2 = 0; jt2 < 2; ++jt2) {
    int jbase = w * 32 + jt2 * 16 + lg * 4;
#pragma unroll
    for (int ht = 0; ht < 8; ++ht) {
      int hi = ht * 16 + lc;
      float av = aL[hi], bv = bL[hi];
      float v[4], rs4[4], mr4[4];
#pragma unroll
      for (int r = 0; r < 4; ++r) {
        int jr = jbase + r;
        rs4[r] = rsL[jr];
        mr4[r] = muL[jr] * rs4[r];
        v[r] = acc[jt2][ht][r] * rs4[r] + av - mr4[r] * bv;
      }
      float mx[4] = {v[0], v[1], v[2], v[3]};
#pragma unroll
      for (int m = 1; m <= 8; m <<= 1)
#pragma unroll
        for (int r = 0; r < 4; ++r) mx[r] = fmaxf(mx[r], __shfl_xor(mx[r], m));
      float e4[4], ss[4];
#pragma unroll
      for (int r = 0; r < 4; ++r) { e4[r] = expf(v[r] - mx[r]); ss[r] = e4[r]; }
#pragma unroll
      for (int m = 1; m <= 8; m <<= 1)
#pragma unroll
        for (int r = 0; r < 4; ++r) ss[r] += __shfl_xor(ss[r], m);
      float ps = 0.0f, pc = 0.0f;
      float p0 = e4[0] / ss[0] + kEps, p1 = e4[1] / ss[1] + kEps;
      float p2 = e4[2] / ss[2] + kEps, p3 = e4[3] / ss[3] + kEps;
      uint4 o4;
      o4.x = packhm(p0 * rs4[0]); o4.y = packhm(p1 * rs4[1]);
      o4.z = packhm(p2 * rs4[2]); o4.w = packhm(p3 * rs4[3]);
      ps = p0 + p1 + p2 + p3;
      pc = p0 * mr4[0] + p1 * mr4[1] + p2 * mr4[2] + p3 * mr4[3];
      *reinterpret_cast<uint4*>(&A[(size_t)(b * HIn + hi) * Nn + j0 + jbase]) = o4;
      ps += __shfl_xor(ps, 16); ps += __shfl_xor(ps, 32);
      pc += __shfl_xor(pc, 16); pc += __shfl_xor(pc, 32);
      sS[ht] += ps; sC[ht] += pc;
    }
  }
  if (l < 16) {
#pragma unroll
    for (int ht = 0; ht < 8; ++ht) {
      sredS[w][ht * 16 + l] = sS[ht];
      sredC[w][ht * 16 + l] = sC[ht];
    }
  }
  __syncthreads();
  if (t < 128) {
    float s_ = sredS[0][t] + sredS[1][t] + sredS[2][t] + sredS[3][t];
    float c_ = sredC[0][t] + sredC[1][t] + sredC[2][t] + sredC[3][t];
    int sub = (b * 32 + jt) * HIn + t;
    Spart[sub] = s_;
    c1part[sub] = c_;
  }
}

// ---------------- AX = A @ X via 2-level bf16-split MFMA (K-split x4) ----------------
// A from packed u32 hi|mid; X from inT packed u32 [B,D,N].
__global__ __launch_bounds__(256) void k_ax(const unsigned* __restrict__ Au, const unsigned* __restrict__ inT,
                                            float* __restrict__ AXp) {
  __shared__ __align__(16) unsigned short as_h[128][40];
  __shared__ __align__(16) unsigned short as_m[128][40];
  __shared__ __align__(16) unsigned short xs_h[128][40];
  __shared__ __align__(16) unsigned short xs_m[128][40];

  int d0 = blockIdx.x * 128, kp = blockIdx.y, b = blockIdx.z;
  int t = threadIdx.x, w = t >> 6, l = t & 63;
  int lc = l & 15, lg = l >> 4, koff = lg * 8;
  const size_t abase = (size_t)b * HIn * Nn + kp * 1024;
  const size_t xbase = ((size_t)b * Dn + d0) * Nn + kp * 1024;

  f32x4 acc[2][8];
#pragma unroll
  for (int i = 0; i < 2; ++i)
#pragma unroll
    for (int j2 = 0; j2 < 8; ++j2) acc[i][j2] = {0.0f, 0.0f, 0.0f, 0.0f};

  uint2 pa[8];
  uint4 px[4];
#pragma unroll
  for (int e = 0; e < 8; ++e) {
    int idx = t + e * 256;
    int hi = idx >> 4, jp = (idx & 15) * 2;
    pa[e] = *reinterpret_cast<const uint2*>(&Au[abase + (size_t)hi * Nn + jp]);
  }
#pragma unroll
  for (int e = 0; e < 4; ++e) {
    int idx = t + e * 256;
    int d = idx >> 3, jg = idx & 7;
    px[e] = *reinterpret_cast<const uint4*>(&inT[xbase + (size_t)d * Nn + jg * 4]);
  }

  for (int c0 = 0; c0 < 1024; c0 += 32) {
#pragma unroll
    for (int e = 0; e < 8; ++e) {
      int idx = t + e * 256;
      int hi = idx >> 4, jp = (idx & 15) * 2;
      unsigned h = (pa[e].x & 0xffffu) | (pa[e].y << 16);
      unsigned m = (pa[e].x >> 16) | (pa[e].y & 0xffff0000u);
      *reinterpret_cast<unsigned*>(&as_h[hi][jp]) = h;
      *reinterpret_cast<unsigned*>(&as_m[hi][jp]) = m;
    }
#pragma unroll
    for (int e = 0; e < 4; ++e) {
      int idx = t + e * 256;
      int d = idx >> 3, jg = idx & 7;
      unsigned h0 = (px[e].x & 0xffffu) | (px[e].y << 16);
      unsigned h1 = (px[e].z & 0xffffu) | (px[e].w << 16);
      unsigned m0 = (px[e].x >> 16) | (px[e].y & 0xffff0000u);
      unsigned m1 = (px[e].z >> 16) | (px[e].w & 0xffff0000u);
      uint2 hv = {h0, h1}, mv = {m0, m1};
      *reinterpret_cast<uint2*>(&xs_h[d][jg * 4]) = hv;
      *reinterpret_cast<uint2*>(&xs_m[d][jg * 4]) = mv;
    }
    if (c0 + 32 < 1024) {
#pragma unroll
      for (int e = 0; e < 8; ++e) {
        int idx = t + e * 256;
        int hi = idx >> 4, jp = (idx & 15) * 2;
        pa[e] = *reinterpret_cast<const uint2*>(&Au[abase + (size_t)hi * Nn + c0 + 32 + jp]);
      }
#pragma unroll
      for (int e = 0; e < 4; ++e) {
        int idx = t + e * 256;
        int d = idx >> 3, jg = idx & 7;
        px[e] = *reinterpret_cast<const uint4*>(&inT[xbase + (size_t)d * Nn + c0 + 32 + jg * 4]);
      }
    }
    __syncthreads();
    short8 ah0 = *reinterpret_cast<const short8*>(&as_h[w * 32 + lc][koff]);
    short8 am0 = *reinterpret_cast<const short8*>(&as_m[w * 32 + lc][koff]);
    short8 ah1 = *reinterpret_cast<const short8*>(&as_h[w * 32 + 16 + lc][koff]);
    short8 am1 = *reinterpret_cast<const short8*>(&as_m[w * 32 + 16 + lc][koff]);
#pragma unroll
    for (int dt = 0; dt < 8; ++dt) {
      short8 bh = *reinterpret_cast<const short8*>(&xs_h[dt * 16 + lc][koff]);
      short8 bm = *reinterpret_cast<const short8*>(&xs_m[dt * 16 + lc][koff]);
      acc[0][dt] = __builtin_amdgcn_mfma_f32_16x16x32_bf16(ah0, bh, acc[0][dt], 0, 0, 0);
      acc[0][dt] = __builtin_amdgcn_mfma_f32_16x16x32_bf16(ah0, bm, acc[0][dt], 0, 0, 0);
      acc[0][dt] = __builtin_amdgcn_mfma_f32_16x16x32_bf16(am0, bh, acc[0][dt], 0, 0, 0);
      acc[1][dt] = __builtin_amdgcn_mfma_f32_16x16x32_bf16(ah1, bh, acc[1][dt], 0, 0, 0);
      acc[1][dt] = __builtin_amdgcn_mfma_f32_16x16x32_bf16(ah1, bm, acc[1][dt], 0, 0, 0);
      acc[1][dt] = __builtin_amdgcn_mfma_f32_16x16x32_bf16(am1, bh, acc[1][dt], 0, 0, 0);
    }
    __syncthreads();
  }

  const size_t obase = (((size_t)kp * Bn + b) * HIn) * Dn + d0;
#pragma unroll
  for (int jt2 = 0; jt2 < 2; ++jt2) {
#pragma unroll
    for (int dt = 0; dt < 8; ++dt) {
#pragma unroll
      for (int r = 0; r < 4; ++r) {
        int hi = w * 32 + jt2 * 16 + lg * 4 + r;
        int d = dt * 16 + lc;
        AXp[obase + (size_t)hi * Dn + d] = acc[jt2][dt][r];
      }
    }
  }
}

// ---------------- upd = ((w*(G-c1)/S + b) @ Wv_h) + bv, S/c1 reduced inline ----------------
__global__ __launch_bounds__(256) void k_updS(const float* __restrict__ AXp, const float* __restrict__ Spart,
                                              const float* __restrict__ c1part, const float* __restrict__ lnw,
                                              const float* __restrict__ lnb, const float* __restrict__ Wv,
                                              const float* __restrict__ bv, float* __restrict__ upd) {
  int b = blockIdx.y, hi = blockIdx.x, h = hi >> 4, i = hi & 15;
  __shared__ float vx[512];
  __shared__ float red[256];
  __shared__ float sSC[2];
  int t = threadIdx.x;
  if (t < 64) {
    float vs = 0.0f, vc = 0.0f;
    if (t < 32) {
      vs = Spart[(size_t)(b * 32 + t) * HIn + hi];
      vc = c1part[(size_t)(b * 32 + t) * HIn + hi];
    }
    vs = wred(vs); vc = wred(vc);
    if (t == 0) { sSC[0] = vs; sSC[1] = vc; }
  }
  __syncthreads();
  float c1v = sSC[1];
  float invS = 1.0f / sSC[0];
  for (int d = t; d < Dn; d += 256) {
    float G = AXp[((size_t)(0 * Bn + b) * HIn + hi) * Dn + d]
            + AXp[((size_t)(1 * Bn + b) * HIn + hi) * Dn + d]
            + AXp[((size_t)(2 * Bn + b) * HIn + hi) * Dn + d]
            + AXp[((size_t)(3 * Bn + b) * HIn + hi) * Dn + d];
    vx[d] = lnw[d] * (G - c1v) * invS + lnb[d];
  }
  __syncthreads();
  int cc = t & 63, qd = t >> 6;
  float p = 0.0f;
  for (int d = qd * 128; d < qd * 128 + 128; ++d) p += vx[d] * Wv[(size_t)d * Dn + h * 64 + cc];
  red[t] = p;
  __syncthreads();
  if (qd == 0) {
    float v = red[cc] + red[64 + cc] + red[128 + cc] + red[192 + cc] + bv[h * 64 + cc];
    upd[(size_t)(b * NSn + i) * Dn + h * 64 + cc] = v;
  }
}

// ---------------- dual GEMM: z=0: gi = upd@T1 + bcih ; z=1: gh = slots@Whh^T + bhh ----------------
__global__ __launch_bounds__(256) void k_gg(const float* __restrict__ upd, const float* __restrict__ T1,
                                            const float* __restrict__ bcih, const float* __restrict__ slots,
                                            const float* __restrict__ Whh, const float* __restrict__ bhh,
                                            float* __restrict__ gi, float* __restrict__ gh) {
  bool z = (blockIdx.z == 1);
  const float* A = z ? slots : upd;
  const float* W = z ? Whh : T1;
  const float* bias = z ? bhh : bcih;
  float* out = z ? gh : gi;
  __shared__ float as_[64][17];
  __shared__ float ws_[16][65];
  int m0 = blockIdx.y * 64, n0 = blockIdx.x * 64;
  int t = threadIdx.x, tx = t & 15, ty = t >> 4;
  float acc[4][4] = {};
  for (int k0 = 0; k0 < 512; k0 += 16) {
#pragma unroll
    for (int e = 0; e < 4; ++e) {
      int idx = t + e * 256;
      int r = idx >> 4, c = idx & 15;
      as_[r][c] = A[(size_t)(m0 + r) * 512 + k0 + c];
    }
    if (!z) {
#pragma unroll
      for (int e = 0; e < 4; ++e) {
        int idx = t + e * 256;
        int r = idx >> 6, c = idx & 63;
        ws_[r][c] = W[(size_t)(k0 + r) * 1536 + n0 + c];
      }
    } else {
#pragma unroll
      for (int e = 0; e < 4; ++e) {
        int idx = t + e * 256;
        int r = idx >> 4, c = idx & 15;
        ws_[c][r] = W[(size_t)(n0 + r) * 512 + k0 + c];
      }
    }
    __syncthreads();
#pragma unroll
    for (int kc = 0; kc < 16; ++kc) {
      float av[4], wv[4];
#pragma unroll
      for (int i = 0; i < 4; ++i) av[i] = as_[ty * 4 + i][kc];
#pragma unroll
      for (int j = 0; j < 4; ++j) wv[j] = ws_[kc][tx * 4 + j];
#pragma unroll
      for (int i = 0; i < 4; ++i)
#pragma unroll
        for (int j = 0; j < 4; ++j) acc[i][j] += av[i] * wv[j];
    }
    __syncthreads();
  }
#pragma unroll
  for (int i = 0; i < 4; ++i)
#pragma unroll
    for (int j = 0; j < 4; ++j) {
      int m = m0 + ty * 4 + i, n = n0 + tx * 4 + j;
      out[(size_t)m * 1536 + n] = acc[i][j] + bias[n];
    }
}

// ---------------- GRU pointwise + LN_ff fused ----------------
__global__ __launch_bounds__(256) void k_gruln(const float* __restrict__ gi, const float* __restrict__ gh,
                                               float* __restrict__ slots, float* __restrict__ slnff,
                                               const float* __restrict__ lnffw, const float* __restrict__ lnffb) {
  int r = blockIdx.x, t = threadIdx.x;
  __shared__ float red[8];
  float sn[2];
#pragma unroll
  for (int j = 0; j < 2; ++j) {
    int c = j * 256 + t;
    float gir = gi[(size_t)r * 1536 + c];
    float giz = gi[(size_t)r * 1536 + 512 + c];
    float gin = gi[(size_t)r * 1536 + 1024 + c];
    float ghr = gh[(size_t)r * 1536 + c];
    float ghz = gh[(size_t)r * 1536 + 512 + c];
    float ghn = gh[(size_t)r * 1536 + 1024 + c];
    float rg = 1.0f / (1.0f + expf(-(gir + ghr)));
    float zg = 1.0f / (1.0f + expf(-(giz + ghz)));
    float ng = tanhf(gin + rg * ghn);
    sn[j] = (1.0f - zg) * ng + zg * slots[(size_t)r * Dn + c];
  }
  float s = sn[0] + sn[1], q = sn[0] * sn[0] + sn[1] * sn[1];
  s = wred(s); q = wred(q);
  if ((t & 63) == 0) { red[t >> 6] = s; red[4 + (t >> 6)] = q; }
  __syncthreads();
  float S = red[0] + red[1] + red[2] + red[3];
  float Q = red[4] + red[5] + red[6] + red[7];
  float m = S * (1.0f / 512.0f);
  float rs = 1.0f / sqrtf(Q * (1.0f / 512.0f) - m * m + 1e-5f);
#pragma unroll
  for (int j = 0; j < 2; ++j) {
    int c = j * 256 + t;
    slots[(size_t)r * Dn + c] = sn[j];
    slnff[(size_t)r * Dn + c] = (sn[j] - m) * rs * lnffw[c] + lnffb[c];
  }
}

// ---------------- keep gate (zero dropped slots in place) ----------------
__global__ void k_keepscale(const float* __restrict__ Wkeep, const float* __restrict__ gk,
                            float* __restrict__ slots) {
  int g = blockIdx.x;
  int lane = threadIdx.x;
  float4* sp = reinterpret_cast<float4*>(slots + (size_t)g * Dn) + lane * 2;
  float4 s0 = sp[0], s1 = sp[1];
  float sv[8] = {s0.x, s0.y, s0.z, s0.w, s1.x, s1.y, s1.z, s1.w};
  double d0 = 0.0, d1 = 0.0;
#pragma unroll
  for (int e = 0; e < 8; ++e) {
    int d = lane * 8 + e;
    d0 += (double)sv[e] * (double)Wkeep[d * 2];
    d1 += (double)sv[e] * (double)Wkeep[d * 2 + 1];
  }
  d0 = wredd(d0);
  d1 = wredd(d1);
  int keepi = 0;
  if (lane == 0) keepi = ((d1 + (double)gk[g * 2 + 1]) > (d0 + (double)gk[g * 2])) ? 1 : 0;
  keepi = __shfl(keepi, 0);
  if (!keepi) {
    float4 z = {0.0f, 0.0f, 0.0f, 0.0f};
    sp[0] = z;
    sp[1] = z;
  }
}

// ---------------- per-slot scalars for route decomposition ----------------
__global__ void k_slotscalars(const float* __restrict__ slots, const float* __restrict__ lnw,
                              const float* __restrict__ lnb, double* __restrict__ swd,
                              double* __restrict__ sbd) {
  int g = blockIdx.x, lane = threadIdx.x;
  const float4* sp = reinterpret_cast<const float4*>(slots + (size_t)g * Dn) + lane * 2;
  const float4* wp = reinterpret_cast<const float4*>(lnw) + lane * 2;
  const float4* bp = reinterpret_cast<const float4*>(lnb) + lane * 2;
  float4 s0 = sp[0], s1 = sp[1], w0 = wp[0], w1 = wp[1], b0 = bp[0], b1 = bp[1];
  double pw = (double)s0.x * w0.x + (double)s0.y * w0.y + (double)s0.z * w0.z + (double)s0.w * w0.w +
              (double)s1.x * w1.x + (double)s1.y * w1.y + (double)s1.z * w1.z + (double)s1.w * w1.w;
  double pb = (double)s0.x * b0.x + (double)s0.y * b0.y + (double)s0.z * b0.z + (double)s0.w * b0.w +
              (double)s1.x * b1.x + (double)s1.y * b1.y + (double)s1.z * b1.z + (double)s1.w * b1.w;
  pw = wredd(pw);
  pb = wredd(pb);
  if (lane == 0) { swd[g] = pw; sbd[g] = pb; }
}

// ---------------- hard route + gather output (tiled mini-GEMM) ----------------
__global__ __launch_bounds__(256) void k_route_out(const float* __restrict__ in, const float* __restrict__ slots,
                                                   const float* __restrict__ lnw, const double* __restrict__ swd,
                                                   const double* __restrict__ sbd, const float* __restrict__ mu,
                                                   const float* __restrict__ rsig,
                                                   const float* __restrict__ g_route, float* __restrict__ out) {
  int b = blockIdx.y, j0 = blockIdx.x * 128;
  __shared__ __align__(16) float sl[16 * 516];
  __shared__ __align__(16) float lw[512];
  __shared__ __align__(16) float xs[16][132];
  __shared__ double lgd[128][17];
  __shared__ int besti[128];
  int t = threadIdx.x, tx = t & 15, ty = t >> 4;

  for (int idx = t; idx < 2048; idx += 256) {
    int i = idx >> 7, c = idx & 127;
    *reinterpret_cast<float4*>(&sl[i * 516 + c * 4]) =
        *reinterpret_cast<const float4*>(&slots[(size_t)(b * NSn + i) * Dn + c * 4]);
  }
  if (t < 128)
    *reinterpret_cast<float4*>(&lw[t * 4]) = *reinterpret_cast<const float4*>(&lnw[t * 4]);

  float acc[8] = {};
  double accd[8] = {};
  const size_t inbase = ((size_t)b * Nn + j0) * Dn;
  __syncthreads();

  for (int k0 = 0; k0 < Dn; k0 += 16) {
    float pre[8];
#pragma unroll
    for (int e = 0; e < 8; ++e) {
      int idx = t + e * 256;
      int r = idx >> 4, c = idx & 15;
      pre[e] = in[inbase + (size_t)r * Dn + k0 + c];
    }
    __syncthreads();
#pragma unroll
    for (int e = 0; e < 8; ++e) {
      int idx = t + e * 256;
      int r = idx >> 4, c = idx & 15;
      xs[c][r] = pre[e] * lw[k0 + c];
    }
    __syncthreads();
#pragma unroll
    for (int kc = 0; kc < 16; ++kc) {
      float sv = sl[tx * 516 + k0 + kc];
      float4 x0 = *reinterpret_cast<const float4*>(&xs[kc][ty * 8]);
      float4 x1 = *reinterpret_cast<const float4*>(&xs[kc][ty * 8 + 4]);
      acc[0] += x0.x * sv; acc[1] += x0.y * sv; acc[2] += x0.z * sv; acc[3] += x0.w * sv;
      acc[4] += x1.x * sv; acc[5] += x1.y * sv; acc[6] += x1.z * sv; acc[7] += x1.w * sv;
    }
    if ((k0 & 127) == 112) {
#pragma unroll
      for (int e = 0; e < 8; ++e) { accd[e] += (double)acc[e]; acc[e] = 0.0f; }
    }
  }

  double sw_i = swd[b * NSn + tx], sb_i = sbd[b * NSn + tx];
#pragma unroll
  for (int r = 0; r < 8; ++r) {
    int j = ty * 8 + r;
    double rsj = (double)rsig[(size_t)b * Nn + j0 + j];
    double muj = (double)mu[(size_t)b * Nn + j0 + j];
    double g = (double)g_route[((size_t)b * NSn + tx) * Nn + j0 + j];
    lgd[j][tx] = (double)kScale * (rsj * accd[r] + sb_i - muj * rsj * sw_i) + g;
  }
  __syncthreads();
  if (t < 128) {
    double best = lgd[t][0];
    int bi = 0;
#pragma unroll
    for (int i = 1; i < 16; ++i) {
      double v = lgd[t][i];
      if (v > best) { best = v; bi = i; }
    }
    besti[t] = bi;
  }
  __syncthreads();
  for (int idx = t; idx < 128 * 128; idx += 256) {
    int j = idx >> 7, c = idx & 127;
    *reinterpret_cast<float4*>(&out[inbase + (size_t)j * Dn + c * 4]) =
        *reinterpret_cast<const float4*>(&sl[besti[j] * 516 + c * 4]);
  }
}

extern "C" void kernel_launch(void* const* d_in, const int* in_sizes, int n_in,
                              void* d_out, int out_size, void* d_ws, size_t ws_size,
                              hipStream_t stream) {
  (void)in_sizes; (void)n_in; (void)out_size; (void)ws_size;
  const float* in = (const float*)d_in[0];
  const float* slots_mu = (const float*)d_in[1];
  const float* slots_ls = (const float*)d_in[2];
  const float* ln_in_w = (const float*)d_in[3];
  const float* ln_in_b = (const float*)d_in[4];
  const float* ln_s_w = (const float*)d_in[5];
  const float* ln_s_b = (const float*)d_in[6];
  const float* ln_ff_w = (const float*)d_in[7];
  const float* ln_ff_b = (const float*)d_in[8];
  const float* Wq = (const float*)d_in[9];
  const float* bq = (const float*)d_in[10];
  const float* Wk = (const float*)d_in[11];
  const float* bk = (const float*)d_in[12];
  const float* Wv = (const float*)d_in[13];
  const float* bv = (const float*)d_in[14];
  const float* Wc = (const float*)d_in[15];
  const float* bc = (const float*)d_in[16];
  const float* Wih = (const float*)d_in[17];
  const float* bih = (const float*)d_in[18];
  const float* Whh = (const float*)d_in[19];
  const float* bhh = (const float*)d_in[20];
  const float* W1 = (const float*)d_in[21];
  const float* b1 = (const float*)d_in[22];
  const float* W2 = (const float*)d_in[23];
  const float* b2 = (const float*)d_in[24];
  const float* Wkeep = (const float*)d_in[25];
  const float* noise = (const float*)d_in[26];
  const float* g_keep = (const float*)d_in[27];
  const float* g_route = (const float*)d_in[28];
  float* out = (float*)d_out;
  unsigned* inTu = (unsigned*)d_out;   // scratch during iterations; overwritten by k_route_out

  char* wptr = (char*)d_ws;
  auto alloc = [&](size_t bytes) {
    char* p = wptr;
    wptr += (bytes + 255) & ~(size_t)255;
    return p;
  };
  float* mu = (float*)alloc((size_t)Bn * Nn * 4);
  float* rsig = (float*)alloc((size_t)Bn * Nn * 4);
  float* slots = (float*)alloc((size_t)Bn * NSn * Dn * 4);
  float* sln = (float*)alloc((size_t)Bn * NSn * Dn * 4);
  float* qkt = (float*)alloc((size_t)Bn * HIn * Dn * 4);
  float* alpha = (float*)alloc((size_t)Bn * HIn * 4);
  float* beta = (float*)alloc((size_t)Bn * HIn * 4);
  unsigned* Abuf = (unsigned*)alloc((size_t)Bn * HIn * Nn * 4);
  float* Spart = (float*)alloc((size_t)Bn * 64 * HIn * 4);
  float* c1part = (float*)alloc((size_t)Bn * 64 * HIn * 4);
  float* AXp = (float*)alloc((size_t)4 * Bn * HIn * Dn * 4);
  float* updb = (float*)alloc((size_t)Bn * NSn * Dn * 4);
  float* gibuf = (float*)alloc((size_t)Bn * NSn * 1536 * 4);
  float* ghbuf = (float*)alloc((size_t)Bn * NSn * 1536 * 4);
  float* hbuf = (float*)alloc((size_t)Bn * NSn * 2048 * 4);
  float* T1 = (float*)alloc((size_t)Dn * 1536 * 4);
  float* bcih = (float*)alloc((size_t)1536 * 4);
  float* Ms = (float*)alloc((size_t)Dn * 4096 * 4);
  float* vb_raw = (float*)alloc((size_t)4096 * 4);
  float* vb_s = (float*)alloc((size_t)4096 * 4);
  float* avec = (float*)alloc((size_t)4096 * 4);
  float* bvec = (float*)alloc((size_t)4096 * 4);
  float* aconst = (float*)alloc((size_t)8 * 4);
  float* bconst = (float*)alloc((size_t)8 * 4);
  double* swd = (double*)alloc((size_t)Bn * NSn * 8);
  double* sbd = (double*)alloc((size_t)Bn * NSn * 8);

  // prologue
  k_rowstats<<<Bn * Nn / 4, 256, 0, stream>>>(in, mu, rsig);
  k_tsplit<<<dim3(Nn / 64, Dn / 64, Bn), 256, 0, stream>>>(in, inTu);
  k_slots_init<<<Bn * NSn, 256, 0, stream>>>(slots_mu, slots_ls, noise, slots);
  k_gemm_sm<true, false, false><<<dim3(24, 8), 256, 0, stream>>>(Wc, Wih, nullptr, T1, 1536, 512);
  k_bcih<<<6, 256, 0, stream>>>(bc, Wih, bih, bcih);
  k_mh<<<dim3(8, 8, 8), 256, 0, stream>>>(Wq, Wk, Ms);
  k_vbias<<<2, 256, 0, stream>>>(Wk, bq, ln_in_w, vb_raw, vb_s);
  k_mfold<<<16, 256, 0, stream>>>(Ms, Wq, bk, ln_in_w, ln_in_b, avec, bvec);
  k_consts<<<1, 256, 0, stream>>>(vb_raw, bq, bk, ln_in_w, ln_in_b, aconst, bconst);
  k_ln_rows<<<Bn * NSn, 256, 0, stream>>>(slots, ln_s_w, ln_s_b, sln);

  for (int it = 0; it < 3; ++it) {
    k_qu<<<dim3(64, 8), 256, 0, stream>>>(sln, Ms, vb_s, qkt);
    k_ab<<<Bn * HIn, 64, 0, stream>>>(sln, avec, bvec, aconst, bconst, alpha, beta);
    k_dots<<<dim3(Nn / 128, Bn), 256, 0, stream>>>(in, qkt, alpha, beta, mu, rsig, Abuf, Spart, c1part);
    k_ax<<<dim3(4, 4, Bn), 256, 0, stream>>>(Abuf, inTu, AXp);
    k_updS<<<dim3(HIn, Bn), 256, 0, stream>>>(AXp, Spart, c1part, ln_in_w, ln_in_b, Wv, bv, updb);
    k_gg<<<dim3(24, 8, 2), 256, 0, stream>>>(updb, T1, bcih, slots, Whh, bhh, gibuf, ghbuf);
    k_gruln<<<Bn * NSn, 256, 0, stream>>>(gibuf, ghbuf, slots, sln, ln_ff_w, ln_ff_b);
    k_gemm_sm<false, true, false><<<dim3(32, 8), 256, 0, stream>>>(sln, W1, b1, hbuf, 2048, 512);
    k_gemm_sm<false, false, true><<<dim3(8, 8), 256, 0, stream>>>(hbuf, W2, b2, slots, 512, 2048);
    k_ln_rows<<<Bn * NSn, 256, 0, stream>>>(slots, ln_s_w, ln_s_b, sln);
  }

  k_keepscale<<<Bn * NSn, 64, 0, stream>>>(Wkeep, g_keep, slots);
  k_slotscalars<<<Bn * NSn, 64, 0, stream>>>(slots, ln_in_w, ln_in_b, swd, sbd);
  k_route_out<<<dim3(Nn / 128, Bn), 256, 0, stream>>>(in, slots, ln_in_w, swd, sbd, mu, rsig, g_route, out);
}

// Round 7
// 1925.041 us; speedup vs baseline: 1.8525x; 1.2701x over previous
//
#include <hip/hip_runtime.h>
#include <hip/hip_bf16.h>
#include <math.h>

constexpr int Bn = 32, Nn = 4096, Dn = 512, NSn = 16, HIn = 128;
constexpr float kScale = 0.04419417382415922f; // 512^-0.5
constexpr float kEps = 1e-8f;

typedef __attribute__((ext_vector_type(8))) short short8;
typedef __attribute__((ext_vector_type(4))) float f32x4;

__device__ __forceinline__ float wred(float v) {
#pragma unroll
  for (int m = 32; m > 0; m >>= 1) v += __shfl_xor(v, m);
  return v;
}
__device__ __forceinline__ double wredd(double v) {
#pragma unroll
  for (int m = 32; m > 0; m >>= 1) v += __shfl_xor(v, m);
  return v;
}

// ---- bf16 split helpers (RNE) ----
__device__ __forceinline__ unsigned short f2bf(float x) {
  unsigned u = __float_as_uint(x);
  unsigned r = (u + 0x7fffu + ((u >> 16) & 1u)) >> 16;
  return (unsigned short)r;
}
__device__ __forceinline__ float bf2f(unsigned short h) {
  return __uint_as_float(((unsigned)h) << 16);
}
__device__ __forceinline__ unsigned pack3(float x0, float x1, unsigned& mo, unsigned& lo) {
  unsigned short h0 = f2bf(x0); float r0 = x0 - bf2f(h0);
  unsigned short m0 = f2bf(r0); float q0 = r0 - bf2f(m0);
  unsigned short l0 = f2bf(q0);
  unsigned short h1 = f2bf(x1); float r1 = x1 - bf2f(h1);
  unsigned short m1 = f2bf(r1); float q1 = r1 - bf2f(m1);
  unsigned short l1 = f2bf(q1);
  mo = (unsigned)m0 | ((unsigned)m1 << 16);
  lo = (unsigned)l0 | ((unsigned)l1 << 16);
  return (unsigned)h0 | ((unsigned)h1 << 16);
}
__device__ __forceinline__ unsigned packhm(float x) {
  unsigned short h = f2bf(x);
  unsigned short m = f2bf(x - bf2f(h));
  return (unsigned)h | ((unsigned)m << 16);
}

// ---------------- per-row LN stats of inputs ----------------
__global__ __launch_bounds__(256) void k_rowstats(const float* __restrict__ in,
                                                  float* __restrict__ mu, float* __restrict__ rsig) {
  int row = blockIdx.x * 4 + (threadIdx.x >> 6);
  int lane = threadIdx.x & 63;
  const float4* p = reinterpret_cast<const float4*>(in + (size_t)row * Dn) + lane * 2;
  float4 a = p[0], b = p[1];
  float s = a.x + a.y + a.z + a.w + b.x + b.y + b.z + b.w;
  float q = a.x*a.x + a.y*a.y + a.z*a.z + a.w*a.w + b.x*b.x + b.y*b.y + b.z*b.z + b.w*b.w;
  s = wred(s); q = wred(q);
  if (lane == 0) {
    float m = s * (1.0f / 512.0f);
    float var = q * (1.0f / 512.0f) - m * m;
    mu[row] = m;
    rsig[row] = 1.0f / sqrtf(var + 1e-5f);
  }
}

// ---------------- transpose + hi/mid split: in[B,N,D] -> inT[B,D,N] (u32 = h|m<<16) ----------------
__global__ __launch_bounds__(256) void k_tsplit(const float* __restrict__ in, unsigned* __restrict__ inT) {
  __shared__ float tile[64][65];
  int b = blockIdx.z, j0 = blockIdx.x * 64, d0 = blockIdx.y * 64;
  int t = threadIdx.x;
#pragma unroll
  for (int e = 0; e < 16; ++e) {
    int idx = t + e * 256;
    int r = idx >> 6, c = idx & 63;
    tile[r][c] = in[((size_t)b * Nn + j0 + r) * Dn + d0 + c];
  }
  __syncthreads();
#pragma unroll
  for (int e = 0; e < 16; ++e) {
    int idx = t + e * 256;
    int r = idx >> 6, c = idx & 63;
    inT[((size_t)b * Dn + d0 + r) * Nn + j0 + c] = packhm(tile[c][r]);
  }
}

// ---------------- slots init ----------------
__global__ __launch_bounds__(256) void k_slots_init(const float* __restrict__ smu, const float* __restrict__ sls,
                                                    const float* __restrict__ noise, float* __restrict__ slots) {
  int r = blockIdx.x;
  for (int d = threadIdx.x; d < Dn; d += 256)
    slots[(size_t)r * Dn + d] = smu[d] + expf(sls[d]) * noise[(size_t)r * Dn + d];
}

// ---------------- LN of [R,512] rows ----------------
__global__ __launch_bounds__(256) void k_ln_rows(const float* __restrict__ src, const float* __restrict__ w,
                                                 const float* __restrict__ b, float* __restrict__ dst) {
  int r = blockIdx.x;
  __shared__ float red[8];
  int t = threadIdx.x;
  float x0 = src[(size_t)r * Dn + t], x1 = src[(size_t)r * Dn + 256 + t];
  float s = x0 + x1, q = x0 * x0 + x1 * x1;
  s = wred(s); q = wred(q);
  if ((t & 63) == 0) { red[t >> 6] = s; red[4 + (t >> 6)] = q; }
  __syncthreads();
  float S = red[0] + red[1] + red[2] + red[3];
  float Q = red[4] + red[5] + red[6] + red[7];
  float m = S * (1.0f / 512.0f);
  float rs = 1.0f / sqrtf(Q * (1.0f / 512.0f) - m * m + 1e-5f);
  dst[(size_t)r * Dn + t] = (x0 - m) * rs * w[t] + b[t];
  dst[(size_t)r * Dn + 256 + t] = (x1 - m) * rs * w[256 + t] + b[256 + t];
}

// ---------------- small GEMM with register prefetch: out = act(A@W (+bias) (+out)) ----------------
template <bool TRANS, bool RELU, bool ADD>
__global__ __launch_bounds__(256) void k_gemm_sm(const float* __restrict__ A, const float* __restrict__ W,
                                                 const float* __restrict__ bias, float* __restrict__ out,
                                                 int Nc, int K) {
  __shared__ float as_[64][17];
  __shared__ float ws_[16][65];
  int m0 = blockIdx.y * 64, n0 = blockIdx.x * 64;
  int t = threadIdx.x, tx = t & 15, ty = t >> 4;
  float acc[4][4] = {};
  float pa[4], pw[4];
  auto loadA = [&](int k0) {
#pragma unroll
    for (int e = 0; e < 4; ++e) {
      int idx = t + e * 256;
      int r = idx >> 4, c = idx & 15;
      pa[e] = A[(size_t)(m0 + r) * K + k0 + c];
    }
  };
  auto loadW = [&](int k0) {
#pragma unroll
    for (int e = 0; e < 4; ++e) {
      int idx = t + e * 256;
      if (!TRANS) {
        int r = idx >> 6, c = idx & 63;
        pw[e] = W[(size_t)(k0 + r) * Nc + n0 + c];
      } else {
        int r = idx >> 4, c = idx & 15;
        pw[e] = W[(size_t)(n0 + r) * K + k0 + c];
      }
    }
  };
  loadA(0); loadW(0);
  for (int k0 = 0; k0 < K; k0 += 16) {
#pragma unroll
    for (int e = 0; e < 4; ++e) {
      int idx = t + e * 256;
      int r = idx >> 4, c = idx & 15;
      as_[r][c] = pa[e];
    }
#pragma unroll
    for (int e = 0; e < 4; ++e) {
      int idx = t + e * 256;
      if (!TRANS) {
        int r = idx >> 6, c = idx & 63;
        ws_[r][c] = pw[e];
      } else {
        int r = idx >> 4, c = idx & 15;
        ws_[c][r] = pw[e];
      }
    }
    __syncthreads();
    if (k0 + 16 < K) { loadA(k0 + 16); loadW(k0 + 16); }
#pragma unroll
    for (int kc = 0; kc < 16; ++kc) {
      float av[4], wv[4];
#pragma unroll
      for (int i = 0; i < 4; ++i) av[i] = as_[ty * 4 + i][kc];
#pragma unroll
      for (int j = 0; j < 4; ++j) wv[j] = ws_[kc][tx * 4 + j];
#pragma unroll
      for (int i = 0; i < 4; ++i)
#pragma unroll
        for (int j = 0; j < 4; ++j) acc[i][j] += av[i] * wv[j];
    }
    __syncthreads();
  }
#pragma unroll
  for (int i = 0; i < 4; ++i)
#pragma unroll
    for (int j = 0; j < 4; ++j) {
      int m = m0 + ty * 4 + i, n = n0 + tx * 4 + j;
      float v = acc[i][j] + (bias ? bias[n] : 0.0f);
      if (RELU) v = fmaxf(v, 0.0f);
      if (ADD) v += out[(size_t)m * Nc + n];
      out[(size_t)m * Nc + n] = v;
    }
}

// ---------------- W2 K-split partial GEMM: part[kp] = hbuf[:, kp*512:+512] @ W2[kp*512:+512, :] ----------------
__global__ __launch_bounds__(256) void k_w2split(const float* __restrict__ A, const float* __restrict__ W,
                                                 float* __restrict__ part) {
  __shared__ float as_[64][17];
  __shared__ float ws_[16][65];
  int m0 = blockIdx.y * 64, n0 = blockIdx.x * 64, kb = blockIdx.z * 512;
  int t = threadIdx.x, tx = t & 15, ty = t >> 4;
  float acc[4][4] = {};
  float pa[4], pw[4];
  auto loadA = [&](int k0) {
#pragma unroll
    for (int e = 0; e < 4; ++e) {
      int idx = t + e * 256;
      int r = idx >> 4, c = idx & 15;
      pa[e] = A[(size_t)(m0 + r) * 2048 + kb + k0 + c];
    }
  };
  auto loadW = [&](int k0) {
#pragma unroll
    for (int e = 0; e < 4; ++e) {
      int idx = t + e * 256;
      int r = idx >> 6, c = idx & 63;
      pw[e] = W[(size_t)(kb + k0 + r) * 512 + n0 + c];
    }
  };
  loadA(0); loadW(0);
  for (int k0 = 0; k0 < 512; k0 += 16) {
#pragma unroll
    for (int e = 0; e < 4; ++e) {
      int idx = t + e * 256;
      int r = idx >> 4, c = idx & 15;
      as_[r][c] = pa[e];
    }
#pragma unroll
    for (int e = 0; e < 4; ++e) {
      int idx = t + e * 256;
      int r = idx >> 6, c = idx & 63;
      ws_[r][c] = pw[e];
    }
    __syncthreads();
    if (k0 + 16 < 512) { loadA(k0 + 16); loadW(k0 + 16); }
#pragma unroll
    for (int kc = 0; kc < 16; ++kc) {
      float av[4], wv[4];
#pragma unroll
      for (int i = 0; i < 4; ++i) av[i] = as_[ty * 4 + i][kc];
#pragma unroll
      for (int j = 0; j < 4; ++j) wv[j] = ws_[kc][tx * 4 + j];
#pragma unroll
      for (int i = 0; i < 4; ++i)
#pragma unroll
        for (int j = 0; j < 4; ++j) acc[i][j] += av[i] * wv[j];
    }
    __syncthreads();
  }
#pragma unroll
  for (int i = 0; i < 4; ++i)
#pragma unroll
    for (int j = 0; j < 4; ++j) {
      int m = m0 + ty * 4 + i, n = n0 + tx * 4 + j;
      part[((size_t)blockIdx.z * 512 + m) * 512 + n] = acc[i][j];
    }
}

// ---------------- W2 reduce + bias + residual into slots ----------------
__global__ __launch_bounds__(256) void k_w2red(const float* __restrict__ part, const float* __restrict__ b2,
                                               float* __restrict__ slots) {
  int i = blockIdx.x * 256 + threadIdx.x;   // float4 index over 512*512/4 = 65536
  const float4* p4 = reinterpret_cast<const float4*>(part);
  float4 a = p4[i];
  float4 b = p4[65536 + i];
  float4 c = p4[2 * 65536 + i];
  float4 d = p4[3 * 65536 + i];
  float4 bb = reinterpret_cast<const float4*>(b2)[i & 127];
  float4* s4 = reinterpret_cast<float4*>(slots) + i;
  float4 s = *s4;
  s.x += a.x + b.x + c.x + d.x + bb.x;
  s.y += a.y + b.y + c.y + d.y + bb.y;
  s.z += a.z + b.z + c.z + d.z + bb.z;
  s.w += a.w + b.w + c.w + d.w + bb.w;
  *s4 = s;
}

// ---------------- M_h = Wq_h @ Wk_h^T per head (raw) -> Ms[k*4096 + h*512 + d] ----------------
__global__ __launch_bounds__(256) void k_mh(const float* __restrict__ Wq, const float* __restrict__ Wk,
                                            float* __restrict__ Ms) {
  int h = blockIdx.z, k0 = blockIdx.y * 64, d0 = blockIdx.x * 64;
  __shared__ float qa[64][65];
  __shared__ float ka[64][65];
  int t = threadIdx.x, tx = t & 15, ty = t >> 4;
#pragma unroll
  for (int e = 0; e < 16; ++e) {
    int idx = t + e * 256;
    int r = idx >> 6, c = idx & 63;
    qa[c][r] = Wq[(size_t)(k0 + r) * Dn + h * 64 + c];
    ka[c][r] = Wk[(size_t)(d0 + r) * Dn + h * 64 + c];
  }
  __syncthreads();
  float acc[4][4] = {};
#pragma unroll 4
  for (int c = 0; c < 64; ++c) {
    float av[4], bv[4];
#pragma unroll
    for (int i = 0; i < 4; ++i) av[i] = qa[c][ty * 4 + i];
#pragma unroll
    for (int j = 0; j < 4; ++j) bv[j] = ka[c][tx * 4 + j];
#pragma unroll
    for (int i = 0; i < 4; ++i)
#pragma unroll
      for (int j = 0; j < 4; ++j) acc[i][j] += av[i] * bv[j];
  }
#pragma unroll
  for (int i = 0; i < 4; ++i)
#pragma unroll
    for (int j = 0; j < 4; ++j)
      Ms[(size_t)(k0 + ty * 4 + i) * 4096 + h * 512 + d0 + tx * 4 + j] = acc[i][j];
}

// ---------------- vbias_h[d] = Wk[d, h64:]·bq[h64:]; raw + scaled ----------------
__global__ __launch_bounds__(256) void k_vbias(const float* __restrict__ Wk, const float* __restrict__ bq,
                                               const float* __restrict__ lnw, float* __restrict__ vb_raw,
                                               float* __restrict__ vb_s) {
  __shared__ float bqs[512];
  int t = threadIdx.x;
  bqs[t] = bq[t]; bqs[256 + t] = bq[256 + t];
  __syncthreads();
  int d = blockIdx.x * 256 + t;
  float vb[8] = {};
  const float4* wr = reinterpret_cast<const float4*>(Wk + (size_t)d * Dn);
#pragma unroll 8
  for (int c4 = 0; c4 < 128; ++c4) {
    float4 wv = wr[c4];
    int h = c4 >> 4;
    int c = c4 * 4;
    vb[h] += wv.x * bqs[c] + wv.y * bqs[c + 1] + wv.z * bqs[c + 2] + wv.w * bqs[c + 3];
  }
  float lw = lnw[d];
#pragma unroll
  for (int h = 0; h < 8; ++h) {
    vb_raw[h * 512 + d] = vb[h];
    vb_s[h * 512 + d] = kScale * lw * vb[h];
  }
}

// ---------------- fold: scale Ms in place by kScale*lnw[d]; avec/bvec ----------------
__global__ __launch_bounds__(256) void k_mfold(float* __restrict__ Ms, const float* __restrict__ Wq,
                                               const float* __restrict__ bk, const float* __restrict__ lnw,
                                               const float* __restrict__ lnb, float* __restrict__ avec,
                                               float* __restrict__ bvec) {
  __shared__ float lws[512], lbs[512], bks[512];
  int t = threadIdx.x;
  lws[t] = lnw[t]; lws[256 + t] = lnw[256 + t];
  lbs[t] = lnb[t]; lbs[256 + t] = lnb[256 + t];
  bks[t] = bk[t]; bks[256 + t] = bk[256 + t];
  __syncthreads();
  int g = blockIdx.x * 256 + t;
  int k = g >> 3, h = g & 7;
  float* mr = Ms + (size_t)k * 4096 + h * 512;
  float mlnb = 0.0f, mlnw = 0.0f;
  for (int d = 0; d < 512; d += 4) {
    float4 m4 = *reinterpret_cast<const float4*>(mr + d);
    mlnb += m4.x * lbs[d] + m4.y * lbs[d + 1] + m4.z * lbs[d + 2] + m4.w * lbs[d + 3];
    mlnw += m4.x * lws[d] + m4.y * lws[d + 1] + m4.z * lws[d + 2] + m4.w * lws[d + 3];
    float4 o4 = {m4.x * kScale * lws[d], m4.y * kScale * lws[d + 1],
                 m4.z * kScale * lws[d + 2], m4.w * kScale * lws[d + 3]};
    *reinterpret_cast<float4*>(mr + d) = o4;
  }
  float wqdot = 0.0f;
  const float* qr = Wq + (size_t)k * Dn + h * 64;
  for (int c = 0; c < 64; c += 4) {
    float4 q4 = *reinterpret_cast<const float4*>(qr + c);
    wqdot += q4.x * bks[h * 64 + c] + q4.y * bks[h * 64 + c + 1] +
             q4.z * bks[h * 64 + c + 2] + q4.w * bks[h * 64 + c + 3];
  }
  avec[h * 512 + k] = kScale * (mlnb + wqdot);
  bvec[h * 512 + k] = kScale * mlnw;
}

// ---------------- aconst/bconst scalars ----------------
__global__ __launch_bounds__(256) void k_consts(const float* __restrict__ vb_raw, const float* __restrict__ bq,
                                                const float* __restrict__ bk, const float* __restrict__ lnw,
                                                const float* __restrict__ lnb, float* __restrict__ aconst,
                                                float* __restrict__ bconst) {
  __shared__ float r1[256], r2[256], r3[256];
  int t = threadIdx.x;
  for (int h = 0; h < 8; ++h) {
    float p1 = 0.0f, p2 = 0.0f, p3 = 0.0f;
    for (int d = t; d < 512; d += 256) {
      float vr = vb_raw[h * 512 + d];
      p1 += lnb[d] * vr;
      p2 += lnw[d] * vr;
    }
    if (t < 64) p3 = bq[h * 64 + t] * bk[h * 64 + t];
    r1[t] = p1; r2[t] = p2; r3[t] = p3;
    __syncthreads();
    for (int s = 128; s > 0; s >>= 1) {
      if (t < s) { r1[t] += r1[t + s]; r2[t] += r2[t + s]; r3[t] += r3[t + s]; }
      __syncthreads();
    }
    if (t == 0) {
      aconst[h] = kScale * (r1[0] + r3[0]);
      bconst[h] = kScale * r2[0];
    }
    __syncthreads();
  }
}

// ---------------- bcih[n] = bc·Wih[n,:] + bih[n] ----------------
__global__ __launch_bounds__(256) void k_bcih(const float* __restrict__ bc, const float* __restrict__ Wih,
                                              const float* __restrict__ bih, float* __restrict__ bcih) {
  __shared__ float bcs[512];
  int t = threadIdx.x;
  bcs[t] = bc[t]; bcs[256 + t] = bc[256 + t];
  __syncthreads();
  int n = blockIdx.x * 256 + t;
  const float4* wr = reinterpret_cast<const float4*>(Wih + (size_t)n * Dn);
  float a = 0.0f;
#pragma unroll 8
  for (int c4 = 0; c4 < 128; ++c4) {
    float4 wv = wr[c4];
    int c = c4 * 4;
    a += wv.x * bcs[c] + wv.y * bcs[c + 1] + wv.z * bcs[c + 2] + wv.w * bcs[c + 3];
  }
  bcih[n] = a + bih[n];
}

// ---------------- qkt = sln @ Ms + vb_s, remapped to [b,hi,d] (prefetched) ----------------
__global__ __launch_bounds__(256) void k_qu(const float* __restrict__ sln, const float* __restrict__ Ms,
                                            const float* __restrict__ vb_s, float* __restrict__ qkt) {
  __shared__ float as_[64][17];
  __shared__ float ws_[16][65];
  int m0 = blockIdx.y * 64, n0 = blockIdx.x * 64;
  int t = threadIdx.x, tx = t & 15, ty = t >> 4;
  float acc[4][4] = {};
  float pa[4], pw[4];
  auto loadA = [&](int k0) {
#pragma unroll
    for (int e = 0; e < 4; ++e) {
      int idx = t + e * 256;
      int r = idx >> 4, c = idx & 15;
      pa[e] = sln[(size_t)(m0 + r) * Dn + k0 + c];
    }
  };
  auto loadW = [&](int k0) {
#pragma unroll
    for (int e = 0; e < 4; ++e) {
      int idx = t + e * 256;
      int r = idx >> 6, c = idx & 63;
      pw[e] = Ms[(size_t)(k0 + r) * 4096 + n0 + c];
    }
  };
  loadA(0); loadW(0);
  for (int k0 = 0; k0 < 512; k0 += 16) {
#pragma unroll
    for (int e = 0; e < 4; ++e) {
      int idx = t + e * 256;
      int r = idx >> 4, c = idx & 15;
      as_[r][c] = pa[e];
    }
#pragma unroll
    for (int e = 0; e < 4; ++e) {
      int idx = t + e * 256;
      int r = idx >> 6, c = idx & 63;
      ws_[r][c] = pw[e];
    }
    __syncthreads();
    if (k0 + 16 < 512) { loadA(k0 + 16); loadW(k0 + 16); }
#pragma unroll
    for (int kc = 0; kc < 16; ++kc) {
      float av[4], wv[4];
#pragma unroll
      for (int i = 0; i < 4; ++i) av[i] = as_[ty * 4 + i][kc];
#pragma unroll
      for (int j = 0; j < 4; ++j) wv[j] = ws_[kc][tx * 4 + j];
#pragma unroll
      for (int i = 0; i < 4; ++i)
#pragma unroll
        for (int j = 0; j < 4; ++j) acc[i][j] += av[i] * wv[j];
    }
    __syncthreads();
  }
#pragma unroll
  for (int i = 0; i < 4; ++i)
#pragma unroll
    for (int j = 0; j < 4; ++j) {
      int m = m0 + ty * 4 + i, n = n0 + tx * 4 + j;
      int bb = m >> 4, isl = m & 15, h = n >> 9, d = n & 511;
      qkt[((size_t)bb * HIn + h * 16 + isl) * Dn + d] = acc[i][j] + vb_s[n];
    }
}

// ---------------- alpha/beta = sln·avec_h + aconst_h ----------------
__global__ void k_ab(const float* __restrict__ sln, const float* __restrict__ avec,
                     const float* __restrict__ bvec, const float* __restrict__ aconst,
                     const float* __restrict__ bconst, float* __restrict__ alpha,
                     float* __restrict__ beta) {
  int g = blockIdx.x;           // b*128 + hi
  int hi = g & 127, b = g >> 7;
  int h = hi >> 4, i = hi & 15;
  int lane = threadIdx.x;
  const float4* sp = reinterpret_cast<const float4*>(sln + (size_t)(b * NSn + i) * Dn) + lane * 2;
  const float4* ap = reinterpret_cast<const float4*>(avec + h * 512) + lane * 2;
  const float4* bp = reinterpret_cast<const float4*>(bvec + h * 512) + lane * 2;
  float4 s0 = sp[0], s1 = sp[1], a0 = ap[0], a1 = ap[1], b0 = bp[0], b1 = bp[1];
  float pa = s0.x*a0.x + s0.y*a0.y + s0.z*a0.z + s0.w*a0.w + s1.x*a1.x + s1.y*a1.y + s1.z*a1.z + s1.w*a1.w;
  float pb = s0.x*b0.x + s0.y*b0.y + s0.z*b0.z + s0.w*b0.w + s1.x*b1.x + s1.y*b1.y + s1.z*b1.z + s1.w*b1.w;
  pa = wred(pa); pb = wred(pb);
  if (lane == 0) {
    alpha[g] = pa + aconst[h];
    beta[g] = pb + bconst[h];
  }
}

// ---------------- dots via 3-way bf16-split MFMA + in-register softmax ----------------
__global__ __launch_bounds__(256) void k_dots(const float* __restrict__ in, const float* __restrict__ qkt,
                                              const float* __restrict__ alpha, const float* __restrict__ beta,
                                              const float* __restrict__ mu, const float* __restrict__ rsig,
                                              unsigned* __restrict__ A, float* __restrict__ Spart,
                                              float* __restrict__ c1part) {
  __shared__ __align__(16) unsigned short xs_h[128][40];
  __shared__ __align__(16) unsigned short xs_m[128][40];
  __shared__ __align__(16) unsigned short xs_l[128][40];
  __shared__ __align__(16) unsigned short us_h[128][40];
  __shared__ __align__(16) unsigned short us_m[128][40];
  __shared__ __align__(16) unsigned short us_l[128][40];

  int b = blockIdx.y, jt = blockIdx.x, j0 = jt * 128;
  int t = threadIdx.x, w = t >> 6, l = t & 63;
  int lc = l & 15, lg = l >> 4, koff = lg * 8;
  const size_t inbase = ((size_t)b * Nn + j0) * Dn;
  const size_t ubase = (size_t)b * HIn * Dn;

  f32x4 acc[2][8];
#pragma unroll
  for (int i = 0; i < 2; ++i)
#pragma unroll
    for (int j2 = 0; j2 < 8; ++j2) acc[i][j2] = {0.0f, 0.0f, 0.0f, 0.0f};

  float2 nx[8], nu[8];
#pragma unroll
  for (int e = 0; e < 8; ++e) {
    int idx = t + e * 256;
    int j = idx >> 4, kp = (idx & 15) * 2;
    nx[e] = *reinterpret_cast<const float2*>(&in[inbase + (size_t)j * Dn + kp]);
    nu[e] = *reinterpret_cast<const float2*>(&qkt[ubase + (size_t)j * Dn + kp]);
  }

  for (int k0 = 0; k0 < 512; k0 += 32) {
#pragma unroll
    for (int e = 0; e < 8; ++e) {
      int idx = t + e * 256;
      int j = idx >> 4, kp = (idx & 15) * 2;
      unsigned mm, lm;
      unsigned hm = pack3(nx[e].x, nx[e].y, mm, lm);
      *reinterpret_cast<unsigned*>(&xs_h[j][kp]) = hm;
      *reinterpret_cast<unsigned*>(&xs_m[j][kp]) = mm;
      *reinterpret_cast<unsigned*>(&xs_l[j][kp]) = lm;
      hm = pack3(nu[e].x, nu[e].y, mm, lm);
      *reinterpret_cast<unsigned*>(&us_h[j][kp]) = hm;
      *reinterpret_cast<unsigned*>(&us_m[j][kp]) = mm;
      *reinterpret_cast<unsigned*>(&us_l[j][kp]) = lm;
    }
    if (k0 + 32 < 512) {
#pragma unroll
      for (int e = 0; e < 8; ++e) {
        int idx = t + e * 256;
        int j = idx >> 4, kp = (idx & 15) * 2;
        nx[e] = *reinterpret_cast<const float2*>(&in[inbase + (size_t)j * Dn + k0 + 32 + kp]);
        nu[e] = *reinterpret_cast<const float2*>(&qkt[ubase + (size_t)j * Dn + k0 + 32 + kp]);
      }
    }
    __syncthreads();
    short8 ah0 = *reinterpret_cast<const short8*>(&xs_h[w * 32 + lc][koff]);
    short8 am0 = *reinterpret_cast<const short8*>(&xs_m[w * 32 + lc][koff]);
    short8 al0 = *reinterpret_cast<const short8*>(&xs_l[w * 32 + lc][koff]);
    short8 ah1 = *reinterpret_cast<const short8*>(&xs_h[w * 32 + 16 + lc][koff]);
    short8 am1 = *reinterpret_cast<const short8*>(&xs_m[w * 32 + 16 + lc][koff]);
    short8 al1 = *reinterpret_cast<const short8*>(&xs_l[w * 32 + 16 + lc][koff]);
#pragma unroll
    for (int ht = 0; ht < 8; ++ht) {
      short8 bh = *reinterpret_cast<const short8*>(&us_h[ht * 16 + lc][koff]);
      short8 bm = *reinterpret_cast<const short8*>(&us_m[ht * 16 + lc][koff]);
      short8 bl = *reinterpret_cast<const short8*>(&us_l[ht * 16 + lc][koff]);
      acc[0][ht] = __builtin_amdgcn_mfma_f32_16x16x32_bf16(ah0, bh, acc[0][ht], 0, 0, 0);
      acc[0][ht] = __builtin_amdgcn_mfma_f32_16x16x32_bf16(ah0, bm, acc[0][ht], 0, 0, 0);
      acc[0][ht] = __builtin_amdgcn_mfma_f32_16x16x32_bf16(am0, bh, acc[0][ht], 0, 0, 0);
      acc[0][ht] = __builtin_amdgcn_mfma_f32_16x16x32_bf16(ah0, bl, acc[0][ht], 0, 0, 0);
      acc[0][ht] = __builtin_amdgcn_mfma_f32_16x16x32_bf16(al0, bh, acc[0][ht], 0, 0, 0);
      acc[0][ht] = __builtin_amdgcn_mfma_f32_16x16x32_bf16(am0, bm, acc[0][ht], 0, 0, 0);
      acc[1][ht] = __builtin_amdgcn_mfma_f32_16x16x32_bf16(ah1, bh, acc[1][ht], 0, 0, 0);
      acc[1][ht] = __builtin_amdgcn_mfma_f32_16x16x32_bf16(ah1, bm, acc[1][ht], 0, 0, 0);
      acc[1][ht] = __builtin_amdgcn_mfma_f32_16x16x32_bf16(am1, bh, acc[1][ht], 0, 0, 0);
      acc[1][ht] = __builtin_amdgcn_mfma_f32_16x16x32_bf16(ah1, bl, acc[1][ht], 0, 0, 0);
      acc[1][ht] = __builtin_amdgcn_mfma_f32_16x16x32_bf16(al1, bh, acc[1][ht], 0, 0, 0);
      acc[1][ht] = __builtin_amdgcn_mfma_f32_16x16x32_bf16(am1, bm, acc[1][ht], 0, 0, 0);
    }
    __syncthreads();
  }

  float* rsL = reinterpret_cast<float*>(&xs_h[0][0]);
  float* muL = rsL + 128;
  float* aL = rsL + 256;
  float* bL = rsL + 384;
  float (*sredS)[128] = reinterpret_cast<float(*)[128]>(rsL + 512);
  float (*sredC)[128] = reinterpret_cast<float(*)[128]>(rsL + 512 + 4 * 128);
  if (t < 128) {
    rsL[t] = rsig[(size_t)b * Nn + j0 + t];
    muL[t] = mu[(size_t)b * Nn + j0 + t];
    aL[t] = alpha[b * HIn + t];
    bL[t] = beta[b * HIn + t];
  }
  __syncthreads();

  float sS[8] = {}, sC[8] = {};
#pragma unroll
  for (int jt2 = 0; jt2 < 2; ++jt2) {
    int jbase = w * 32 + jt2 * 16 + lg * 4;
#pragma unroll
    for (int ht = 0; ht < 8; ++ht) {
      int hi = ht * 16 + lc;
      float av = aL[hi], bv = bL[hi];
      float v[4], rs4[4], mr4[4];
#pragma unroll
      for (int r = 0; r < 4; ++r) {
        int jr = jbase + r;
        rs4[r] = rsL[jr];
        mr4[r] = muL[jr] * rs4[r];
        v[r] = acc[jt2][ht][r] * rs4[r] + av - mr4[r] * bv;
      }
      float mx[4] = {v[0], v[1], v[2], v[3]};
#pragma unroll
      for (int m = 1; m <= 8; m <<= 1)
#pragma unroll
        for (int r = 0; r < 4; ++r) mx[r] = fmaxf(mx[r], __shfl_xor(mx[r], m));
      float e4[4], ss[4];
#pragma unroll
      for (int r = 0; r < 4; ++r) { e4[r] = expf(v[r] - mx[r]); ss[r] = e4[r]; }
#pragma unroll
      for (int m = 1; m <= 8; m <<= 1)
#pragma unroll
        for (int r = 0; r < 4; ++r) ss[r] += __shfl_xor(ss[r], m);
      float ps = 0.0f, pc = 0.0f;
      float p0 = e4[0] / ss[0] + kEps, p1 = e4[1] / ss[1] + kEps;
      float p2 = e4[2] / ss[2] + kEps, p3 = e4[3] / ss[3] + kEps;
      uint4 o4;
      o4.x = packhm(p0 * rs4[0]); o4.y = packhm(p1 * rs4[1]);
      o4.z = packhm(p2 * rs4[2]); o4.w = packhm(p3 * rs4[3]);
      ps = p0 + p1 + p2 + p3;
      pc = p0 * mr4[0] + p1 * mr4[1] + p2 * mr4[2] + p3 * mr4[3];
      *reinterpret_cast<uint4*>(&A[(size_t)(b * HIn + hi) * Nn + j0 + jbase]) = o4;
      ps += __shfl_xor(ps, 16); ps += __shfl_xor(ps, 32);
      pc += __shfl_xor(pc, 16); pc += __shfl_xor(pc, 32);
      sS[ht] += ps; sC[ht] += pc;
    }
  }
  if (l < 16) {
#pragma unroll
    for (int ht = 0; ht < 8; ++ht) {
      sredS[w][ht * 16 + l] = sS[ht];
      sredC[w][ht * 16 + l] = sC[ht];
    }
  }
  __syncthreads();
  if (t < 128) {
    float s_ = sredS[0][t] + sredS[1][t] + sredS[2][t] + sredS[3][t];
    float c_ = sredC[0][t] + sredC[1][t] + sredC[2][t] + sredC[3][t];
    int sub = (b * 32 + jt) * HIn + t;
    Spart[sub] = s_;
    c1part[sub] = c_;
  }
}

// ---------------- AX = A @ X via 2-level bf16-split MFMA (K-split x4) ----------------
__global__ __launch_bounds__(256) void k_ax(const unsigned* __restrict__ Au, const unsigned* __restrict__ inT,
                                            float* __restrict__ AXp) {
  __shared__ __align__(16) unsigned short as_h[128][40];
  __shared__ __align__(16) unsigned short as_m[128][40];
  __shared__ __align__(16) unsigned short xs_h[128][40];
  __shared__ __align__(16) unsigned short xs_m[128][40];

  int d0 = blockIdx.x * 128, kp = blockIdx.y, b = blockIdx.z;
  int t = threadIdx.x, w = t >> 6, l = t & 63;
  int lc = l & 15, lg = l >> 4, koff = lg * 8;
  const size_t abase = (size_t)b * HIn * Nn + kp * 1024;
  const size_t xbase = ((size_t)b * Dn + d0) * Nn + kp * 1024;

  f32x4 acc[2][8];
#pragma unroll
  for (int i = 0; i < 2; ++i)
#pragma unroll
    for (int j2 = 0; j2 < 8; ++j2) acc[i][j2] = {0.0f, 0.0f, 0.0f, 0.0f};

  uint2 pa[8];
  uint4 px[4];
#pragma unroll
  for (int e = 0; e < 8; ++e) {
    int idx = t + e * 256;
    int hi = idx >> 4, jp = (idx & 15) * 2;
    pa[e] = *reinterpret_cast<const uint2*>(&Au[abase + (size_t)hi * Nn + jp]);
  }
#pragma unroll
  for (int e = 0; e < 4; ++e) {
    int idx = t + e * 256;
    int d = idx >> 3, jg = idx & 7;
    px[e] = *reinterpret_cast<const uint4*>(&inT[xbase + (size_t)d * Nn + jg * 4]);
  }

  for (int c0 = 0; c0 < 1024; c0 += 32) {
#pragma unroll
    for (int e = 0; e < 8; ++e) {
      int idx = t + e * 256;
      int hi = idx >> 4, jp = (idx & 15) * 2;
      unsigned h = (pa[e].x & 0xffffu) | (pa[e].y << 16);
      unsigned m = (pa[e].x >> 16) | (pa[e].y & 0xffff0000u);
      *reinterpret_cast<unsigned*>(&as_h[hi][jp]) = h;
      *reinterpret_cast<unsigned*>(&as_m[hi][jp]) = m;
    }
#pragma unroll
    for (int e = 0; e < 4; ++e) {
      int idx = t + e * 256;
      int d = idx >> 3, jg = idx & 7;
      unsigned h0 = (px[e].x & 0xffffu) | (px[e].y << 16);
      unsigned h1 = (px[e].z & 0xffffu) | (px[e].w << 16);
      unsigned m0 = (px[e].x >> 16) | (px[e].y & 0xffff0000u);
      unsigned m1 = (px[e].z >> 16) | (px[e].w & 0xffff0000u);
      uint2 hv = {h0, h1}, mv = {m0, m1};
      *reinterpret_cast<uint2*>(&xs_h[d][jg * 4]) = hv;
      *reinterpret_cast<uint2*>(&xs_m[d][jg * 4]) = mv;
    }
    if (c0 + 32 < 1024) {
#pragma unroll
      for (int e = 0; e < 8; ++e) {
        int idx = t + e * 256;
        int hi = idx >> 4, jp = (idx & 15) * 2;
        pa[e] = *reinterpret_cast<const uint2*>(&Au[abase + (size_t)hi * Nn + c0 + 32 + jp]);
      }
#pragma unroll
      for (int e = 0; e < 4; ++e) {
        int idx = t + e * 256;
        int d = idx >> 3, jg = idx & 7;
        px[e] = *reinterpret_cast<const uint4*>(&inT[xbase + (size_t)d * Nn + c0 + 32 + jg * 4]);
      }
    }
    __syncthreads();
    short8 ah0 = *reinterpret_cast<const short8*>(&as_h[w * 32 + lc][koff]);
    short8 am0 = *reinterpret_cast<const short8*>(&as_m[w * 32 + lc][koff]);
    short8 ah1 = *reinterpret_cast<const short8*>(&as_h[w * 32 + 16 + lc][koff]);
    short8 am1 = *reinterpret_cast<const short8*>(&as_m[w * 32 + 16 + lc][koff]);
#pragma unroll
    for (int dt = 0; dt < 8; ++dt) {
      short8 bh = *reinterpret_cast<const short8*>(&xs_h[dt * 16 + lc][koff]);
      short8 bm = *reinterpret_cast<const short8*>(&xs_m[dt * 16 + lc][koff]);
      acc[0][dt] = __builtin_amdgcn_mfma_f32_16x16x32_bf16(ah0, bh, acc[0][dt], 0, 0, 0);
      acc[0][dt] = __builtin_amdgcn_mfma_f32_16x16x32_bf16(ah0, bm, acc[0][dt], 0, 0, 0);
      acc[0][dt] = __builtin_amdgcn_mfma_f32_16x16x32_bf16(am0, bh, acc[0][dt], 0, 0, 0);
      acc[1][dt] = __builtin_amdgcn_mfma_f32_16x16x32_bf16(ah1, bh, acc[1][dt], 0, 0, 0);
      acc[1][dt] = __builtin_amdgcn_mfma_f32_16x16x32_bf16(ah1, bm, acc[1][dt], 0, 0, 0);
      acc[1][dt] = __builtin_amdgcn_mfma_f32_16x16x32_bf16(am1, bh, acc[1][dt], 0, 0, 0);
    }
    __syncthreads();
  }

  const size_t obase = (((size_t)kp * Bn + b) * HIn) * Dn + d0;
#pragma unroll
  for (int jt2 = 0; jt2 < 2; ++jt2) {
#pragma unroll
    for (int dt = 0; dt < 8; ++dt) {
#pragma unroll
      for (int r = 0; r < 4; ++r) {
        int hi = w * 32 + jt2 * 16 + lg * 4 + r;
        int d = dt * 16 + lc;
        AXp[obase + (size_t)hi * Dn + d] = acc[jt2][dt][r];
      }
    }
  }
}

// ---------------- upd = ((w*(G-c1)/S + b) @ Wv_h) + bv, S/c1 reduced inline ----------------
__global__ __launch_bounds__(256) void k_updS(const float* __restrict__ AXp, const float* __restrict__ Spart,
                                              const float* __restrict__ c1part, const float* __restrict__ lnw,
                                              const float* __restrict__ lnb, const float* __restrict__ Wv,
                                              const float* __restrict__ bv, float* __restrict__ upd) {
  int b = blockIdx.y, hi = blockIdx.x, h = hi >> 4, i = hi & 15;
  __shared__ float vx[512];
  __shared__ float red[256];
  __shared__ float sSC[2];
  int t = threadIdx.x;
  if (t < 64) {
    float vs = 0.0f, vc = 0.0f;
    if (t < 32) {
      vs = Spart[(size_t)(b * 32 + t) * HIn + hi];
      vc = c1part[(size_t)(b * 32 + t) * HIn + hi];
    }
    vs = wred(vs); vc = wred(vc);
    if (t == 0) { sSC[0] = vs; sSC[1] = vc; }
  }
  __syncthreads();
  float c1v = sSC[1];
  float invS = 1.0f / sSC[0];
  for (int d = t; d < Dn; d += 256) {
    float G = AXp[((size_t)(0 * Bn + b) * HIn + hi) * Dn + d]
            + AXp[((size_t)(1 * Bn + b) * HIn + hi) * Dn + d]
            + AXp[((size_t)(2 * Bn + b) * HIn + hi) * Dn + d]
            + AXp[((size_t)(3 * Bn + b) * HIn + hi) * Dn + d];
    vx[d] = lnw[d] * (G - c1v) * invS + lnb[d];
  }
  __syncthreads();
  int cc = t & 63, qd = t >> 6;
  float p = 0.0f;
  for (int d = qd * 128; d < qd * 128 + 128; ++d) p += vx[d] * Wv[(size_t)d * Dn + h * 64 + cc];
  red[t] = p;
  __syncthreads();
  if (qd == 0) {
    float v = red[cc] + red[64 + cc] + red[128 + cc] + red[192 + cc] + bv[h * 64 + cc];
    upd[(size_t)(b * NSn + i) * Dn + h * 64 + cc] = v;
  }
}

// ---------------- dual GEMM (prefetched): z=0: gi = upd@T1 + bcih ; z=1: gh = slots@Whh^T + bhh ----------------
__global__ __launch_bounds__(256) void k_gg(const float* __restrict__ upd, const float* __restrict__ T1,
                                            const float* __restrict__ bcih, const float* __restrict__ slots,
                                            const float* __restrict__ Whh, const float* __restrict__ bhh,
                                            float* __restrict__ gi, float* __restrict__ gh) {
  bool z = (blockIdx.z == 1);
  const float* A = z ? slots : upd;
  const float* W = z ? Whh : T1;
  const float* bias = z ? bhh : bcih;
  float* out = z ? gh : gi;
  __shared__ float as_[64][17];
  __shared__ float ws_[16][65];
  int m0 = blockIdx.y * 64, n0 = blockIdx.x * 64;
  int t = threadIdx.x, tx = t & 15, ty = t >> 4;
  float acc[4][4] = {};
  float pa[4], pw[4];
  auto loadA = [&](int k0) {
#pragma unroll
    for (int e = 0; e < 4; ++e) {
      int idx = t + e * 256;
      int r = idx >> 4, c = idx & 15;
      pa[e] = A[(size_t)(m0 + r) * 512 + k0 + c];
    }
  };
  auto loadW = [&](int k0) {
#pragma unroll
    for (int e = 0; e < 4; ++e) {
      int idx = t + e * 256;
      if (!z) {
        int r = idx >> 6, c = idx & 63;
        pw[e] = W[(size_t)(k0 + r) * 1536 + n0 + c];
      } else {
        int r = idx >> 4, c = idx & 15;
        pw[e] = W[(size_t)(n0 + r) * 512 + k0 + c];
      }
    }
  };
  loadA(0); loadW(0);
  for (int k0 = 0; k0 < 512; k0 += 16) {
#pragma unroll
    for (int e = 0; e < 4; ++e) {
      int idx = t + e * 256;
      int r = idx >> 4, c = idx & 15;
      as_[r][c] = pa[e];
    }
#pragma unroll
    for (int e = 0; e < 4; ++e) {
      int idx = t + e * 256;
      if (!z) {
        int r = idx >> 6, c = idx & 63;
        ws_[r][c] = pw[e];
      } else {
        int r = idx >> 4, c = idx & 15;
        ws_[c][r] = pw[e];
      }
    }
    __syncthreads();
    if (k0 + 16 < 512) { loadA(k0 + 16); loadW(k0 + 16); }
#pragma unroll
    for (int kc = 0; kc < 16; ++kc) {
      float av[4], wv[4];
#pragma unroll
      for (int i = 0; i < 4; ++i) av[i] = as_[ty * 4 + i][kc];
#pragma unroll
      for (int j = 0; j < 4; ++j) wv[j] = ws_[kc][tx * 4 + j];
#pragma unroll
      for (int i = 0; i < 4; ++i)
#pragma unroll
        for (int j = 0; j < 4; ++j) acc[i][j] += av[i] * wv[j];
    }
    __syncthreads();
  }
#pragma unroll
  for (int i = 0; i < 4; ++i)
#pragma unroll
    for (int j = 0; j < 4; ++j) {
      int m = m0 + ty * 4 + i, n = n0 + tx * 4 + j;
      out[(size_t)m * 1536 + n] = acc[i][j] + bias[n];
    }
}

// ---------------- GRU pointwise + LN_ff fused ----------------
__global__ __launch_bounds__(256) void k_gruln(const float* __restrict__ gi, const float* __restrict__ gh,
                                               float* __restrict__ slots, float* __restrict__ slnff,
                                               const float* __restrict__ lnffw, const float* __restrict__ lnffb) {
  int r = blockIdx.x, t = threadIdx.x;
  __shared__ float red[8];
  float sn[2];
#pragma unroll
  for (int j = 0; j < 2; ++j) {
    int c = j * 256 + t;
    float gir = gi[(size_t)r * 1536 + c];
    float giz = gi[(size_t)r * 1536 + 512 + c];
    float gin = gi[(size_t)r * 1536 + 1024 + c];
    float ghr = gh[(size_t)r * 1536 + c];
    float ghz = gh[(size_t)r * 1536 + 512 + c];
    float ghn = gh[(size_t)r * 1536 + 1024 + c];
    float rg = 1.0f / (1.0f + expf(-(gir + ghr)));
    float zg = 1.0f / (1.0f + expf(-(giz + ghz)));
    float ng = tanhf(gin + rg * ghn);
    sn[j] = (1.0f - zg) * ng + zg * slots[(size_t)r * Dn + c];
  }
  float s = sn[0] + sn[1], q = sn[0] * sn[0] + sn[1] * sn[1];
  s = wred(s); q = wred(q);
  if ((t & 63) == 0) { red[t >> 6] = s; red[4 + (t >> 6)] = q; }
  __syncthreads();
  float S = red[0] + red[1] + red[2] + red[3];
  float Q = red[4] + red[5] + red[6] + red[7];
  float m = S * (1.0f / 512.0f);
  float rs = 1.0f / sqrtf(Q * (1.0f / 512.0f) - m * m + 1e-5f);
#pragma unroll
  for (int j = 0; j < 2; ++j) {
    int c = j * 256 + t;
    slots[(size_t)r * Dn + c] = sn[j];
    slnff[(size_t)r * Dn + c] = (sn[j] - m) * rs * lnffw[c] + lnffb[c];
  }
}

// ---------------- keep gate (zero dropped slots in place) ----------------
__global__ void k_keepscale(const float* __restrict__ Wkeep, const float* __restrict__ gk,
                            float* __restrict__ slots) {
  int g = blockIdx.x;
  int lane = threadIdx.x;
  float4* sp = reinterpret_cast<float4*>(slots + (size_t)g * Dn) + lane * 2;
  float4 s0 = sp[0], s1 = sp[1];
  float sv[8] = {s0.x, s0.y, s0.z, s0.w, s1.x, s1.y, s1.z, s1.w};
  double d0 = 0.0, d1 = 0.0;
#pragma unroll
  for (int e = 0; e < 8; ++e) {
    int d = lane * 8 + e;
    d0 += (double)sv[e] * (double)Wkeep[d * 2];
    d1 += (double)sv[e] * (double)Wkeep[d * 2 + 1];
  }
  d0 = wredd(d0);
  d1 = wredd(d1);
  int keepi = 0;
  if (lane == 0) keepi = ((d1 + (double)gk[g * 2 + 1]) > (d0 + (double)gk[g * 2])) ? 1 : 0;
  keepi = __shfl(keepi, 0);
  if (!keepi) {
    float4 z = {0.0f, 0.0f, 0.0f, 0.0f};
    sp[0] = z;
    sp[1] = z;
  }
}

// ---------------- per-slot scalars for route decomposition ----------------
__global__ void k_slotscalars(const float* __restrict__ slots, const float* __restrict__ lnw,
                              const float* __restrict__ lnb, double* __restrict__ swd,
                              double* __restrict__ sbd) {
  int g = blockIdx.x, lane = threadIdx.x;
  const float4* sp = reinterpret_cast<const float4*>(slots + (size_t)g * Dn) + lane * 2;
  const float4* wp = reinterpret_cast<const float4*>(lnw) + lane * 2;
  const float4* bp = reinterpret_cast<const float4*>(lnb) + lane * 2;
  float4 s0 = sp[0], s1 = sp[1], w0 = wp[0], w1 = wp[1], b0 = bp[0], b1 = bp[1];
  double pw = (double)s0.x * w0.x + (double)s0.y * w0.y + (double)s0.z * w0.z + (double)s0.w * w0.w +
              (double)s1.x * w1.x + (double)s1.y * w1.y + (double)s1.z * w1.z + (double)s1.w * w1.w;
  double pb = (double)s0.x * b0.x + (double)s0.y * b0.y + (double)s0.z * b0.z + (double)s0.w * b0.w +
              (double)s1.x * b1.x + (double)s1.y * b1.y + (double)s1.z * b1.z + (double)s1.w * b1.w;
  pw = wredd(pw);
  pb = wredd(pb);
  if (lane == 0) { swd[g] = pw; sbd[g] = pb; }
}

// ---------------- hard route + gather output (tiled mini-GEMM) ----------------
__global__ __launch_bounds__(256) void k_route_out(const float* __restrict__ in, const float* __restrict__ slots,
                                                   const float* __restrict__ lnw, const double* __restrict__ swd,
                                                   const double* __restrict__ sbd, const float* __restrict__ mu,
                                                   const float* __restrict__ rsig,
                                                   const float* __restrict__ g_route, float* __restrict__ out) {
  int b = blockIdx.y, j0 = blockIdx.x * 128;
  __shared__ __align__(16) float sl[16 * 516];
  __shared__ __align__(16) float lw[512];
  __shared__ __align__(16) float xs[16][132];
  __shared__ double lgd[128][17];
  __shared__ int besti[128];
  int t = threadIdx.x, tx = t & 15, ty = t >> 4;

  for (int idx = t; idx < 2048; idx += 256) {
    int i = idx >> 7, c = idx & 127;
    *reinterpret_cast<float4*>(&sl[i * 516 + c * 4]) =
        *reinterpret_cast<const float4*>(&slots[(size_t)(b * NSn + i) * Dn + c * 4]);
  }
  if (t < 128)
    *reinterpret_cast<float4*>(&lw[t * 4]) = *reinterpret_cast<const float4*>(&lnw[t * 4]);

  float acc[8] = {};
  double accd[8] = {};
  const size_t inbase = ((size_t)b * Nn + j0) * Dn;
  __syncthreads();

  for (int k0 = 0; k0 < Dn; k0 += 16) {
    float pre[8];
#pragma unroll
    for (int e = 0; e < 8; ++e) {
      int idx = t + e * 256;
      int r = idx >> 4, c = idx & 15;
      pre[e] = in[inbase + (size_t)r * Dn + k0 + c];
    }
    __syncthreads();
#pragma unroll
    for (int e = 0; e < 8; ++e) {
      int idx = t + e * 256;
      int r = idx >> 4, c = idx & 15;
      xs[c][r] = pre[e] * lw[k0 + c];
    }
    __syncthreads();
#pragma unroll
    for (int kc = 0; kc < 16; ++kc) {
      float sv = sl[tx * 516 + k0 + kc];
      float4 x0 = *reinterpret_cast<const float4*>(&xs[kc][ty * 8]);
      float4 x1 = *reinterpret_cast<const float4*>(&xs[kc][ty * 8 + 4]);
      acc[0] += x0.x * sv; acc[1] += x0.y * sv; acc[2] += x0.z * sv; acc[3] += x0.w * sv;
      acc[4] += x1.x * sv; acc[5] += x1.y * sv; acc[6] += x1.z * sv; acc[7] += x1.w * sv;
    }
    if ((k0 & 127) == 112) {
#pragma unroll
      for (int e = 0; e < 8; ++e) { accd[e] += (double)acc[e]; acc[e] = 0.0f; }
    }
  }

  double sw_i = swd[b * NSn + tx], sb_i = sbd[b * NSn + tx];
#pragma unroll
  for (int r = 0; r < 8; ++r) {
    int j = ty * 8 + r;
    double rsj = (double)rsig[(size_t)b * Nn + j0 + j];
    double muj = (double)mu[(size_t)b * Nn + j0 + j];
    double g = (double)g_route[((size_t)b * NSn + tx) * Nn + j0 + j];
    lgd[j][tx] = (double)kScale * (rsj * accd[r] + sb_i - muj * rsj * sw_i) + g;
  }
  __syncthreads();
  if (t < 128) {
    double best = lgd[t][0];
    int bi = 0;
#pragma unroll
    for (int i = 1; i < 16; ++i) {
      double v = lgd[t][i];
      if (v > best) { best = v; bi = i; }
    }
    besti[t] = bi;
  }
  __syncthreads();
  for (int idx = t; idx < 128 * 128; idx += 256) {
    int j = idx >> 7, c = idx & 127;
    *reinterpret_cast<float4*>(&out[inbase + (size_t)j * Dn + c * 4]) =
        *reinterpret_cast<const float4*>(&sl[besti[j] * 516 + c * 4]);
  }
}

extern "C" void kernel_launch(void* const* d_in, const int* in_sizes, int n_in,
                              void* d_out, int out_size, void* d_ws, size_t ws_size,
                              hipStream_t stream) {
  (void)in_sizes; (void)n_in; (void)out_size; (void)ws_size;
  const float* in = (const float*)d_in[0];
  const float* slots_mu = (const float*)d_in[1];
  const float* slots_ls = (const float*)d_in[2];
  const float* ln_in_w = (const float*)d_in[3];
  const float* ln_in_b = (const float*)d_in[4];
  const float* ln_s_w = (const float*)d_in[5];
  const float* ln_s_b = (const float*)d_in[6];
  const float* ln_ff_w = (const float*)d_in[7];
  const float* ln_ff_b = (const float*)d_in[8];
  const float* Wq = (const float*)d_in[9];
  const float* bq = (const float*)d_in[10];
  const float* Wk = (const float*)d_in[11];
  const float* bk = (const float*)d_in[12];
  const float* Wv = (const float*)d_in[13];
  const float* bv = (const float*)d_in[14];
  const float* Wc = (const float*)d_in[15];
  const float* bc = (const float*)d_in[16];
  const float* Wih = (const float*)d_in[17];
  const float* bih = (const float*)d_in[18];
  const float* Whh = (const float*)d_in[19];
  const float* bhh = (const float*)d_in[20];
  const float* W1 = (const float*)d_in[21];
  const float* b1 = (const float*)d_in[22];
  const float* W2 = (const float*)d_in[23];
  const float* b2 = (const float*)d_in[24];
  const float* Wkeep = (const float*)d_in[25];
  const float* noise = (const float*)d_in[26];
  const float* g_keep = (const float*)d_in[27];
  const float* g_route = (const float*)d_in[28];
  float* out = (float*)d_out;
  unsigned* inTu = (unsigned*)d_out;   // scratch during iterations; overwritten by k_route_out

  char* wptr = (char*)d_ws;
  auto alloc = [&](size_t bytes) {
    char* p = wptr;
    wptr += (bytes + 255) & ~(size_t)255;
    return p;
  };
  float* mu = (float*)alloc((size_t)Bn * Nn * 4);
  float* rsig = (float*)alloc((size_t)Bn * Nn * 4);
  float* slots = (float*)alloc((size_t)Bn * NSn * Dn * 4);
  float* sln = (float*)alloc((size_t)Bn * NSn * Dn * 4);
  float* qkt = (float*)alloc((size_t)Bn * HIn * Dn * 4);
  float* alpha = (float*)alloc((size_t)Bn * HIn * 4);
  float* beta = (float*)alloc((size_t)Bn * HIn * 4);
  unsigned* Abuf = (unsigned*)alloc((size_t)Bn * HIn * Nn * 4);
  float* Spart = (float*)alloc((size_t)Bn * 64 * HIn * 4);
  float* c1part = (float*)alloc((size_t)Bn * 64 * HIn * 4);
  float* AXp = (float*)alloc((size_t)4 * Bn * HIn * Dn * 4);
  float* updb = (float*)alloc((size_t)Bn * NSn * Dn * 4);
  float* gibuf = (float*)alloc((size_t)Bn * NSn * 1536 * 4);
  float* ghbuf = (float*)alloc((size_t)Bn * NSn * 1536 * 4);
  float* hbuf = (float*)alloc((size_t)Bn * NSn * 2048 * 4);
  float* ffp = (float*)alloc((size_t)4 * 512 * 512 * 4);
  float* T1 = (float*)alloc((size_t)Dn * 1536 * 4);
  float* bcih = (float*)alloc((size_t)1536 * 4);
  float* Ms = (float*)alloc((size_t)Dn * 4096 * 4);
  float* vb_raw = (float*)alloc((size_t)4096 * 4);
  float* vb_s = (float*)alloc((size_t)4096 * 4);
  float* avec = (float*)alloc((size_t)4096 * 4);
  float* bvec = (float*)alloc((size_t)4096 * 4);
  float* aconst = (float*)alloc((size_t)8 * 4);
  float* bconst = (float*)alloc((size_t)8 * 4);
  double* swd = (double*)alloc((size_t)Bn * NSn * 8);
  double* sbd = (double*)alloc((size_t)Bn * NSn * 8);

  // prologue
  k_rowstats<<<Bn * Nn / 4, 256, 0, stream>>>(in, mu, rsig);
  k_tsplit<<<dim3(Nn / 64, Dn / 64, Bn), 256, 0, stream>>>(in, inTu);
  k_slots_init<<<Bn * NSn, 256, 0, stream>>>(slots_mu, slots_ls, noise, slots);
  k_gemm_sm<true, false, false><<<dim3(24, 8), 256, 0, stream>>>(Wc, Wih, nullptr, T1, 1536, 512);
  k_bcih<<<6, 256, 0, stream>>>(bc, Wih, bih, bcih);
  k_mh<<<dim3(8, 8, 8), 256, 0, stream>>>(Wq, Wk, Ms);
  k_vbias<<<2, 256, 0, stream>>>(Wk, bq, ln_in_w, vb_raw, vb_s);
  k_mfold<<<16, 256, 0, stream>>>(Ms, Wq, bk, ln_in_w, ln_in_b, avec, bvec);
  k_consts<<<1, 256, 0, stream>>>(vb_raw, bq, bk, ln_in_w, ln_in_b, aconst, bconst);
  k_ln_rows<<<Bn * NSn, 256, 0, stream>>>(slots, ln_s_w, ln_s_b, sln);

  for (int it = 0; it < 3; ++it) {
    k_qu<<<dim3(64, 8), 256, 0, stream>>>(sln, Ms, vb_s, qkt);
    k_ab<<<Bn * HIn, 64, 0, stream>>>(sln, avec, bvec, aconst, bconst, alpha, beta);
    k_dots<<<dim3(Nn / 128, Bn), 256, 0, stream>>>(in, qkt, alpha, beta, mu, rsig, Abuf, Spart, c1part);
    k_ax<<<dim3(4, 4, Bn), 256, 0, stream>>>(Abuf, inTu, AXp);
    k_updS<<<dim3(HIn, Bn), 256, 0, stream>>>(AXp, Spart, c1part, ln_in_w, ln_in_b, Wv, bv, updb);
    k_gg<<<dim3(24, 8, 2), 256, 0, stream>>>(updb, T1, bcih, slots, Whh, bhh, gibuf, ghbuf);
    k_gruln<<<Bn * NSn, 256, 0, stream>>>(gibuf, ghbuf, slots, sln, ln_ff_w, ln_ff_b);
    k_gemm_sm<false, true, false><<<dim3(32, 8), 256, 0, stream>>>(sln, W1, b1, hbuf, 2048, 512);
    k_w2split<<<dim3(8, 8, 4), 256, 0, stream>>>(hbuf, W2, ffp);
    k_w2red<<<256, 256, 0, stream>>>(ffp, b2, slots);
    k_ln_rows<<<Bn * NSn, 256, 0, stream>>>(slots, ln_s_w, ln_s_b, sln);
  }

  k_keepscale<<<Bn * NSn, 64, 0, stream>>>(Wkeep, g_keep, slots);
  k_slotscalars<<<Bn * NSn, 64, 0, stream>>>(slots, ln_in_w, ln_in_b, swd, sbd);
  k_route_out<<<dim3(Nn / 128, Bn), 256, 0, stream>>>(in, slots, ln_in_w, swd, sbd, mu, rsig, g_route, out);
}

// Round 8
// 1841.393 us; speedup vs baseline: 1.9367x; 1.0454x over previous
//
#include <hip/hip_runtime.h>
#include <hip/hip_bf16.h>
#include <math.h>

constexpr int Bn = 32, Nn = 4096, Dn = 512, NSn = 16, HIn = 128;
constexpr float kScale = 0.04419417382415922f; // 512^-0.5
constexpr float kEps = 1e-8f;

typedef __attribute__((ext_vector_type(8))) short short8;
typedef __attribute__((ext_vector_type(4))) float f32x4;

__device__ __forceinline__ float wred(float v) {
#pragma unroll
  for (int m = 32; m > 0; m >>= 1) v += __shfl_xor(v, m);
  return v;
}
__device__ __forceinline__ double wredd(double v) {
#pragma unroll
  for (int m = 32; m > 0; m >>= 1) v += __shfl_xor(v, m);
  return v;
}

// ---- bf16 split helpers (RNE) ----
__device__ __forceinline__ unsigned short f2bf(float x) {
  unsigned u = __float_as_uint(x);
  unsigned r = (u + 0x7fffu + ((u >> 16) & 1u)) >> 16;
  return (unsigned short)r;
}
__device__ __forceinline__ float bf2f(unsigned short h) {
  return __uint_as_float(((unsigned)h) << 16);
}
__device__ __forceinline__ unsigned packhm(float x) {
  unsigned short h = f2bf(x);
  unsigned short m = f2bf(x - bf2f(h));
  return (unsigned)h | ((unsigned)m << 16);
}
// 2-element 2-level pack: returns h-word, m-word via ref
__device__ __forceinline__ unsigned pack2x(float x0, float x1, unsigned& mo) {
  unsigned p0 = packhm(x0), p1 = packhm(x1);
  mo = (p0 >> 16) | (p1 & 0xffff0000u);
  return (p0 & 0xffffu) | (p1 << 16);
}

// ---------------- per-row LN stats of inputs ----------------
__global__ __launch_bounds__(256) void k_rowstats(const float* __restrict__ in,
                                                  float* __restrict__ mu, float* __restrict__ rsig) {
  int row = blockIdx.x * 4 + (threadIdx.x >> 6);
  int lane = threadIdx.x & 63;
  const float4* p = reinterpret_cast<const float4*>(in + (size_t)row * Dn) + lane * 2;
  float4 a = p[0], b = p[1];
  float s = a.x + a.y + a.z + a.w + b.x + b.y + b.z + b.w;
  float q = a.x*a.x + a.y*a.y + a.z*a.z + a.w*a.w + b.x*b.x + b.y*b.y + b.z*b.z + b.w*b.w;
  s = wred(s); q = wred(q);
  if (lane == 0) {
    float m = s * (1.0f / 512.0f);
    float var = q * (1.0f / 512.0f) - m * m;
    mu[row] = m;
    rsig[row] = 1.0f / sqrtf(var + 1e-5f);
  }
}

// ---------------- transpose + hi/mid split: in[B,N,D] -> inT[B,D,N] (u32 = h|m<<16) ----------------
__global__ __launch_bounds__(256) void k_tsplit(const float* __restrict__ in, unsigned* __restrict__ inT) {
  __shared__ float tile[64][65];
  int b = blockIdx.z, j0 = blockIdx.x * 64, d0 = blockIdx.y * 64;
  int t = threadIdx.x;
#pragma unroll
  for (int e = 0; e < 16; ++e) {
    int idx = t + e * 256;
    int r = idx >> 6, c = idx & 63;
    tile[r][c] = in[((size_t)b * Nn + j0 + r) * Dn + d0 + c];
  }
  __syncthreads();
#pragma unroll
  for (int e = 0; e < 16; ++e) {
    int idx = t + e * 256;
    int r = idx >> 6, c = idx & 63;
    inT[((size_t)b * Dn + d0 + r) * Nn + j0 + c] = packhm(tile[c][r]);
  }
}

// ---------------- slots init ----------------
__global__ __launch_bounds__(256) void k_slots_init(const float* __restrict__ smu, const float* __restrict__ sls,
                                                    const float* __restrict__ noise, float* __restrict__ slots) {
  int r = blockIdx.x;
  for (int d = threadIdx.x; d < Dn; d += 256)
    slots[(size_t)r * Dn + d] = smu[d] + expf(sls[d]) * noise[(size_t)r * Dn + d];
}

// ---------------- LN of [R,512] rows ----------------
__global__ __launch_bounds__(256) void k_ln_rows(const float* __restrict__ src, const float* __restrict__ w,
                                                 const float* __restrict__ b, float* __restrict__ dst) {
  int r = blockIdx.x;
  __shared__ float red[8];
  int t = threadIdx.x;
  float x0 = src[(size_t)r * Dn + t], x1 = src[(size_t)r * Dn + 256 + t];
  float s = x0 + x1, q = x0 * x0 + x1 * x1;
  s = wred(s); q = wred(q);
  if ((t & 63) == 0) { red[t >> 6] = s; red[4 + (t >> 6)] = q; }
  __syncthreads();
  float S = red[0] + red[1] + red[2] + red[3];
  float Q = red[4] + red[5] + red[6] + red[7];
  float m = S * (1.0f / 512.0f);
  float rs = 1.0f / sqrtf(Q * (1.0f / 512.0f) - m * m + 1e-5f);
  dst[(size_t)r * Dn + t] = (x0 - m) * rs * w[t] + b[t];
  dst[(size_t)r * Dn + 256 + t] = (x1 - m) * rs * w[256 + t] + b[256 + t];
}

// ---------------- small GEMM with register prefetch: out = act(A@W (+bias) (+out)) ----------------
template <bool TRANS, bool RELU, bool ADD>
__global__ __launch_bounds__(256) void k_gemm_sm(const float* __restrict__ A, const float* __restrict__ W,
                                                 const float* __restrict__ bias, float* __restrict__ out,
                                                 int Nc, int K) {
  __shared__ float as_[64][17];
  __shared__ float ws_[16][65];
  int m0 = blockIdx.y * 64, n0 = blockIdx.x * 64;
  int t = threadIdx.x, tx = t & 15, ty = t >> 4;
  float acc[4][4] = {};
  float pa[4], pw[4];
  auto loadA = [&](int k0) {
#pragma unroll
    for (int e = 0; e < 4; ++e) {
      int idx = t + e * 256;
      int r = idx >> 4, c = idx & 15;
      pa[e] = A[(size_t)(m0 + r) * K + k0 + c];
    }
  };
  auto loadW = [&](int k0) {
#pragma unroll
    for (int e = 0; e < 4; ++e) {
      int idx = t + e * 256;
      if (!TRANS) {
        int r = idx >> 6, c = idx & 63;
        pw[e] = W[(size_t)(k0 + r) * Nc + n0 + c];
      } else {
        int r = idx >> 4, c = idx & 15;
        pw[e] = W[(size_t)(n0 + r) * K + k0 + c];
      }
    }
  };
  loadA(0); loadW(0);
  for (int k0 = 0; k0 < K; k0 += 16) {
#pragma unroll
    for (int e = 0; e < 4; ++e) {
      int idx = t + e * 256;
      int r = idx >> 4, c = idx & 15;
      as_[r][c] = pa[e];
    }
#pragma unroll
    for (int e = 0; e < 4; ++e) {
      int idx = t + e * 256;
      if (!TRANS) {
        int r = idx >> 6, c = idx & 63;
        ws_[r][c] = pw[e];
      } else {
        int r = idx >> 4, c = idx & 15;
        ws_[c][r] = pw[e];
      }
    }
    __syncthreads();
    if (k0 + 16 < K) { loadA(k0 + 16); loadW(k0 + 16); }
#pragma unroll
    for (int kc = 0; kc < 16; ++kc) {
      float av[4], wv[4];
#pragma unroll
      for (int i = 0; i < 4; ++i) av[i] = as_[ty * 4 + i][kc];
#pragma unroll
      for (int j = 0; j < 4; ++j) wv[j] = ws_[kc][tx * 4 + j];
#pragma unroll
      for (int i = 0; i < 4; ++i)
#pragma unroll
        for (int j = 0; j < 4; ++j) acc[i][j] += av[i] * wv[j];
    }
    __syncthreads();
  }
#pragma unroll
  for (int i = 0; i < 4; ++i)
#pragma unroll
    for (int j = 0; j < 4; ++j) {
      int m = m0 + ty * 4 + i, n = n0 + tx * 4 + j;
      float v = acc[i][j] + (bias ? bias[n] : 0.0f);
      if (RELU) v = fmaxf(v, 0.0f);
      if (ADD) v += out[(size_t)m * Nc + n];
      out[(size_t)m * Nc + n] = v;
    }
}

// ---------------- W2 K-split partial GEMM ----------------
__global__ __launch_bounds__(256) void k_w2split(const float* __restrict__ A, const float* __restrict__ W,
                                                 float* __restrict__ part) {
  __shared__ float as_[64][17];
  __shared__ float ws_[16][65];
  int m0 = blockIdx.y * 64, n0 = blockIdx.x * 64, kb = blockIdx.z * 512;
  int t = threadIdx.x, tx = t & 15, ty = t >> 4;
  float acc[4][4] = {};
  float pa[4], pw[4];
  auto loadA = [&](int k0) {
#pragma unroll
    for (int e = 0; e < 4; ++e) {
      int idx = t + e * 256;
      int r = idx >> 4, c = idx & 15;
      pa[e] = A[(size_t)(m0 + r) * 2048 + kb + k0 + c];
    }
  };
  auto loadW = [&](int k0) {
#pragma unroll
    for (int e = 0; e < 4; ++e) {
      int idx = t + e * 256;
      int r = idx >> 6, c = idx & 63;
      pw[e] = W[(size_t)(kb + k0 + r) * 512 + n0 + c];
    }
  };
  loadA(0); loadW(0);
  for (int k0 = 0; k0 < 512; k0 += 16) {
#pragma unroll
    for (int e = 0; e < 4; ++e) {
      int idx = t + e * 256;
      int r = idx >> 4, c = idx & 15;
      as_[r][c] = pa[e];
    }
#pragma unroll
    for (int e = 0; e < 4; ++e) {
      int idx = t + e * 256;
      int r = idx >> 6, c = idx & 63;
      ws_[r][c] = pw[e];
    }
    __syncthreads();
    if (k0 + 16 < 512) { loadA(k0 + 16); loadW(k0 + 16); }
#pragma unroll
    for (int kc = 0; kc < 16; ++kc) {
      float av[4], wv[4];
#pragma unroll
      for (int i = 0; i < 4; ++i) av[i] = as_[ty * 4 + i][kc];
#pragma unroll
      for (int j = 0; j < 4; ++j) wv[j] = ws_[kc][tx * 4 + j];
#pragma unroll
      for (int i = 0; i < 4; ++i)
#pragma unroll
        for (int j = 0; j < 4; ++j) acc[i][j] += av[i] * wv[j];
    }
    __syncthreads();
  }
#pragma unroll
  for (int i = 0; i < 4; ++i)
#pragma unroll
    for (int j = 0; j < 4; ++j) {
      int m = m0 + ty * 4 + i, n = n0 + tx * 4 + j;
      part[((size_t)blockIdx.z * 512 + m) * 512 + n] = acc[i][j];
    }
}

// ---------------- W2 reduce + bias + residual into slots ----------------
__global__ __launch_bounds__(256) void k_w2red(const float* __restrict__ part, const float* __restrict__ b2,
                                               float* __restrict__ slots) {
  int i = blockIdx.x * 256 + threadIdx.x;
  const float4* p4 = reinterpret_cast<const float4*>(part);
  float4 a = p4[i];
  float4 b = p4[65536 + i];
  float4 c = p4[2 * 65536 + i];
  float4 d = p4[3 * 65536 + i];
  float4 bb = reinterpret_cast<const float4*>(b2)[i & 127];
  float4* s4 = reinterpret_cast<float4*>(slots) + i;
  float4 s = *s4;
  s.x += a.x + b.x + c.x + d.x + bb.x;
  s.y += a.y + b.y + c.y + d.y + bb.y;
  s.z += a.z + b.z + c.z + d.z + bb.z;
  s.w += a.w + b.w + c.w + d.w + bb.w;
  *s4 = s;
}

// ---------------- M_h = Wq_h @ Wk_h^T per head (raw) -> Ms[k*4096 + h*512 + d] ----------------
__global__ __launch_bounds__(256) void k_mh(const float* __restrict__ Wq, const float* __restrict__ Wk,
                                            float* __restrict__ Ms) {
  int h = blockIdx.z, k0 = blockIdx.y * 64, d0 = blockIdx.x * 64;
  __shared__ float qa[64][65];
  __shared__ float ka[64][65];
  int t = threadIdx.x, tx = t & 15, ty = t >> 4;
#pragma unroll
  for (int e = 0; e < 16; ++e) {
    int idx = t + e * 256;
    int r = idx >> 6, c = idx & 63;
    qa[c][r] = Wq[(size_t)(k0 + r) * Dn + h * 64 + c];
    ka[c][r] = Wk[(size_t)(d0 + r) * Dn + h * 64 + c];
  }
  __syncthreads();
  float acc[4][4] = {};
#pragma unroll 4
  for (int c = 0; c < 64; ++c) {
    float av[4], bv[4];
#pragma unroll
    for (int i = 0; i < 4; ++i) av[i] = qa[c][ty * 4 + i];
#pragma unroll
    for (int j = 0; j < 4; ++j) bv[j] = ka[c][tx * 4 + j];
#pragma unroll
    for (int i = 0; i < 4; ++i)
#pragma unroll
      for (int j = 0; j < 4; ++j) acc[i][j] += av[i] * bv[j];
  }
#pragma unroll
  for (int i = 0; i < 4; ++i)
#pragma unroll
    for (int j = 0; j < 4; ++j)
      Ms[(size_t)(k0 + ty * 4 + i) * 4096 + h * 512 + d0 + tx * 4 + j] = acc[i][j];
}

// ---------------- vbias_h[d] = Wk[d, h64:]·bq[h64:]; raw + scaled ----------------
__global__ __launch_bounds__(256) void k_vbias(const float* __restrict__ Wk, const float* __restrict__ bq,
                                               const float* __restrict__ lnw, float* __restrict__ vb_raw,
                                               float* __restrict__ vb_s) {
  __shared__ float bqs[512];
  int t = threadIdx.x;
  bqs[t] = bq[t]; bqs[256 + t] = bq[256 + t];
  __syncthreads();
  int d = blockIdx.x * 256 + t;
  float vb[8] = {};
  const float4* wr = reinterpret_cast<const float4*>(Wk + (size_t)d * Dn);
#pragma unroll 8
  for (int c4 = 0; c4 < 128; ++c4) {
    float4 wv = wr[c4];
    int h = c4 >> 4;
    int c = c4 * 4;
    vb[h] += wv.x * bqs[c] + wv.y * bqs[c + 1] + wv.z * bqs[c + 2] + wv.w * bqs[c + 3];
  }
  float lw = lnw[d];
#pragma unroll
  for (int h = 0; h < 8; ++h) {
    vb_raw[h * 512 + d] = vb[h];
    vb_s[h * 512 + d] = kScale * lw * vb[h];
  }
}

// ---------------- fold: scale Ms in place by kScale*lnw[d]; avec/bvec ----------------
__global__ __launch_bounds__(256) void k_mfold(float* __restrict__ Ms, const float* __restrict__ Wq,
                                               const float* __restrict__ bk, const float* __restrict__ lnw,
                                               const float* __restrict__ lnb, float* __restrict__ avec,
                                               float* __restrict__ bvec) {
  __shared__ float lws[512], lbs[512], bks[512];
  int t = threadIdx.x;
  lws[t] = lnw[t]; lws[256 + t] = lnw[256 + t];
  lbs[t] = lnb[t]; lbs[256 + t] = lnb[256 + t];
  bks[t] = bk[t]; bks[256 + t] = bk[256 + t];
  __syncthreads();
  int g = blockIdx.x * 256 + t;
  int k = g >> 3, h = g & 7;
  float* mr = Ms + (size_t)k * 4096 + h * 512;
  float mlnb = 0.0f, mlnw = 0.0f;
  for (int d = 0; d < 512; d += 4) {
    float4 m4 = *reinterpret_cast<const float4*>(mr + d);
    mlnb += m4.x * lbs[d] + m4.y * lbs[d + 1] + m4.z * lbs[d + 2] + m4.w * lbs[d + 3];
    mlnw += m4.x * lws[d] + m4.y * lws[d + 1] + m4.z * lws[d + 2] + m4.w * lws[d + 3];
    float4 o4 = {m4.x * kScale * lws[d], m4.y * kScale * lws[d + 1],
                 m4.z * kScale * lws[d + 2], m4.w * kScale * lws[d + 3]};
    *reinterpret_cast<float4*>(mr + d) = o4;
  }
  float wqdot = 0.0f;
  const float* qr = Wq + (size_t)k * Dn + h * 64;
  for (int c = 0; c < 64; c += 4) {
    float4 q4 = *reinterpret_cast<const float4*>(qr + c);
    wqdot += q4.x * bks[h * 64 + c] + q4.y * bks[h * 64 + c + 1] +
             q4.z * bks[h * 64 + c + 2] + q4.w * bks[h * 64 + c + 3];
  }
  avec[h * 512 + k] = kScale * (mlnb + wqdot);
  bvec[h * 512 + k] = kScale * mlnw;
}

// ---------------- aconst/bconst scalars ----------------
__global__ __launch_bounds__(256) void k_consts(const float* __restrict__ vb_raw, const float* __restrict__ bq,
                                                const float* __restrict__ bk, const float* __restrict__ lnw,
                                                const float* __restrict__ lnb, float* __restrict__ aconst,
                                                float* __restrict__ bconst) {
  __shared__ float r1[256], r2[256], r3[256];
  int t = threadIdx.x;
  for (int h = 0; h < 8; ++h) {
    float p1 = 0.0f, p2 = 0.0f, p3 = 0.0f;
    for (int d = t; d < 512; d += 256) {
      float vr = vb_raw[h * 512 + d];
      p1 += lnb[d] * vr;
      p2 += lnw[d] * vr;
    }
    if (t < 64) p3 = bq[h * 64 + t] * bk[h * 64 + t];
    r1[t] = p1; r2[t] = p2; r3[t] = p3;
    __syncthreads();
    for (int s = 128; s > 0; s >>= 1) {
      if (t < s) { r1[t] += r1[t + s]; r2[t] += r2[t + s]; r3[t] += r3[t + s]; }
      __syncthreads();
    }
    if (t == 0) {
      aconst[h] = kScale * (r1[0] + r3[0]);
      bconst[h] = kScale * r2[0];
    }
    __syncthreads();
  }
}

// ---------------- bcih[n] = bc·Wih[n,:] + bih[n] ----------------
__global__ __launch_bounds__(256) void k_bcih(const float* __restrict__ bc, const float* __restrict__ Wih,
                                              const float* __restrict__ bih, float* __restrict__ bcih) {
  __shared__ float bcs[512];
  int t = threadIdx.x;
  bcs[t] = bc[t]; bcs[256 + t] = bc[256 + t];
  __syncthreads();
  int n = blockIdx.x * 256 + t;
  const float4* wr = reinterpret_cast<const float4*>(Wih + (size_t)n * Dn);
  float a = 0.0f;
#pragma unroll 8
  for (int c4 = 0; c4 < 128; ++c4) {
    float4 wv = wr[c4];
    int c = c4 * 4;
    a += wv.x * bcs[c] + wv.y * bcs[c + 1] + wv.z * bcs[c + 2] + wv.w * bcs[c + 3];
  }
  bcih[n] = a + bih[n];
}

// ---------------- qkt = sln @ Ms + vb_s, packed hi|mid u32, remapped to [b,hi,d] ----------------
__global__ __launch_bounds__(256) void k_qu(const float* __restrict__ sln, const float* __restrict__ Ms,
                                            const float* __restrict__ vb_s, unsigned* __restrict__ qkt) {
  __shared__ float as_[64][17];
  __shared__ float ws_[16][65];
  int m0 = blockIdx.y * 64, n0 = blockIdx.x * 64;
  int t = threadIdx.x, tx = t & 15, ty = t >> 4;
  float acc[4][4] = {};
  float pa[4], pw[4];
  auto loadA = [&](int k0) {
#pragma unroll
    for (int e = 0; e < 4; ++e) {
      int idx = t + e * 256;
      int r = idx >> 4, c = idx & 15;
      pa[e] = sln[(size_t)(m0 + r) * Dn + k0 + c];
    }
  };
  auto loadW = [&](int k0) {
#pragma unroll
    for (int e = 0; e < 4; ++e) {
      int idx = t + e * 256;
      int r = idx >> 6, c = idx & 63;
      pw[e] = Ms[(size_t)(k0 + r) * 4096 + n0 + c];
    }
  };
  loadA(0); loadW(0);
  for (int k0 = 0; k0 < 512; k0 += 16) {
#pragma unroll
    for (int e = 0; e < 4; ++e) {
      int idx = t + e * 256;
      int r = idx >> 4, c = idx & 15;
      as_[r][c] = pa[e];
    }
#pragma unroll
    for (int e = 0; e < 4; ++e) {
      int idx = t + e * 256;
      int r = idx >> 6, c = idx & 63;
      ws_[r][c] = pw[e];
    }
    __syncthreads();
    if (k0 + 16 < 512) { loadA(k0 + 16); loadW(k0 + 16); }
#pragma unroll
    for (int kc = 0; kc < 16; ++kc) {
      float av[4], wv[4];
#pragma unroll
      for (int i = 0; i < 4; ++i) av[i] = as_[ty * 4 + i][kc];
#pragma unroll
      for (int j = 0; j < 4; ++j) wv[j] = ws_[kc][tx * 4 + j];
#pragma unroll
      for (int i = 0; i < 4; ++i)
#pragma unroll
        for (int j = 0; j < 4; ++j) acc[i][j] += av[i] * wv[j];
    }
    __syncthreads();
  }
#pragma unroll
  for (int i = 0; i < 4; ++i)
#pragma unroll
    for (int j = 0; j < 4; ++j) {
      int m = m0 + ty * 4 + i, n = n0 + tx * 4 + j;
      int bb = m >> 4, isl = m & 15, h = n >> 9, d = n & 511;
      qkt[((size_t)bb * HIn + h * 16 + isl) * Dn + d] = packhm(acc[i][j] + vb_s[n]);
    }
}

// ---------------- alpha/beta = sln·avec_h + aconst_h ----------------
__global__ void k_ab(const float* __restrict__ sln, const float* __restrict__ avec,
                     const float* __restrict__ bvec, const float* __restrict__ aconst,
                     const float* __restrict__ bconst, float* __restrict__ alpha,
                     float* __restrict__ beta) {
  int g = blockIdx.x;           // b*128 + hi
  int hi = g & 127, b = g >> 7;
  int h = hi >> 4, i = hi & 15;
  int lane = threadIdx.x;
  const float4* sp = reinterpret_cast<const float4*>(sln + (size_t)(b * NSn + i) * Dn) + lane * 2;
  const float4* ap = reinterpret_cast<const float4*>(avec + h * 512) + lane * 2;
  const float4* bp = reinterpret_cast<const float4*>(bvec + h * 512) + lane * 2;
  float4 s0 = sp[0], s1 = sp[1], a0 = ap[0], a1 = ap[1], b0 = bp[0], b1 = bp[1];
  float pa = s0.x*a0.x + s0.y*a0.y + s0.z*a0.z + s0.w*a0.w + s1.x*a1.x + s1.y*a1.y + s1.z*a1.z + s1.w*a1.w;
  float pb = s0.x*b0.x + s0.y*b0.y + s0.z*b0.z + s0.w*b0.w + s1.x*b1.x + s1.y*b1.y + s1.z*b1.z + s1.w*b1.w;
  pa = wred(pa); pb = wred(pb);
  if (lane == 0) {
    alpha[g] = pa + aconst[h];
    beta[g] = pb + bconst[h];
  }
}

// ---------------- dots via 2-level bf16-split MFMA (3 passes) + in-register softmax ----------------
// u (qkt) arrives packed u32 hi|mid; x converted on the fly; A emitted packed.
__global__ __launch_bounds__(256) void k_dots(const float* __restrict__ in, const unsigned* __restrict__ qkt,
                                              const float* __restrict__ alpha, const float* __restrict__ beta,
                                              const float* __restrict__ mu, const float* __restrict__ rsig,
                                              unsigned* __restrict__ A, float* __restrict__ Spart,
                                              float* __restrict__ c1part) {
  __shared__ __align__(16) unsigned short xs_h[128][40];
  __shared__ __align__(16) unsigned short xs_m[128][40];
  __shared__ __align__(16) unsigned short us_h[128][40];
  __shared__ __align__(16) unsigned short us_m[128][40];   // 40960 B

  int b = blockIdx.y, jt = blockIdx.x, j0 = jt * 128;
  int t = threadIdx.x, w = t >> 6, l = t & 63;
  int lc = l & 15, lg = l >> 4, koff = lg * 8;
  const size_t inbase = ((size_t)b * Nn + j0) * Dn;
  const size_t ubase = (size_t)b * HIn * Dn;

  f32x4 acc[2][8];
#pragma unroll
  for (int i = 0; i < 2; ++i)
#pragma unroll
    for (int j2 = 0; j2 < 8; ++j2) acc[i][j2] = {0.0f, 0.0f, 0.0f, 0.0f};

  float2 nx[8];
  uint2 nu[8];
#pragma unroll
  for (int e = 0; e < 8; ++e) {
    int idx = t + e * 256;
    int j = idx >> 4, kp = (idx & 15) * 2;
    nx[e] = *reinterpret_cast<const float2*>(&in[inbase + (size_t)j * Dn + kp]);
    nu[e] = *reinterpret_cast<const uint2*>(&qkt[ubase + (size_t)j * Dn + kp]);
  }

  for (int k0 = 0; k0 < 512; k0 += 32) {
#pragma unroll
    for (int e = 0; e < 8; ++e) {
      int idx = t + e * 256;
      int j = idx >> 4, kp = (idx & 15) * 2;
      unsigned mm;
      unsigned hm = pack2x(nx[e].x, nx[e].y, mm);
      *reinterpret_cast<unsigned*>(&xs_h[j][kp]) = hm;
      *reinterpret_cast<unsigned*>(&xs_m[j][kp]) = mm;
      unsigned uh = (nu[e].x & 0xffffu) | (nu[e].y << 16);
      unsigned um = (nu[e].x >> 16) | (nu[e].y & 0xffff0000u);
      *reinterpret_cast<unsigned*>(&us_h[j][kp]) = uh;
      *reinterpret_cast<unsigned*>(&us_m[j][kp]) = um;
    }
    if (k0 + 32 < 512) {
#pragma unroll
      for (int e = 0; e < 8; ++e) {
        int idx = t + e * 256;
        int j = idx >> 4, kp = (idx & 15) * 2;
        nx[e] = *reinterpret_cast<const float2*>(&in[inbase + (size_t)j * Dn + k0 + 32 + kp]);
        nu[e] = *reinterpret_cast<const uint2*>(&qkt[ubase + (size_t)j * Dn + k0 + 32 + kp]);
      }
    }
    __syncthreads();
    short8 ah0 = *reinterpret_cast<const short8*>(&xs_h[w * 32 + lc][koff]);
    short8 am0 = *reinterpret_cast<const short8*>(&xs_m[w * 32 + lc][koff]);
    short8 ah1 = *reinterpret_cast<const short8*>(&xs_h[w * 32 + 16 + lc][koff]);
    short8 am1 = *reinterpret_cast<const short8*>(&xs_m[w * 32 + 16 + lc][koff]);
#pragma unroll
    for (int ht = 0; ht < 8; ++ht) {
      short8 bh = *reinterpret_cast<const short8*>(&us_h[ht * 16 + lc][koff]);
      short8 bm = *reinterpret_cast<const short8*>(&us_m[ht * 16 + lc][koff]);
      acc[0][ht] = __builtin_amdgcn_mfma_f32_16x16x32_bf16(ah0, bh, acc[0][ht], 0, 0, 0);
      acc[0][ht] = __builtin_amdgcn_mfma_f32_16x16x32_bf16(ah0, bm, acc[0][ht], 0, 0, 0);
      acc[0][ht] = __builtin_amdgcn_mfma_f32_16x16x32_bf16(am0, bh, acc[0][ht], 0, 0, 0);
      acc[1][ht] = __builtin_amdgcn_mfma_f32_16x16x32_bf16(ah1, bh, acc[1][ht], 0, 0, 0);
      acc[1][ht] = __builtin_amdgcn_mfma_f32_16x16x32_bf16(ah1, bm, acc[1][ht], 0, 0, 0);
      acc[1][ht] = __builtin_amdgcn_mfma_f32_16x16x32_bf16(am1, bh, acc[1][ht], 0, 0, 0);
    }
    __syncthreads();
  }

  float* rsL = reinterpret_cast<float*>(&xs_h[0][0]);
  float* muL = rsL + 128;
  float* aL = rsL + 256;
  float* bL = rsL + 384;
  float (*sredS)[128] = reinterpret_cast<float(*)[128]>(rsL + 512);
  float (*sredC)[128] = reinterpret_cast<float(*)[128]>(rsL + 512 + 4 * 128);
  if (t < 128) {
    rsL[t] = rsig[(size_t)b * Nn + j0 + t];
    muL[t] = mu[(size_t)b * Nn + j0 + t];
    aL[t] = alpha[b * HIn + t];
    bL[t] = beta[b * HIn + t];
  }
  __syncthreads();

  float sS[8] = {}, sC[8] = {};
#pragma unroll
  for (int jt2 = 0; jt2 < 2; ++jt2) {
    int jbase = w * 32 + jt2 * 16 + lg * 4;
#pragma unroll
    for (int ht = 0; ht < 8; ++ht) {
      int hi = ht * 16 + lc;
      float av = aL[hi], bv = bL[hi];
      float v[4], rs4[4], mr4[4];
#pragma unroll
      for (int r = 0; r < 4; ++r) {
        int jr = jbase + r;
        rs4[r] = rsL[jr];
        mr4[r] = muL[jr] * rs4[r];
        v[r] = acc[jt2][ht][r] * rs4[r] + av - mr4[r] * bv;
      }
      float mx[4] = {v[0], v[1], v[2], v[3]};
#pragma unroll
      for (int m = 1; m <= 8; m <<= 1)
#pragma unroll
        for (int r = 0; r < 4; ++r) mx[r] = fmaxf(mx[r], __shfl_xor(mx[r], m));
      float e4[4], ss[4];
#pragma unroll
      for (int r = 0; r < 4; ++r) { e4[r] = expf(v[r] - mx[r]); ss[r] = e4[r]; }
#pragma unroll
      for (int m = 1; m <= 8; m <<= 1)
#pragma unroll
        for (int r = 0; r < 4; ++r) ss[r] += __shfl_xor(ss[r], m);
      float ps = 0.0f, pc = 0.0f;
      float p0 = e4[0] / ss[0] + kEps, p1 = e4[1] / ss[1] + kEps;
      float p2 = e4[2] / ss[2] + kEps, p3 = e4[3] / ss[3] + kEps;
      uint4 o4;
      o4.x = packhm(p0 * rs4[0]); o4.y = packhm(p1 * rs4[1]);
      o4.z = packhm(p2 * rs4[2]); o4.w = packhm(p3 * rs4[3]);
      ps = p0 + p1 + p2 + p3;
      pc = p0 * mr4[0] + p1 * mr4[1] + p2 * mr4[2] + p3 * mr4[3];
      *reinterpret_cast<uint4*>(&A[(size_t)(b * HIn + hi) * Nn + j0 + jbase]) = o4;
      ps += __shfl_xor(ps, 16); ps += __shfl_xor(ps, 32);
      pc += __shfl_xor(pc, 16); pc += __shfl_xor(pc, 32);
      sS[ht] += ps; sC[ht] += pc;
    }
  }
  if (l < 16) {
#pragma unroll
    for (int ht = 0; ht < 8; ++ht) {
      sredS[w][ht * 16 + l] = sS[ht];
      sredC[w][ht * 16 + l] = sC[ht];
    }
  }
  __syncthreads();
  if (t < 128) {
    float s_ = sredS[0][t] + sredS[1][t] + sredS[2][t] + sredS[3][t];
    float c_ = sredC[0][t] + sredC[1][t] + sredC[2][t] + sredC[3][t];
    int sub = (b * 32 + jt) * HIn + t;
    Spart[sub] = s_;
    c1part[sub] = c_;
  }
}

// ---------------- AX = A @ X via 2-level bf16-split MFMA (K-split x4) ----------------
__global__ __launch_bounds__(256) void k_ax(const unsigned* __restrict__ Au, const unsigned* __restrict__ inT,
                                            float* __restrict__ AXp) {
  __shared__ __align__(16) unsigned short as_h[128][40];
  __shared__ __align__(16) unsigned short as_m[128][40];
  __shared__ __align__(16) unsigned short xs_h[128][40];
  __shared__ __align__(16) unsigned short xs_m[128][40];

  int d0 = blockIdx.x * 128, kp = blockIdx.y, b = blockIdx.z;
  int t = threadIdx.x, w = t >> 6, l = t & 63;
  int lc = l & 15, lg = l >> 4, koff = lg * 8;
  const size_t abase = (size_t)b * HIn * Nn + kp * 1024;
  const size_t xbase = ((size_t)b * Dn + d0) * Nn + kp * 1024;

  f32x4 acc[2][8];
#pragma unroll
  for (int i = 0; i < 2; ++i)
#pragma unroll
    for (int j2 = 0; j2 < 8; ++j2) acc[i][j2] = {0.0f, 0.0f, 0.0f, 0.0f};

  uint2 pa[8];
  uint4 px[4];
#pragma unroll
  for (int e = 0; e < 8; ++e) {
    int idx = t + e * 256;
    int hi = idx >> 4, jp = (idx & 15) * 2;
    pa[e] = *reinterpret_cast<const uint2*>(&Au[abase + (size_t)hi * Nn + jp]);
  }
#pragma unroll
  for (int e = 0; e < 4; ++e) {
    int idx = t + e * 256;
    int d = idx >> 3, jg = idx & 7;
    px[e] = *reinterpret_cast<const uint4*>(&inT[xbase + (size_t)d * Nn + jg * 4]);
  }

  for (int c0 = 0; c0 < 1024; c0 += 32) {
#pragma unroll
    for (int e = 0; e < 8; ++e) {
      int idx = t + e * 256;
      int hi = idx >> 4, jp = (idx & 15) * 2;
      unsigned h = (pa[e].x & 0xffffu) | (pa[e].y << 16);
      unsigned m = (pa[e].x >> 16) | (pa[e].y & 0xffff0000u);
      *reinterpret_cast<unsigned*>(&as_h[hi][jp]) = h;
      *reinterpret_cast<unsigned*>(&as_m[hi][jp]) = m;
    }
#pragma unroll
    for (int e = 0; e < 4; ++e) {
      int idx = t + e * 256;
      int d = idx >> 3, jg = idx & 7;
      unsigned h0 = (px[e].x & 0xffffu) | (px[e].y << 16);
      unsigned h1 = (px[e].z & 0xffffu) | (px[e].w << 16);
      unsigned m0 = (px[e].x >> 16) | (px[e].y & 0xffff0000u);
      unsigned m1 = (px[e].z >> 16) | (px[e].w & 0xffff0000u);
      uint2 hv = {h0, h1}, mv = {m0, m1};
      *reinterpret_cast<uint2*>(&xs_h[d][jg * 4]) = hv;
      *reinterpret_cast<uint2*>(&xs_m[d][jg * 4]) = mv;
    }
    if (c0 + 32 < 1024) {
#pragma unroll
      for (int e = 0; e < 8; ++e) {
        int idx = t + e * 256;
        int hi = idx >> 4, jp = (idx & 15) * 2;
        pa[e] = *reinterpret_cast<const uint2*>(&Au[abase + (size_t)hi * Nn + c0 + 32 + jp]);
      }
#pragma unroll
      for (int e = 0; e < 4; ++e) {
        int idx = t + e * 256;
        int d = idx >> 3, jg = idx & 7;
        px[e] = *reinterpret_cast<const uint4*>(&inT[xbase + (size_t)d * Nn + c0 + 32 + jg * 4]);
      }
    }
    __syncthreads();
    short8 ah0 = *reinterpret_cast<const short8*>(&as_h[w * 32 + lc][koff]);
    short8 am0 = *reinterpret_cast<const short8*>(&as_m[w * 32 + lc][koff]);
    short8 ah1 = *reinterpret_cast<const short8*>(&as_h[w * 32 + 16 + lc][koff]);
    short8 am1 = *reinterpret_cast<const short8*>(&as_m[w * 32 + 16 + lc][koff]);
#pragma unroll
    for (int dt = 0; dt < 8; ++dt) {
      short8 bh = *reinterpret_cast<const short8*>(&xs_h[dt * 16 + lc][koff]);
      short8 bm = *reinterpret_cast<const short8*>(&xs_m[dt * 16 + lc][koff]);
      acc[0][dt] = __builtin_amdgcn_mfma_f32_16x16x32_bf16(ah0, bh, acc[0][dt], 0, 0, 0);
      acc[0][dt] = __builtin_amdgcn_mfma_f32_16x16x32_bf16(ah0, bm, acc[0][dt], 0, 0, 0);
      acc[0][dt] = __builtin_amdgcn_mfma_f32_16x16x32_bf16(am0, bh, acc[0][dt], 0, 0, 0);
      acc[1][dt] = __builtin_amdgcn_mfma_f32_16x16x32_bf16(ah1, bh, acc[1][dt], 0, 0, 0);
      acc[1][dt] = __builtin_amdgcn_mfma_f32_16x16x32_bf16(ah1, bm, acc[1][dt], 0, 0, 0);
      acc[1][dt] = __builtin_amdgcn_mfma_f32_16x16x32_bf16(am1, bh, acc[1][dt], 0, 0, 0);
    }
    __syncthreads();
  }

  const size_t obase = (((size_t)kp * Bn + b) * HIn) * Dn + d0;
#pragma unroll
  for (int jt2 = 0; jt2 < 2; ++jt2) {
#pragma unroll
    for (int dt = 0; dt < 8; ++dt) {
#pragma unroll
      for (int r = 0; r < 4; ++r) {
        int hi = w * 32 + jt2 * 16 + lg * 4 + r;
        int d = dt * 16 + lc;
        AXp[obase + (size_t)hi * Dn + d] = acc[jt2][dt][r];
      }
    }
  }
}

// ---------------- upd = ((w*(G-c1)/S + b) @ Wv_h) + bv, S/c1 reduced inline ----------------
__global__ __launch_bounds__(256) void k_updS(const float* __restrict__ AXp, const float* __restrict__ Spart,
                                              const float* __restrict__ c1part, const float* __restrict__ lnw,
                                              const float* __restrict__ lnb, const float* __restrict__ Wv,
                                              const float* __restrict__ bv, float* __restrict__ upd) {
  int b = blockIdx.y, hi = blockIdx.x, h = hi >> 4, i = hi & 15;
  __shared__ float vx[512];
  __shared__ float red[256];
  __shared__ float sSC[2];
  int t = threadIdx.x;
  if (t < 64) {
    float vs = 0.0f, vc = 0.0f;
    if (t < 32) {
      vs = Spart[(size_t)(b * 32 + t) * HIn + hi];
      vc = c1part[(size_t)(b * 32 + t) * HIn + hi];
    }
    vs = wred(vs); vc = wred(vc);
    if (t == 0) { sSC[0] = vs; sSC[1] = vc; }
  }
  __syncthreads();
  float c1v = sSC[1];
  float invS = 1.0f / sSC[0];
  for (int d = t; d < Dn; d += 256) {
    float G = AXp[((size_t)(0 * Bn + b) * HIn + hi) * Dn + d]
            + AXp[((size_t)(1 * Bn + b) * HIn + hi) * Dn + d]
            + AXp[((size_t)(2 * Bn + b) * HIn + hi) * Dn + d]
            + AXp[((size_t)(3 * Bn + b) * HIn + hi) * Dn + d];
    vx[d] = lnw[d] * (G - c1v) * invS + lnb[d];
  }
  __syncthreads();
  int cc = t & 63, qd = t >> 6;
  float p = 0.0f;
  for (int d = qd * 128; d < qd * 128 + 128; ++d) p += vx[d] * Wv[(size_t)d * Dn + h * 64 + cc];
  red[t] = p;
  __syncthreads();
  if (qd == 0) {
    float v = red[cc] + red[64 + cc] + red[128 + cc] + red[192 + cc] + bv[h * 64 + cc];
    upd[(size_t)(b * NSn + i) * Dn + h * 64 + cc] = v;
  }
}

// ---------------- dual GEMM (prefetched): z=0: gi = upd@T1 + bcih ; z=1: gh = slots@Whh^T + bhh ----------------
__global__ __launch_bounds__(256) void k_gg(const float* __restrict__ upd, const float* __restrict__ T1,
                                            const float* __restrict__ bcih, const float* __restrict__ slots,
                                            const float* __restrict__ Whh, const float* __restrict__ bhh,
                                            float* __restrict__ gi, float* __restrict__ gh) {
  bool z = (blockIdx.z == 1);
  const float* A = z ? slots : upd;
  const float* W = z ? Whh : T1;
  const float* bias = z ? bhh : bcih;
  float* out = z ? gh : gi;
  __shared__ float as_[64][17];
  __shared__ float ws_[16][65];
  int m0 = blockIdx.y * 64, n0 = blockIdx.x * 64;
  int t = threadIdx.x, tx = t & 15, ty = t >> 4;
  float acc[4][4] = {};
  float pa[4], pw[4];
  auto loadA = [&](int k0) {
#pragma unroll
    for (int e = 0; e < 4; ++e) {
      int idx = t + e * 256;
      int r = idx >> 4, c = idx & 15;
      pa[e] = A[(size_t)(m0 + r) * 512 + k0 + c];
    }
  };
  auto loadW = [&](int k0) {
#pragma unroll
    for (int e = 0; e < 4; ++e) {
      int idx = t + e * 256;
      if (!z) {
        int r = idx >> 6, c = idx & 63;
        pw[e] = W[(size_t)(k0 + r) * 1536 + n0 + c];
      } else {
        int r = idx >> 4, c = idx & 15;
        pw[e] = W[(size_t)(n0 + r) * 512 + k0 + c];
      }
    }
  };
  loadA(0); loadW(0);
  for (int k0 = 0; k0 < 512; k0 += 16) {
#pragma unroll
    for (int e = 0; e < 4; ++e) {
      int idx = t + e * 256;
      int r = idx >> 4, c = idx & 15;
      as_[r][c] = pa[e];
    }
#pragma unroll
    for (int e = 0; e < 4; ++e) {
      int idx = t + e * 256;
      if (!z) {
        int r = idx >> 6, c = idx & 63;
        ws_[r][c] = pw[e];
      } else {
        int r = idx >> 4, c = idx & 15;
        ws_[c][r] = pw[e];
      }
    }
    __syncthreads();
    if (k0 + 16 < 512) { loadA(k0 + 16); loadW(k0 + 16); }
#pragma unroll
    for (int kc = 0; kc < 16; ++kc) {
      float av[4], wv[4];
#pragma unroll
      for (int i = 0; i < 4; ++i) av[i] = as_[ty * 4 + i][kc];
#pragma unroll
      for (int j = 0; j < 4; ++j) wv[j] = ws_[kc][tx * 4 + j];
#pragma unroll
      for (int i = 0; i < 4; ++i)
#pragma unroll
        for (int j = 0; j < 4; ++j) acc[i][j] += av[i] * wv[j];
    }
    __syncthreads();
  }
#pragma unroll
  for (int i = 0; i < 4; ++i)
#pragma unroll
    for (int j = 0; j < 4; ++j) {
      int m = m0 + ty * 4 + i, n = n0 + tx * 4 + j;
      out[(size_t)m * 1536 + n] = acc[i][j] + bias[n];
    }
}

// ---------------- GRU pointwise + LN_ff fused ----------------
__global__ __launch_bounds__(256) void k_gruln(const float* __restrict__ gi, const float* __restrict__ gh,
                                               float* __restrict__ slots, float* __restrict__ slnff,
                                               const float* __restrict__ lnffw, const float* __restrict__ lnffb) {
  int r = blockIdx.x, t = threadIdx.x;
  __shared__ float red[8];
  float sn[2];
#pragma unroll
  for (int j = 0; j < 2; ++j) {
    int c = j * 256 + t;
    float gir = gi[(size_t)r * 1536 + c];
    float giz = gi[(size_t)r * 1536 + 512 + c];
    float gin = gi[(size_t)r * 1536 + 1024 + c];
    float ghr = gh[(size_t)r * 1536 + c];
    float ghz = gh[(size_t)r * 1536 + 512 + c];
    float ghn = gh[(size_t)r * 1536 + 1024 + c];
    float rg = 1.0f / (1.0f + expf(-(gir + ghr)));
    float zg = 1.0f / (1.0f + expf(-(giz + ghz)));
    float ng = tanhf(gin + rg * ghn);
    sn[j] = (1.0f - zg) * ng + zg * slots[(size_t)r * Dn + c];
  }
  float s = sn[0] + sn[1], q = sn[0] * sn[0] + sn[1] * sn[1];
  s = wred(s); q = wred(q);
  if ((t & 63) == 0) { red[t >> 6] = s; red[4 + (t >> 6)] = q; }
  __syncthreads();
  float S = red[0] + red[1] + red[2] + red[3];
  float Q = red[4] + red[5] + red[6] + red[7];
  float m = S * (1.0f / 512.0f);
  float rs = 1.0f / sqrtf(Q * (1.0f / 512.0f) - m * m + 1e-5f);
#pragma unroll
  for (int j = 0; j < 2; ++j) {
    int c = j * 256 + t;
    slots[(size_t)r * Dn + c] = sn[j];
    slnff[(size_t)r * Dn + c] = (sn[j] - m) * rs * lnffw[c] + lnffb[c];
  }
}

// ---------------- keep gate (zero dropped slots in place) ----------------
__global__ void k_keepscale(const float* __restrict__ Wkeep, const float* __restrict__ gk,
                            float* __restrict__ slots) {
  int g = blockIdx.x;
  int lane = threadIdx.x;
  float4* sp = reinterpret_cast<float4*>(slots + (size_t)g * Dn) + lane * 2;
  float4 s0 = sp[0], s1 = sp[1];
  float sv[8] = {s0.x, s0.y, s0.z, s0.w, s1.x, s1.y, s1.z, s1.w};
  double d0 = 0.0, d1 = 0.0;
#pragma unroll
  for (int e = 0; e < 8; ++e) {
    int d = lane * 8 + e;
    d0 += (double)sv[e] * (double)Wkeep[d * 2];
    d1 += (double)sv[e] * (double)Wkeep[d * 2 + 1];
  }
  d0 = wredd(d0);
  d1 = wredd(d1);
  int keepi = 0;
  if (lane == 0) keepi = ((d1 + (double)gk[g * 2 + 1]) > (d0 + (double)gk[g * 2])) ? 1 : 0;
  keepi = __shfl(keepi, 0);
  if (!keepi) {
    float4 z = {0.0f, 0.0f, 0.0f, 0.0f};
    sp[0] = z;
    sp[1] = z;
  }
}

// ---------------- per-slot scalars for route decomposition ----------------
__global__ void k_slotscalars(const float* __restrict__ slots, const float* __restrict__ lnw,
                              const float* __restrict__ lnb, double* __restrict__ swd,
                              double* __restrict__ sbd) {
  int g = blockIdx.x, lane = threadIdx.x;
  const float4* sp = reinterpret_cast<const float4*>(slots + (size_t)g * Dn) + lane * 2;
  const float4* wp = reinterpret_cast<const float4*>(lnw) + lane * 2;
  const float4* bp = reinterpret_cast<const float4*>(lnb) + lane * 2;
  float4 s0 = sp[0], s1 = sp[1], w0 = wp[0], w1 = wp[1], b0 = bp[0], b1 = bp[1];
  double pw = (double)s0.x * w0.x + (double)s0.y * w0.y + (double)s0.z * w0.z + (double)s0.w * w0.w +
              (double)s1.x * w1.x + (double)s1.y * w1.y + (double)s1.z * w1.z + (double)s1.w * w1.w;
  double pb = (double)s0.x * b0.x + (double)s0.y * b0.y + (double)s0.z * b0.z + (double)s0.w * b0.w +
              (double)s1.x * b1.x + (double)s1.y * b1.y + (double)s1.z * b1.z + (double)s1.w * b1.w;
  pw = wredd(pw);
  pb = wredd(pb);
  if (lane == 0) { swd[g] = pw; sbd[g] = pb; }
}

// ---------------- hard route + gather output (tiled mini-GEMM) ----------------
__global__ __launch_bounds__(256) void k_route_out(const float* __restrict__ in, const float* __restrict__ slots,
                                                   const float* __restrict__ lnw, const double* __restrict__ swd,
                                                   const double* __restrict__ sbd, const float* __restrict__ mu,
                                                   const float* __restrict__ rsig,
                                                   const float* __restrict__ g_route, float* __restrict__ out) {
  int b = blockIdx.y, j0 = blockIdx.x * 128;
  __shared__ __align__(16) float sl[16 * 516];
  __shared__ __align__(16) float lw[512];
  __shared__ __align__(16) float xs[16][132];
  __shared__ double lgd[128][17];
  __shared__ int besti[128];
  int t = threadIdx.x, tx = t & 15, ty = t >> 4;

  for (int idx = t; idx < 2048; idx += 256) {
    int i = idx >> 7, c = idx & 127;
    *reinterpret_cast<float4*>(&sl[i * 516 + c * 4]) =
        *reinterpret_cast<const float4*>(&slots[(size_t)(b * NSn + i) * Dn + c * 4]);
  }
  if (t < 128)
    *reinterpret_cast<float4*>(&lw[t * 4]) = *reinterpret_cast<const float4*>(&lnw[t * 4]);

  float acc[8] = {};
  double accd[8] = {};
  const size_t inbase = ((size_t)b * Nn + j0) * Dn;
  __syncthreads();

  for (int k0 = 0; k0 < Dn; k0 += 16) {
    float pre[8];
#pragma unroll
    for (int e = 0; e < 8; ++e) {
      int idx = t + e * 256;
      int r = idx >> 4, c = idx & 15;
      pre[e] = in[inbase + (size_t)r * Dn + k0 + c];
    }
    __syncthreads();
#pragma unroll
    for (int e = 0; e < 8; ++e) {
      int idx = t + e * 256;
      int r = idx >> 4, c = idx & 15;
      xs[c][r] = pre[e] * lw[k0 + c];
    }
    __syncthreads();
#pragma unroll
    for (int kc = 0; kc < 16; ++kc) {
      float sv = sl[tx * 516 + k0 + kc];
      float4 x0 = *reinterpret_cast<const float4*>(&xs[kc][ty * 8]);
      float4 x1 = *reinterpret_cast<const float4*>(&xs[kc][ty * 8 + 4]);
      acc[0] += x0.x * sv; acc[1] += x0.y * sv; acc[2] += x0.z * sv; acc[3] += x0.w * sv;
      acc[4] += x1.x * sv; acc[5] += x1.y * sv; acc[6] += x1.z * sv; acc[7] += x1.w * sv;
    }
    if ((k0 & 127) == 112) {
#pragma unroll
      for (int e = 0; e < 8; ++e) { accd[e] += (double)acc[e]; acc[e] = 0.0f; }
    }
  }

  double sw_i = swd[b * NSn + tx], sb_i = sbd[b * NSn + tx];
#pragma unroll
  for (int r = 0; r < 8; ++r) {
    int j = ty * 8 + r;
    double rsj = (double)rsig[(size_t)b * Nn + j0 + j];
    double muj = (double)mu[(size_t)b * Nn + j0 + j];
    double g = (double)g_route[((size_t)b * NSn + tx) * Nn + j0 + j];
    lgd[j][tx] = (double)kScale * (rsj * accd[r] + sb_i - muj * rsj * sw_i) + g;
  }
  __syncthreads();
  if (t < 128) {
    double best = lgd[t][0];
    int bi = 0;
#pragma unroll
    for (int i = 1; i < 16; ++i) {
      double v = lgd[t][i];
      if (v > best) { best = v; bi = i; }
    }
    besti[t] = bi;
  }
  __syncthreads();
  for (int idx = t; idx < 128 * 128; idx += 256) {
    int j = idx >> 7, c = idx & 127;
    *reinterpret_cast<float4*>(&out[inbase + (size_t)j * Dn + c * 4]) =
        *reinterpret_cast<const float4*>(&sl[besti[j] * 516 + c * 4]);
  }
}

extern "C" void kernel_launch(void* const* d_in, const int* in_sizes, int n_in,
                              void* d_out, int out_size, void* d_ws, size_t ws_size,
                              hipStream_t stream) {
  (void)in_sizes; (void)n_in; (void)out_size; (void)ws_size;
  const float* in = (const float*)d_in[0];
  const float* slots_mu = (const float*)d_in[1];
  const float* slots_ls = (const float*)d_in[2];
  const float* ln_in_w = (const float*)d_in[3];
  const float* ln_in_b = (const float*)d_in[4];
  const float* ln_s_w = (const float*)d_in[5];
  const float* ln_s_b = (const float*)d_in[6];
  const float* ln_ff_w = (const float*)d_in[7];
  const float* ln_ff_b = (const float*)d_in[8];
  const float* Wq = (const float*)d_in[9];
  const float* bq = (const float*)d_in[10];
  const float* Wk = (const float*)d_in[11];
  const float* bk = (const float*)d_in[12];
  const float* Wv = (const float*)d_in[13];
  const float* bv = (const float*)d_in[14];
  const float* Wc = (const float*)d_in[15];
  const float* bc = (const float*)d_in[16];
  const float* Wih = (const float*)d_in[17];
  const float* bih = (const float*)d_in[18];
  const float* Whh = (const float*)d_in[19];
  const float* bhh = (const float*)d_in[20];
  const float* W1 = (const float*)d_in[21];
  const float* b1 = (const float*)d_in[22];
  const float* W2 = (const float*)d_in[23];
  const float* b2 = (const float*)d_in[24];
  const float* Wkeep = (const float*)d_in[25];
  const float* noise = (const float*)d_in[26];
  const float* g_keep = (const float*)d_in[27];
  const float* g_route = (const float*)d_in[28];
  float* out = (float*)d_out;
  unsigned* inTu = (unsigned*)d_out;   // scratch during iterations; overwritten by k_route_out

  char* wptr = (char*)d_ws;
  auto alloc = [&](size_t bytes) {
    char* p = wptr;
    wptr += (bytes + 255) & ~(size_t)255;
    return p;
  };
  float* mu = (float*)alloc((size_t)Bn * Nn * 4);
  float* rsig = (float*)alloc((size_t)Bn * Nn * 4);
  float* slots = (float*)alloc((size_t)Bn * NSn * Dn * 4);
  float* sln = (float*)alloc((size_t)Bn * NSn * Dn * 4);
  unsigned* qkt = (unsigned*)alloc((size_t)Bn * HIn * Dn * 4);
  float* alpha = (float*)alloc((size_t)Bn * HIn * 4);
  float* beta = (float*)alloc((size_t)Bn * HIn * 4);
  unsigned* Abuf = (unsigned*)alloc((size_t)Bn * HIn * Nn * 4);
  float* Spart = (float*)alloc((size_t)Bn * 64 * HIn * 4);
  float* c1part = (float*)alloc((size_t)Bn * 64 * HIn * 4);
  float* AXp = (float*)alloc((size_t)4 * Bn * HIn * Dn * 4);
  float* updb = (float*)alloc((size_t)Bn * NSn * Dn * 4);
  float* gibuf = (float*)alloc((size_t)Bn * NSn * 1536 * 4);
  float* ghbuf = (float*)alloc((size_t)Bn * NSn * 1536 * 4);
  float* hbuf = (float*)alloc((size_t)Bn * NSn * 2048 * 4);
  float* ffp = (float*)alloc((size_t)4 * 512 * 512 * 4);
  float* T1 = (float*)alloc((size_t)Dn * 1536 * 4);
  float* bcih = (float*)alloc((size_t)1536 * 4);
  float* Ms = (float*)alloc((size_t)Dn * 4096 * 4);
  float* vb_raw = (float*)alloc((size_t)4096 * 4);
  float* vb_s = (float*)alloc((size_t)4096 * 4);
  float* avec = (float*)alloc((size_t)4096 * 4);
  float* bvec = (float*)alloc((size_t)4096 * 4);
  float* aconst = (float*)alloc((size_t)8 * 4);
  float* bconst = (float*)alloc((size_t)8 * 4);
  double* swd = (double*)alloc((size_t)Bn * NSn * 8);
  double* sbd = (double*)alloc((size_t)Bn * NSn * 8);

  // prologue
  k_rowstats<<<Bn * Nn / 4, 256, 0, stream>>>(in, mu, rsig);
  k_tsplit<<<dim3(Nn / 64, Dn / 64, Bn), 256, 0, stream>>>(in, inTu);
  k_slots_init<<<Bn * NSn, 256, 0, stream>>>(slots_mu, slots_ls, noise, slots);
  k_gemm_sm<true, false, false><<<dim3(24, 8), 256, 0, stream>>>(Wc, Wih, nullptr, T1, 1536, 512);
  k_bcih<<<6, 256, 0, stream>>>(bc, Wih, bih, bcih);
  k_mh<<<dim3(8, 8, 8), 256, 0, stream>>>(Wq, Wk, Ms);
  k_vbias<<<2, 256, 0, stream>>>(Wk, bq, ln_in_w, vb_raw, vb_s);
  k_mfold<<<16, 256, 0, stream>>>(Ms, Wq, bk, ln_in_w, ln_in_b, avec, bvec);
  k_consts<<<1, 256, 0, stream>>>(vb_raw, bq, bk, ln_in_w, ln_in_b, aconst, bconst);
  k_ln_rows<<<Bn * NSn, 256, 0, stream>>>(slots, ln_s_w, ln_s_b, sln);

  for (int it = 0; it < 3; ++it) {
    k_qu<<<dim3(64, 8), 256, 0, stream>>>(sln, Ms, vb_s, qkt);
    k_ab<<<Bn * HIn, 64, 0, stream>>>(sln, avec, bvec, aconst, bconst, alpha, beta);
    k_dots<<<dim3(Nn / 128, Bn), 256, 0, stream>>>(in, qkt, alpha, beta, mu, rsig, Abuf, Spart, c1part);
    k_ax<<<dim3(4, 4, Bn), 256, 0, stream>>>(Abuf, inTu, AXp);
    k_updS<<<dim3(HIn, Bn), 256, 0, stream>>>(AXp, Spart, c1part, ln_in_w, ln_in_b, Wv, bv, updb);
    k_gg<<<dim3(24, 8, 2), 256, 0, stream>>>(updb, T1, bcih, slots, Whh, bhh, gibuf, ghbuf);
    k_gruln<<<Bn * NSn, 256, 0, stream>>>(gibuf, ghbuf, slots, sln, ln_ff_w, ln_ff_b);
    k_gemm_sm<false, true, false><<<dim3(32, 8), 256, 0, stream>>>(sln, W1, b1, hbuf, 2048, 512);
    k_w2split<<<dim3(8, 8, 4), 256, 0, stream>>>(hbuf, W2, ffp);
    k_w2red<<<256, 256, 0, stream>>>(ffp, b2, slots);
    k_ln_rows<<<Bn * NSn, 256, 0, stream>>>(slots, ln_s_w, ln_s_b, sln);
  }

  k_keepscale<<<Bn * NSn, 64, 0, stream>>>(Wkeep, g_keep, slots);
  k_slotscalars<<<Bn * NSn, 64, 0, stream>>>(slots, ln_in_w, ln_in_b, swd, sbd);
  k_route_out<<<dim3(Nn / 128, Bn), 256, 0, stream>>>(in, slots, ln_in_w, swd, sbd, mu, rsig, g_route, out);
}

// Round 9
// 1799.536 us; speedup vs baseline: 1.9817x; 1.0233x over previous
//
#include <hip/hip_runtime.h>
#include <hip/hip_bf16.h>
#include <math.h>

constexpr int Bn = 32, Nn = 4096, Dn = 512, NSn = 16, HIn = 128;
constexpr float kScale = 0.04419417382415922f; // 512^-0.5
constexpr float kEps = 1e-8f;

typedef __attribute__((ext_vector_type(8))) short short8;
typedef __attribute__((ext_vector_type(4))) float f32x4;

__device__ __forceinline__ float wred(float v) {
#pragma unroll
  for (int m = 32; m > 0; m >>= 1) v += __shfl_xor(v, m);
  return v;
}
__device__ __forceinline__ double wredd(double v) {
#pragma unroll
  for (int m = 32; m > 0; m >>= 1) v += __shfl_xor(v, m);
  return v;
}

// ---- bf16 split helpers (RNE) ----
__device__ __forceinline__ unsigned short f2bf(float x) {
  unsigned u = __float_as_uint(x);
  unsigned r = (u + 0x7fffu + ((u >> 16) & 1u)) >> 16;
  return (unsigned short)r;
}
__device__ __forceinline__ float bf2f(unsigned short h) {
  return __uint_as_float(((unsigned)h) << 16);
}
__device__ __forceinline__ unsigned packhm(float x) {
  unsigned short h = f2bf(x);
  unsigned short m = f2bf(x - bf2f(h));
  return (unsigned)h | ((unsigned)m << 16);
}
// 2-element 2-level pack: returns h-word, m-word via ref
__device__ __forceinline__ unsigned pack2x(float x0, float x1, unsigned& mo) {
  unsigned p0 = packhm(x0), p1 = packhm(x1);
  mo = (p0 >> 16) | (p1 & 0xffff0000u);
  return (p0 & 0xffffu) | (p1 << 16);
}

// ---------------- per-row LN stats of inputs ----------------
__global__ __launch_bounds__(256) void k_rowstats(const float* __restrict__ in,
                                                  float* __restrict__ mu, float* __restrict__ rsig) {
  int row = blockIdx.x * 4 + (threadIdx.x >> 6);
  int lane = threadIdx.x & 63;
  const float4* p = reinterpret_cast<const float4*>(in + (size_t)row * Dn) + lane * 2;
  float4 a = p[0], b = p[1];
  float s = a.x + a.y + a.z + a.w + b.x + b.y + b.z + b.w;
  float q = a.x*a.x + a.y*a.y + a.z*a.z + a.w*a.w + b.x*b.x + b.y*b.y + b.z*b.z + b.w*b.w;
  s = wred(s); q = wred(q);
  if (lane == 0) {
    float m = s * (1.0f / 512.0f);
    float var = q * (1.0f / 512.0f) - m * m;
    mu[row] = m;
    rsig[row] = 1.0f / sqrtf(var + 1e-5f);
  }
}

// ---------------- transpose + hi/mid split: in[B,N,D] -> inT[B,D,N] (u32 = h|m<<16) ----------------
__global__ __launch_bounds__(256) void k_tsplit(const float* __restrict__ in, unsigned* __restrict__ inT) {
  __shared__ float tile[64][65];
  int b = blockIdx.z, j0 = blockIdx.x * 64, d0 = blockIdx.y * 64;
  int t = threadIdx.x;
#pragma unroll
  for (int e = 0; e < 16; ++e) {
    int idx = t + e * 256;
    int r = idx >> 6, c = idx & 63;
    tile[r][c] = in[((size_t)b * Nn + j0 + r) * Dn + d0 + c];
  }
  __syncthreads();
#pragma unroll
  for (int e = 0; e < 16; ++e) {
    int idx = t + e * 256;
    int r = idx >> 6, c = idx & 63;
    inT[((size_t)b * Dn + d0 + r) * Nn + j0 + c] = packhm(tile[c][r]);
  }
}

// ---------------- slots init ----------------
__global__ __launch_bounds__(256) void k_slots_init(const float* __restrict__ smu, const float* __restrict__ sls,
                                                    const float* __restrict__ noise, float* __restrict__ slots) {
  int r = blockIdx.x;
  for (int d = threadIdx.x; d < Dn; d += 256)
    slots[(size_t)r * Dn + d] = smu[d] + expf(sls[d]) * noise[(size_t)r * Dn + d];
}

// ---------------- LN of [R,512] rows (prologue) ----------------
__global__ __launch_bounds__(256) void k_ln_rows(const float* __restrict__ src, const float* __restrict__ w,
                                                 const float* __restrict__ b, float* __restrict__ dst) {
  int r = blockIdx.x;
  __shared__ float red[8];
  int t = threadIdx.x;
  float x0 = src[(size_t)r * Dn + t], x1 = src[(size_t)r * Dn + 256 + t];
  float s = x0 + x1, q = x0 * x0 + x1 * x1;
  s = wred(s); q = wred(q);
  if ((t & 63) == 0) { red[t >> 6] = s; red[4 + (t >> 6)] = q; }
  __syncthreads();
  float S = red[0] + red[1] + red[2] + red[3];
  float Q = red[4] + red[5] + red[6] + red[7];
  float m = S * (1.0f / 512.0f);
  float rs = 1.0f / sqrtf(Q * (1.0f / 512.0f) - m * m + 1e-5f);
  dst[(size_t)r * Dn + t] = (x0 - m) * rs * w[t] + b[t];
  dst[(size_t)r * Dn + 256 + t] = (x1 - m) * rs * w[256 + t] + b[256 + t];
}

// ---------------- small GEMM with register prefetch: out = act(A@W (+bias) (+out)) ----------------
template <bool TRANS, bool RELU, bool ADD>
__global__ __launch_bounds__(256) void k_gemm_sm(const float* __restrict__ A, const float* __restrict__ W,
                                                 const float* __restrict__ bias, float* __restrict__ out,
                                                 int Nc, int K) {
  __shared__ float as_[64][17];
  __shared__ float ws_[16][65];
  int m0 = blockIdx.y * 64, n0 = blockIdx.x * 64;
  int t = threadIdx.x, tx = t & 15, ty = t >> 4;
  float acc[4][4] = {};
  float pa[4], pw[4];
  auto loadA = [&](int k0) {
#pragma unroll
    for (int e = 0; e < 4; ++e) {
      int idx = t + e * 256;
      int r = idx >> 4, c = idx & 15;
      pa[e] = A[(size_t)(m0 + r) * K + k0 + c];
    }
  };
  auto loadW = [&](int k0) {
#pragma unroll
    for (int e = 0; e < 4; ++e) {
      int idx = t + e * 256;
      if (!TRANS) {
        int r = idx >> 6, c = idx & 63;
        pw[e] = W[(size_t)(k0 + r) * Nc + n0 + c];
      } else {
        int r = idx >> 4, c = idx & 15;
        pw[e] = W[(size_t)(n0 + r) * K + k0 + c];
      }
    }
  };
  loadA(0); loadW(0);
  for (int k0 = 0; k0 < K; k0 += 16) {
#pragma unroll
    for (int e = 0; e < 4; ++e) {
      int idx = t + e * 256;
      int r = idx >> 4, c = idx & 15;
      as_[r][c] = pa[e];
    }
#pragma unroll
    for (int e = 0; e < 4; ++e) {
      int idx = t + e * 256;
      if (!TRANS) {
        int r = idx >> 6, c = idx & 63;
        ws_[r][c] = pw[e];
      } else {
        int r = idx >> 4, c = idx & 15;
        ws_[c][r] = pw[e];
      }
    }
    __syncthreads();
    if (k0 + 16 < K) { loadA(k0 + 16); loadW(k0 + 16); }
#pragma unroll
    for (int kc = 0; kc < 16; ++kc) {
      float av[4], wv[4];
#pragma unroll
      for (int i = 0; i < 4; ++i) av[i] = as_[ty * 4 + i][kc];
#pragma unroll
      for (int j = 0; j < 4; ++j) wv[j] = ws_[kc][tx * 4 + j];
#pragma unroll
      for (int i = 0; i < 4; ++i)
#pragma unroll
        for (int j = 0; j < 4; ++j) acc[i][j] += av[i] * wv[j];
    }
    __syncthreads();
  }
#pragma unroll
  for (int i = 0; i < 4; ++i)
#pragma unroll
    for (int j = 0; j < 4; ++j) {
      int m = m0 + ty * 4 + i, n = n0 + tx * 4 + j;
      float v = acc[i][j] + (bias ? bias[n] : 0.0f);
      if (RELU) v = fmaxf(v, 0.0f);
      if (ADD) v += out[(size_t)m * Nc + n];
      out[(size_t)m * Nc + n] = v;
    }
}

// ---------------- W2 K-split partial GEMM ----------------
__global__ __launch_bounds__(256) void k_w2split(const float* __restrict__ A, const float* __restrict__ W,
                                                 float* __restrict__ part) {
  __shared__ float as_[64][17];
  __shared__ float ws_[16][65];
  int m0 = blockIdx.y * 64, n0 = blockIdx.x * 64, kb = blockIdx.z * 512;
  int t = threadIdx.x, tx = t & 15, ty = t >> 4;
  float acc[4][4] = {};
  float pa[4], pw[4];
  auto loadA = [&](int k0) {
#pragma unroll
    for (int e = 0; e < 4; ++e) {
      int idx = t + e * 256;
      int r = idx >> 4, c = idx & 15;
      pa[e] = A[(size_t)(m0 + r) * 2048 + kb + k0 + c];
    }
  };
  auto loadW = [&](int k0) {
#pragma unroll
    for (int e = 0; e < 4; ++e) {
      int idx = t + e * 256;
      int r = idx >> 6, c = idx & 63;
      pw[e] = W[(size_t)(kb + k0 + r) * 512 + n0 + c];
    }
  };
  loadA(0); loadW(0);
  for (int k0 = 0; k0 < 512; k0 += 16) {
#pragma unroll
    for (int e = 0; e < 4; ++e) {
      int idx = t + e * 256;
      int r = idx >> 4, c = idx & 15;
      as_[r][c] = pa[e];
    }
#pragma unroll
    for (int e = 0; e < 4; ++e) {
      int idx = t + e * 256;
      int r = idx >> 6, c = idx & 63;
      ws_[r][c] = pw[e];
    }
    __syncthreads();
    if (k0 + 16 < 512) { loadA(k0 + 16); loadW(k0 + 16); }
#pragma unroll
    for (int kc = 0; kc < 16; ++kc) {
      float av[4], wv[4];
#pragma unroll
      for (int i = 0; i < 4; ++i) av[i] = as_[ty * 4 + i][kc];
#pragma unroll
      for (int j = 0; j < 4; ++j) wv[j] = ws_[kc][tx * 4 + j];
#pragma unroll
      for (int i = 0; i < 4; ++i)
#pragma unroll
        for (int j = 0; j < 4; ++j) acc[i][j] += av[i] * wv[j];
    }
    __syncthreads();
  }
#pragma unroll
  for (int i = 0; i < 4; ++i)
#pragma unroll
    for (int j = 0; j < 4; ++j) {
      int m = m0 + ty * 4 + i, n = n0 + tx * 4 + j;
      part[((size_t)blockIdx.z * 512 + m) * 512 + n] = acc[i][j];
    }
}

// ---------------- W2 reduce + bias + residual + LN_s fused -> slots, sln ----------------
__global__ __launch_bounds__(256) void k_w2ln(const float* __restrict__ part, const float* __restrict__ b2,
                                              float* __restrict__ slots, float* __restrict__ sln,
                                              const float* __restrict__ lnsw, const float* __restrict__ lnsb) {
  int r = blockIdx.x, t = threadIdx.x;
  __shared__ float red[8];
  float sn[2];
#pragma unroll
  for (int j = 0; j < 2; ++j) {
    int c = j * 256 + t;
    size_t idx = (size_t)r * 512 + c;
    sn[j] = part[idx] + part[262144 + idx] + part[2 * 262144 + idx] + part[3 * 262144 + idx]
          + b2[c] + slots[idx];
  }
  float s = sn[0] + sn[1], q = sn[0] * sn[0] + sn[1] * sn[1];
  s = wred(s); q = wred(q);
  if ((t & 63) == 0) { red[t >> 6] = s; red[4 + (t >> 6)] = q; }
  __syncthreads();
  float S = red[0] + red[1] + red[2] + red[3];
  float Q = red[4] + red[5] + red[6] + red[7];
  float m = S * (1.0f / 512.0f);
  float rs = 1.0f / sqrtf(Q * (1.0f / 512.0f) - m * m + 1e-5f);
#pragma unroll
  for (int j = 0; j < 2; ++j) {
    int c = j * 256 + t;
    size_t idx = (size_t)r * 512 + c;
    slots[idx] = sn[j];
    sln[idx] = (sn[j] - m) * rs * lnsw[c] + lnsb[c];
  }
}

// ---------------- M_h = Wq_h @ Wk_h^T per head (raw) -> Ms[k*4096 + h*512 + d] ----------------
__global__ __launch_bounds__(256) void k_mh(const float* __restrict__ Wq, const float* __restrict__ Wk,
                                            float* __restrict__ Ms) {
  int h = blockIdx.z, k0 = blockIdx.y * 64, d0 = blockIdx.x * 64;
  __shared__ float qa[64][65];
  __shared__ float ka[64][65];
  int t = threadIdx.x, tx = t & 15, ty = t >> 4;
#pragma unroll
  for (int e = 0; e < 16; ++e) {
    int idx = t + e * 256;
    int r = idx >> 6, c = idx & 63;
    qa[c][r] = Wq[(size_t)(k0 + r) * Dn + h * 64 + c];
    ka[c][r] = Wk[(size_t)(d0 + r) * Dn + h * 64 + c];
  }
  __syncthreads();
  float acc[4][4] = {};
#pragma unroll 4
  for (int c = 0; c < 64; ++c) {
    float av[4], bv[4];
#pragma unroll
    for (int i = 0; i < 4; ++i) av[i] = qa[c][ty * 4 + i];
#pragma unroll
    for (int j = 0; j < 4; ++j) bv[j] = ka[c][tx * 4 + j];
#pragma unroll
    for (int i = 0; i < 4; ++i)
#pragma unroll
      for (int j = 0; j < 4; ++j) acc[i][j] += av[i] * bv[j];
  }
#pragma unroll
  for (int i = 0; i < 4; ++i)
#pragma unroll
    for (int j = 0; j < 4; ++j)
      Ms[(size_t)(k0 + ty * 4 + i) * 4096 + h * 512 + d0 + tx * 4 + j] = acc[i][j];
}

// ---------------- vbias_h[d] = Wk[d, h64:]·bq[h64:]; raw + scaled ----------------
__global__ __launch_bounds__(256) void k_vbias(const float* __restrict__ Wk, const float* __restrict__ bq,
                                               const float* __restrict__ lnw, float* __restrict__ vb_raw,
                                               float* __restrict__ vb_s) {
  __shared__ float bqs[512];
  int t = threadIdx.x;
  bqs[t] = bq[t]; bqs[256 + t] = bq[256 + t];
  __syncthreads();
  int d = blockIdx.x * 256 + t;
  float vb[8] = {};
  const float4* wr = reinterpret_cast<const float4*>(Wk + (size_t)d * Dn);
#pragma unroll 8
  for (int c4 = 0; c4 < 128; ++c4) {
    float4 wv = wr[c4];
    int h = c4 >> 4;
    int c = c4 * 4;
    vb[h] += wv.x * bqs[c] + wv.y * bqs[c + 1] + wv.z * bqs[c + 2] + wv.w * bqs[c + 3];
  }
  float lw = lnw[d];
#pragma unroll
  for (int h = 0; h < 8; ++h) {
    vb_raw[h * 512 + d] = vb[h];
    vb_s[h * 512 + d] = kScale * lw * vb[h];
  }
}

// ---------------- fold: scale Ms in place by kScale*lnw[d]; avec/bvec ----------------
__global__ __launch_bounds__(256) void k_mfold(float* __restrict__ Ms, const float* __restrict__ Wq,
                                               const float* __restrict__ bk, const float* __restrict__ lnw,
                                               const float* __restrict__ lnb, float* __restrict__ avec,
                                               float* __restrict__ bvec) {
  __shared__ float lws[512], lbs[512], bks[512];
  int t = threadIdx.x;
  lws[t] = lnw[t]; lws[256 + t] = lnw[256 + t];
  lbs[t] = lnb[t]; lbs[256 + t] = lnb[256 + t];
  bks[t] = bk[t]; bks[256 + t] = bk[256 + t];
  __syncthreads();
  int g = blockIdx.x * 256 + t;
  int k = g >> 3, h = g & 7;
  float* mr = Ms + (size_t)k * 4096 + h * 512;
  float mlnb = 0.0f, mlnw = 0.0f;
  for (int d = 0; d < 512; d += 4) {
    float4 m4 = *reinterpret_cast<const float4*>(mr + d);
    mlnb += m4.x * lbs[d] + m4.y * lbs[d + 1] + m4.z * lbs[d + 2] + m4.w * lbs[d + 3];
    mlnw += m4.x * lws[d] + m4.y * lws[d + 1] + m4.z * lws[d + 2] + m4.w * lws[d + 3];
    float4 o4 = {m4.x * kScale * lws[d], m4.y * kScale * lws[d + 1],
                 m4.z * kScale * lws[d + 2], m4.w * kScale * lws[d + 3]};
    *reinterpret_cast<float4*>(mr + d) = o4;
  }
  float wqdot = 0.0f;
  const float* qr = Wq + (size_t)k * Dn + h * 64;
  for (int c = 0; c < 64; c += 4) {
    float4 q4 = *reinterpret_cast<const float4*>(qr + c);
    wqdot += q4.x * bks[h * 64 + c] + q4.y * bks[h * 64 + c + 1] +
             q4.z * bks[h * 64 + c + 2] + q4.w * bks[h * 64 + c + 3];
  }
  avec[h * 512 + k] = kScale * (mlnb + wqdot);
  bvec[h * 512 + k] = kScale * mlnw;
}

// ---------------- aconst/bconst scalars ----------------
__global__ __launch_bounds__(256) void k_consts(const float* __restrict__ vb_raw, const float* __restrict__ bq,
                                                const float* __restrict__ bk, const float* __restrict__ lnw,
                                                const float* __restrict__ lnb, float* __restrict__ aconst,
                                                float* __restrict__ bconst) {
  __shared__ float r1[256], r2[256], r3[256];
  int t = threadIdx.x;
  for (int h = 0; h < 8; ++h) {
    float p1 = 0.0f, p2 = 0.0f, p3 = 0.0f;
    for (int d = t; d < 512; d += 256) {
      float vr = vb_raw[h * 512 + d];
      p1 += lnb[d] * vr;
      p2 += lnw[d] * vr;
    }
    if (t < 64) p3 = bq[h * 64 + t] * bk[h * 64 + t];
    r1[t] = p1; r2[t] = p2; r3[t] = p3;
    __syncthreads();
    for (int s = 128; s > 0; s >>= 1) {
      if (t < s) { r1[t] += r1[t + s]; r2[t] += r2[t + s]; r3[t] += r3[t + s]; }
      __syncthreads();
    }
    if (t == 0) {
      aconst[h] = kScale * (r1[0] + r3[0]);
      bconst[h] = kScale * r2[0];
    }
    __syncthreads();
  }
}

// ---------------- bcih[n] = bc·Wih[n,:] + bih[n] ----------------
__global__ __launch_bounds__(256) void k_bcih(const float* __restrict__ bc, const float* __restrict__ Wih,
                                              const float* __restrict__ bih, float* __restrict__ bcih) {
  __shared__ float bcs[512];
  int t = threadIdx.x;
  bcs[t] = bc[t]; bcs[256 + t] = bc[256 + t];
  __syncthreads();
  int n = blockIdx.x * 256 + t;
  const float4* wr = reinterpret_cast<const float4*>(Wih + (size_t)n * Dn);
  float a = 0.0f;
#pragma unroll 8
  for (int c4 = 0; c4 < 128; ++c4) {
    float4 wv = wr[c4];
    int c = c4 * 4;
    a += wv.x * bcs[c] + wv.y * bcs[c + 1] + wv.z * bcs[c + 2] + wv.w * bcs[c + 3];
  }
  bcih[n] = a + bih[n];
}

// ---------------- qkt = sln @ Ms + vb_s, packed hi|mid u32, remapped to [b,hi,d] ----------------
__global__ __launch_bounds__(256) void k_qu(const float* __restrict__ sln, const float* __restrict__ Ms,
                                            const float* __restrict__ vb_s, unsigned* __restrict__ qkt) {
  __shared__ float as_[64][17];
  __shared__ float ws_[16][65];
  int m0 = blockIdx.y * 64, n0 = blockIdx.x * 64;
  int t = threadIdx.x, tx = t & 15, ty = t >> 4;
  float acc[4][4] = {};
  float pa[4], pw[4];
  auto loadA = [&](int k0) {
#pragma unroll
    for (int e = 0; e < 4; ++e) {
      int idx = t + e * 256;
      int r = idx >> 4, c = idx & 15;
      pa[e] = sln[(size_t)(m0 + r) * Dn + k0 + c];
    }
  };
  auto loadW = [&](int k0) {
#pragma unroll
    for (int e = 0; e < 4; ++e) {
      int idx = t + e * 256;
      int r = idx >> 6, c = idx & 63;
      pw[e] = Ms[(size_t)(k0 + r) * 4096 + n0 + c];
    }
  };
  loadA(0); loadW(0);
  for (int k0 = 0; k0 < 512; k0 += 16) {
#pragma unroll
    for (int e = 0; e < 4; ++e) {
      int idx = t + e * 256;
      int r = idx >> 4, c = idx & 15;
      as_[r][c] = pa[e];
    }
#pragma unroll
    for (int e = 0; e < 4; ++e) {
      int idx = t + e * 256;
      int r = idx >> 6, c = idx & 63;
      ws_[r][c] = pw[e];
    }
    __syncthreads();
    if (k0 + 16 < 512) { loadA(k0 + 16); loadW(k0 + 16); }
#pragma unroll
    for (int kc = 0; kc < 16; ++kc) {
      float av[4], wv[4];
#pragma unroll
      for (int i = 0; i < 4; ++i) av[i] = as_[ty * 4 + i][kc];
#pragma unroll
      for (int j = 0; j < 4; ++j) wv[j] = ws_[kc][tx * 4 + j];
#pragma unroll
      for (int i = 0; i < 4; ++i)
#pragma unroll
        for (int j = 0; j < 4; ++j) acc[i][j] += av[i] * wv[j];
    }
    __syncthreads();
  }
#pragma unroll
  for (int i = 0; i < 4; ++i)
#pragma unroll
    for (int j = 0; j < 4; ++j) {
      int m = m0 + ty * 4 + i, n = n0 + tx * 4 + j;
      int bb = m >> 4, isl = m & 15, h = n >> 9, d = n & 511;
      qkt[((size_t)bb * HIn + h * 16 + isl) * Dn + d] = packhm(acc[i][j] + vb_s[n]);
    }
}

// ---------------- alpha/beta = sln·avec_h + aconst_h ----------------
__global__ void k_ab(const float* __restrict__ sln, const float* __restrict__ avec,
                     const float* __restrict__ bvec, const float* __restrict__ aconst,
                     const float* __restrict__ bconst, float* __restrict__ alpha,
                     float* __restrict__ beta) {
  int g = blockIdx.x;           // b*128 + hi
  int hi = g & 127, b = g >> 7;
  int h = hi >> 4, i = hi & 15;
  int lane = threadIdx.x;
  const float4* sp = reinterpret_cast<const float4*>(sln + (size_t)(b * NSn + i) * Dn) + lane * 2;
  const float4* ap = reinterpret_cast<const float4*>(avec + h * 512) + lane * 2;
  const float4* bp = reinterpret_cast<const float4*>(bvec + h * 512) + lane * 2;
  float4 s0 = sp[0], s1 = sp[1], a0 = ap[0], a1 = ap[1], b0 = bp[0], b1 = bp[1];
  float pa = s0.x*a0.x + s0.y*a0.y + s0.z*a0.z + s0.w*a0.w + s1.x*a1.x + s1.y*a1.y + s1.z*a1.z + s1.w*a1.w;
  float pb = s0.x*b0.x + s0.y*b0.y + s0.z*b0.z + s0.w*b0.w + s1.x*b1.x + s1.y*b1.y + s1.z*b1.z + s1.w*b1.w;
  pa = wred(pa); pb = wred(pb);
  if (lane == 0) {
    alpha[g] = pa + aconst[h];
    beta[g] = pb + bconst[h];
  }
}

// ---------------- dots via 2-level bf16-split MFMA (3 passes) + in-register softmax ----------------
__global__ __launch_bounds__(256) void k_dots(const float* __restrict__ in, const unsigned* __restrict__ qkt,
                                              const float* __restrict__ alpha, const float* __restrict__ beta,
                                              const float* __restrict__ mu, const float* __restrict__ rsig,
                                              unsigned* __restrict__ A, float* __restrict__ Spart,
                                              float* __restrict__ c1part) {
  __shared__ __align__(16) unsigned short xs_h[128][40];
  __shared__ __align__(16) unsigned short xs_m[128][40];
  __shared__ __align__(16) unsigned short us_h[128][40];
  __shared__ __align__(16) unsigned short us_m[128][40];   // 40960 B

  int b = blockIdx.y, jt = blockIdx.x, j0 = jt * 128;
  int t = threadIdx.x, w = t >> 6, l = t & 63;
  int lc = l & 15, lg = l >> 4, koff = lg * 8;
  const size_t inbase = ((size_t)b * Nn + j0) * Dn;
  const size_t ubase = (size_t)b * HIn * Dn;

  f32x4 acc[2][8];
#pragma unroll
  for (int i = 0; i < 2; ++i)
#pragma unroll
    for (int j2 = 0; j2 < 8; ++j2) acc[i][j2] = {0.0f, 0.0f, 0.0f, 0.0f};

  float2 nx[8];
  uint2 nu[8];
#pragma unroll
  for (int e = 0; e < 8; ++e) {
    int idx = t + e * 256;
    int j = idx >> 4, kp = (idx & 15) * 2;
    nx[e] = *reinterpret_cast<const float2*>(&in[inbase + (size_t)j * Dn + kp]);
    nu[e] = *reinterpret_cast<const uint2*>(&qkt[ubase + (size_t)j * Dn + kp]);
  }

  for (int k0 = 0; k0 < 512; k0 += 32) {
#pragma unroll
    for (int e = 0; e < 8; ++e) {
      int idx = t + e * 256;
      int j = idx >> 4, kp = (idx & 15) * 2;
      unsigned mm;
      unsigned hm = pack2x(nx[e].x, nx[e].y, mm);
      *reinterpret_cast<unsigned*>(&xs_h[j][kp]) = hm;
      *reinterpret_cast<unsigned*>(&xs_m[j][kp]) = mm;
      unsigned uh = (nu[e].x & 0xffffu) | (nu[e].y << 16);
      unsigned um = (nu[e].x >> 16) | (nu[e].y & 0xffff0000u);
      *reinterpret_cast<unsigned*>(&us_h[j][kp]) = uh;
      *reinterpret_cast<unsigned*>(&us_m[j][kp]) = um;
    }
    if (k0 + 32 < 512) {
#pragma unroll
      for (int e = 0; e < 8; ++e) {
        int idx = t + e * 256;
        int j = idx >> 4, kp = (idx & 15) * 2;
        nx[e] = *reinterpret_cast<const float2*>(&in[inbase + (size_t)j * Dn + k0 + 32 + kp]);
        nu[e] = *reinterpret_cast<const uint2*>(&qkt[ubase + (size_t)j * Dn + k0 + 32 + kp]);
      }
    }
    __syncthreads();
    short8 ah0 = *reinterpret_cast<const short8*>(&xs_h[w * 32 + lc][koff]);
    short8 am0 = *reinterpret_cast<const short8*>(&xs_m[w * 32 + lc][koff]);
    short8 ah1 = *reinterpret_cast<const short8*>(&xs_h[w * 32 + 16 + lc][koff]);
    short8 am1 = *reinterpret_cast<const short8*>(&xs_m[w * 32 + 16 + lc][koff]);
#pragma unroll
    for (int ht = 0; ht < 8; ++ht) {
      short8 bh = *reinterpret_cast<const short8*>(&us_h[ht * 16 + lc][koff]);
      short8 bm = *reinterpret_cast<const short8*>(&us_m[ht * 16 + lc][koff]);
      acc[0][ht] = __builtin_amdgcn_mfma_f32_16x16x32_bf16(ah0, bh, acc[0][ht], 0, 0, 0);
      acc[0][ht] = __builtin_amdgcn_mfma_f32_16x16x32_bf16(ah0, bm, acc[0][ht], 0, 0, 0);
      acc[0][ht] = __builtin_amdgcn_mfma_f32_16x16x32_bf16(am0, bh, acc[0][ht], 0, 0, 0);
      acc[1][ht] = __builtin_amdgcn_mfma_f32_16x16x32_bf16(ah1, bh, acc[1][ht], 0, 0, 0);
      acc[1][ht] = __builtin_amdgcn_mfma_f32_16x16x32_bf16(ah1, bm, acc[1][ht], 0, 0, 0);
      acc[1][ht] = __builtin_amdgcn_mfma_f32_16x16x32_bf16(am1, bh, acc[1][ht], 0, 0, 0);
    }
    __syncthreads();
  }

  float* rsL = reinterpret_cast<float*>(&xs_h[0][0]);
  float* muL = rsL + 128;
  float* aL = rsL + 256;
  float* bL = rsL + 384;
  float (*sredS)[128] = reinterpret_cast<float(*)[128]>(rsL + 512);
  float (*sredC)[128] = reinterpret_cast<float(*)[128]>(rsL + 512 + 4 * 128);
  if (t < 128) {
    rsL[t] = rsig[(size_t)b * Nn + j0 + t];
    muL[t] = mu[(size_t)b * Nn + j0 + t];
    aL[t] = alpha[b * HIn + t];
    bL[t] = beta[b * HIn + t];
  }
  __syncthreads();

  float sS[8] = {}, sC[8] = {};
#pragma unroll
  for (int jt2 = 0; jt2 < 2; ++jt2) {
    int jbase = w * 32 + jt2 * 16 + lg * 4;
#pragma unroll
    for (int ht = 0; ht < 8; ++ht) {
      int hi = ht * 16 + lc;
      float av = aL[hi], bv = bL[hi];
      float v[4], rs4[4], mr4[4];
#pragma unroll
      for (int r = 0; r < 4; ++r) {
        int jr = jbase + r;
        rs4[r] = rsL[jr];
        mr4[r] = muL[jr] * rs4[r];
        v[r] = acc[jt2][ht][r] * rs4[r] + av - mr4[r] * bv;
      }
      float mx[4] = {v[0], v[1], v[2], v[3]};
#pragma unroll
      for (int m = 1; m <= 8; m <<= 1)
#pragma unroll
        for (int r = 0; r < 4; ++r) mx[r] = fmaxf(mx[r], __shfl_xor(mx[r], m));
      float e4[4], ss[4];
#pragma unroll
      for (int r = 0; r < 4; ++r) { e4[r] = expf(v[r] - mx[r]); ss[r] = e4[r]; }
#pragma unroll
      for (int m = 1; m <= 8; m <<= 1)
#pragma unroll
        for (int r = 0; r < 4; ++r) ss[r] += __shfl_xor(ss[r], m);
      float ps = 0.0f, pc = 0.0f;
      float p0 = e4[0] / ss[0] + kEps, p1 = e4[1] / ss[1] + kEps;
      float p2 = e4[2] / ss[2] + kEps, p3 = e4[3] / ss[3] + kEps;
      uint4 o4;
      o4.x = packhm(p0 * rs4[0]); o4.y = packhm(p1 * rs4[1]);
      o4.z = packhm(p2 * rs4[2]); o4.w = packhm(p3 * rs4[3]);
      ps = p0 + p1 + p2 + p3;
      pc = p0 * mr4[0] + p1 * mr4[1] + p2 * mr4[2] + p3 * mr4[3];
      *reinterpret_cast<uint4*>(&A[(size_t)(b * HIn + hi) * Nn + j0 + jbase]) = o4;
      ps += __shfl_xor(ps, 16); ps += __shfl_xor(ps, 32);
      pc += __shfl_xor(pc, 16); pc += __shfl_xor(pc, 32);
      sS[ht] += ps; sC[ht] += pc;
    }
  }
  if (l < 16) {
#pragma unroll
    for (int ht = 0; ht < 8; ++ht) {
      sredS[w][ht * 16 + l] = sS[ht];
      sredC[w][ht * 16 + l] = sC[ht];
    }
  }
  __syncthreads();
  if (t < 128) {
    float s_ = sredS[0][t] + sredS[1][t] + sredS[2][t] + sredS[3][t];
    float c_ = sredC[0][t] + sredC[1][t] + sredC[2][t] + sredC[3][t];
    int sub = (b * 32 + jt) * HIn + t;
    Spart[sub] = s_;
    c1part[sub] = c_;
  }
}

// ---------------- AX = A @ X via 2-level bf16-split MFMA (K-split x4) ----------------
__global__ __launch_bounds__(256) void k_ax(const unsigned* __restrict__ Au, const unsigned* __restrict__ inT,
                                            float* __restrict__ AXp) {
  __shared__ __align__(16) unsigned short as_h[128][40];
  __shared__ __align__(16) unsigned short as_m[128][40];
  __shared__ __align__(16) unsigned short xs_h[128][40];
  __shared__ __align__(16) unsigned short xs_m[128][40];

  int d0 = blockIdx.x * 128, kp = blockIdx.y, b = blockIdx.z;
  int t = threadIdx.x, w = t >> 6, l = t & 63;
  int lc = l & 15, lg = l >> 4, koff = lg * 8;
  const size_t abase = (size_t)b * HIn * Nn + kp * 1024;
  const size_t xbase = ((size_t)b * Dn + d0) * Nn + kp * 1024;

  f32x4 acc[2][8];
#pragma unroll
  for (int i = 0; i < 2; ++i)
#pragma unroll
    for (int j2 = 0; j2 < 8; ++j2) acc[i][j2] = {0.0f, 0.0f, 0.0f, 0.0f};

  uint2 pa[8];
  uint4 px[4];
#pragma unroll
  for (int e = 0; e < 8; ++e) {
    int idx = t + e * 256;
    int hi = idx >> 4, jp = (idx & 15) * 2;
    pa[e] = *reinterpret_cast<const uint2*>(&Au[abase + (size_t)hi * Nn + jp]);
  }
#pragma unroll
  for (int e = 0; e < 4; ++e) {
    int idx = t + e * 256;
    int d = idx >> 3, jg = idx & 7;
    px[e] = *reinterpret_cast<const uint4*>(&inT[xbase + (size_t)d * Nn + jg * 4]);
  }

  for (int c0 = 0; c0 < 1024; c0 += 32) {
#pragma unroll
    for (int e = 0; e < 8; ++e) {
      int idx = t + e * 256;
      int hi = idx >> 4, jp = (idx & 15) * 2;
      unsigned h = (pa[e].x & 0xffffu) | (pa[e].y << 16);
      unsigned m = (pa[e].x >> 16) | (pa[e].y & 0xffff0000u);
      *reinterpret_cast<unsigned*>(&as_h[hi][jp]) = h;
      *reinterpret_cast<unsigned*>(&as_m[hi][jp]) = m;
    }
#pragma unroll
    for (int e = 0; e < 4; ++e) {
      int idx = t + e * 256;
      int d = idx >> 3, jg = idx & 7;
      unsigned h0 = (px[e].x & 0xffffu) | (px[e].y << 16);
      unsigned h1 = (px[e].z & 0xffffu) | (px[e].w << 16);
      unsigned m0 = (px[e].x >> 16) | (px[e].y & 0xffff0000u);
      unsigned m1 = (px[e].z >> 16) | (px[e].w & 0xffff0000u);
      uint2 hv = {h0, h1}, mv = {m0, m1};
      *reinterpret_cast<uint2*>(&xs_h[d][jg * 4]) = hv;
      *reinterpret_cast<uint2*>(&xs_m[d][jg * 4]) = mv;
    }
    if (c0 + 32 < 1024) {
#pragma unroll
      for (int e = 0; e < 8; ++e) {
        int idx = t + e * 256;
        int hi = idx >> 4, jp = (idx & 15) * 2;
        pa[e] = *reinterpret_cast<const uint2*>(&Au[abase + (size_t)hi * Nn + c0 + 32 + jp]);
      }
#pragma unroll
      for (int e = 0; e < 4; ++e) {
        int idx = t + e * 256;
        int d = idx >> 3, jg = idx & 7;
        px[e] = *reinterpret_cast<const uint4*>(&inT[xbase + (size_t)d * Nn + c0 + 32 + jg * 4]);
      }
    }
    __syncthreads();
    short8 ah0 = *reinterpret_cast<const short8*>(&as_h[w * 32 + lc][koff]);
    short8 am0 = *reinterpret_cast<const short8*>(&as_m[w * 32 + lc][koff]);
    short8 ah1 = *reinterpret_cast<const short8*>(&as_h[w * 32 + 16 + lc][koff]);
    short8 am1 = *reinterpret_cast<const short8*>(&as_m[w * 32 + 16 + lc][koff]);
#pragma unroll
    for (int dt = 0; dt < 8; ++dt) {
      short8 bh = *reinterpret_cast<const short8*>(&xs_h[dt * 16 + lc][koff]);
      short8 bm = *reinterpret_cast<const short8*>(&xs_m[dt * 16 + lc][koff]);
      acc[0][dt] = __builtin_amdgcn_mfma_f32_16x16x32_bf16(ah0, bh, acc[0][dt], 0, 0, 0);
      acc[0][dt] = __builtin_amdgcn_mfma_f32_16x16x32_bf16(ah0, bm, acc[0][dt], 0, 0, 0);
      acc[0][dt] = __builtin_amdgcn_mfma_f32_16x16x32_bf16(am0, bh, acc[0][dt], 0, 0, 0);
      acc[1][dt] = __builtin_amdgcn_mfma_f32_16x16x32_bf16(ah1, bh, acc[1][dt], 0, 0, 0);
      acc[1][dt] = __builtin_amdgcn_mfma_f32_16x16x32_bf16(ah1, bm, acc[1][dt], 0, 0, 0);
      acc[1][dt] = __builtin_amdgcn_mfma_f32_16x16x32_bf16(am1, bh, acc[1][dt], 0, 0, 0);
    }
    __syncthreads();
  }

  const size_t obase = (((size_t)kp * Bn + b) * HIn) * Dn + d0;
#pragma unroll
  for (int jt2 = 0; jt2 < 2; ++jt2) {
#pragma unroll
    for (int dt = 0; dt < 8; ++dt) {
#pragma unroll
      for (int r = 0; r < 4; ++r) {
        int hi = w * 32 + jt2 * 16 + lg * 4 + r;
        int d = dt * 16 + lc;
        AXp[obase + (size_t)hi * Dn + d] = acc[jt2][dt][r];
      }
    }
  }
}

// ---------------- upd = ((w*(G-c1)/S + b) @ Wv_h) + bv, S/c1 reduced inline ----------------
__global__ __launch_bounds__(256) void k_updS(const float* __restrict__ AXp, const float* __restrict__ Spart,
                                              const float* __restrict__ c1part, const float* __restrict__ lnw,
                                              const float* __restrict__ lnb, const float* __restrict__ Wv,
                                              const float* __restrict__ bv, float* __restrict__ upd) {
  int b = blockIdx.y, hi = blockIdx.x, h = hi >> 4, i = hi & 15;
  __shared__ float vx[512];
  __shared__ float red[256];
  __shared__ float sSC[2];
  int t = threadIdx.x;
  if (t < 64) {
    float vs = 0.0f, vc = 0.0f;
    if (t < 32) {
      vs = Spart[(size_t)(b * 32 + t) * HIn + hi];
      vc = c1part[(size_t)(b * 32 + t) * HIn + hi];
    }
    vs = wred(vs); vc = wred(vc);
    if (t == 0) { sSC[0] = vs; sSC[1] = vc; }
  }
  __syncthreads();
  float c1v = sSC[1];
  float invS = 1.0f / sSC[0];
  for (int d = t; d < Dn; d += 256) {
    float G = AXp[((size_t)(0 * Bn + b) * HIn + hi) * Dn + d]
            + AXp[((size_t)(1 * Bn + b) * HIn + hi) * Dn + d]
            + AXp[((size_t)(2 * Bn + b) * HIn + hi) * Dn + d]
            + AXp[((size_t)(3 * Bn + b) * HIn + hi) * Dn + d];
    vx[d] = lnw[d] * (G - c1v) * invS + lnb[d];
  }
  __syncthreads();
  int cc = t & 63, qd = t >> 6;
  float p = 0.0f;
  for (int d = qd * 128; d < qd * 128 + 128; ++d) p += vx[d] * Wv[(size_t)d * Dn + h * 64 + cc];
  red[t] = p;
  __syncthreads();
  if (qd == 0) {
    float v = red[cc] + red[64 + cc] + red[128 + cc] + red[192 + cc] + bv[h * 64 + cc];
    upd[(size_t)(b * NSn + i) * Dn + h * 64 + cc] = v;
  }
}

// ---------------- dual GEMM (prefetched): z=0: gi = upd@T1 + bcih ; z=1: gh = slots@Whh^T + bhh ----------------
__global__ __launch_bounds__(256) void k_gg(const float* __restrict__ upd, const float* __restrict__ T1,
                                            const float* __restrict__ bcih, const float* __restrict__ slots,
                                            const float* __restrict__ Whh, const float* __restrict__ bhh,
                                            float* __restrict__ gi, float* __restrict__ gh) {
  bool z = (blockIdx.z == 1);
  const float* A = z ? slots : upd;
  const float* W = z ? Whh : T1;
  const float* bias = z ? bhh : bcih;
  float* out = z ? gh : gi;
  __shared__ float as_[64][17];
  __shared__ float ws_[16][65];
  int m0 = blockIdx.y * 64, n0 = blockIdx.x * 64;
  int t = threadIdx.x, tx = t & 15, ty = t >> 4;
  float acc[4][4] = {};
  float pa[4], pw[4];
  auto loadA = [&](int k0) {
#pragma unroll
    for (int e = 0; e < 4; ++e) {
      int idx = t + e * 256;
      int r = idx >> 4, c = idx & 15;
      pa[e] = A[(size_t)(m0 + r) * 512 + k0 + c];
    }
  };
  auto loadW = [&](int k0) {
#pragma unroll
    for (int e = 0; e < 4; ++e) {
      int idx = t + e * 256;
      if (!z) {
        int r = idx >> 6, c = idx & 63;
        pw[e] = W[(size_t)(k0 + r) * 1536 + n0 + c];
      } else {
        int r = idx >> 4, c = idx & 15;
        pw[e] = W[(size_t)(n0 + r) * 512 + k0 + c];
      }
    }
  };
  loadA(0); loadW(0);
  for (int k0 = 0; k0 < 512; k0 += 16) {
#pragma unroll
    for (int e = 0; e < 4; ++e) {
      int idx = t + e * 256;
      int r = idx >> 4, c = idx & 15;
      as_[r][c] = pa[e];
    }
#pragma unroll
    for (int e = 0; e < 4; ++e) {
      int idx = t + e * 256;
      if (!z) {
        int r = idx >> 6, c = idx & 63;
        ws_[r][c] = pw[e];
      } else {
        int r = idx >> 4, c = idx & 15;
        ws_[c][r] = pw[e];
      }
    }
    __syncthreads();
    if (k0 + 16 < 512) { loadA(k0 + 16); loadW(k0 + 16); }
#pragma unroll
    for (int kc = 0; kc < 16; ++kc) {
      float av[4], wv[4];
#pragma unroll
      for (int i = 0; i < 4; ++i) av[i] = as_[ty * 4 + i][kc];
#pragma unroll
      for (int j = 0; j < 4; ++j) wv[j] = ws_[kc][tx * 4 + j];
#pragma unroll
      for (int i = 0; i < 4; ++i)
#pragma unroll
        for (int j = 0; j < 4; ++j) acc[i][j] += av[i] * wv[j];
    }
    __syncthreads();
  }
#pragma unroll
  for (int i = 0; i < 4; ++i)
#pragma unroll
    for (int j = 0; j < 4; ++j) {
      int m = m0 + ty * 4 + i, n = n0 + tx * 4 + j;
      out[(size_t)m * 1536 + n] = acc[i][j] + bias[n];
    }
}

// ---------------- GRU pointwise + LN_ff fused ----------------
__global__ __launch_bounds__(256) void k_gruln(const float* __restrict__ gi, const float* __restrict__ gh,
                                               float* __restrict__ slots, float* __restrict__ slnff,
                                               const float* __restrict__ lnffw, const float* __restrict__ lnffb) {
  int r = blockIdx.x, t = threadIdx.x;
  __shared__ float red[8];
  float sn[2];
#pragma unroll
  for (int j = 0; j < 2; ++j) {
    int c = j * 256 + t;
    float gir = gi[(size_t)r * 1536 + c];
    float giz = gi[(size_t)r * 1536 + 512 + c];
    float gin = gi[(size_t)r * 1536 + 1024 + c];
    float ghr = gh[(size_t)r * 1536 + c];
    float ghz = gh[(size_t)r * 1536 + 512 + c];
    float ghn = gh[(size_t)r * 1536 + 1024 + c];
    float rg = 1.0f / (1.0f + expf(-(gir + ghr)));
    float zg = 1.0f / (1.0f + expf(-(giz + ghz)));
    float ng = tanhf(gin + rg * ghn);
    sn[j] = (1.0f - zg) * ng + zg * slots[(size_t)r * Dn + c];
  }
  float s = sn[0] + sn[1], q = sn[0] * sn[0] + sn[1] * sn[1];
  s = wred(s); q = wred(q);
  if ((t & 63) == 0) { red[t >> 6] = s; red[4 + (t >> 6)] = q; }
  __syncthreads();
  float S = red[0] + red[1] + red[2] + red[3];
  float Q = red[4] + red[5] + red[6] + red[7];
  float m = S * (1.0f / 512.0f);
  float rs = 1.0f / sqrtf(Q * (1.0f / 512.0f) - m * m + 1e-5f);
#pragma unroll
  for (int j = 0; j < 2; ++j) {
    int c = j * 256 + t;
    slots[(size_t)r * Dn + c] = sn[j];
    slnff[(size_t)r * Dn + c] = (sn[j] - m) * rs * lnffw[c] + lnffb[c];
  }
}

// ---------------- keep gate (zero dropped slots in place) ----------------
__global__ void k_keepscale(const float* __restrict__ Wkeep, const float* __restrict__ gk,
                            float* __restrict__ slots) {
  int g = blockIdx.x;
  int lane = threadIdx.x;
  float4* sp = reinterpret_cast<float4*>(slots + (size_t)g * Dn) + lane * 2;
  float4 s0 = sp[0], s1 = sp[1];
  float sv[8] = {s0.x, s0.y, s0.z, s0.w, s1.x, s1.y, s1.z, s1.w};
  double d0 = 0.0, d1 = 0.0;
#pragma unroll
  for (int e = 0; e < 8; ++e) {
    int d = lane * 8 + e;
    d0 += (double)sv[e] * (double)Wkeep[d * 2];
    d1 += (double)sv[e] * (double)Wkeep[d * 2 + 1];
  }
  d0 = wredd(d0);
  d1 = wredd(d1);
  int keepi = 0;
  if (lane == 0) keepi = ((d1 + (double)gk[g * 2 + 1]) > (d0 + (double)gk[g * 2])) ? 1 : 0;
  keepi = __shfl(keepi, 0);
  if (!keepi) {
    float4 z = {0.0f, 0.0f, 0.0f, 0.0f};
    sp[0] = z;
    sp[1] = z;
  }
}

// ---------------- per-slot scalars for route decomposition ----------------
__global__ void k_slotscalars(const float* __restrict__ slots, const float* __restrict__ lnw,
                              const float* __restrict__ lnb, double* __restrict__ swd,
                              double* __restrict__ sbd) {
  int g = blockIdx.x, lane = threadIdx.x;
  const float4* sp = reinterpret_cast<const float4*>(slots + (size_t)g * Dn) + lane * 2;
  const float4* wp = reinterpret_cast<const float4*>(lnw) + lane * 2;
  const float4* bp = reinterpret_cast<const float4*>(lnb) + lane * 2;
  float4 s0 = sp[0], s1 = sp[1], w0 = wp[0], w1 = wp[1], b0 = bp[0], b1 = bp[1];
  double pw = (double)s0.x * w0.x + (double)s0.y * w0.y + (double)s0.z * w0.z + (double)s0.w * w0.w +
              (double)s1.x * w1.x + (double)s1.y * w1.y + (double)s1.z * w1.z + (double)s1.w * w1.w;
  double pb = (double)s0.x * b0.x + (double)s0.y * b0.y + (double)s0.z * b0.z + (double)s0.w * b0.w +
              (double)s1.x * b1.x + (double)s1.y * b1.y + (double)s1.z * b1.z + (double)s1.w * b1.w;
  pw = wredd(pw);
  pb = wredd(pb);
  if (lane == 0) { swd[g] = pw; sbd[g] = pb; }
}

// ---------------- hard route + gather output (tiled mini-GEMM, prefetched) ----------------
__global__ __launch_bounds__(256) void k_route_out(const float* __restrict__ in, const float* __restrict__ slots,
                                                   const float* __restrict__ lnw, const double* __restrict__ swd,
                                                   const double* __restrict__ sbd, const float* __restrict__ mu,
                                                   const float* __restrict__ rsig,
                                                   const float* __restrict__ g_route, float* __restrict__ out) {
  int b = blockIdx.y, j0 = blockIdx.x * 128;
  __shared__ __align__(16) float sl[16 * 516];
  __shared__ __align__(16) float lw[512];
  __shared__ __align__(16) float xs[16][132];
  __shared__ double lgd[128][17];
  __shared__ int besti[128];
  int t = threadIdx.x, tx = t & 15, ty = t >> 4;

  for (int idx = t; idx < 2048; idx += 256) {
    int i = idx >> 7, c = idx & 127;
    *reinterpret_cast<float4*>(&sl[i * 516 + c * 4]) =
        *reinterpret_cast<const float4*>(&slots[(size_t)(b * NSn + i) * Dn + c * 4]);
  }
  if (t < 128)
    *reinterpret_cast<float4*>(&lw[t * 4]) = *reinterpret_cast<const float4*>(&lnw[t * 4]);

  float acc[8] = {};
  double accd[8] = {};
  const size_t inbase = ((size_t)b * Nn + j0) * Dn;

  // prefetch chunk 0 (before first barrier)
  float pre[8];
#pragma unroll
  for (int e = 0; e < 8; ++e) {
    int idx = t + e * 256;
    int r = idx >> 4, c = idx & 15;
    pre[e] = in[inbase + (size_t)r * Dn + c];
  }
  __syncthreads();

  for (int k0 = 0; k0 < Dn; k0 += 16) {
#pragma unroll
    for (int e = 0; e < 8; ++e) {
      int idx = t + e * 256;
      int r = idx >> 4, c = idx & 15;
      xs[c][r] = pre[e] * lw[k0 + c];
    }
    __syncthreads();
    // issue next chunk's loads before computing (overlaps HBM latency with FMA)
    float nxt[8] = {};
    if (k0 + 16 < Dn) {
#pragma unroll
      for (int e = 0; e < 8; ++e) {
        int idx = t + e * 256;
        int r = idx >> 4, c = idx & 15;
        nxt[e] = in[inbase + (size_t)r * Dn + k0 + 16 + c];
      }
    }
#pragma unroll
    for (int kc = 0; kc < 16; ++kc) {
      float sv = sl[tx * 516 + k0 + kc];
      float4 x0 = *reinterpret_cast<const float4*>(&xs[kc][ty * 8]);
      float4 x1 = *reinterpret_cast<const float4*>(&xs[kc][ty * 8 + 4]);
      acc[0] += x0.x * sv; acc[1] += x0.y * sv; acc[2] += x0.z * sv; acc[3] += x0.w * sv;
      acc[4] += x1.x * sv; acc[5] += x1.y * sv; acc[6] += x1.z * sv; acc[7] += x1.w * sv;
    }
    if ((k0 & 127) == 112) {
#pragma unroll
      for (int e = 0; e < 8; ++e) { accd[e] += (double)acc[e]; acc[e] = 0.0f; }
    }
#pragma unroll
    for (int e = 0; e < 8; ++e) pre[e] = nxt[e];
    __syncthreads();
  }

  double sw_i = swd[b * NSn + tx], sb_i = sbd[b * NSn + tx];
#pragma unroll
  for (int r = 0; r < 8; ++r) {
    int j = ty * 8 + r;
    double rsj = (double)rsig[(size_t)b * Nn + j0 + j];
    double muj = (double)mu[(size_t)b * Nn + j0 + j];
    double g = (double)g_route[((size_t)b * NSn + tx) * Nn + j0 + j];
    lgd[j][tx] = (double)kScale * (rsj * accd[r] + sb_i - muj * rsj * sw_i) + g;
  }
  __syncthreads();
  if (t < 128) {
    double best = lgd[t][0];
    int bi = 0;
#pragma unroll
    for (int i = 1; i < 16; ++i) {
      double v = lgd[t][i];
      if (v > best) { best = v; bi = i; }
    }
    besti[t] = bi;
  }
  __syncthreads();
  for (int idx = t; idx < 128 * 128; idx += 256) {
    int j = idx >> 7, c = idx & 127;
    *reinterpret_cast<float4*>(&out[inbase + (size_t)j * Dn + c * 4]) =
        *reinterpret_cast<const float4*>(&sl[besti[j] * 516 + c * 4]);
  }
}

extern "C" void kernel_launch(void* const* d_in, const int* in_sizes, int n_in,
                              void* d_out, int out_size, void* d_ws, size_t ws_size,
                              hipStream_t stream) {
  (void)in_sizes; (void)n_in; (void)out_size; (void)ws_size;
  const float* in = (const float*)d_in[0];
  const float* slots_mu = (const float*)d_in[1];
  const float* slots_ls = (const float*)d_in[2];
  const float* ln_in_w = (const float*)d_in[3];
  const float* ln_in_b = (const float*)d_in[4];
  const float* ln_s_w = (const float*)d_in[5];
  const float* ln_s_b = (const float*)d_in[6];
  const float* ln_ff_w = (const float*)d_in[7];
  const float* ln_ff_b = (const float*)d_in[8];
  const float* Wq = (const float*)d_in[9];
  const float* bq = (const float*)d_in[10];
  const float* Wk = (const float*)d_in[11];
  const float* bk = (const float*)d_in[12];
  const float* Wv = (const float*)d_in[13];
  const float* bv = (const float*)d_in[14];
  const float* Wc = (const float*)d_in[15];
  const float* bc = (const float*)d_in[16];
  const float* Wih = (const float*)d_in[17];
  const float* bih = (const float*)d_in[18];
  const float* Whh = (const float*)d_in[19];
  const float* bhh = (const float*)d_in[20];
  const float* W1 = (const float*)d_in[21];
  const float* b1 = (const float*)d_in[22];
  const float* W2 = (const float*)d_in[23];
  const float* b2 = (const float*)d_in[24];
  const float* Wkeep = (const float*)d_in[25];
  const float* noise = (const float*)d_in[26];
  const float* g_keep = (const float*)d_in[27];
  const float* g_route = (const float*)d_in[28];
  float* out = (float*)d_out;
  unsigned* inTu = (unsigned*)d_out;   // scratch during iterations; overwritten by k_route_out

  char* wptr = (char*)d_ws;
  auto alloc = [&](size_t bytes) {
    char* p = wptr;
    wptr += (bytes + 255) & ~(size_t)255;
    return p;
  };
  float* mu = (float*)alloc((size_t)Bn * Nn * 4);
  float* rsig = (float*)alloc((size_t)Bn * Nn * 4);
  float* slots = (float*)alloc((size_t)Bn * NSn * Dn * 4);
  float* sln = (float*)alloc((size_t)Bn * NSn * Dn * 4);
  unsigned* qkt = (unsigned*)alloc((size_t)Bn * HIn * Dn * 4);
  float* alpha = (float*)alloc((size_t)Bn * HIn * 4);
  float* beta = (float*)alloc((size_t)Bn * HIn * 4);
  unsigned* Abuf = (unsigned*)alloc((size_t)Bn * HIn * Nn * 4);
  float* Spart = (float*)alloc((size_t)Bn * 64 * HIn * 4);
  float* c1part = (float*)alloc((size_t)Bn * 64 * HIn * 4);
  float* AXp = (float*)alloc((size_t)4 * Bn * HIn * Dn * 4);
  float* updb = (float*)alloc((size_t)Bn * NSn * Dn * 4);
  float* gibuf = (float*)alloc((size_t)Bn * NSn * 1536 * 4);
  float* ghbuf = (float*)alloc((size_t)Bn * NSn * 1536 * 4);
  float* hbuf = (float*)alloc((size_t)Bn * NSn * 2048 * 4);
  float* ffp = (float*)alloc((size_t)4 * 512 * 512 * 4);
  float* T1 = (float*)alloc((size_t)Dn * 1536 * 4);
  float* bcih = (float*)alloc((size_t)1536 * 4);
  float* Ms = (float*)alloc((size_t)Dn * 4096 * 4);
  float* vb_raw = (float*)alloc((size_t)4096 * 4);
  float* vb_s = (float*)alloc((size_t)4096 * 4);
  float* avec = (float*)alloc((size_t)4096 * 4);
  float* bvec = (float*)alloc((size_t)4096 * 4);
  float* aconst = (float*)alloc((size_t)8 * 4);
  float* bconst = (float*)alloc((size_t)8 * 4);
  double* swd = (double*)alloc((size_t)Bn * NSn * 8);
  double* sbd = (double*)alloc((size_t)Bn * NSn * 8);

  // prologue
  k_rowstats<<<Bn * Nn / 4, 256, 0, stream>>>(in, mu, rsig);
  k_tsplit<<<dim3(Nn / 64, Dn / 64, Bn), 256, 0, stream>>>(in, inTu);
  k_slots_init<<<Bn * NSn, 256, 0, stream>>>(slots_mu, slots_ls, noise, slots);
  k_gemm_sm<true, false, false><<<dim3(24, 8), 256, 0, stream>>>(Wc, Wih, nullptr, T1, 1536, 512);
  k_bcih<<<6, 256, 0, stream>>>(bc, Wih, bih, bcih);
  k_mh<<<dim3(8, 8, 8), 256, 0, stream>>>(Wq, Wk, Ms);
  k_vbias<<<2, 256, 0, stream>>>(Wk, bq, ln_in_w, vb_raw, vb_s);
  k_mfold<<<16, 256, 0, stream>>>(Ms, Wq, bk, ln_in_w, ln_in_b, avec, bvec);
  k_consts<<<1, 256, 0, stream>>>(vb_raw, bq, bk, ln_in_w, ln_in_b, aconst, bconst);
  k_ln_rows<<<Bn * NSn, 256, 0, stream>>>(slots, ln_s_w, ln_s_b, sln);

  for (int it = 0; it < 3; ++it) {
    k_qu<<<dim3(64, 8), 256, 0, stream>>>(sln, Ms, vb_s, qkt);
    k_ab<<<Bn * HIn, 64, 0, stream>>>(sln, avec, bvec, aconst, bconst, alpha, beta);
    k_dots<<<dim3(Nn / 128, Bn), 256, 0, stream>>>(in, qkt, alpha, beta, mu, rsig, Abuf, Spart, c1part);
    k_ax<<<dim3(4, 4, Bn), 256, 0, stream>>>(Abuf, inTu, AXp);
    k_updS<<<dim3(HIn, Bn), 256, 0, stream>>>(AXp, Spart, c1part, ln_in_w, ln_in_b, Wv, bv, updb);
    k_gg<<<dim3(24, 8, 2), 256, 0, stream>>>(updb, T1, bcih, slots, Whh, bhh, gibuf, ghbuf);
    k_gruln<<<Bn * NSn, 256, 0, stream>>>(gibuf, ghbuf, slots, sln, ln_ff_w, ln_ff_b);
    k_gemm_sm<false, true, false><<<dim3(32, 8), 256, 0, stream>>>(sln, W1, b1, hbuf, 2048, 512);
    k_w2split<<<dim3(8, 8, 4), 256, 0, stream>>>(hbuf, W2, ffp);
    k_w2ln<<<Bn * NSn, 256, 0, stream>>>(ffp, b2, slots, sln, ln_s_w, ln_s_b);
  }

  k_keepscale<<<Bn * NSn, 64, 0, stream>>>(Wkeep, g_keep, slots);
  k_slotscalars<<<Bn * NSn, 64, 0, stream>>>(slots, ln_in_w, ln_in_b, swd, sbd);
  k_route_out<<<dim3(Nn / 128, Bn), 256, 0, stream>>>(in, slots, ln_in_w, swd, sbd, mu, rsig, g_route, out);
}

// Round 10
// 1733.456 us; speedup vs baseline: 2.0572x; 1.0381x over previous
//
#include <hip/hip_runtime.h>
#include <hip/hip_bf16.h>
#include <math.h>

constexpr int Bn = 32, Nn = 4096, Dn = 512, NSn = 16, HIn = 128;
constexpr float kScale = 0.04419417382415922f; // 512^-0.5
constexpr float kEps = 1e-8f;

typedef __attribute__((ext_vector_type(8))) short short8;
typedef __attribute__((ext_vector_type(4))) float f32x4;

__device__ __forceinline__ float wred(float v) {
#pragma unroll
  for (int m = 32; m > 0; m >>= 1) v += __shfl_xor(v, m);
  return v;
}
__device__ __forceinline__ double wredd(double v) {
#pragma unroll
  for (int m = 32; m > 0; m >>= 1) v += __shfl_xor(v, m);
  return v;
}

// ---- bf16 split helpers (RNE) ----
__device__ __forceinline__ unsigned short f2bf(float x) {
  unsigned u = __float_as_uint(x);
  unsigned r = (u + 0x7fffu + ((u >> 16) & 1u)) >> 16;
  return (unsigned short)r;
}
__device__ __forceinline__ float bf2f(unsigned short h) {
  return __uint_as_float(((unsigned)h) << 16);
}
__device__ __forceinline__ unsigned packhm(float x) {
  unsigned short h = f2bf(x);
  unsigned short m = f2bf(x - bf2f(h));
  return (unsigned)h | ((unsigned)m << 16);
}
// 2-element 2-level pack: returns h-word, m-word via ref
__device__ __forceinline__ unsigned pack2x(float x0, float x1, unsigned& mo) {
  unsigned p0 = packhm(x0), p1 = packhm(x1);
  mo = (p0 >> 16) | (p1 & 0xffff0000u);
  return (p0 & 0xffffu) | (p1 << 16);
}

// ---------------- per-row LN stats of inputs ----------------
__global__ __launch_bounds__(256) void k_rowstats(const float* __restrict__ in,
                                                  float* __restrict__ mu, float* __restrict__ rsig) {
  int row = blockIdx.x * 4 + (threadIdx.x >> 6);
  int lane = threadIdx.x & 63;
  const float4* p = reinterpret_cast<const float4*>(in + (size_t)row * Dn) + lane * 2;
  float4 a = p[0], b = p[1];
  float s = a.x + a.y + a.z + a.w + b.x + b.y + b.z + b.w;
  float q = a.x*a.x + a.y*a.y + a.z*a.z + a.w*a.w + b.x*b.x + b.y*b.y + b.z*b.z + b.w*b.w;
  s = wred(s); q = wred(q);
  if (lane == 0) {
    float m = s * (1.0f / 512.0f);
    float var = q * (1.0f / 512.0f) - m * m;
    mu[row] = m;
    rsig[row] = 1.0f / sqrtf(var + 1e-5f);
  }
}

// ---------------- transpose + hi/mid split: in[B,N,D] -> inT[B,D,N] (u32 = h|m<<16) ----------------
__global__ __launch_bounds__(256) void k_tsplit(const float* __restrict__ in, unsigned* __restrict__ inT) {
  __shared__ float tile[64][65];
  int b = blockIdx.z, j0 = blockIdx.x * 64, d0 = blockIdx.y * 64;
  int t = threadIdx.x;
#pragma unroll
  for (int e = 0; e < 16; ++e) {
    int idx = t + e * 256;
    int r = idx >> 6, c = idx & 63;
    tile[r][c] = in[((size_t)b * Nn + j0 + r) * Dn + d0 + c];
  }
  __syncthreads();
#pragma unroll
  for (int e = 0; e < 16; ++e) {
    int idx = t + e * 256;
    int r = idx >> 6, c = idx & 63;
    inT[((size_t)b * Dn + d0 + r) * Nn + j0 + c] = packhm(tile[c][r]);
  }
}

// ---------------- slots init ----------------
__global__ __launch_bounds__(256) void k_slots_init(const float* __restrict__ smu, const float* __restrict__ sls,
                                                    const float* __restrict__ noise, float* __restrict__ slots) {
  int r = blockIdx.x;
  for (int d = threadIdx.x; d < Dn; d += 256)
    slots[(size_t)r * Dn + d] = smu[d] + expf(sls[d]) * noise[(size_t)r * Dn + d];
}

// ---------------- LN of [R,512] rows (prologue) ----------------
__global__ __launch_bounds__(256) void k_ln_rows(const float* __restrict__ src, const float* __restrict__ w,
                                                 const float* __restrict__ b, float* __restrict__ dst) {
  int r = blockIdx.x;
  __shared__ float red[8];
  int t = threadIdx.x;
  float x0 = src[(size_t)r * Dn + t], x1 = src[(size_t)r * Dn + 256 + t];
  float s = x0 + x1, q = x0 * x0 + x1 * x1;
  s = wred(s); q = wred(q);
  if ((t & 63) == 0) { red[t >> 6] = s; red[4 + (t >> 6)] = q; }
  __syncthreads();
  float S = red[0] + red[1] + red[2] + red[3];
  float Q = red[4] + red[5] + red[6] + red[7];
  float m = S * (1.0f / 512.0f);
  float rs = 1.0f / sqrtf(Q * (1.0f / 512.0f) - m * m + 1e-5f);
  dst[(size_t)r * Dn + t] = (x0 - m) * rs * w[t] + b[t];
  dst[(size_t)r * Dn + 256 + t] = (x1 - m) * rs * w[256 + t] + b[256 + t];
}

// ---------------- small GEMM with register prefetch (f32 path, used for T1/qu-like) ----------------
template <bool TRANS, bool RELU, bool ADD>
__global__ __launch_bounds__(256) void k_gemm_sm(const float* __restrict__ A, const float* __restrict__ W,
                                                 const float* __restrict__ bias, float* __restrict__ out,
                                                 int Nc, int K) {
  __shared__ float as_[64][17];
  __shared__ float ws_[16][65];
  int m0 = blockIdx.y * 64, n0 = blockIdx.x * 64;
  int t = threadIdx.x, tx = t & 15, ty = t >> 4;
  float acc[4][4] = {};
  float pa[4], pw[4];
  auto loadA = [&](int k0) {
#pragma unroll
    for (int e = 0; e < 4; ++e) {
      int idx = t + e * 256;
      int r = idx >> 4, c = idx & 15;
      pa[e] = A[(size_t)(m0 + r) * K + k0 + c];
    }
  };
  auto loadW = [&](int k0) {
#pragma unroll
    for (int e = 0; e < 4; ++e) {
      int idx = t + e * 256;
      if (!TRANS) {
        int r = idx >> 6, c = idx & 63;
        pw[e] = W[(size_t)(k0 + r) * Nc + n0 + c];
      } else {
        int r = idx >> 4, c = idx & 15;
        pw[e] = W[(size_t)(n0 + r) * K + k0 + c];
      }
    }
  };
  loadA(0); loadW(0);
  for (int k0 = 0; k0 < K; k0 += 16) {
#pragma unroll
    for (int e = 0; e < 4; ++e) {
      int idx = t + e * 256;
      int r = idx >> 4, c = idx & 15;
      as_[r][c] = pa[e];
    }
#pragma unroll
    for (int e = 0; e < 4; ++e) {
      int idx = t + e * 256;
      if (!TRANS) {
        int r = idx >> 6, c = idx & 63;
        ws_[r][c] = pw[e];
      } else {
        int r = idx >> 4, c = idx & 15;
        ws_[c][r] = pw[e];
      }
    }
    __syncthreads();
    if (k0 + 16 < K) { loadA(k0 + 16); loadW(k0 + 16); }
#pragma unroll
    for (int kc = 0; kc < 16; ++kc) {
      float av[4], wv[4];
#pragma unroll
      for (int i = 0; i < 4; ++i) av[i] = as_[ty * 4 + i][kc];
#pragma unroll
      for (int j = 0; j < 4; ++j) wv[j] = ws_[kc][tx * 4 + j];
#pragma unroll
      for (int i = 0; i < 4; ++i)
#pragma unroll
        for (int j = 0; j < 4; ++j) acc[i][j] += av[i] * wv[j];
    }
    __syncthreads();
  }
#pragma unroll
  for (int i = 0; i < 4; ++i)
#pragma unroll
    for (int j = 0; j < 4; ++j) {
      int m = m0 + ty * 4 + i, n = n0 + tx * 4 + j;
      float v = acc[i][j] + (bias ? bias[n] : 0.0f);
      if (RELU) v = fmaxf(v, 0.0f);
      if (ADD) v += out[(size_t)m * Nc + n];
      out[(size_t)m * Nc + n] = v;
    }
}

// ---------------- split-bf16 MFMA small GEMM: 64m x 64n tiles, K runtime ----------------
// C[m][n] = act( sum_k A[m][kbase+k] * W[(kbase+k)][n] + bias )
// PARTIAL: write part[(z*512 + m)*512 + n]; else out[m*ldo + n].
template <bool RELU, bool PARTIAL>
__global__ __launch_bounds__(256) void k_mm(const float* __restrict__ A, int lda,
                                            const float* __restrict__ W, int ldw,
                                            const float* __restrict__ bias,
                                            float* __restrict__ out, int ldo, int K) {
  __shared__ __align__(16) unsigned short as_h[64][40];
  __shared__ __align__(16) unsigned short as_m[64][40];
  __shared__ __align__(16) unsigned short ws_h[64][40];
  __shared__ __align__(16) unsigned short ws_m[64][40];
  int n0 = blockIdx.x * 64, m0 = blockIdx.y * 64, kbase = blockIdx.z * K;
  int t = threadIdx.x, w = t >> 6, l = t & 63;
  int lc = l & 15, lg = l >> 4, koff = lg * 8;

  f32x4 acc[4];
#pragma unroll
  for (int s = 0; s < 4; ++s) acc[s] = {0.0f, 0.0f, 0.0f, 0.0f};

  float2 na[4];
  float nw0[4], nw1[4];
  auto loadA = [&](int k0) {
#pragma unroll
    for (int e = 0; e < 4; ++e) {
      int idx = t + e * 256;
      int m = idx >> 4, kp = (idx & 15) * 2;
      na[e] = *reinterpret_cast<const float2*>(&A[(size_t)(m0 + m) * lda + kbase + k0 + kp]);
    }
  };
  auto loadW = [&](int k0) {
#pragma unroll
    for (int e = 0; e < 4; ++e) {
      int idx = t + e * 256;
      int kp = idx >> 6, n = idx & 63;
      nw0[e] = W[(size_t)(kbase + k0 + 2 * kp) * ldw + n0 + n];
      nw1[e] = W[(size_t)(kbase + k0 + 2 * kp + 1) * ldw + n0 + n];
    }
  };
  loadA(0); loadW(0);

  for (int k0 = 0; k0 < K; k0 += 32) {
#pragma unroll
    for (int e = 0; e < 4; ++e) {
      int idx = t + e * 256;
      int m = idx >> 4, kp = (idx & 15) * 2;
      unsigned mm;
      unsigned hm = pack2x(na[e].x, na[e].y, mm);
      *reinterpret_cast<unsigned*>(&as_h[m][kp]) = hm;
      *reinterpret_cast<unsigned*>(&as_m[m][kp]) = mm;
    }
#pragma unroll
    for (int e = 0; e < 4; ++e) {
      int idx = t + e * 256;
      int kp = idx >> 6, n = idx & 63;
      unsigned mm;
      unsigned hm = pack2x(nw0[e], nw1[e], mm);
      *reinterpret_cast<unsigned*>(&ws_h[n][kp * 2]) = hm;
      *reinterpret_cast<unsigned*>(&ws_m[n][kp * 2]) = mm;
    }
    __syncthreads();
    if (k0 + 32 < K) { loadA(k0 + 32); loadW(k0 + 32); }
    short8 ah = *reinterpret_cast<const short8*>(&as_h[w * 16 + lc][koff]);
    short8 am = *reinterpret_cast<const short8*>(&as_m[w * 16 + lc][koff]);
#pragma unroll
    for (int s = 0; s < 4; ++s) {
      short8 bh = *reinterpret_cast<const short8*>(&ws_h[s * 16 + lc][koff]);
      short8 bm = *reinterpret_cast<const short8*>(&ws_m[s * 16 + lc][koff]);
      acc[s] = __builtin_amdgcn_mfma_f32_16x16x32_bf16(ah, bh, acc[s], 0, 0, 0);
      acc[s] = __builtin_amdgcn_mfma_f32_16x16x32_bf16(ah, bm, acc[s], 0, 0, 0);
      acc[s] = __builtin_amdgcn_mfma_f32_16x16x32_bf16(am, bh, acc[s], 0, 0, 0);
    }
    __syncthreads();
  }

#pragma unroll
  for (int s = 0; s < 4; ++s) {
#pragma unroll
    for (int r = 0; r < 4; ++r) {
      int m = m0 + w * 16 + lg * 4 + r;
      int n = n0 + s * 16 + lc;
      float v = acc[s][r] + (bias ? bias[n] : 0.0f);
      if (RELU) v = fmaxf(v, 0.0f);
      if (PARTIAL)
        out[((size_t)blockIdx.z * 512 + m) * 512 + n] = v;
      else
        out[(size_t)m * ldo + n] = v;
    }
  }
}

// ---------------- W2 reduce + bias + residual + LN_s fused -> slots, sln ----------------
__global__ __launch_bounds__(256) void k_w2ln(const float* __restrict__ part, const float* __restrict__ b2,
                                              float* __restrict__ slots, float* __restrict__ sln,
                                              const float* __restrict__ lnsw, const float* __restrict__ lnsb) {
  int r = blockIdx.x, t = threadIdx.x;
  __shared__ float red[8];
  float sn[2];
#pragma unroll
  for (int j = 0; j < 2; ++j) {
    int c = j * 256 + t;
    size_t idx = (size_t)r * 512 + c;
    sn[j] = part[idx] + part[262144 + idx] + part[2 * 262144 + idx] + part[3 * 262144 + idx]
          + b2[c] + slots[idx];
  }
  float s = sn[0] + sn[1], q = sn[0] * sn[0] + sn[1] * sn[1];
  s = wred(s); q = wred(q);
  if ((t & 63) == 0) { red[t >> 6] = s; red[4 + (t >> 6)] = q; }
  __syncthreads();
  float S = red[0] + red[1] + red[2] + red[3];
  float Q = red[4] + red[5] + red[6] + red[7];
  float m = S * (1.0f / 512.0f);
  float rs = 1.0f / sqrtf(Q * (1.0f / 512.0f) - m * m + 1e-5f);
#pragma unroll
  for (int j = 0; j < 2; ++j) {
    int c = j * 256 + t;
    size_t idx = (size_t)r * 512 + c;
    slots[idx] = sn[j];
    sln[idx] = (sn[j] - m) * rs * lnsw[c] + lnsb[c];
  }
}

// ---------------- M_h = Wq_h @ Wk_h^T per head (raw) -> Ms[k*4096 + h*512 + d] ----------------
__global__ __launch_bounds__(256) void k_mh(const float* __restrict__ Wq, const float* __restrict__ Wk,
                                            float* __restrict__ Ms) {
  int h = blockIdx.z, k0 = blockIdx.y * 64, d0 = blockIdx.x * 64;
  __shared__ float qa[64][65];
  __shared__ float ka[64][65];
  int t = threadIdx.x, tx = t & 15, ty = t >> 4;
#pragma unroll
  for (int e = 0; e < 16; ++e) {
    int idx = t + e * 256;
    int r = idx >> 6, c = idx & 63;
    qa[c][r] = Wq[(size_t)(k0 + r) * Dn + h * 64 + c];
    ka[c][r] = Wk[(size_t)(d0 + r) * Dn + h * 64 + c];
  }
  __syncthreads();
  float acc[4][4] = {};
#pragma unroll 4
  for (int c = 0; c < 64; ++c) {
    float av[4], bv[4];
#pragma unroll
    for (int i = 0; i < 4; ++i) av[i] = qa[c][ty * 4 + i];
#pragma unroll
    for (int j = 0; j < 4; ++j) bv[j] = ka[c][tx * 4 + j];
#pragma unroll
    for (int i = 0; i < 4; ++i)
#pragma unroll
      for (int j = 0; j < 4; ++j) acc[i][j] += av[i] * bv[j];
  }
#pragma unroll
  for (int i = 0; i < 4; ++i)
#pragma unroll
    for (int j = 0; j < 4; ++j)
      Ms[(size_t)(k0 + ty * 4 + i) * 4096 + h * 512 + d0 + tx * 4 + j] = acc[i][j];
}

// ---------------- vbias_h[d] = Wk[d, h64:]·bq[h64:]; raw + scaled ----------------
__global__ __launch_bounds__(256) void k_vbias(const float* __restrict__ Wk, const float* __restrict__ bq,
                                               const float* __restrict__ lnw, float* __restrict__ vb_raw,
                                               float* __restrict__ vb_s) {
  __shared__ float bqs[512];
  int t = threadIdx.x;
  bqs[t] = bq[t]; bqs[256 + t] = bq[256 + t];
  __syncthreads();
  int d = blockIdx.x * 256 + t;
  float vb[8] = {};
  const float4* wr = reinterpret_cast<const float4*>(Wk + (size_t)d * Dn);
#pragma unroll 8
  for (int c4 = 0; c4 < 128; ++c4) {
    float4 wv = wr[c4];
    int h = c4 >> 4;
    int c = c4 * 4;
    vb[h] += wv.x * bqs[c] + wv.y * bqs[c + 1] + wv.z * bqs[c + 2] + wv.w * bqs[c + 3];
  }
  float lw = lnw[d];
#pragma unroll
  for (int h = 0; h < 8; ++h) {
    vb_raw[h * 512 + d] = vb[h];
    vb_s[h * 512 + d] = kScale * lw * vb[h];
  }
}

// ---------------- fold: scale Ms in place by kScale*lnw[d]; avec/bvec ----------------
__global__ __launch_bounds__(256) void k_mfold(float* __restrict__ Ms, const float* __restrict__ Wq,
                                               const float* __restrict__ bk, const float* __restrict__ lnw,
                                               const float* __restrict__ lnb, float* __restrict__ avec,
                                               float* __restrict__ bvec) {
  __shared__ float lws[512], lbs[512], bks[512];
  int t = threadIdx.x;
  lws[t] = lnw[t]; lws[256 + t] = lnw[256 + t];
  lbs[t] = lnb[t]; lbs[256 + t] = lnb[256 + t];
  bks[t] = bk[t]; bks[256 + t] = bk[256 + t];
  __syncthreads();
  int g = blockIdx.x * 256 + t;
  int k = g >> 3, h = g & 7;
  float* mr = Ms + (size_t)k * 4096 + h * 512;
  float mlnb = 0.0f, mlnw = 0.0f;
  for (int d = 0; d < 512; d += 4) {
    float4 m4 = *reinterpret_cast<const float4*>(mr + d);
    mlnb += m4.x * lbs[d] + m4.y * lbs[d + 1] + m4.z * lbs[d + 2] + m4.w * lbs[d + 3];
    mlnw += m4.x * lws[d] + m4.y * lws[d + 1] + m4.z * lws[d + 2] + m4.w * lws[d + 3];
    float4 o4 = {m4.x * kScale * lws[d], m4.y * kScale * lws[d + 1],
                 m4.z * kScale * lws[d + 2], m4.w * kScale * lws[d + 3]};
    *reinterpret_cast<float4*>(mr + d) = o4;
  }
  float wqdot = 0.0f;
  const float* qr = Wq + (size_t)k * Dn + h * 64;
  for (int c = 0; c < 64; c += 4) {
    float4 q4 = *reinterpret_cast<const float4*>(qr + c);
    wqdot += q4.x * bks[h * 64 + c] + q4.y * bks[h * 64 + c + 1] +
             q4.z * bks[h * 64 + c + 2] + q4.w * bks[h * 64 + c + 3];
  }
  avec[h * 512 + k] = kScale * (mlnb + wqdot);
  bvec[h * 512 + k] = kScale * mlnw;
}

// ---------------- aconst/bconst scalars ----------------
__global__ __launch_bounds__(256) void k_consts(const float* __restrict__ vb_raw, const float* __restrict__ bq,
                                                const float* __restrict__ bk, const float* __restrict__ lnw,
                                                const float* __restrict__ lnb, float* __restrict__ aconst,
                                                float* __restrict__ bconst) {
  __shared__ float r1[256], r2[256], r3[256];
  int t = threadIdx.x;
  for (int h = 0; h < 8; ++h) {
    float p1 = 0.0f, p2 = 0.0f, p3 = 0.0f;
    for (int d = t; d < 512; d += 256) {
      float vr = vb_raw[h * 512 + d];
      p1 += lnb[d] * vr;
      p2 += lnw[d] * vr;
    }
    if (t < 64) p3 = bq[h * 64 + t] * bk[h * 64 + t];
    r1[t] = p1; r2[t] = p2; r3[t] = p3;
    __syncthreads();
    for (int s = 128; s > 0; s >>= 1) {
      if (t < s) { r1[t] += r1[t + s]; r2[t] += r2[t + s]; r3[t] += r3[t + s]; }
      __syncthreads();
    }
    if (t == 0) {
      aconst[h] = kScale * (r1[0] + r3[0]);
      bconst[h] = kScale * r2[0];
    }
    __syncthreads();
  }
}

// ---------------- bcih[n] = bc·Wih[n,:] + bih[n] ----------------
__global__ __launch_bounds__(256) void k_bcih(const float* __restrict__ bc, const float* __restrict__ Wih,
                                              const float* __restrict__ bih, float* __restrict__ bcih) {
  __shared__ float bcs[512];
  int t = threadIdx.x;
  bcs[t] = bc[t]; bcs[256 + t] = bc[256 + t];
  __syncthreads();
  int n = blockIdx.x * 256 + t;
  const float4* wr = reinterpret_cast<const float4*>(Wih + (size_t)n * Dn);
  float a = 0.0f;
#pragma unroll 8
  for (int c4 = 0; c4 < 128; ++c4) {
    float4 wv = wr[c4];
    int c = c4 * 4;
    a += wv.x * bcs[c] + wv.y * bcs[c + 1] + wv.z * bcs[c + 2] + wv.w * bcs[c + 3];
  }
  bcih[n] = a + bih[n];
}

// ---------------- qkt = sln @ Ms + vb_s, packed hi|mid u32, remapped to [b,hi,d] ----------------
__global__ __launch_bounds__(256) void k_qu(const float* __restrict__ sln, const float* __restrict__ Ms,
                                            const float* __restrict__ vb_s, unsigned* __restrict__ qkt) {
  __shared__ float as_[64][17];
  __shared__ float ws_[16][65];
  int m0 = blockIdx.y * 64, n0 = blockIdx.x * 64;
  int t = threadIdx.x, tx = t & 15, ty = t >> 4;
  float acc[4][4] = {};
  float pa[4], pw[4];
  auto loadA = [&](int k0) {
#pragma unroll
    for (int e = 0; e < 4; ++e) {
      int idx = t + e * 256;
      int r = idx >> 4, c = idx & 15;
      pa[e] = sln[(size_t)(m0 + r) * Dn + k0 + c];
    }
  };
  auto loadW = [&](int k0) {
#pragma unroll
    for (int e = 0; e < 4; ++e) {
      int idx = t + e * 256;
      int r = idx >> 6, c = idx & 63;
      pw[e] = Ms[(size_t)(k0 + r) * 4096 + n0 + c];
    }
  };
  loadA(0); loadW(0);
  for (int k0 = 0; k0 < 512; k0 += 16) {
#pragma unroll
    for (int e = 0; e < 4; ++e) {
      int idx = t + e * 256;
      int r = idx >> 4, c = idx & 15;
      as_[r][c] = pa[e];
    }
#pragma unroll
    for (int e = 0; e < 4; ++e) {
      int idx = t + e * 256;
      int r = idx >> 6, c = idx & 63;
      ws_[r][c] = pw[e];
    }
    __syncthreads();
    if (k0 + 16 < 512) { loadA(k0 + 16); loadW(k0 + 16); }
#pragma unroll
    for (int kc = 0; kc < 16; ++kc) {
      float av[4], wv[4];
#pragma unroll
      for (int i = 0; i < 4; ++i) av[i] = as_[ty * 4 + i][kc];
#pragma unroll
      for (int j = 0; j < 4; ++j) wv[j] = ws_[kc][tx * 4 + j];
#pragma unroll
      for (int i = 0; i < 4; ++i)
#pragma unroll
        for (int j = 0; j < 4; ++j) acc[i][j] += av[i] * wv[j];
    }
    __syncthreads();
  }
#pragma unroll
  for (int i = 0; i < 4; ++i)
#pragma unroll
    for (int j = 0; j < 4; ++j) {
      int m = m0 + ty * 4 + i, n = n0 + tx * 4 + j;
      int bb = m >> 4, isl = m & 15, h = n >> 9, d = n & 511;
      qkt[((size_t)bb * HIn + h * 16 + isl) * Dn + d] = packhm(acc[i][j] + vb_s[n]);
    }
}

// ---------------- alpha/beta = sln·avec_h + aconst_h ----------------
__global__ void k_ab(const float* __restrict__ sln, const float* __restrict__ avec,
                     const float* __restrict__ bvec, const float* __restrict__ aconst,
                     const float* __restrict__ bconst, float* __restrict__ alpha,
                     float* __restrict__ beta) {
  int g = blockIdx.x;           // b*128 + hi
  int hi = g & 127, b = g >> 7;
  int h = hi >> 4, i = hi & 15;
  int lane = threadIdx.x;
  const float4* sp = reinterpret_cast<const float4*>(sln + (size_t)(b * NSn + i) * Dn) + lane * 2;
  const float4* ap = reinterpret_cast<const float4*>(avec + h * 512) + lane * 2;
  const float4* bp = reinterpret_cast<const float4*>(bvec + h * 512) + lane * 2;
  float4 s0 = sp[0], s1 = sp[1], a0 = ap[0], a1 = ap[1], b0 = bp[0], b1 = bp[1];
  float pa = s0.x*a0.x + s0.y*a0.y + s0.z*a0.z + s0.w*a0.w + s1.x*a1.x + s1.y*a1.y + s1.z*a1.z + s1.w*a1.w;
  float pb = s0.x*b0.x + s0.y*b0.y + s0.z*b0.z + s0.w*b0.w + s1.x*b1.x + s1.y*b1.y + s1.z*b1.z + s1.w*b1.w;
  pa = wred(pa); pb = wred(pb);
  if (lane == 0) {
    alpha[g] = pa + aconst[h];
    beta[g] = pb + bconst[h];
  }
}

// ---------------- dots via 2-level bf16-split MFMA (3 passes) + in-register softmax ----------------
__global__ __launch_bounds__(256) void k_dots(const float* __restrict__ in, const unsigned* __restrict__ qkt,
                                              const float* __restrict__ alpha, const float* __restrict__ beta,
                                              const float* __restrict__ mu, const float* __restrict__ rsig,
                                              unsigned* __restrict__ A, float* __restrict__ Spart,
                                              float* __restrict__ c1part) {
  __shared__ __align__(16) unsigned short xs_h[128][40];
  __shared__ __align__(16) unsigned short xs_m[128][40];
  __shared__ __align__(16) unsigned short us_h[128][40];
  __shared__ __align__(16) unsigned short us_m[128][40];   // 40960 B

  int b = blockIdx.y, jt = blockIdx.x, j0 = jt * 128;
  int t = threadIdx.x, w = t >> 6, l = t & 63;
  int lc = l & 15, lg = l >> 4, koff = lg * 8;
  const size_t inbase = ((size_t)b * Nn + j0) * Dn;
  const size_t ubase = (size_t)b * HIn * Dn;

  f32x4 acc[2][8];
#pragma unroll
  for (int i = 0; i < 2; ++i)
#pragma unroll
    for (int j2 = 0; j2 < 8; ++j2) acc[i][j2] = {0.0f, 0.0f, 0.0f, 0.0f};

  float2 nx[8];
  uint2 nu[8];
#pragma unroll
  for (int e = 0; e < 8; ++e) {
    int idx = t + e * 256;
    int j = idx >> 4, kp = (idx & 15) * 2;
    nx[e] = *reinterpret_cast<const float2*>(&in[inbase + (size_t)j * Dn + kp]);
    nu[e] = *reinterpret_cast<const uint2*>(&qkt[ubase + (size_t)j * Dn + kp]);
  }

  for (int k0 = 0; k0 < 512; k0 += 32) {
#pragma unroll
    for (int e = 0; e < 8; ++e) {
      int idx = t + e * 256;
      int j = idx >> 4, kp = (idx & 15) * 2;
      unsigned mm;
      unsigned hm = pack2x(nx[e].x, nx[e].y, mm);
      *reinterpret_cast<unsigned*>(&xs_h[j][kp]) = hm;
      *reinterpret_cast<unsigned*>(&xs_m[j][kp]) = mm;
      unsigned uh = (nu[e].x & 0xffffu) | (nu[e].y << 16);
      unsigned um = (nu[e].x >> 16) | (nu[e].y & 0xffff0000u);
      *reinterpret_cast<unsigned*>(&us_h[j][kp]) = uh;
      *reinterpret_cast<unsigned*>(&us_m[j][kp]) = um;
    }
    if (k0 + 32 < 512) {
#pragma unroll
      for (int e = 0; e < 8; ++e) {
        int idx = t + e * 256;
        int j = idx >> 4, kp = (idx & 15) * 2;
        nx[e] = *reinterpret_cast<const float2*>(&in[inbase + (size_t)j * Dn + k0 + 32 + kp]);
        nu[e] = *reinterpret_cast<const uint2*>(&qkt[ubase + (size_t)j * Dn + k0 + 32 + kp]);
      }
    }
    __syncthreads();
    short8 ah0 = *reinterpret_cast<const short8*>(&xs_h[w * 32 + lc][koff]);
    short8 am0 = *reinterpret_cast<const short8*>(&xs_m[w * 32 + lc][koff]);
    short8 ah1 = *reinterpret_cast<const short8*>(&xs_h[w * 32 + 16 + lc][koff]);
    short8 am1 = *reinterpret_cast<const short8*>(&xs_m[w * 32 + 16 + lc][koff]);
#pragma unroll
    for (int ht = 0; ht < 8; ++ht) {
      short8 bh = *reinterpret_cast<const short8*>(&us_h[ht * 16 + lc][koff]);
      short8 bm = *reinterpret_cast<const short8*>(&us_m[ht * 16 + lc][koff]);
      acc[0][ht] = __builtin_amdgcn_mfma_f32_16x16x32_bf16(ah0, bh, acc[0][ht], 0, 0, 0);
      acc[0][ht] = __builtin_amdgcn_mfma_f32_16x16x32_bf16(ah0, bm, acc[0][ht], 0, 0, 0);
      acc[0][ht] = __builtin_amdgcn_mfma_f32_16x16x32_bf16(am0, bh, acc[0][ht], 0, 0, 0);
      acc[1][ht] = __builtin_amdgcn_mfma_f32_16x16x32_bf16(ah1, bh, acc[1][ht], 0, 0, 0);
      acc[1][ht] = __builtin_amdgcn_mfma_f32_16x16x32_bf16(ah1, bm, acc[1][ht], 0, 0, 0);
      acc[1][ht] = __builtin_amdgcn_mfma_f32_16x16x32_bf16(am1, bh, acc[1][ht], 0, 0, 0);
    }
    __syncthreads();
  }

  float* rsL = reinterpret_cast<float*>(&xs_h[0][0]);
  float* muL = rsL + 128;
  float* aL = rsL + 256;
  float* bL = rsL + 384;
  float (*sredS)[128] = reinterpret_cast<float(*)[128]>(rsL + 512);
  float (*sredC)[128] = reinterpret_cast<float(*)[128]>(rsL + 512 + 4 * 128);
  if (t < 128) {
    rsL[t] = rsig[(size_t)b * Nn + j0 + t];
    muL[t] = mu[(size_t)b * Nn + j0 + t];
    aL[t] = alpha[b * HIn + t];
    bL[t] = beta[b * HIn + t];
  }
  __syncthreads();

  float sS[8] = {}, sC[8] = {};
#pragma unroll
  for (int jt2 = 0; jt2 < 2; ++jt2) {
    int jbase = w * 32 + jt2 * 16 + lg * 4;
#pragma unroll
    for (int ht = 0; ht < 8; ++ht) {
      int hi = ht * 16 + lc;
      float av = aL[hi], bv = bL[hi];
      float v[4], rs4[4], mr4[4];
#pragma unroll
      for (int r = 0; r < 4; ++r) {
        int jr = jbase + r;
        rs4[r] = rsL[jr];
        mr4[r] = muL[jr] * rs4[r];
        v[r] = acc[jt2][ht][r] * rs4[r] + av - mr4[r] * bv;
      }
      float mx[4] = {v[0], v[1], v[2], v[3]};
#pragma unroll
      for (int m = 1; m <= 8; m <<= 1)
#pragma unroll
        for (int r = 0; r < 4; ++r) mx[r] = fmaxf(mx[r], __shfl_xor(mx[r], m));
      float e4[4], ss[4];
#pragma unroll
      for (int r = 0; r < 4; ++r) { e4[r] = expf(v[r] - mx[r]); ss[r] = e4[r]; }
#pragma unroll
      for (int m = 1; m <= 8; m <<= 1)
#pragma unroll
        for (int r = 0; r < 4; ++r) ss[r] += __shfl_xor(ss[r], m);
      float ps = 0.0f, pc = 0.0f;
      float p0 = e4[0] / ss[0] + kEps, p1 = e4[1] / ss[1] + kEps;
      float p2 = e4[2] / ss[2] + kEps, p3 = e4[3] / ss[3] + kEps;
      uint4 o4;
      o4.x = packhm(p0 * rs4[0]); o4.y = packhm(p1 * rs4[1]);
      o4.z = packhm(p2 * rs4[2]); o4.w = packhm(p3 * rs4[3]);
      ps = p0 + p1 + p2 + p3;
      pc = p0 * mr4[0] + p1 * mr4[1] + p2 * mr4[2] + p3 * mr4[3];
      *reinterpret_cast<uint4*>(&A[(size_t)(b * HIn + hi) * Nn + j0 + jbase]) = o4;
      ps += __shfl_xor(ps, 16); ps += __shfl_xor(ps, 32);
      pc += __shfl_xor(pc, 16); pc += __shfl_xor(pc, 32);
      sS[ht] += ps; sC[ht] += pc;
    }
  }
  if (l < 16) {
#pragma unroll
    for (int ht = 0; ht < 8; ++ht) {
      sredS[w][ht * 16 + l] = sS[ht];
      sredC[w][ht * 16 + l] = sC[ht];
    }
  }
  __syncthreads();
  if (t < 128) {
    float s_ = sredS[0][t] + sredS[1][t] + sredS[2][t] + sredS[3][t];
    float c_ = sredC[0][t] + sredC[1][t] + sredC[2][t] + sredC[3][t];
    int sub = (b * 32 + jt) * HIn + t;
    Spart[sub] = s_;
    c1part[sub] = c_;
  }
}

// ---------------- AX = A @ X via 2-level bf16-split MFMA (K-split x2) ----------------
__global__ __launch_bounds__(256) void k_ax(const unsigned* __restrict__ Au, const unsigned* __restrict__ inT,
                                            float* __restrict__ AXp) {
  __shared__ __align__(16) unsigned short as_h[128][40];
  __shared__ __align__(16) unsigned short as_m[128][40];
  __shared__ __align__(16) unsigned short xs_h[128][40];
  __shared__ __align__(16) unsigned short xs_m[128][40];

  int d0 = blockIdx.x * 128, kp = blockIdx.y, b = blockIdx.z;
  int t = threadIdx.x, w = t >> 6, l = t & 63;
  int lc = l & 15, lg = l >> 4, koff = lg * 8;
  const size_t abase = (size_t)b * HIn * Nn + kp * 2048;
  const size_t xbase = ((size_t)b * Dn + d0) * Nn + kp * 2048;

  f32x4 acc[2][8];
#pragma unroll
  for (int i = 0; i < 2; ++i)
#pragma unroll
    for (int j2 = 0; j2 < 8; ++j2) acc[i][j2] = {0.0f, 0.0f, 0.0f, 0.0f};

  uint2 pa[8];
  uint4 px[4];
#pragma unroll
  for (int e = 0; e < 8; ++e) {
    int idx = t + e * 256;
    int hi = idx >> 4, jp = (idx & 15) * 2;
    pa[e] = *reinterpret_cast<const uint2*>(&Au[abase + (size_t)hi * Nn + jp]);
  }
#pragma unroll
  for (int e = 0; e < 4; ++e) {
    int idx = t + e * 256;
    int d = idx >> 3, jg = idx & 7;
    px[e] = *reinterpret_cast<const uint4*>(&inT[xbase + (size_t)d * Nn + jg * 4]);
  }

  for (int c0 = 0; c0 < 2048; c0 += 32) {
#pragma unroll
    for (int e = 0; e < 8; ++e) {
      int idx = t + e * 256;
      int hi = idx >> 4, jp = (idx & 15) * 2;
      unsigned h = (pa[e].x & 0xffffu) | (pa[e].y << 16);
      unsigned m = (pa[e].x >> 16) | (pa[e].y & 0xffff0000u);
      *reinterpret_cast<unsigned*>(&as_h[hi][jp]) = h;
      *reinterpret_cast<unsigned*>(&as_m[hi][jp]) = m;
    }
#pragma unroll
    for (int e = 0; e < 4; ++e) {
      int idx = t + e * 256;
      int d = idx >> 3, jg = idx & 7;
      unsigned h0 = (px[e].x & 0xffffu) | (px[e].y << 16);
      unsigned h1 = (px[e].z & 0xffffu) | (px[e].w << 16);
      unsigned m0 = (px[e].x >> 16) | (px[e].y & 0xffff0000u);
      unsigned m1 = (px[e].z >> 16) | (px[e].w & 0xffff0000u);
      uint2 hv = {h0, h1}, mv = {m0, m1};
      *reinterpret_cast<uint2*>(&xs_h[d][jg * 4]) = hv;
      *reinterpret_cast<uint2*>(&xs_m[d][jg * 4]) = mv;
    }
    if (c0 + 32 < 2048) {
#pragma unroll
      for (int e = 0; e < 8; ++e) {
        int idx = t + e * 256;
        int hi = idx >> 4, jp = (idx & 15) * 2;
        pa[e] = *reinterpret_cast<const uint2*>(&Au[abase + (size_t)hi * Nn + c0 + 32 + jp]);
      }
#pragma unroll
      for (int e = 0; e < 4; ++e) {
        int idx = t + e * 256;
        int d = idx >> 3, jg = idx & 7;
        px[e] = *reinterpret_cast<const uint4*>(&inT[xbase + (size_t)d * Nn + c0 + 32 + jg * 4]);
      }
    }
    __syncthreads();
    short8 ah0 = *reinterpret_cast<const short8*>(&as_h[w * 32 + lc][koff]);
    short8 am0 = *reinterpret_cast<const short8*>(&as_m[w * 32 + lc][koff]);
    short8 ah1 = *reinterpret_cast<const short8*>(&as_h[w * 32 + 16 + lc][koff]);
    short8 am1 = *reinterpret_cast<const short8*>(&as_m[w * 32 + 16 + lc][koff]);
#pragma unroll
    for (int dt = 0; dt < 8; ++dt) {
      short8 bh = *reinterpret_cast<const short8*>(&xs_h[dt * 16 + lc][koff]);
      short8 bm = *reinterpret_cast<const short8*>(&xs_m[dt * 16 + lc][koff]);
      acc[0][dt] = __builtin_amdgcn_mfma_f32_16x16x32_bf16(ah0, bh, acc[0][dt], 0, 0, 0);
      acc[0][dt] = __builtin_amdgcn_mfma_f32_16x16x32_bf16(ah0, bm, acc[0][dt], 0, 0, 0);
      acc[0][dt] = __builtin_amdgcn_mfma_f32_16x16x32_bf16(am0, bh, acc[0][dt], 0, 0, 0);
      acc[1][dt] = __builtin_amdgcn_mfma_f32_16x16x32_bf16(ah1, bh, acc[1][dt], 0, 0, 0);
      acc[1][dt] = __builtin_amdgcn_mfma_f32_16x16x32_bf16(ah1, bm, acc[1][dt], 0, 0, 0);
      acc[1][dt] = __builtin_amdgcn_mfma_f32_16x16x32_bf16(am1, bh, acc[1][dt], 0, 0, 0);
    }
    __syncthreads();
  }

  const size_t obase = (((size_t)kp * Bn + b) * HIn) * Dn + d0;
#pragma unroll
  for (int jt2 = 0; jt2 < 2; ++jt2) {
#pragma unroll
    for (int dt = 0; dt < 8; ++dt) {
#pragma unroll
      for (int r = 0; r < 4; ++r) {
        int hi = w * 32 + jt2 * 16 + lg * 4 + r;
        int d = dt * 16 + lc;
        AXp[obase + (size_t)hi * Dn + d] = acc[jt2][dt][r];
      }
    }
  }
}

// ---------------- upd = ((w*(G-c1)/S + b) @ Wv_h) + bv, S/c1 reduced inline ----------------
__global__ __launch_bounds__(256) void k_updS(const float* __restrict__ AXp, const float* __restrict__ Spart,
                                              const float* __restrict__ c1part, const float* __restrict__ lnw,
                                              const float* __restrict__ lnb, const float* __restrict__ Wv,
                                              const float* __restrict__ bv, float* __restrict__ upd) {
  int b = blockIdx.y, hi = blockIdx.x, h = hi >> 4, i = hi & 15;
  __shared__ float vx[512];
  __shared__ float red[256];
  __shared__ float sSC[2];
  int t = threadIdx.x;
  if (t < 64) {
    float vs = 0.0f, vc = 0.0f;
    if (t < 32) {
      vs = Spart[(size_t)(b * 32 + t) * HIn + hi];
      vc = c1part[(size_t)(b * 32 + t) * HIn + hi];
    }
    vs = wred(vs); vc = wred(vc);
    if (t == 0) { sSC[0] = vs; sSC[1] = vc; }
  }
  __syncthreads();
  float c1v = sSC[1];
  float invS = 1.0f / sSC[0];
  for (int d = t; d < Dn; d += 256) {
    float G = AXp[((size_t)(0 * Bn + b) * HIn + hi) * Dn + d]
            + AXp[((size_t)(1 * Bn + b) * HIn + hi) * Dn + d];
    vx[d] = lnw[d] * (G - c1v) * invS + lnb[d];
  }
  __syncthreads();
  int cc = t & 63, qd = t >> 6;
  float p = 0.0f;
  for (int d = qd * 128; d < qd * 128 + 128; ++d) p += vx[d] * Wv[(size_t)d * Dn + h * 64 + cc];
  red[t] = p;
  __syncthreads();
  if (qd == 0) {
    float v = red[cc] + red[64 + cc] + red[128 + cc] + red[192 + cc] + bv[h * 64 + cc];
    upd[(size_t)(b * NSn + i) * Dn + h * 64 + cc] = v;
  }
}

// ---------------- dual GEMM (prefetched): z=0: gi = upd@T1 + bcih ; z=1: gh = slots@Whh^T + bhh ----------------
__global__ __launch_bounds__(256) void k_gg(const float* __restrict__ upd, const float* __restrict__ T1,
                                            const float* __restrict__ bcih, const float* __restrict__ slots,
                                            const float* __restrict__ Whh, const float* __restrict__ bhh,
                                            float* __restrict__ gi, float* __restrict__ gh) {
  bool z = (blockIdx.z == 1);
  const float* A = z ? slots : upd;
  const float* W = z ? Whh : T1;
  const float* bias = z ? bhh : bcih;
  float* out = z ? gh : gi;
  __shared__ float as_[64][17];
  __shared__ float ws_[16][65];
  int m0 = blockIdx.y * 64, n0 = blockIdx.x * 64;
  int t = threadIdx.x, tx = t & 15, ty = t >> 4;
  float acc[4][4] = {};
  float pa[4], pw[4];
  auto loadA = [&](int k0) {
#pragma unroll
    for (int e = 0; e < 4; ++e) {
      int idx = t + e * 256;
      int r = idx >> 4, c = idx & 15;
      pa[e] = A[(size_t)(m0 + r) * 512 + k0 + c];
    }
  };
  auto loadW = [&](int k0) {
#pragma unroll
    for (int e = 0; e < 4; ++e) {
      int idx = t + e * 256;
      if (!z) {
        int r = idx >> 6, c = idx & 63;
        pw[e] = W[(size_t)(k0 + r) * 1536 + n0 + c];
      } else {
        int r = idx >> 4, c = idx & 15;
        pw[e] = W[(size_t)(n0 + r) * 512 + k0 + c];
      }
    }
  };
  loadA(0); loadW(0);
  for (int k0 = 0; k0 < 512; k0 += 16) {
#pragma unroll
    for (int e = 0; e < 4; ++e) {
      int idx = t + e * 256;
      int r = idx >> 4, c = idx & 15;
      as_[r][c] = pa[e];
    }
#pragma unroll
    for (int e = 0; e < 4; ++e) {
      int idx = t + e * 256;
      if (!z) {
        int r = idx >> 6, c = idx & 63;
        ws_[r][c] = pw[e];
      } else {
        int r = idx >> 4, c = idx & 15;
        ws_[c][r] = pw[e];
      }
    }
    __syncthreads();
    if (k0 + 16 < 512) { loadA(k0 + 16); loadW(k0 + 16); }
#pragma unroll
    for (int kc = 0; kc < 16; ++kc) {
      float av[4], wv[4];
#pragma unroll
      for (int i = 0; i < 4; ++i) av[i] = as_[ty * 4 + i][kc];
#pragma unroll
      for (int j = 0; j < 4; ++j) wv[j] = ws_[kc][tx * 4 + j];
#pragma unroll
      for (int i = 0; i < 4; ++i)
#pragma unroll
        for (int j = 0; j < 4; ++j) acc[i][j] += av[i] * wv[j];
    }
    __syncthreads();
  }
#pragma unroll
  for (int i = 0; i < 4; ++i)
#pragma unroll
    for (int j = 0; j < 4; ++j) {
      int m = m0 + ty * 4 + i, n = n0 + tx * 4 + j;
      out[(size_t)m * 1536 + n] = acc[i][j] + bias[n];
    }
}

// ---------------- GRU pointwise + LN_ff fused ----------------
__global__ __launch_bounds__(256) void k_gruln(const float* __restrict__ gi, const float* __restrict__ gh,
                                               float* __restrict__ slots, float* __restrict__ slnff,
                                               const float* __restrict__ lnffw, const float* __restrict__ lnffb) {
  int r = blockIdx.x, t = threadIdx.x;
  __shared__ float red[8];
  float sn[2];
#pragma unroll
  for (int j = 0; j < 2; ++j) {
    int c = j * 256 + t;
    float gir = gi[(size_t)r * 1536 + c];
    float giz = gi[(size_t)r * 1536 + 512 + c];
    float gin = gi[(size_t)r * 1536 + 1024 + c];
    float ghr = gh[(size_t)r * 1536 + c];
    float ghz = gh[(size_t)r * 1536 + 512 + c];
    float ghn = gh[(size_t)r * 1536 + 1024 + c];
    float rg = 1.0f / (1.0f + expf(-(gir + ghr)));
    float zg = 1.0f / (1.0f + expf(-(giz + ghz)));
    float ng = tanhf(gin + rg * ghn);
    sn[j] = (1.0f - zg) * ng + zg * slots[(size_t)r * Dn + c];
  }
  float s = sn[0] + sn[1], q = sn[0] * sn[0] + sn[1] * sn[1];
  s = wred(s); q = wred(q);
  if ((t & 63) == 0) { red[t >> 6] = s; red[4 + (t >> 6)] = q; }
  __syncthreads();
  float S = red[0] + red[1] + red[2] + red[3];
  float Q = red[4] + red[5] + red[6] + red[7];
  float m = S * (1.0f / 512.0f);
  float rs = 1.0f / sqrtf(Q * (1.0f / 512.0f) - m * m + 1e-5f);
#pragma unroll
  for (int j = 0; j < 2; ++j) {
    int c = j * 256 + t;
    slots[(size_t)r * Dn + c] = sn[j];
    slnff[(size_t)r * Dn + c] = (sn[j] - m) * rs * lnffw[c] + lnffb[c];
  }
}

// ---------------- keep gate + per-slot route scalars (merged) ----------------
__global__ void k_keepsc(const float* __restrict__ Wkeep, const float* __restrict__ gk,
                         float* __restrict__ slots, const float* __restrict__ lnw,
                         const float* __restrict__ lnb, double* __restrict__ swd,
                         double* __restrict__ sbd) {
  int g = blockIdx.x;
  int lane = threadIdx.x;
  float4* sp = reinterpret_cast<float4*>(slots + (size_t)g * Dn) + lane * 2;
  float4 s0 = sp[0], s1 = sp[1];
  float sv[8] = {s0.x, s0.y, s0.z, s0.w, s1.x, s1.y, s1.z, s1.w};
  double d0 = 0.0, d1 = 0.0;
#pragma unroll
  for (int e = 0; e < 8; ++e) {
    int d = lane * 8 + e;
    d0 += (double)sv[e] * (double)Wkeep[d * 2];
    d1 += (double)sv[e] * (double)Wkeep[d * 2 + 1];
  }
  d0 = wredd(d0);
  d1 = wredd(d1);
  int keepi = 0;
  if (lane == 0) keepi = ((d1 + (double)gk[g * 2 + 1]) > (d0 + (double)gk[g * 2])) ? 1 : 0;
  keepi = __shfl(keepi, 0);
  if (!keepi) {
    float4 z = {0.0f, 0.0f, 0.0f, 0.0f};
    sp[0] = z;
    sp[1] = z;
#pragma unroll
    for (int e = 0; e < 8; ++e) sv[e] = 0.0f;
  }
  // route scalars from final (post-keep) slot values
  const float4* wp = reinterpret_cast<const float4*>(lnw) + lane * 2;
  const float4* bp = reinterpret_cast<const float4*>(lnb) + lane * 2;
  float4 w0 = wp[0], w1 = wp[1], b0 = bp[0], b1 = bp[1];
  float wv8[8] = {w0.x, w0.y, w0.z, w0.w, w1.x, w1.y, w1.z, w1.w};
  float bv8[8] = {b0.x, b0.y, b0.z, b0.w, b1.x, b1.y, b1.z, b1.w};
  double pw = 0.0, pb = 0.0;
#pragma unroll
  for (int e = 0; e < 8; ++e) {
    pw += (double)sv[e] * (double)wv8[e];
    pb += (double)sv[e] * (double)bv8[e];
  }
  pw = wredd(pw);
  pb = wredd(pb);
  if (lane == 0) { swd[g] = pw; sbd[g] = pb; }
}

// ---------------- hard route + gather output (tiled mini-GEMM, prefetched) ----------------
__global__ __launch_bounds__(256) void k_route_out(const float* __restrict__ in, const float* __restrict__ slots,
                                                   const float* __restrict__ lnw, const double* __restrict__ swd,
                                                   const double* __restrict__ sbd, const float* __restrict__ mu,
                                                   const float* __restrict__ rsig,
                                                   const float* __restrict__ g_route, float* __restrict__ out) {
  int b = blockIdx.y, j0 = blockIdx.x * 128;
  __shared__ __align__(16) float sl[16 * 516];
  __shared__ __align__(16) float lw[512];
  __shared__ __align__(16) float xs[16][132];
  __shared__ double lgd[128][17];
  __shared__ int besti[128];
  int t = threadIdx.x, tx = t & 15, ty = t >> 4;

  for (int idx = t; idx < 2048; idx += 256) {
    int i = idx >> 7, c = idx & 127;
    *reinterpret_cast<float4*>(&sl[i * 516 + c * 4]) =
        *reinterpret_cast<const float4*>(&slots[(size_t)(b * NSn + i) * Dn + c * 4]);
  }
  if (t < 128)
    *reinterpret_cast<float4*>(&lw[t * 4]) = *reinterpret_cast<const float4*>(&lnw[t * 4]);

  float acc[8] = {};
  double accd[8] = {};
  const size_t inbase = ((size_t)b * Nn + j0) * Dn;

  float pre[8];
#pragma unroll
  for (int e = 0; e < 8; ++e) {
    int idx = t + e * 256;
    int r = idx >> 4, c = idx & 15;
    pre[e] = in[inbase + (size_t)r * Dn + c];
  }
  __syncthreads();

  for (int k0 = 0; k0 < Dn; k0 += 16) {
#pragma unroll
    for (int e = 0; e < 8; ++e) {
      int idx = t + e * 256;
      int r = idx >> 4, c = idx & 15;
      xs[c][r] = pre[e] * lw[k0 + c];
    }
    __syncthreads();
    float nxt[8] = {};
    if (k0 + 16 < Dn) {
#pragma unroll
      for (int e = 0; e < 8; ++e) {
        int idx = t + e * 256;
        int r = idx >> 4, c = idx & 15;
        nxt[e] = in[inbase + (size_t)r * Dn + k0 + 16 + c];
      }
    }
#pragma unroll
    for (int kc = 0; kc < 16; ++kc) {
      float sv = sl[tx * 516 + k0 + kc];
      float4 x0 = *reinterpret_cast<const float4*>(&xs[kc][ty * 8]);
      float4 x1 = *reinterpret_cast<const float4*>(&xs[kc][ty * 8 + 4]);
      acc[0] += x0.x * sv; acc[1] += x0.y * sv; acc[2] += x0.z * sv; acc[3] += x0.w * sv;
      acc[4] += x1.x * sv; acc[5] += x1.y * sv; acc[6] += x1.z * sv; acc[7] += x1.w * sv;
    }
    if ((k0 & 127) == 112) {
#pragma unroll
      for (int e = 0; e < 8; ++e) { accd[e] += (double)acc[e]; acc[e] = 0.0f; }
    }
#pragma unroll
    for (int e = 0; e < 8; ++e) pre[e] = nxt[e];
    __syncthreads();
  }

  double sw_i = swd[b * NSn + tx], sb_i = sbd[b * NSn + tx];
#pragma unroll
  for (int r = 0; r < 8; ++r) {
    int j = ty * 8 + r;
    double rsj = (double)rsig[(size_t)b * Nn + j0 + j];
    double muj = (double)mu[(size_t)b * Nn + j0 + j];
    double g = (double)g_route[((size_t)b * NSn + tx) * Nn + j0 + j];
    lgd[j][tx] = (double)kScale * (rsj * accd[r] + sb_i - muj * rsj * sw_i) + g;
  }
  __syncthreads();
  if (t < 128) {
    double best = lgd[t][0];
    int bi = 0;
#pragma unroll
    for (int i = 1; i < 16; ++i) {
      double v = lgd[t][i];
      if (v > best) { best = v; bi = i; }
    }
    besti[t] = bi;
  }
  __syncthreads();
  for (int idx = t; idx < 128 * 128; idx += 256) {
    int j = idx >> 7, c = idx & 127;
    *reinterpret_cast<float4*>(&out[inbase + (size_t)j * Dn + c * 4]) =
        *reinterpret_cast<const float4*>(&sl[besti[j] * 516 + c * 4]);
  }
}

extern "C" void kernel_launch(void* const* d_in, const int* in_sizes, int n_in,
                              void* d_out, int out_size, void* d_ws, size_t ws_size,
                              hipStream_t stream) {
  (void)in_sizes; (void)n_in; (void)out_size; (void)ws_size;
  const float* in = (const float*)d_in[0];
  const float* slots_mu = (const float*)d_in[1];
  const float* slots_ls = (const float*)d_in[2];
  const float* ln_in_w = (const float*)d_in[3];
  const float* ln_in_b = (const float*)d_in[4];
  const float* ln_s_w = (const float*)d_in[5];
  const float* ln_s_b = (const float*)d_in[6];
  const float* ln_ff_w = (const float*)d_in[7];
  const float* ln_ff_b = (const float*)d_in[8];
  const float* Wq = (const float*)d_in[9];
  const float* bq = (const float*)d_in[10];
  const float* Wk = (const float*)d_in[11];
  const float* bk = (const float*)d_in[12];
  const float* Wv = (const float*)d_in[13];
  const float* bv = (const float*)d_in[14];
  const float* Wc = (const float*)d_in[15];
  const float* bc = (const float*)d_in[16];
  const float* Wih = (const float*)d_in[17];
  const float* bih = (const float*)d_in[18];
  const float* Whh = (const float*)d_in[19];
  const float* bhh = (const float*)d_in[20];
  const float* W1 = (const float*)d_in[21];
  const float* b1 = (const float*)d_in[22];
  const float* W2 = (const float*)d_in[23];
  const float* b2 = (const float*)d_in[24];
  const float* Wkeep = (const float*)d_in[25];
  const float* noise = (const float*)d_in[26];
  const float* g_keep = (const float*)d_in[27];
  const float* g_route = (const float*)d_in[28];
  float* out = (float*)d_out;
  unsigned* inTu = (unsigned*)d_out;   // scratch during iterations; overwritten by k_route_out

  char* wptr = (char*)d_ws;
  auto alloc = [&](size_t bytes) {
    char* p = wptr;
    wptr += (bytes + 255) & ~(size_t)255;
    return p;
  };
  float* mu = (float*)alloc((size_t)Bn * Nn * 4);
  float* rsig = (float*)alloc((size_t)Bn * Nn * 4);
  float* slots = (float*)alloc((size_t)Bn * NSn * Dn * 4);
  float* sln = (float*)alloc((size_t)Bn * NSn * Dn * 4);
  unsigned* qkt = (unsigned*)alloc((size_t)Bn * HIn * Dn * 4);
  float* alpha = (float*)alloc((size_t)Bn * HIn * 4);
  float* beta = (float*)alloc((size_t)Bn * HIn * 4);
  unsigned* Abuf = (unsigned*)alloc((size_t)Bn * HIn * Nn * 4);
  float* Spart = (float*)alloc((size_t)Bn * 64 * HIn * 4);
  float* c1part = (float*)alloc((size_t)Bn * 64 * HIn * 4);
  float* AXp = (float*)alloc((size_t)4 * Bn * HIn * Dn * 4);
  float* updb = (float*)alloc((size_t)Bn * NSn * Dn * 4);
  float* gibuf = (float*)alloc((size_t)Bn * NSn * 1536 * 4);
  float* ghbuf = (float*)alloc((size_t)Bn * NSn * 1536 * 4);
  float* hbuf = (float*)alloc((size_t)Bn * NSn * 2048 * 4);
  float* ffp = (float*)alloc((size_t)4 * 512 * 512 * 4);
  float* T1 = (float*)alloc((size_t)Dn * 1536 * 4);
  float* bcih = (float*)alloc((size_t)1536 * 4);
  float* Ms = (float*)alloc((size_t)Dn * 4096 * 4);
  float* vb_raw = (float*)alloc((size_t)4096 * 4);
  float* vb_s = (float*)alloc((size_t)4096 * 4);
  float* avec = (float*)alloc((size_t)4096 * 4);
  float* bvec = (float*)alloc((size_t)4096 * 4);
  float* aconst = (float*)alloc((size_t)8 * 4);
  float* bconst = (float*)alloc((size_t)8 * 4);
  double* swd = (double*)alloc((size_t)Bn * NSn * 8);
  double* sbd = (double*)alloc((size_t)Bn * NSn * 8);

  // prologue
  k_rowstats<<<Bn * Nn / 4, 256, 0, stream>>>(in, mu, rsig);
  k_tsplit<<<dim3(Nn / 64, Dn / 64, Bn), 256, 0, stream>>>(in, inTu);
  k_slots_init<<<Bn * NSn, 256, 0, stream>>>(slots_mu, slots_ls, noise, slots);
  k_gemm_sm<true, false, false><<<dim3(24, 8), 256, 0, stream>>>(Wc, Wih, nullptr, T1, 1536, 512);
  k_bcih<<<6, 256, 0, stream>>>(bc, Wih, bih, bcih);
  k_mh<<<dim3(8, 8, 8), 256, 0, stream>>>(Wq, Wk, Ms);
  k_vbias<<<2, 256, 0, stream>>>(Wk, bq, ln_in_w, vb_raw, vb_s);
  k_mfold<<<16, 256, 0, stream>>>(Ms, Wq, bk, ln_in_w, ln_in_b, avec, bvec);
  k_consts<<<1, 256, 0, stream>>>(vb_raw, bq, bk, ln_in_w, ln_in_b, aconst, bconst);
  k_ln_rows<<<Bn * NSn, 256, 0, stream>>>(slots, ln_s_w, ln_s_b, sln);

  for (int it = 0; it < 3; ++it) {
    k_qu<<<dim3(64, 8), 256, 0, stream>>>(sln, Ms, vb_s, qkt);
    k_ab<<<Bn * HIn, 64, 0, stream>>>(sln, avec, bvec, aconst, bconst, alpha, beta);
    k_dots<<<dim3(Nn / 128, Bn), 256, 0, stream>>>(in, qkt, alpha, beta, mu, rsig, Abuf, Spart, c1part);
    k_ax<<<dim3(4, 2, Bn), 256, 0, stream>>>(Abuf, inTu, AXp);
    k_updS<<<dim3(HIn, Bn), 256, 0, stream>>>(AXp, Spart, c1part, ln_in_w, ln_in_b, Wv, bv, updb);
    k_gg<<<dim3(24, 8, 2), 256, 0, stream>>>(updb, T1, bcih, slots, Whh, bhh, gibuf, ghbuf);
    k_gruln<<<Bn * NSn, 256, 0, stream>>>(gibuf, ghbuf, slots, sln, ln_ff_w, ln_ff_b);
    k_mm<true, false><<<dim3(32, 8, 1), 256, 0, stream>>>(sln, 512, W1, 2048, b1, hbuf, 2048, 512);
    k_mm<false, true><<<dim3(8, 8, 4), 256, 0, stream>>>(hbuf, 2048, W2, 512, nullptr, ffp, 512, 512);
    k_w2ln<<<Bn * NSn, 256, 0, stream>>>(ffp, b2, slots, sln, ln_s_w, ln_s_b);
  }

  k_keepsc<<<Bn * NSn, 64, 0, stream>>>(Wkeep, g_keep, slots, ln_in_w, ln_in_b, swd, sbd);
  k_route_out<<<dim3(Nn / 128, Bn), 256, 0, stream>>>(in, slots, ln_in_w, swd, sbd, mu, rsig, g_route, out);
}

// Round 11
// 1658.014 us; speedup vs baseline: 2.1509x; 1.0455x over previous
//
#include <hip/hip_runtime.h>
#include <hip/hip_bf16.h>
#include <math.h>

constexpr int Bn = 32, Nn = 4096, Dn = 512, NSn = 16, HIn = 128;
constexpr float kScale = 0.04419417382415922f; // 512^-0.5
constexpr float kEps = 1e-8f;

typedef __attribute__((ext_vector_type(8))) short short8;
typedef __attribute__((ext_vector_type(4))) float f32x4;

__device__ __forceinline__ float wred(float v) {
#pragma unroll
  for (int m = 32; m > 0; m >>= 1) v += __shfl_xor(v, m);
  return v;
}
__device__ __forceinline__ double wredd(double v) {
#pragma unroll
  for (int m = 32; m > 0; m >>= 1) v += __shfl_xor(v, m);
  return v;
}

// ---- bf16 split helpers (RNE) ----
__device__ __forceinline__ unsigned short f2bf(float x) {
  unsigned u = __float_as_uint(x);
  unsigned r = (u + 0x7fffu + ((u >> 16) & 1u)) >> 16;
  return (unsigned short)r;
}
__device__ __forceinline__ float bf2f(unsigned short h) {
  return __uint_as_float(((unsigned)h) << 16);
}
__device__ __forceinline__ unsigned packhm(float x) {
  unsigned short h = f2bf(x);
  unsigned short m = f2bf(x - bf2f(h));
  return (unsigned)h | ((unsigned)m << 16);
}
__device__ __forceinline__ unsigned pack2x(float x0, float x1, unsigned& mo) {
  unsigned p0 = packhm(x0), p1 = packhm(x1);
  mo = (p0 >> 16) | (p1 & 0xffff0000u);
  return (p0 & 0xffffu) | (p1 << 16);
}

// ---------------- per-row LN stats of inputs ----------------
__global__ __launch_bounds__(256) void k_rowstats(const float* __restrict__ in,
                                                  float* __restrict__ mu, float* __restrict__ rsig) {
  int row = blockIdx.x * 4 + (threadIdx.x >> 6);
  int lane = threadIdx.x & 63;
  const float4* p = reinterpret_cast<const float4*>(in + (size_t)row * Dn) + lane * 2;
  float4 a = p[0], b = p[1];
  float s = a.x + a.y + a.z + a.w + b.x + b.y + b.z + b.w;
  float q = a.x*a.x + a.y*a.y + a.z*a.z + a.w*a.w + b.x*b.x + b.y*b.y + b.z*b.z + b.w*b.w;
  s = wred(s); q = wred(q);
  if (lane == 0) {
    float m = s * (1.0f / 512.0f);
    float var = q * (1.0f / 512.0f) - m * m;
    mu[row] = m;
    rsig[row] = 1.0f / sqrtf(var + 1e-5f);
  }
}

// ---------------- transpose + hi/mid split: in -> inT[B,D,N] and Xp[B,N,D] (both u32 h|m) ----------------
__global__ __launch_bounds__(256) void k_tsplit(const float* __restrict__ in, unsigned* __restrict__ inT,
                                                unsigned* __restrict__ Xp) {
  __shared__ float tile[64][65];
  int b = blockIdx.z, j0 = blockIdx.x * 64, d0 = blockIdx.y * 64;
  int t = threadIdx.x;
#pragma unroll
  for (int e = 0; e < 16; ++e) {
    int idx = t + e * 256;
    int r = idx >> 6, c = idx & 63;
    tile[r][c] = in[((size_t)b * Nn + j0 + r) * Dn + d0 + c];
  }
  __syncthreads();
#pragma unroll
  for (int e = 0; e < 16; ++e) {
    int idx = t + e * 256;
    int r = idx >> 6, c = idx & 63;
    inT[((size_t)b * Dn + d0 + r) * Nn + j0 + c] = packhm(tile[c][r]);
    Xp[((size_t)b * Nn + j0 + r) * Dn + d0 + c] = packhm(tile[r][c]);
  }
}

// ---------------- slots init ----------------
__global__ __launch_bounds__(256) void k_slots_init(const float* __restrict__ smu, const float* __restrict__ sls,
                                                    const float* __restrict__ noise, float* __restrict__ slots) {
  int r = blockIdx.x;
  for (int d = threadIdx.x; d < Dn; d += 256)
    slots[(size_t)r * Dn + d] = smu[d] + expf(sls[d]) * noise[(size_t)r * Dn + d];
}

// ---------------- LN of [R,512] rows (prologue) ----------------
__global__ __launch_bounds__(256) void k_ln_rows(const float* __restrict__ src, const float* __restrict__ w,
                                                 const float* __restrict__ b, float* __restrict__ dst) {
  int r = blockIdx.x;
  __shared__ float red[8];
  int t = threadIdx.x;
  float x0 = src[(size_t)r * Dn + t], x1 = src[(size_t)r * Dn + 256 + t];
  float s = x0 + x1, q = x0 * x0 + x1 * x1;
  s = wred(s); q = wred(q);
  if ((t & 63) == 0) { red[t >> 6] = s; red[4 + (t >> 6)] = q; }
  __syncthreads();
  float S = red[0] + red[1] + red[2] + red[3];
  float Q = red[4] + red[5] + red[6] + red[7];
  float m = S * (1.0f / 512.0f);
  float rs = 1.0f / sqrtf(Q * (1.0f / 512.0f) - m * m + 1e-5f);
  dst[(size_t)r * Dn + t] = (x0 - m) * rs * w[t] + b[t];
  dst[(size_t)r * Dn + 256 + t] = (x1 - m) * rs * w[256 + t] + b[256 + t];
}

// ---------------- transpose src[R][C] -> dst[C][R] (prologue, WhhT) ----------------
__global__ __launch_bounds__(256) void k_transp(const float* __restrict__ src, float* __restrict__ dst,
                                                int R, int C) {
  __shared__ float tile[64][65];
  int j0 = blockIdx.x * 64, i0 = blockIdx.y * 64;
  int t = threadIdx.x;
#pragma unroll
  for (int e = 0; e < 16; ++e) {
    int idx = t + e * 256;
    int r = idx >> 6, c = idx & 63;
    tile[r][c] = src[(size_t)(i0 + r) * C + j0 + c];
  }
  __syncthreads();
#pragma unroll
  for (int e = 0; e < 16; ++e) {
    int idx = t + e * 256;
    int r = idx >> 6, c = idx & 63;
    dst[(size_t)(j0 + r) * R + i0 + c] = tile[c][r];
  }
}

// ---------------- small GEMM with register prefetch (f32 path, prologue T1) ----------------
template <bool TRANS, bool RELU, bool ADD>
__global__ __launch_bounds__(256) void k_gemm_sm(const float* __restrict__ A, const float* __restrict__ W,
                                                 const float* __restrict__ bias, float* __restrict__ out,
                                                 int Nc, int K) {
  __shared__ float as_[64][17];
  __shared__ float ws_[16][65];
  int m0 = blockIdx.y * 64, n0 = blockIdx.x * 64;
  int t = threadIdx.x, tx = t & 15, ty = t >> 4;
  float acc[4][4] = {};
  float pa[4], pw[4];
  auto loadA = [&](int k0) {
#pragma unroll
    for (int e = 0; e < 4; ++e) {
      int idx = t + e * 256;
      int r = idx >> 4, c = idx & 15;
      pa[e] = A[(size_t)(m0 + r) * K + k0 + c];
    }
  };
  auto loadW = [&](int k0) {
#pragma unroll
    for (int e = 0; e < 4; ++e) {
      int idx = t + e * 256;
      if (!TRANS) {
        int r = idx >> 6, c = idx & 63;
        pw[e] = W[(size_t)(k0 + r) * Nc + n0 + c];
      } else {
        int r = idx >> 4, c = idx & 15;
        pw[e] = W[(size_t)(n0 + r) * K + k0 + c];
      }
    }
  };
  loadA(0); loadW(0);
  for (int k0 = 0; k0 < K; k0 += 16) {
#pragma unroll
    for (int e = 0; e < 4; ++e) {
      int idx = t + e * 256;
      int r = idx >> 4, c = idx & 15;
      as_[r][c] = pa[e];
    }
#pragma unroll
    for (int e = 0; e < 4; ++e) {
      int idx = t + e * 256;
      if (!TRANS) {
        int r = idx >> 6, c = idx & 63;
        ws_[r][c] = pw[e];
      } else {
        int r = idx >> 4, c = idx & 15;
        ws_[c][r] = pw[e];
      }
    }
    __syncthreads();
    if (k0 + 16 < K) { loadA(k0 + 16); loadW(k0 + 16); }
#pragma unroll
    for (int kc = 0; kc < 16; ++kc) {
      float av[4], wv[4];
#pragma unroll
      for (int i = 0; i < 4; ++i) av[i] = as_[ty * 4 + i][kc];
#pragma unroll
      for (int j = 0; j < 4; ++j) wv[j] = ws_[kc][tx * 4 + j];
#pragma unroll
      for (int i = 0; i < 4; ++i)
#pragma unroll
        for (int j = 0; j < 4; ++j) acc[i][j] += av[i] * wv[j];
    }
    __syncthreads();
  }
#pragma unroll
  for (int i = 0; i < 4; ++i)
#pragma unroll
    for (int j = 0; j < 4; ++j) {
      int m = m0 + ty * 4 + i, n = n0 + tx * 4 + j;
      float v = acc[i][j] + (bias ? bias[n] : 0.0f);
      if (RELU) v = fmaxf(v, 0.0f);
      if (ADD) v += out[(size_t)m * Nc + n];
      out[(size_t)m * Nc + n] = v;
    }
}

// ---------------- split-bf16 MFMA small GEMM: 64m x 64n tiles, K runtime ----------------
template <bool RELU, bool PARTIAL>
__global__ __launch_bounds__(256) void k_mm(const float* __restrict__ A, int lda,
                                            const float* __restrict__ W, int ldw,
                                            const float* __restrict__ bias,
                                            float* __restrict__ out, int ldo, int K) {
  __shared__ __align__(16) unsigned short as_h[64][40];
  __shared__ __align__(16) unsigned short as_m[64][40];
  __shared__ __align__(16) unsigned short ws_h[64][40];
  __shared__ __align__(16) unsigned short ws_m[64][40];
  int n0 = blockIdx.x * 64, m0 = blockIdx.y * 64, kbase = blockIdx.z * K;
  int t = threadIdx.x, w = t >> 6, l = t & 63;
  int lc = l & 15, lg = l >> 4, koff = lg * 8;

  f32x4 acc[4];
#pragma unroll
  for (int s = 0; s < 4; ++s) acc[s] = {0.0f, 0.0f, 0.0f, 0.0f};

  float2 na[4];
  float nw0[4], nw1[4];
  auto loadA = [&](int k0) {
#pragma unroll
    for (int e = 0; e < 4; ++e) {
      int idx = t + e * 256;
      int m = idx >> 4, kp = (idx & 15) * 2;
      na[e] = *reinterpret_cast<const float2*>(&A[(size_t)(m0 + m) * lda + kbase + k0 + kp]);
    }
  };
  auto loadW = [&](int k0) {
#pragma unroll
    for (int e = 0; e < 4; ++e) {
      int idx = t + e * 256;
      int kp = idx >> 6, n = idx & 63;
      nw0[e] = W[(size_t)(kbase + k0 + 2 * kp) * ldw + n0 + n];
      nw1[e] = W[(size_t)(kbase + k0 + 2 * kp + 1) * ldw + n0 + n];
    }
  };
  loadA(0); loadW(0);

  for (int k0 = 0; k0 < K; k0 += 32) {
#pragma unroll
    for (int e = 0; e < 4; ++e) {
      int idx = t + e * 256;
      int m = idx >> 4, kp = (idx & 15) * 2;
      unsigned mm;
      unsigned hm = pack2x(na[e].x, na[e].y, mm);
      *reinterpret_cast<unsigned*>(&as_h[m][kp]) = hm;
      *reinterpret_cast<unsigned*>(&as_m[m][kp]) = mm;
    }
#pragma unroll
    for (int e = 0; e < 4; ++e) {
      int idx = t + e * 256;
      int kp = idx >> 6, n = idx & 63;
      unsigned mm;
      unsigned hm = pack2x(nw0[e], nw1[e], mm);
      *reinterpret_cast<unsigned*>(&ws_h[n][kp * 2]) = hm;
      *reinterpret_cast<unsigned*>(&ws_m[n][kp * 2]) = mm;
    }
    __syncthreads();
    if (k0 + 32 < K) { loadA(k0 + 32); loadW(k0 + 32); }
    short8 ah = *reinterpret_cast<const short8*>(&as_h[w * 16 + lc][koff]);
    short8 am = *reinterpret_cast<const short8*>(&as_m[w * 16 + lc][koff]);
#pragma unroll
    for (int s = 0; s < 4; ++s) {
      short8 bh = *reinterpret_cast<const short8*>(&ws_h[s * 16 + lc][koff]);
      short8 bm = *reinterpret_cast<const short8*>(&ws_m[s * 16 + lc][koff]);
      acc[s] = __builtin_amdgcn_mfma_f32_16x16x32_bf16(ah, bh, acc[s], 0, 0, 0);
      acc[s] = __builtin_amdgcn_mfma_f32_16x16x32_bf16(ah, bm, acc[s], 0, 0, 0);
      acc[s] = __builtin_amdgcn_mfma_f32_16x16x32_bf16(am, bh, acc[s], 0, 0, 0);
    }
    __syncthreads();
  }

#pragma unroll
  for (int s = 0; s < 4; ++s) {
#pragma unroll
    for (int r = 0; r < 4; ++r) {
      int m = m0 + w * 16 + lg * 4 + r;
      int n = n0 + s * 16 + lc;
      float v = acc[s][r] + (bias ? bias[n] : 0.0f);
      if (RELU) v = fmaxf(v, 0.0f);
      if (PARTIAL)
        out[((size_t)blockIdx.z * 512 + m) * 512 + n] = v;
      else
        out[(size_t)m * ldo + n] = v;
    }
  }
}

// ---------------- qkt = sln @ Ms + vb_s via MFMA, packed epilogue (remap to [b,hi,d]) ----------------
__global__ __launch_bounds__(256) void k_qum(const float* __restrict__ A, const float* __restrict__ Ms,
                                             const float* __restrict__ vb_s, unsigned* __restrict__ qkt) {
  __shared__ __align__(16) unsigned short as_h[64][40];
  __shared__ __align__(16) unsigned short as_m[64][40];
  __shared__ __align__(16) unsigned short ws_h[64][40];
  __shared__ __align__(16) unsigned short ws_m[64][40];
  int n0 = blockIdx.x * 64, m0 = blockIdx.y * 64;
  int t = threadIdx.x, w = t >> 6, l = t & 63;
  int lc = l & 15, lg = l >> 4, koff = lg * 8;

  f32x4 acc[4];
#pragma unroll
  for (int s = 0; s < 4; ++s) acc[s] = {0.0f, 0.0f, 0.0f, 0.0f};

  float2 na[4];
  float nw0[4], nw1[4];
  auto loadA = [&](int k0) {
#pragma unroll
    for (int e = 0; e < 4; ++e) {
      int idx = t + e * 256;
      int m = idx >> 4, kp = (idx & 15) * 2;
      na[e] = *reinterpret_cast<const float2*>(&A[(size_t)(m0 + m) * 512 + k0 + kp]);
    }
  };
  auto loadW = [&](int k0) {
#pragma unroll
    for (int e = 0; e < 4; ++e) {
      int idx = t + e * 256;
      int kp = idx >> 6, n = idx & 63;
      nw0[e] = Ms[(size_t)(k0 + 2 * kp) * 4096 + n0 + n];
      nw1[e] = Ms[(size_t)(k0 + 2 * kp + 1) * 4096 + n0 + n];
    }
  };
  loadA(0); loadW(0);

  for (int k0 = 0; k0 < 512; k0 += 32) {
#pragma unroll
    for (int e = 0; e < 4; ++e) {
      int idx = t + e * 256;
      int m = idx >> 4, kp = (idx & 15) * 2;
      unsigned mm;
      unsigned hm = pack2x(na[e].x, na[e].y, mm);
      *reinterpret_cast<unsigned*>(&as_h[m][kp]) = hm;
      *reinterpret_cast<unsigned*>(&as_m[m][kp]) = mm;
    }
#pragma unroll
    for (int e = 0; e < 4; ++e) {
      int idx = t + e * 256;
      int kp = idx >> 6, n = idx & 63;
      unsigned mm;
      unsigned hm = pack2x(nw0[e], nw1[e], mm);
      *reinterpret_cast<unsigned*>(&ws_h[n][kp * 2]) = hm;
      *reinterpret_cast<unsigned*>(&ws_m[n][kp * 2]) = mm;
    }
    __syncthreads();
    if (k0 + 32 < 512) { loadA(k0 + 32); loadW(k0 + 32); }
    short8 ah = *reinterpret_cast<const short8*>(&as_h[w * 16 + lc][koff]);
    short8 am = *reinterpret_cast<const short8*>(&as_m[w * 16 + lc][koff]);
#pragma unroll
    for (int s = 0; s < 4; ++s) {
      short8 bh = *reinterpret_cast<const short8*>(&ws_h[s * 16 + lc][koff]);
      short8 bm = *reinterpret_cast<const short8*>(&ws_m[s * 16 + lc][koff]);
      acc[s] = __builtin_amdgcn_mfma_f32_16x16x32_bf16(ah, bh, acc[s], 0, 0, 0);
      acc[s] = __builtin_amdgcn_mfma_f32_16x16x32_bf16(ah, bm, acc[s], 0, 0, 0);
      acc[s] = __builtin_amdgcn_mfma_f32_16x16x32_bf16(am, bh, acc[s], 0, 0, 0);
    }
    __syncthreads();
  }

#pragma unroll
  for (int s = 0; s < 4; ++s) {
#pragma unroll
    for (int r = 0; r < 4; ++r) {
      int m = m0 + w * 16 + lg * 4 + r;
      int n = n0 + s * 16 + lc;
      int bb = m >> 4, isl = m & 15, h = n >> 9, d = n & 511;
      qkt[((size_t)bb * HIn + h * 16 + isl) * Dn + d] = packhm(acc[s][r] + vb_s[n]);
    }
  }
}

// ---------------- W2 reduce + bias + residual + LN_s fused -> slots, sln ----------------
__global__ __launch_bounds__(256) void k_w2ln(const float* __restrict__ part, const float* __restrict__ b2,
                                              float* __restrict__ slots, float* __restrict__ sln,
                                              const float* __restrict__ lnsw, const float* __restrict__ lnsb) {
  int r = blockIdx.x, t = threadIdx.x;
  __shared__ float red[8];
  float sn[2];
#pragma unroll
  for (int j = 0; j < 2; ++j) {
    int c = j * 256 + t;
    size_t idx = (size_t)r * 512 + c;
    sn[j] = part[idx] + part[262144 + idx] + part[2 * 262144 + idx] + part[3 * 262144 + idx]
          + b2[c] + slots[idx];
  }
  float s = sn[0] + sn[1], q = sn[0] * sn[0] + sn[1] * sn[1];
  s = wred(s); q = wred(q);
  if ((t & 63) == 0) { red[t >> 6] = s; red[4 + (t >> 6)] = q; }
  __syncthreads();
  float S = red[0] + red[1] + red[2] + red[3];
  float Q = red[4] + red[5] + red[6] + red[7];
  float m = S * (1.0f / 512.0f);
  float rs = 1.0f / sqrtf(Q * (1.0f / 512.0f) - m * m + 1e-5f);
#pragma unroll
  for (int j = 0; j < 2; ++j) {
    int c = j * 256 + t;
    size_t idx = (size_t)r * 512 + c;
    slots[idx] = sn[j];
    sln[idx] = (sn[j] - m) * rs * lnsw[c] + lnsb[c];
  }
}

// ---------------- M_h = Wq_h @ Wk_h^T per head (raw) -> Ms[k*4096 + h*512 + d] ----------------
__global__ __launch_bounds__(256) void k_mh(const float* __restrict__ Wq, const float* __restrict__ Wk,
                                            float* __restrict__ Ms) {
  int h = blockIdx.z, k0 = blockIdx.y * 64, d0 = blockIdx.x * 64;
  __shared__ float qa[64][65];
  __shared__ float ka[64][65];
  int t = threadIdx.x, tx = t & 15, ty = t >> 4;
#pragma unroll
  for (int e = 0; e < 16; ++e) {
    int idx = t + e * 256;
    int r = idx >> 6, c = idx & 63;
    qa[c][r] = Wq[(size_t)(k0 + r) * Dn + h * 64 + c];
    ka[c][r] = Wk[(size_t)(d0 + r) * Dn + h * 64 + c];
  }
  __syncthreads();
  float acc[4][4] = {};
#pragma unroll 4
  for (int c = 0; c < 64; ++c) {
    float av[4], bv[4];
#pragma unroll
    for (int i = 0; i < 4; ++i) av[i] = qa[c][ty * 4 + i];
#pragma unroll
    for (int j = 0; j < 4; ++j) bv[j] = ka[c][tx * 4 + j];
#pragma unroll
    for (int i = 0; i < 4; ++i)
#pragma unroll
      for (int j = 0; j < 4; ++j) acc[i][j] += av[i] * bv[j];
  }
#pragma unroll
  for (int i = 0; i < 4; ++i)
#pragma unroll
    for (int j = 0; j < 4; ++j)
      Ms[(size_t)(k0 + ty * 4 + i) * 4096 + h * 512 + d0 + tx * 4 + j] = acc[i][j];
}

// ---------------- vbias_h[d] = Wk[d, h64:]·bq[h64:]; raw + scaled ----------------
__global__ __launch_bounds__(256) void k_vbias(const float* __restrict__ Wk, const float* __restrict__ bq,
                                               const float* __restrict__ lnw, float* __restrict__ vb_raw,
                                               float* __restrict__ vb_s) {
  __shared__ float bqs[512];
  int t = threadIdx.x;
  bqs[t] = bq[t]; bqs[256 + t] = bq[256 + t];
  __syncthreads();
  int d = blockIdx.x * 256 + t;
  float vb[8] = {};
  const float4* wr = reinterpret_cast<const float4*>(Wk + (size_t)d * Dn);
#pragma unroll 8
  for (int c4 = 0; c4 < 128; ++c4) {
    float4 wv = wr[c4];
    int h = c4 >> 4;
    int c = c4 * 4;
    vb[h] += wv.x * bqs[c] + wv.y * bqs[c + 1] + wv.z * bqs[c + 2] + wv.w * bqs[c + 3];
  }
  float lw = lnw[d];
#pragma unroll
  for (int h = 0; h < 8; ++h) {
    vb_raw[h * 512 + d] = vb[h];
    vb_s[h * 512 + d] = kScale * lw * vb[h];
  }
}

// ---------------- fold: scale Ms in place by kScale*lnw[d]; avec/bvec ----------------
__global__ __launch_bounds__(256) void k_mfold(float* __restrict__ Ms, const float* __restrict__ Wq,
                                               const float* __restrict__ bk, const float* __restrict__ lnw,
                                               const float* __restrict__ lnb, float* __restrict__ avec,
                                               float* __restrict__ bvec) {
  __shared__ float lws[512], lbs[512], bks[512];
  int t = threadIdx.x;
  lws[t] = lnw[t]; lws[256 + t] = lnw[256 + t];
  lbs[t] = lnb[t]; lbs[256 + t] = lnb[256 + t];
  bks[t] = bk[t]; bks[256 + t] = bk[256 + t];
  __syncthreads();
  int g = blockIdx.x * 256 + t;
  int k = g >> 3, h = g & 7;
  float* mr = Ms + (size_t)k * 4096 + h * 512;
  float mlnb = 0.0f, mlnw = 0.0f;
  for (int d = 0; d < 512; d += 4) {
    float4 m4 = *reinterpret_cast<const float4*>(mr + d);
    mlnb += m4.x * lbs[d] + m4.y * lbs[d + 1] + m4.z * lbs[d + 2] + m4.w * lbs[d + 3];
    mlnw += m4.x * lws[d] + m4.y * lws[d + 1] + m4.z * lws[d + 2] + m4.w * lws[d + 3];
    float4 o4 = {m4.x * kScale * lws[d], m4.y * kScale * lws[d + 1],
                 m4.z * kScale * lws[d + 2], m4.w * kScale * lws[d + 3]};
    *reinterpret_cast<float4*>(mr + d) = o4;
  }
  float wqdot = 0.0f;
  const float* qr = Wq + (size_t)k * Dn + h * 64;
  for (int c = 0; c < 64; c += 4) {
    float4 q4 = *reinterpret_cast<const float4*>(qr + c);
    wqdot += q4.x * bks[h * 64 + c] + q4.y * bks[h * 64 + c + 1] +
             q4.z * bks[h * 64 + c + 2] + q4.w * bks[h * 64 + c + 3];
  }
  avec[h * 512 + k] = kScale * (mlnb + wqdot);
  bvec[h * 512 + k] = kScale * mlnw;
}

// ---------------- aconst/bconst scalars ----------------
__global__ __launch_bounds__(256) void k_consts(const float* __restrict__ vb_raw, const float* __restrict__ bq,
                                                const float* __restrict__ bk, const float* __restrict__ lnw,
                                                const float* __restrict__ lnb, float* __restrict__ aconst,
                                                float* __restrict__ bconst) {
  __shared__ float r1[256], r2[256], r3[256];
  int t = threadIdx.x;
  for (int h = 0; h < 8; ++h) {
    float p1 = 0.0f, p2 = 0.0f, p3 = 0.0f;
    for (int d = t; d < 512; d += 256) {
      float vr = vb_raw[h * 512 + d];
      p1 += lnb[d] * vr;
      p2 += lnw[d] * vr;
    }
    if (t < 64) p3 = bq[h * 64 + t] * bk[h * 64 + t];
    r1[t] = p1; r2[t] = p2; r3[t] = p3;
    __syncthreads();
    for (int s = 128; s > 0; s >>= 1) {
      if (t < s) { r1[t] += r1[t + s]; r2[t] += r2[t + s]; r3[t] += r3[t + s]; }
      __syncthreads();
    }
    if (t == 0) {
      aconst[h] = kScale * (r1[0] + r3[0]);
      bconst[h] = kScale * r2[0];
    }
    __syncthreads();
  }
}

// ---------------- bcih[n] = bc·Wih[n,:] + bih[n] ----------------
__global__ __launch_bounds__(256) void k_bcih(const float* __restrict__ bc, const float* __restrict__ Wih,
                                              const float* __restrict__ bih, float* __restrict__ bcih) {
  __shared__ float bcs[512];
  int t = threadIdx.x;
  bcs[t] = bc[t]; bcs[256 + t] = bc[256 + t];
  __syncthreads();
  int n = blockIdx.x * 256 + t;
  const float4* wr = reinterpret_cast<const float4*>(Wih + (size_t)n * Dn);
  float a = 0.0f;
#pragma unroll 8
  for (int c4 = 0; c4 < 128; ++c4) {
    float4 wv = wr[c4];
    int c = c4 * 4;
    a += wv.x * bcs[c] + wv.y * bcs[c + 1] + wv.z * bcs[c + 2] + wv.w * bcs[c + 3];
  }
  bcih[n] = a + bih[n];
}

// ---------------- alpha/beta = sln·avec_h + aconst_h ----------------
__global__ void k_ab(const float* __restrict__ sln, const float* __restrict__ avec,
                     const float* __restrict__ bvec, const float* __restrict__ aconst,
                     const float* __restrict__ bconst, float* __restrict__ alpha,
                     float* __restrict__ beta) {
  int g = blockIdx.x;           // b*128 + hi
  int hi = g & 127, b = g >> 7;
  int h = hi >> 4, i = hi & 15;
  int lane = threadIdx.x;
  const float4* sp = reinterpret_cast<const float4*>(sln + (size_t)(b * NSn + i) * Dn) + lane * 2;
  const float4* ap = reinterpret_cast<const float4*>(avec + h * 512) + lane * 2;
  const float4* bp = reinterpret_cast<const float4*>(bvec + h * 512) + lane * 2;
  float4 s0 = sp[0], s1 = sp[1], a0 = ap[0], a1 = ap[1], b0 = bp[0], b1 = bp[1];
  float pa = s0.x*a0.x + s0.y*a0.y + s0.z*a0.z + s0.w*a0.w + s1.x*a1.x + s1.y*a1.y + s1.z*a1.z + s1.w*a1.w;
  float pb = s0.x*b0.x + s0.y*b0.y + s0.z*b0.z + s0.w*b0.w + s1.x*b1.x + s1.y*b1.y + s1.z*b1.z + s1.w*b1.w;
  pa = wred(pa); pb = wred(pb);
  if (lane == 0) {
    alpha[g] = pa + aconst[h];
    beta[g] = pb + bconst[h];
  }
}

// ---------------- dots via 2-level bf16-split MFMA (3 passes) + in-register softmax ----------------
// BOTH operands arrive pre-packed (Xp, qkt): staging is pure bitops.
__global__ __launch_bounds__(256) void k_dots(const unsigned* __restrict__ Xp, const unsigned* __restrict__ qkt,
                                              const float* __restrict__ alpha, const float* __restrict__ beta,
                                              const float* __restrict__ mu, const float* __restrict__ rsig,
                                              unsigned* __restrict__ A, float* __restrict__ Spart,
                                              float* __restrict__ c1part) {
  __shared__ __align__(16) unsigned short xs_h[128][40];
  __shared__ __align__(16) unsigned short xs_m[128][40];
  __shared__ __align__(16) unsigned short us_h[128][40];
  __shared__ __align__(16) unsigned short us_m[128][40];   // 40960 B

  int b = blockIdx.y, jt = blockIdx.x, j0 = jt * 128;
  int t = threadIdx.x, w = t >> 6, l = t & 63;
  int lc = l & 15, lg = l >> 4, koff = lg * 8;
  const size_t inbase = ((size_t)b * Nn + j0) * Dn;
  const size_t ubase = (size_t)b * HIn * Dn;

  f32x4 acc[2][8];
#pragma unroll
  for (int i = 0; i < 2; ++i)
#pragma unroll
    for (int j2 = 0; j2 < 8; ++j2) acc[i][j2] = {0.0f, 0.0f, 0.0f, 0.0f};

  uint2 nx[8], nu[8];
#pragma unroll
  for (int e = 0; e < 8; ++e) {
    int idx = t + e * 256;
    int j = idx >> 4, kp = (idx & 15) * 2;
    nx[e] = *reinterpret_cast<const uint2*>(&Xp[inbase + (size_t)j * Dn + kp]);
    nu[e] = *reinterpret_cast<const uint2*>(&qkt[ubase + (size_t)j * Dn + kp]);
  }

  for (int k0 = 0; k0 < 512; k0 += 32) {
#pragma unroll
    for (int e = 0; e < 8; ++e) {
      int idx = t + e * 256;
      int j = idx >> 4, kp = (idx & 15) * 2;
      unsigned xh = (nx[e].x & 0xffffu) | (nx[e].y << 16);
      unsigned xm = (nx[e].x >> 16) | (nx[e].y & 0xffff0000u);
      *reinterpret_cast<unsigned*>(&xs_h[j][kp]) = xh;
      *reinterpret_cast<unsigned*>(&xs_m[j][kp]) = xm;
      unsigned uh = (nu[e].x & 0xffffu) | (nu[e].y << 16);
      unsigned um = (nu[e].x >> 16) | (nu[e].y & 0xffff0000u);
      *reinterpret_cast<unsigned*>(&us_h[j][kp]) = uh;
      *reinterpret_cast<unsigned*>(&us_m[j][kp]) = um;
    }
    if (k0 + 32 < 512) {
#pragma unroll
      for (int e = 0; e < 8; ++e) {
        int idx = t + e * 256;
        int j = idx >> 4, kp = (idx & 15) * 2;
        nx[e] = *reinterpret_cast<const uint2*>(&Xp[inbase + (size_t)j * Dn + k0 + 32 + kp]);
        nu[e] = *reinterpret_cast<const uint2*>(&qkt[ubase + (size_t)j * Dn + k0 + 32 + kp]);
      }
    }
    __syncthreads();
    short8 ah0 = *reinterpret_cast<const short8*>(&xs_h[w * 32 + lc][koff]);
    short8 am0 = *reinterpret_cast<const short8*>(&xs_m[w * 32 + lc][koff]);
    short8 ah1 = *reinterpret_cast<const short8*>(&xs_h[w * 32 + 16 + lc][koff]);
    short8 am1 = *reinterpret_cast<const short8*>(&xs_m[w * 32 + 16 + lc][koff]);
#pragma unroll
    for (int ht = 0; ht < 8; ++ht) {
      short8 bh = *reinterpret_cast<const short8*>(&us_h[ht * 16 + lc][koff]);
      short8 bm = *reinterpret_cast<const short8*>(&us_m[ht * 16 + lc][koff]);
      acc[0][ht] = __builtin_amdgcn_mfma_f32_16x16x32_bf16(ah0, bh, acc[0][ht], 0, 0, 0);
      acc[0][ht] = __builtin_amdgcn_mfma_f32_16x16x32_bf16(ah0, bm, acc[0][ht], 0, 0, 0);
      acc[0][ht] = __builtin_amdgcn_mfma_f32_16x16x32_bf16(am0, bh, acc[0][ht], 0, 0, 0);
      acc[1][ht] = __builtin_amdgcn_mfma_f32_16x16x32_bf16(ah1, bh, acc[1][ht], 0, 0, 0);
      acc[1][ht] = __builtin_amdgcn_mfma_f32_16x16x32_bf16(ah1, bm, acc[1][ht], 0, 0, 0);
      acc[1][ht] = __builtin_amdgcn_mfma_f32_16x16x32_bf16(am1, bh, acc[1][ht], 0, 0, 0);
    }
    __syncthreads();
  }

  float* rsL = reinterpret_cast<float*>(&xs_h[0][0]);
  float* muL = rsL + 128;
  float* aL = rsL + 256;
  float* bL = rsL + 384;
  float (*sredS)[128] = reinterpret_cast<float(*)[128]>(rsL + 512);
  float (*sredC)[128] = reinterpret_cast<float(*)[128]>(rsL + 512 + 4 * 128);
  if (t < 128) {
    rsL[t] = rsig[(size_t)b * Nn + j0 + t];
    muL[t] = mu[(size_t)b * Nn + j0 + t];
    aL[t] = alpha[b * HIn + t];
    bL[t] = beta[b * HIn + t];
  }
  __syncthreads();

  float sS[8] = {}, sC[8] = {};
#pragma unroll
  for (int jt2 = 0; jt2 < 2; ++jt2) {
    int jbase = w * 32 + jt2 * 16 + lg * 4;
#pragma unroll
    for (int ht = 0; ht < 8; ++ht) {
      int hi = ht * 16 + lc;
      float av = aL[hi], bv = bL[hi];
      float v[4], rs4[4], mr4[4];
#pragma unroll
      for (int r = 0; r < 4; ++r) {
        int jr = jbase + r;
        rs4[r] = rsL[jr];
        mr4[r] = muL[jr] * rs4[r];
        v[r] = acc[jt2][ht][r] * rs4[r] + av - mr4[r] * bv;
      }
      float mx[4] = {v[0], v[1], v[2], v[3]};
#pragma unroll
      for (int m = 1; m <= 8; m <<= 1)
#pragma unroll
        for (int r = 0; r < 4; ++r) mx[r] = fmaxf(mx[r], __shfl_xor(mx[r], m));
      float e4[4], ss[4];
#pragma unroll
      for (int r = 0; r < 4; ++r) { e4[r] = expf(v[r] - mx[r]); ss[r] = e4[r]; }
#pragma unroll
      for (int m = 1; m <= 8; m <<= 1)
#pragma unroll
        for (int r = 0; r < 4; ++r) ss[r] += __shfl_xor(ss[r], m);
      float ps = 0.0f, pc = 0.0f;
      float p0 = e4[0] / ss[0] + kEps, p1 = e4[1] / ss[1] + kEps;
      float p2 = e4[2] / ss[2] + kEps, p3 = e4[3] / ss[3] + kEps;
      uint4 o4;
      o4.x = packhm(p0 * rs4[0]); o4.y = packhm(p1 * rs4[1]);
      o4.z = packhm(p2 * rs4[2]); o4.w = packhm(p3 * rs4[3]);
      ps = p0 + p1 + p2 + p3;
      pc = p0 * mr4[0] + p1 * mr4[1] + p2 * mr4[2] + p3 * mr4[3];
      *reinterpret_cast<uint4*>(&A[(size_t)(b * HIn + hi) * Nn + j0 + jbase]) = o4;
      ps += __shfl_xor(ps, 16); ps += __shfl_xor(ps, 32);
      pc += __shfl_xor(pc, 16); pc += __shfl_xor(pc, 32);
      sS[ht] += ps; sC[ht] += pc;
    }
  }
  if (l < 16) {
#pragma unroll
    for (int ht = 0; ht < 8; ++ht) {
      sredS[w][ht * 16 + l] = sS[ht];
      sredC[w][ht * 16 + l] = sC[ht];
    }
  }
  __syncthreads();
  if (t < 128) {
    float s_ = sredS[0][t] + sredS[1][t] + sredS[2][t] + sredS[3][t];
    float c_ = sredC[0][t] + sredC[1][t] + sredC[2][t] + sredC[3][t];
    int sub = (b * 32 + jt) * HIn + t;
    Spart[sub] = s_;
    c1part[sub] = c_;
  }
}

// ---------------- AX = A @ X via 2-level bf16-split MFMA (K-split x2) ----------------
__global__ __launch_bounds__(256) void k_ax(const unsigned* __restrict__ Au, const unsigned* __restrict__ inT,
                                            float* __restrict__ AXp) {
  __shared__ __align__(16) unsigned short as_h[128][40];
  __shared__ __align__(16) unsigned short as_m[128][40];
  __shared__ __align__(16) unsigned short xs_h[128][40];
  __shared__ __align__(16) unsigned short xs_m[128][40];

  int d0 = blockIdx.x * 128, kp = blockIdx.y, b = blockIdx.z;
  int t = threadIdx.x, w = t >> 6, l = t & 63;
  int lc = l & 15, lg = l >> 4, koff = lg * 8;
  const size_t abase = (size_t)b * HIn * Nn + kp * 2048;
  const size_t xbase = ((size_t)b * Dn + d0) * Nn + kp * 2048;

  f32x4 acc[2][8];
#pragma unroll
  for (int i = 0; i < 2; ++i)
#pragma unroll
    for (int j2 = 0; j2 < 8; ++j2) acc[i][j2] = {0.0f, 0.0f, 0.0f, 0.0f};

  uint2 pa[8];
  uint4 px[4];
#pragma unroll
  for (int e = 0; e < 8; ++e) {
    int idx = t + e * 256;
    int hi = idx >> 4, jp = (idx & 15) * 2;
    pa[e] = *reinterpret_cast<const uint2*>(&Au[abase + (size_t)hi * Nn + jp]);
  }
#pragma unroll
  for (int e = 0; e < 4; ++e) {
    int idx = t + e * 256;
    int d = idx >> 3, jg = idx & 7;
    px[e] = *reinterpret_cast<const uint4*>(&inT[xbase + (size_t)d * Nn + jg * 4]);
  }

  for (int c0 = 0; c0 < 2048; c0 += 32) {
#pragma unroll
    for (int e = 0; e < 8; ++e) {
      int idx = t + e * 256;
      int hi = idx >> 4, jp = (idx & 15) * 2;
      unsigned h = (pa[e].x & 0xffffu) | (pa[e].y << 16);
      unsigned m = (pa[e].x >> 16) | (pa[e].y & 0xffff0000u);
      *reinterpret_cast<unsigned*>(&as_h[hi][jp]) = h;
      *reinterpret_cast<unsigned*>(&as_m[hi][jp]) = m;
    }
#pragma unroll
    for (int e = 0; e < 4; ++e) {
      int idx = t + e * 256;
      int d = idx >> 3, jg = idx & 7;
      unsigned h0 = (px[e].x & 0xffffu) | (px[e].y << 16);
      unsigned h1 = (px[e].z & 0xffffu) | (px[e].w << 16);
      unsigned m0 = (px[e].x >> 16) | (px[e].y & 0xffff0000u);
      unsigned m1 = (px[e].z >> 16) | (px[e].w & 0xffff0000u);
      uint2 hv = {h0, h1}, mv = {m0, m1};
      *reinterpret_cast<uint2*>(&xs_h[d][jg * 4]) = hv;
      *reinterpret_cast<uint2*>(&xs_m[d][jg * 4]) = mv;
    }
    if (c0 + 32 < 2048) {
#pragma unroll
      for (int e = 0; e < 8; ++e) {
        int idx = t + e * 256;
        int hi = idx >> 4, jp = (idx & 15) * 2;
        pa[e] = *reinterpret_cast<const uint2*>(&Au[abase + (size_t)hi * Nn + c0 + 32 + jp]);
      }
#pragma unroll
      for (int e = 0; e < 4; ++e) {
        int idx = t + e * 256;
        int d = idx >> 3, jg = idx & 7;
        px[e] = *reinterpret_cast<const uint4*>(&inT[xbase + (size_t)d * Nn + c0 + 32 + jg * 4]);
      }
    }
    __syncthreads();
    short8 ah0 = *reinterpret_cast<const short8*>(&as_h[w * 32 + lc][koff]);
    short8 am0 = *reinterpret_cast<const short8*>(&as_m[w * 32 + lc][koff]);
    short8 ah1 = *reinterpret_cast<const short8*>(&as_h[w * 32 + 16 + lc][koff]);
    short8 am1 = *reinterpret_cast<const short8*>(&as_m[w * 32 + 16 + lc][koff]);
#pragma unroll
    for (int dt = 0; dt < 8; ++dt) {
      short8 bh = *reinterpret_cast<const short8*>(&xs_h[dt * 16 + lc][koff]);
      short8 bm = *reinterpret_cast<const short8*>(&xs_m[dt * 16 + lc][koff]);
      acc[0][dt] = __builtin_amdgcn_mfma_f32_16x16x32_bf16(ah0, bh, acc[0][dt], 0, 0, 0);
      acc[0][dt] = __builtin_amdgcn_mfma_f32_16x16x32_bf16(ah0, bm, acc[0][dt], 0, 0, 0);
      acc[0][dt] = __builtin_amdgcn_mfma_f32_16x16x32_bf16(am0, bh, acc[0][dt], 0, 0, 0);
      acc[1][dt] = __builtin_amdgcn_mfma_f32_16x16x32_bf16(ah1, bh, acc[1][dt], 0, 0, 0);
      acc[1][dt] = __builtin_amdgcn_mfma_f32_16x16x32_bf16(ah1, bm, acc[1][dt], 0, 0, 0);
      acc[1][dt] = __builtin_amdgcn_mfma_f32_16x16x32_bf16(am1, bh, acc[1][dt], 0, 0, 0);
    }
    __syncthreads();
  }

  const size_t obase = (((size_t)kp * Bn + b) * HIn) * Dn + d0;
#pragma unroll
  for (int jt2 = 0; jt2 < 2; ++jt2) {
#pragma unroll
    for (int dt = 0; dt < 8; ++dt) {
#pragma unroll
      for (int r = 0; r < 4; ++r) {
        int hi = w * 32 + jt2 * 16 + lg * 4 + r;
        int d = dt * 16 + lc;
        AXp[obase + (size_t)hi * Dn + d] = acc[jt2][dt][r];
      }
    }
  }
}

// ---------------- upd = ((w*(G-c1)/S + b) @ Wv_h) + bv, S/c1 reduced inline ----------------
__global__ __launch_bounds__(256) void k_updS(const float* __restrict__ AXp, const float* __restrict__ Spart,
                                              const float* __restrict__ c1part, const float* __restrict__ lnw,
                                              const float* __restrict__ lnb, const float* __restrict__ Wv,
                                              const float* __restrict__ bv, float* __restrict__ upd) {
  int b = blockIdx.y, hi = blockIdx.x, h = hi >> 4, i = hi & 15;
  __shared__ float vx[512];
  __shared__ float red[256];
  __shared__ float sSC[2];
  int t = threadIdx.x;
  if (t < 64) {
    float vs = 0.0f, vc = 0.0f;
    if (t < 32) {
      vs = Spart[(size_t)(b * 32 + t) * HIn + hi];
      vc = c1part[(size_t)(b * 32 + t) * HIn + hi];
    }
    vs = wred(vs); vc = wred(vc);
    if (t == 0) { sSC[0] = vs; sSC[1] = vc; }
  }
  __syncthreads();
  float c1v = sSC[1];
  float invS = 1.0f / sSC[0];
  for (int d = t; d < Dn; d += 256) {
    float G = AXp[((size_t)(0 * Bn + b) * HIn + hi) * Dn + d]
            + AXp[((size_t)(1 * Bn + b) * HIn + hi) * Dn + d];
    vx[d] = lnw[d] * (G - c1v) * invS + lnb[d];
  }
  __syncthreads();
  int cc = t & 63, qd = t >> 6;
  float p = 0.0f;
  for (int d = qd * 128; d < qd * 128 + 128; ++d) p += vx[d] * Wv[(size_t)d * Dn + h * 64 + cc];
  red[t] = p;
  __syncthreads();
  if (qd == 0) {
    float v = red[cc] + red[64 + cc] + red[128 + cc] + red[192 + cc] + bv[h * 64 + cc];
    upd[(size_t)(b * NSn + i) * Dn + h * 64 + cc] = v;
  }
}

// ---------------- GRU pointwise + LN_ff fused ----------------
__global__ __launch_bounds__(256) void k_gruln(const float* __restrict__ gi, const float* __restrict__ gh,
                                               float* __restrict__ slots, float* __restrict__ slnff,
                                               const float* __restrict__ lnffw, const float* __restrict__ lnffb) {
  int r = blockIdx.x, t = threadIdx.x;
  __shared__ float red[8];
  float sn[2];
#pragma unroll
  for (int j = 0; j < 2; ++j) {
    int c = j * 256 + t;
    float gir = gi[(size_t)r * 1536 + c];
    float giz = gi[(size_t)r * 1536 + 512 + c];
    float gin = gi[(size_t)r * 1536 + 1024 + c];
    float ghr = gh[(size_t)r * 1536 + c];
    float ghz = gh[(size_t)r * 1536 + 512 + c];
    float ghn = gh[(size_t)r * 1536 + 1024 + c];
    float rg = 1.0f / (1.0f + expf(-(gir + ghr)));
    float zg = 1.0f / (1.0f + expf(-(giz + ghz)));
    float ng = tanhf(gin + rg * ghn);
    sn[j] = (1.0f - zg) * ng + zg * slots[(size_t)r * Dn + c];
  }
  float s = sn[0] + sn[1], q = sn[0] * sn[0] + sn[1] * sn[1];
  s = wred(s); q = wred(q);
  if ((t & 63) == 0) { red[t >> 6] = s; red[4 + (t >> 6)] = q; }
  __syncthreads();
  float S = red[0] + red[1] + red[2] + red[3];
  float Q = red[4] + red[5] + red[6] + red[7];
  float m = S * (1.0f / 512.0f);
  float rs = 1.0f / sqrtf(Q * (1.0f / 512.0f) - m * m + 1e-5f);
#pragma unroll
  for (int j = 0; j < 2; ++j) {
    int c = j * 256 + t;
    slots[(size_t)r * Dn + c] = sn[j];
    slnff[(size_t)r * Dn + c] = (sn[j] - m) * rs * lnffw[c] + lnffb[c];
  }
}

// ---------------- keep gate + per-slot route scalars (merged) ----------------
__global__ void k_keepsc(const float* __restrict__ Wkeep, const float* __restrict__ gk,
                         float* __restrict__ slots, const float* __restrict__ lnw,
                         const float* __restrict__ lnb, double* __restrict__ swd,
                         double* __restrict__ sbd) {
  int g = blockIdx.x;
  int lane = threadIdx.x;
  float4* sp = reinterpret_cast<float4*>(slots + (size_t)g * Dn) + lane * 2;
  float4 s0 = sp[0], s1 = sp[1];
  float sv[8] = {s0.x, s0.y, s0.z, s0.w, s1.x, s1.y, s1.z, s1.w};
  double d0 = 0.0, d1 = 0.0;
#pragma unroll
  for (int e = 0; e < 8; ++e) {
    int d = lane * 8 + e;
    d0 += (double)sv[e] * (double)Wkeep[d * 2];
    d1 += (double)sv[e] * (double)Wkeep[d * 2 + 1];
  }
  d0 = wredd(d0);
  d1 = wredd(d1);
  int keepi = 0;
  if (lane == 0) keepi = ((d1 + (double)gk[g * 2 + 1]) > (d0 + (double)gk[g * 2])) ? 1 : 0;
  keepi = __shfl(keepi, 0);
  if (!keepi) {
    float4 z = {0.0f, 0.0f, 0.0f, 0.0f};
    sp[0] = z;
    sp[1] = z;
#pragma unroll
    for (int e = 0; e < 8; ++e) sv[e] = 0.0f;
  }
  const float4* wp = reinterpret_cast<const float4*>(lnw) + lane * 2;
  const float4* bp = reinterpret_cast<const float4*>(lnb) + lane * 2;
  float4 w0 = wp[0], w1 = wp[1], b0 = bp[0], b1 = bp[1];
  float wv8[8] = {w0.x, w0.y, w0.z, w0.w, w1.x, w1.y, w1.z, w1.w};
  float bv8[8] = {b0.x, b0.y, b0.z, b0.w, b1.x, b1.y, b1.z, b1.w};
  double pw = 0.0, pb = 0.0;
#pragma unroll
  for (int e = 0; e < 8; ++e) {
    pw += (double)sv[e] * (double)wv8[e];
    pb += (double)sv[e] * (double)bv8[e];
  }
  pw = wredd(pw);
  pb = wredd(pb);
  if (lane == 0) { swd[g] = pw; sbd[g] = pb; }
}

// ---------------- hard route + gather output (tiled mini-GEMM, prefetched) ----------------
__global__ __launch_bounds__(256) void k_route_out(const float* __restrict__ in, const float* __restrict__ slots,
                                                   const float* __restrict__ lnw, const double* __restrict__ swd,
                                                   const double* __restrict__ sbd, const float* __restrict__ mu,
                                                   const float* __restrict__ rsig,
                                                   const float* __restrict__ g_route, float* __restrict__ out) {
  int b = blockIdx.y, j0 = blockIdx.x * 128;
  __shared__ __align__(16) float sl[16 * 516];
  __shared__ __align__(16) float lw[512];
  __shared__ __align__(16) float xs[16][132];
  __shared__ double lgd[128][17];
  __shared__ int besti[128];
  int t = threadIdx.x, tx = t & 15, ty = t >> 4;

  for (int idx = t; idx < 2048; idx += 256) {
    int i = idx >> 7, c = idx & 127;
    *reinterpret_cast<float4*>(&sl[i * 516 + c * 4]) =
        *reinterpret_cast<const float4*>(&slots[(size_t)(b * NSn + i) * Dn + c * 4]);
  }
  if (t < 128)
    *reinterpret_cast<float4*>(&lw[t * 4]) = *reinterpret_cast<const float4*>(&lnw[t * 4]);

  float acc[8] = {};
  double accd[8] = {};
  const size_t inbase = ((size_t)b * Nn + j0) * Dn;

  float pre[8];
#pragma unroll
  for (int e = 0; e < 8; ++e) {
    int idx = t + e * 256;
    int r = idx >> 4, c = idx & 15;
    pre[e] = in[inbase + (size_t)r * Dn + c];
  }
  __syncthreads();

  for (int k0 = 0; k0 < Dn; k0 += 16) {
#pragma unroll
    for (int e = 0; e < 8; ++e) {
      int idx = t + e * 256;
      int r = idx >> 4, c = idx & 15;
      xs[c][r] = pre[e] * lw[k0 + c];
    }
    __syncthreads();
    float nxt[8] = {};
    if (k0 + 16 < Dn) {
#pragma unroll
      for (int e = 0; e < 8; ++e) {
        int idx = t + e * 256;
        int r = idx >> 4, c = idx & 15;
        nxt[e] = in[inbase + (size_t)r * Dn + k0 + 16 + c];
      }
    }
#pragma unroll
    for (int kc = 0; kc < 16; ++kc) {
      float sv = sl[tx * 516 + k0 + kc];
      float4 x0 = *reinterpret_cast<const float4*>(&xs[kc][ty * 8]);
      float4 x1 = *reinterpret_cast<const float4*>(&xs[kc][ty * 8 + 4]);
      acc[0] += x0.x * sv; acc[1] += x0.y * sv; acc[2] += x0.z * sv; acc[3] += x0.w * sv;
      acc[4] += x1.x * sv; acc[5] += x1.y * sv; acc[6] += x1.z * sv; acc[7] += x1.w * sv;
    }
    if ((k0 & 127) == 112) {
#pragma unroll
      for (int e = 0; e < 8; ++e) { accd[e] += (double)acc[e]; acc[e] = 0.0f; }
    }
#pragma unroll
    for (int e = 0; e < 8; ++e) pre[e] = nxt[e];
    __syncthreads();
  }

  double sw_i = swd[b * NSn + tx], sb_i = sbd[b * NSn + tx];
#pragma unroll
  for (int r = 0; r < 8; ++r) {
    int j = ty * 8 + r;
    double rsj = (double)rsig[(size_t)b * Nn + j0 + j];
    double muj = (double)mu[(size_t)b * Nn + j0 + j];
    double g = (double)g_route[((size_t)b * NSn + tx) * Nn + j0 + j];
    lgd[j][tx] = (double)kScale * (rsj * accd[r] + sb_i - muj * rsj * sw_i) + g;
  }
  __syncthreads();
  if (t < 128) {
    double best = lgd[t][0];
    int bi = 0;
#pragma unroll
    for (int i = 1; i < 16; ++i) {
      double v = lgd[t][i];
      if (v > best) { best = v; bi = i; }
    }
    besti[t] = bi;
  }
  __syncthreads();
  for (int idx = t; idx < 128 * 128; idx += 256) {
    int j = idx >> 7, c = idx & 127;
    *reinterpret_cast<float4*>(&out[inbase + (size_t)j * Dn + c * 4]) =
        *reinterpret_cast<const float4*>(&sl[besti[j] * 516 + c * 4]);
  }
}

extern "C" void kernel_launch(void* const* d_in, const int* in_sizes, int n_in,
                              void* d_out, int out_size, void* d_ws, size_t ws_size,
                              hipStream_t stream) {
  (void)in_sizes; (void)n_in; (void)out_size; (void)ws_size;
  const float* in = (const float*)d_in[0];
  const float* slots_mu = (const float*)d_in[1];
  const float* slots_ls = (const float*)d_in[2];
  const float* ln_in_w = (const float*)d_in[3];
  const float* ln_in_b = (const float*)d_in[4];
  const float* ln_s_w = (const float*)d_in[5];
  const float* ln_s_b = (const float*)d_in[6];
  const float* ln_ff_w = (const float*)d_in[7];
  const float* ln_ff_b = (const float*)d_in[8];
  const float* Wq = (const float*)d_in[9];
  const float* bq = (const float*)d_in[10];
  const float* Wk = (const float*)d_in[11];
  const float* bk = (const float*)d_in[12];
  const float* Wv = (const float*)d_in[13];
  const float* bv = (const float*)d_in[14];
  const float* Wc = (const float*)d_in[15];
  const float* bc = (const float*)d_in[16];
  const float* Wih = (const float*)d_in[17];
  const float* bih = (const float*)d_in[18];
  const float* Whh = (const float*)d_in[19];
  const float* bhh = (const float*)d_in[20];
  const float* W1 = (const float*)d_in[21];
  const float* b1 = (const float*)d_in[22];
  const float* W2 = (const float*)d_in[23];
  const float* b2 = (const float*)d_in[24];
  const float* Wkeep = (const float*)d_in[25];
  const float* noise = (const float*)d_in[26];
  const float* g_keep = (const float*)d_in[27];
  const float* g_route = (const float*)d_in[28];
  float* out = (float*)d_out;
  unsigned* inTu = (unsigned*)d_out;   // scratch during iterations; overwritten by k_route_out

  char* wptr = (char*)d_ws;
  auto alloc = [&](size_t bytes) {
    char* p = wptr;
    wptr += (bytes + 255) & ~(size_t)255;
    return p;
  };
  float* mu = (float*)alloc((size_t)Bn * Nn * 4);
  float* rsig = (float*)alloc((size_t)Bn * Nn * 4);
  float* slots = (float*)alloc((size_t)Bn * NSn * Dn * 4);
  float* sln = (float*)alloc((size_t)Bn * NSn * Dn * 4);
  unsigned* qkt = (unsigned*)alloc((size_t)Bn * HIn * Dn * 4);
  float* alpha = (float*)alloc((size_t)Bn * HIn * 4);
  float* beta = (float*)alloc((size_t)Bn * HIn * 4);
  unsigned* Abuf = (unsigned*)alloc((size_t)Bn * HIn * Nn * 4);
  unsigned* Xp = (unsigned*)alloc((size_t)Bn * Nn * Dn * 4);
  float* Spart = (float*)alloc((size_t)Bn * 32 * HIn * 4);
  float* c1part = (float*)alloc((size_t)Bn * 32 * HIn * 4);
  float* AXp = (float*)alloc((size_t)2 * Bn * HIn * Dn * 4);
  float* updb = (float*)alloc((size_t)Bn * NSn * Dn * 4);
  float* gibuf = (float*)alloc((size_t)Bn * NSn * 1536 * 4);
  float* ghbuf = (float*)alloc((size_t)Bn * NSn * 1536 * 4);
  float* hbuf = (float*)alloc((size_t)Bn * NSn * 2048 * 4);
  float* ffp = (float*)alloc((size_t)4 * 512 * 512 * 4);
  float* T1 = (float*)alloc((size_t)Dn * 1536 * 4);
  float* WhhT = (float*)alloc((size_t)Dn * 1536 * 4);
  float* bcih = (float*)alloc((size_t)1536 * 4);
  float* Ms = (float*)alloc((size_t)Dn * 4096 * 4);
  float* vb_raw = (float*)alloc((size_t)4096 * 4);
  float* vb_s = (float*)alloc((size_t)4096 * 4);
  float* avec = (float*)alloc((size_t)4096 * 4);
  float* bvec = (float*)alloc((size_t)4096 * 4);
  float* aconst = (float*)alloc((size_t)8 * 4);
  float* bconst = (float*)alloc((size_t)8 * 4);
  double* swd = (double*)alloc((size_t)Bn * NSn * 8);
  double* sbd = (double*)alloc((size_t)Bn * NSn * 8);

  // prologue
  k_rowstats<<<Bn * Nn / 4, 256, 0, stream>>>(in, mu, rsig);
  k_tsplit<<<dim3(Nn / 64, Dn / 64, Bn), 256, 0, stream>>>(in, inTu, Xp);
  k_slots_init<<<Bn * NSn, 256, 0, stream>>>(slots_mu, slots_ls, noise, slots);
  k_gemm_sm<true, false, false><<<dim3(24, 8), 256, 0, stream>>>(Wc, Wih, nullptr, T1, 1536, 512);
  k_transp<<<dim3(512 / 64, 1536 / 64), 256, 0, stream>>>(Whh, WhhT, 1536, 512);
  k_bcih<<<6, 256, 0, stream>>>(bc, Wih, bih, bcih);
  k_mh<<<dim3(8, 8, 8), 256, 0, stream>>>(Wq, Wk, Ms);
  k_vbias<<<2, 256, 0, stream>>>(Wk, bq, ln_in_w, vb_raw, vb_s);
  k_mfold<<<16, 256, 0, stream>>>(Ms, Wq, bk, ln_in_w, ln_in_b, avec, bvec);
  k_consts<<<1, 256, 0, stream>>>(vb_raw, bq, bk, ln_in_w, ln_in_b, aconst, bconst);
  k_ln_rows<<<Bn * NSn, 256, 0, stream>>>(slots, ln_s_w, ln_s_b, sln);

  for (int it = 0; it < 3; ++it) {
    k_qum<<<dim3(64, 8), 256, 0, stream>>>(sln, Ms, vb_s, qkt);
    k_ab<<<Bn * HIn, 64, 0, stream>>>(sln, avec, bvec, aconst, bconst, alpha, beta);
    k_dots<<<dim3(Nn / 128, Bn), 256, 0, stream>>>(Xp, qkt, alpha, beta, mu, rsig, Abuf, Spart, c1part);
    k_ax<<<dim3(4, 2, Bn), 256, 0, stream>>>(Abuf, inTu, AXp);
    k_updS<<<dim3(HIn, Bn), 256, 0, stream>>>(AXp, Spart, c1part, ln_in_w, ln_in_b, Wv, bv, updb);
    k_mm<false, false><<<dim3(24, 8, 1), 256, 0, stream>>>(updb, 512, T1, 1536, bcih, gibuf, 1536, 512);
    k_mm<false, false><<<dim3(24, 8, 1), 256, 0, stream>>>(slots, 512, WhhT, 1536, bhh, ghbuf, 1536, 512);
    k_gruln<<<Bn * NSn, 256, 0, stream>>>(gibuf, ghbuf, slots, sln, ln_ff_w, ln_ff_b);
    k_mm<true, false><<<dim3(32, 8, 1), 256, 0, stream>>>(sln, 512, W1, 2048, b1, hbuf, 2048, 512);
    k_mm<false, true><<<dim3(8, 8, 4), 256, 0, stream>>>(hbuf, 2048, W2, 512, nullptr, ffp, 512, 512);
    k_w2ln<<<Bn * NSn, 256, 0, stream>>>(ffp, b2, slots, sln, ln_s_w, ln_s_b);
  }

  k_keepsc<<<Bn * NSn, 64, 0, stream>>>(Wkeep, g_keep, slots, ln_in_w, ln_in_b, swd, sbd);
  k_route_out<<<dim3(Nn / 128, Bn), 256, 0, stream>>>(in, slots, ln_in_w, swd, sbd, mu, rsig, g_route, out);
}